// Round 2
// baseline (5998.303 us; speedup 1.0000x reference)
//
#include <hip/hip_runtime.h>
#include <hip/hip_bf16.h>
#include <cstdint>
#include <cstddef>

#define LSEQ   8192
#define DMODEL 2048
#define NH     16      // heads == groups
#define HD     128     // head dim == hidden dim
#define CH     2048    // chunk length (group-space positions)

// ---------------------------------------------------------------- helpers

__device__ __forceinline__ float wave_sum64(float v) {
#pragma unroll
  for (int m = 32; m; m >>= 1) v += __shfl_xor(v, m, 64);
  return v;
}

__device__ __forceinline__ float sigm(float x) { return 1.0f / (1.0f + expf(-x)); }

// 8x8 microtile inner product over a 32-deep LDS K-slice.
__device__ __forceinline__ void mm8x8(const float (*__restrict__ As)[132],
                                      const float (*__restrict__ Bs)[132],
                                      int ty, int tx, float acc[8][8]) {
#pragma unroll
  for (int k2 = 0; k2 < 32; ++k2) {
    float a[8], b[8];
#pragma unroll
    for (int i = 0; i < 8; ++i) a[i] = As[k2][ty * 8 + i];
#pragma unroll
    for (int j = 0; j < 8; ++j) b[j] = Bs[k2][tx * 8 + j];
#pragma unroll
    for (int i = 0; i < 8; ++i)
#pragma unroll
      for (int j = 0; j < 8; ++j) acc[i][j] = fmaf(a[i], b[j], acc[i][j]);
  }
}

// ---------------------------------------------------------------- init w + row norms

// grid: 3*NH*HD blocks of 64. rid = m*2048 + g*128 + r
__global__ void k_init_w(const float* __restrict__ w0, const float* __restrict__ w1,
                         const float* __restrict__ w2, float* __restrict__ WW,
                         float* __restrict__ WN0) {
  int rid = blockIdx.x;
  int m = rid >> 11;
  int gr = rid & 2047;
  const float* src = (m == 0) ? w0 : (m == 1) ? w1 : w2;
  const float* row = src + (size_t)gr * HD;
  float* drow = WW + ((size_t)m * 2048 + gr) * HD;
  int l = threadIdx.x;
  float v0 = row[l], v1 = row[l + 64];
  drow[l] = v0; drow[l + 64] = v1;
  float s = wave_sum64(v0 * v0 + v1 * v1);
  if (l == 0) WN0[rid] = sqrtf(s);
}

// ---------------------------------------------------------------- qkv projection

// grid (64, 48), block 256.  C tile: 128 tokens x 128 cols. silu + scatter to group layout.
__global__ __launch_bounds__(256) void k_qkv(const float* __restrict__ x,
                                             const float* __restrict__ Wq,
                                             float* __restrict__ Q, float* __restrict__ Km,
                                             float* __restrict__ V) {
  __shared__ float As[32][132];
  __shared__ float Bs[32][132];
  const int t0 = blockIdx.x * 128;
  const int ct = blockIdx.y;
  const int col0 = ct * 128;
  const int tid = threadIdx.x;
  const int ty = tid >> 4, tx = tid & 15;
  const int kk = tid & 31, sub = tid >> 5;
  float acc[8][8];
#pragma unroll
  for (int i = 0; i < 8; ++i)
#pragma unroll
    for (int j = 0; j < 8; ++j) acc[i][j] = 0.0f;

  for (int ks = 0; ks < DMODEL; ks += 32) {
#pragma unroll
    for (int r = 0; r < 16; ++r) {
      int t = sub + r * 8;
      As[kk][t] = x[(size_t)(t0 + t) * DMODEL + ks + kk];
    }
#pragma unroll
    for (int r = 0; r < 16; ++r) {
      int idx = tid + r * 256;
      int k2 = idx >> 7, c = idx & 127;
      Bs[k2][c] = Wq[(size_t)(ks + k2) * (3 * DMODEL) + col0 + c];
    }
    __syncthreads();
    mm8x8(As, Bs, ty, tx, acc);
    __syncthreads();
  }
  const int hh = ct / 3, which = ct % 3;
  float* dst = (which == 0) ? Q : (which == 1) ? Km : V;
#pragma unroll
  for (int i = 0; i < 8; ++i) {
    int t = t0 + ty * 8 + i;
    int fth = t * NH + hh;
    int g = fth >> 13, tp = fth & 8191;
    float* drow = dst + ((size_t)g * LSEQ + tp) * HD;
#pragma unroll
    for (int j = 0; j < 8; ++j) {
      float v = acc[i][j];
      drow[tx * 8 + j] = v * sigm(v);
    }
  }
}

// normalize Q and K rows in place. grid = 2*NH*LSEQ/4 blocks of 256 (4 waves -> 4 rows)
__global__ void k_l2norm(float* __restrict__ Q, float* __restrict__ Km) {
  int rid = blockIdx.x * 4 + (threadIdx.x >> 6);
  int l = threadIdx.x & 63;
  float* base = (rid < NH * LSEQ) ? Q : Km;
  int r = (rid < NH * LSEQ) ? rid : rid - NH * LSEQ;
  float* row = base + (size_t)r * HD;
  float v0 = row[l], v1 = row[l + 64];
  float s = wave_sum64(v0 * v0 + v1 * v1);
  float f = 1.0f / (sqrtf(s) + 1e-5f);
  row[l] = v0 * f;
  row[l + 64] = v1 * f;
}

// ---------------------------------------------------------------- lr / momentum / scale

// grid 8192 (token), block 128. threads 0..79 each compute one projection column.
__global__ __launch_bounds__(128) void k_lrms(const float* __restrict__ x,
                                              const float* __restrict__ Wlr,
                                              const float* __restrict__ Wm, const float* __restrict__ bm,
                                              const float* __restrict__ Wsc, const float* __restrict__ bs,
                                              float* __restrict__ LR, float* __restrict__ MOM,
                                              float* __restrict__ SCL) {
  __shared__ float xs[DMODEL];
  const int t = blockIdx.x;
  const int tid = threadIdx.x;
  for (int i = tid; i < DMODEL; i += 128) xs[i] = x[(size_t)t * DMODEL + i];
  __syncthreads();
  const int c = tid;
  if (c >= 80) return;
  const float* Wcol;
  int stride;
  float bias = 0.0f;
  if (c < 48) { Wcol = Wlr + c; stride = 48; }
  else if (c < 64) { Wcol = Wm + (c - 48); stride = 16; bias = bm[c - 48]; }
  else { Wcol = Wsc + (c - 64); stride = 16; bias = bs[c - 64]; }
  float s0 = 0, s1 = 0, s2 = 0, s3 = 0;
  for (int k = 0; k < DMODEL; k += 4) {
    s0 = fmaf(xs[k], Wcol[(size_t)k * stride], s0);
    s1 = fmaf(xs[k + 1], Wcol[(size_t)(k + 1) * stride], s1);
    s2 = fmaf(xs[k + 2], Wcol[(size_t)(k + 2) * stride], s2);
    s3 = fmaf(xs[k + 3], Wcol[(size_t)(k + 3) * stride], s3);
  }
  float dot = (s0 + s1) + (s2 + s3);
  if (c < 48) {
    float base_lr_inv = 0.01f + logf(-expm1f(-0.01f));
    float v = dot + base_lr_inv;
    float sp = fmaxf(v, 0.0f) + log1pf(expf(-fabsf(v)));
    int j = c >> 4, hh = c & 15;
    LR[((size_t)(j * NH + hh)) * LSEQ + t] = sp;
  } else if (c < 64) {
    MOM[(size_t)(c - 48) * LSEQ + t] = sigm(dot + bias);
  } else {
    float v = dot + bias;
    SCL[(size_t)(c - 64) * LSEQ + t] = v * sigm(v);
  }
}

// ---------------------------------------------------------------- per-chunk output (+ fused LN/scale)

// grid (CH/64, NH), block 256. Computes o = w1 @ (silu(w0@Q^T) * (w2@Q^T)) for a
// 64-token tile, then LayerNorm over d=128 + scale, writes U[t][g*128+d].
__global__ __launch_bounds__(256) void k_out(const float* __restrict__ WW,
                                             const float* __restrict__ Q,
                                             const float* __restrict__ SCL,
                                             const float* __restrict__ lng,
                                             const float* __restrict__ lnb,
                                             float* __restrict__ U, int s) {
  __shared__ float A0s[32][132];
  __shared__ float A1s[32][132];
  __shared__ float Bs[32][132];
  __shared__ float gh[128][68];
  const int tt0 = blockIdx.x * 64;
  const int g = blockIdx.y;
  const int tid = threadIdx.x;
  const int ty = tid >> 4, tx = tid & 15;
  const int kk = tid & 31, sub = tid >> 5;
  const float* w0g = WW + ((size_t)0 * 2048 + g * 128) * 128;
  const float* w1g = WW + ((size_t)1 * 2048 + g * 128) * 128;
  const float* w2g = WW + ((size_t)2 * 2048 + g * 128) * 128;

  float acc1[8][4], acc2[8][4];
#pragma unroll
  for (int i = 0; i < 8; ++i)
#pragma unroll
    for (int j = 0; j < 4; ++j) { acc1[i][j] = 0.0f; acc2[i][j] = 0.0f; }

  for (int ks = 0; ks < 128; ks += 32) {
#pragma unroll
    for (int r = 0; r < 16; ++r) {
      int e = sub + r * 8;
      A0s[kk][e] = w0g[(size_t)e * 128 + ks + kk];
      A1s[kk][e] = w2g[(size_t)e * 128 + ks + kk];
    }
#pragma unroll
    for (int r = 0; r < 8; ++r) {
      int tc = sub + r * 8;
      Bs[kk][tc] = Q[((size_t)g * LSEQ + s + tt0 + tc) * HD + ks + kk];
    }
    __syncthreads();
#pragma unroll
    for (int k2 = 0; k2 < 32; ++k2) {
      float a0[8], a1[8], b[4];
#pragma unroll
      for (int i = 0; i < 8; ++i) { a0[i] = A0s[k2][ty * 8 + i]; a1[i] = A1s[k2][ty * 8 + i]; }
#pragma unroll
      for (int j = 0; j < 4; ++j) b[j] = Bs[k2][tx * 4 + j];
#pragma unroll
      for (int i = 0; i < 8; ++i)
#pragma unroll
        for (int j = 0; j < 4; ++j) {
          acc1[i][j] = fmaf(a0[i], b[j], acc1[i][j]);
          acc2[i][j] = fmaf(a1[i], b[j], acc2[i][j]);
        }
    }
    __syncthreads();
  }
  // gh = silu(gate) * hidden
#pragma unroll
  for (int i = 0; i < 8; ++i)
#pragma unroll
    for (int j = 0; j < 4; ++j) {
      float gv = acc1[i][j];
      gh[ty * 8 + i][tx * 4 + j] = gv * sigm(gv) * acc2[i][j];
    }
  __syncthreads();

  float acco[8][4];
#pragma unroll
  for (int i = 0; i < 8; ++i)
#pragma unroll
    for (int j = 0; j < 4; ++j) acco[i][j] = 0.0f;

  for (int es = 0; es < 128; es += 32) {
#pragma unroll
    for (int r = 0; r < 16; ++r) {
      int d = sub + r * 8;
      A0s[kk][d] = w1g[(size_t)d * 128 + es + kk];
    }
    __syncthreads();
#pragma unroll
    for (int k2 = 0; k2 < 32; ++k2) {
      float a[8], b[4];
#pragma unroll
      for (int i = 0; i < 8; ++i) a[i] = A0s[k2][ty * 8 + i];
#pragma unroll
      for (int j = 0; j < 4; ++j) b[j] = gh[es + k2][tx * 4 + j];
#pragma unroll
      for (int i = 0; i < 8; ++i)
#pragma unroll
        for (int j = 0; j < 4; ++j) acco[i][j] = fmaf(a[i], b[j], acco[i][j]);
    }
    __syncthreads();
  }
  // stash o into gh, then LN + scale per token
#pragma unroll
  for (int i = 0; i < 8; ++i)
#pragma unroll
    for (int j = 0; j < 4; ++j) gh[ty * 8 + i][tx * 4 + j] = acco[i][j];
  __syncthreads();

  const int tok = tid >> 2;     // 0..63
  const int part = tid & 3;     // 0..3 -> d range [part*32, part*32+32)
  float sum = 0.0f;
#pragma unroll
  for (int dd = 0; dd < 32; ++dd) sum += gh[part * 32 + dd][tok];
  sum += __shfl_xor(sum, 1, 64);
  sum += __shfl_xor(sum, 2, 64);
  float mu = sum * (1.0f / 128.0f);
  float vs = 0.0f;
#pragma unroll
  for (int dd = 0; dd < 32; ++dd) {
    float dv = gh[part * 32 + dd][tok] - mu;
    vs = fmaf(dv, dv, vs);
  }
  vs += __shfl_xor(vs, 1, 64);
  vs += __shfl_xor(vs, 2, 64);
  float rstd = rsqrtf(vs * (1.0f / 128.0f) + 1e-6f);
  int tabs = s + tt0 + tok;
  float sc = SCL[(size_t)g * LSEQ + tabs];
  float* urow = U + (size_t)tabs * DMODEL + g * HD + part * 32;
#pragma unroll
  for (int dd = 0; dd < 32; ++dd) {
    int d = part * 32 + dd;
    float o = (gh[d][tok] - mu) * rstd * lng[d] + lnb[d];
    urow[dd] = o * sc;
  }
}

// ---------------------------------------------------------------- chunk backward front GEMMs

// grid (16, NH, 3).  z=0: Gb=w0@K^T  z=1: Hb=w2@K^T  z=2: Dh=w1^T@V^T
__global__ __launch_bounds__(256) void k_front(const float* __restrict__ WW,
                                               const float* __restrict__ Km,
                                               const float* __restrict__ V,
                                               float* __restrict__ BUF, int s) {
  __shared__ float As[32][132];
  __shared__ float Bs[32][132];
  const int tt0 = blockIdx.x * 128;
  const int g = blockIdx.y;
  const int z = blockIdx.z;
  const int tid = threadIdx.x;
  const int ty = tid >> 4, tx = tid & 15;
  const int kk = tid & 31, sub = tid >> 5;
  const int wsel = (z == 0) ? 0 : (z == 1) ? 2 : 1;
  const float* wg = WW + ((size_t)wsel * 2048 + g * 128) * 128;
  const float* X = (z == 2) ? V : Km;
  float* out = BUF + (size_t)z * (NH * 128 * CH) + (size_t)g * 128 * CH;

  float acc[8][8];
#pragma unroll
  for (int i = 0; i < 8; ++i)
#pragma unroll
    for (int j = 0; j < 8; ++j) acc[i][j] = 0.0f;

  for (int ks = 0; ks < 128; ks += 32) {
    if (z != 2) {
#pragma unroll
      for (int r = 0; r < 16; ++r) {
        int e = sub + r * 8;
        As[kk][e] = wg[(size_t)e * 128 + ks + kk];
      }
    } else {
#pragma unroll
      for (int r = 0; r < 16; ++r) {
        int idx = tid + r * 256;
        int k2 = idx >> 7, e = idx & 127;
        As[k2][e] = wg[(size_t)(ks + k2) * 128 + e];
      }
    }
#pragma unroll
    for (int r = 0; r < 16; ++r) {
      int t = sub + r * 8;
      Bs[kk][t] = X[((size_t)g * LSEQ + s + tt0 + t) * HD + ks + kk];
    }
    __syncthreads();
    mm8x8(As, Bs, ty, tx, acc);
    __syncthreads();
  }
#pragma unroll
  for (int i = 0; i < 8; ++i)
#pragma unroll
    for (int j = 0; j < 8; ++j)
      out[(size_t)(ty * 8 + i) * CH + tt0 + tx * 8 + j] = acc[i][j];
}

// elementwise: (Gb,Hb,Dh) -> (hid, dgate_before, dhidden_before) in place
__global__ void k_elem(float* __restrict__ BA, float* __restrict__ BB, float* __restrict__ BC) {
  size_t i = ((size_t)blockIdx.x * 256 + threadIdx.x) * 4;
  float4 a = *(const float4*)(BA + i);
  float4 b = *(const float4*)(BB + i);
  float4 c = *(const float4*)(BC + i);
  float4 ha, hb2, hc;
  float* pa = (float*)&a; float* pb = (float*)&b; float* pc = (float*)&c;
  float* oa = (float*)&ha; float* ob = (float*)&hb2; float* oc = (float*)&hc;
#pragma unroll
  for (int k = 0; k < 4; ++k) {
    float gb = pa[k], hb = pb[k], dh = pc[k];
    float sg = sigm(gb);
    float sgb = gb * sg;
    float hid = sgb * hb;
    float dgate = dh * hb;
    float dgb = dgate * sg * (1.0f + gb * (1.0f - sg));
    float dhb = dh * sgb;
    oa[k] = hid; ob[k] = dgb; oc[k] = dhb;
  }
  *(float4*)(BA + i) = ha;
  *(float4*)(BB + i) = hb2;
  *(float4*)(BC + i) = hc;
}

// per-head mean of momentum over chunk
__global__ void k_mom_mean(const float* __restrict__ MOM, float* __restrict__ MI, int s) {
  __shared__ float red[4];
  int g = blockIdx.x;
  int tid = threadIdx.x;
  float sum = 0.0f;
  for (int i = tid; i < CH; i += 256) sum += MOM[(size_t)g * LSEQ + s + i];
  sum = wave_sum64(sum);
  if ((tid & 63) == 0) red[tid >> 6] = sum;
  __syncthreads();
  if (tid == 0) MI[g] = (red[0] + red[1] + red[2] + red[3]) * (1.0f / (float)CH);
}

// partial dW GEMMs over 1024-token halves.
// z=0: dw0 = dgb @ (K*lr0);  z=1: dw1(partial, transposed) = hid @ (V*lr1);  z=2: dw2 = dhb @ (K*lr2)
__global__ __launch_bounds__(256) void k_dwp(const float* __restrict__ BUF,
                                             const float* __restrict__ Km,
                                             const float* __restrict__ V,
                                             const float* __restrict__ LR,
                                             float* __restrict__ DWP, int s) {
  __shared__ float As[32][132];
  __shared__ float Bs[32][132];
  const int p = blockIdx.x;     // 2 token halves of 1024
  const int g = blockIdx.y;
  const int z = blockIdx.z;
  const int tid = threadIdx.x;
  const int ty = tid >> 4, tx = tid & 15;
  const int kk = tid & 31, sub = tid >> 5;
  const int msel = (z == 0) ? 1 : (z == 1) ? 0 : 2;  // bufB=dgb, bufA=hid, bufC=dhb
  const float* M = BUF + (size_t)msel * (NH * 128 * CH) + (size_t)g * 128 * CH;
  const float* N = (z == 1) ? V : Km;
  const float* lr = LR + (size_t)(z * NH + g) * LSEQ;
  const int ts = p * 1024;

  float acc[8][8];
#pragma unroll
  for (int i = 0; i < 8; ++i)
#pragma unroll
    for (int j = 0; j < 8; ++j) acc[i][j] = 0.0f;

  for (int ks = 0; ks < 1024; ks += 32) {
#pragma unroll
    for (int r = 0; r < 16; ++r) {
      int o1 = sub + r * 8;
      As[kk][o1] = M[(size_t)o1 * CH + ts + ks + kk];
    }
#pragma unroll
    for (int r = 0; r < 16; ++r) {
      int idx = tid + r * 256;
      int k2 = idx >> 7, o2 = idx & 127;
      int tok = s + ts + ks + k2;
      Bs[k2][o2] = N[((size_t)g * LSEQ + tok) * HD + o2] * lr[tok];
    }
    __syncthreads();
    mm8x8(As, Bs, ty, tx, acc);
    __syncthreads();
  }
  float* outp = DWP + (((size_t)(z * NH + g)) * 2 + p) * 16384;
#pragma unroll
  for (int i = 0; i < 8; ++i)
#pragma unroll
    for (int j = 0; j < 8; ++j)
      outp[(ty * 8 + i) * 128 + tx * 8 + j] = acc[i][j];
}

// reduce partials, apply (1+m_i), transpose dw1
__global__ void k_dwred(const float* __restrict__ DWP, const float* __restrict__ MI,
                        float* __restrict__ DW) {
  int zg = blockIdx.x;
  int g = zg & 15, z = zg >> 4;
  float mi = 1.0f + MI[g];
  const float* base = DWP + (size_t)zg * 2 * 16384;
  float* out = DW + (size_t)zg * 16384;
  for (int idx = threadIdx.x; idx < 16384; idx += 256) {
    float sv = base[idx] + base[(size_t)16384 + idx];
    sv *= mi;
    int oidx = (z == 1) ? ((idx & 127) * 128 + (idx >> 7)) : idx;
    out[oidx] = sv;
  }
}

// ---------------------------------------------------------------- Newton-Schulz 5

// grid 48 (one matrix each), block 1024.  X and A resident in 128 KiB LDS.
__global__ __launch_bounds__(1024) void k_ns5(float* __restrict__ DW) {
  __shared__ float Xs[128 * 128];
  __shared__ float Aw[128 * 128];
  const float NA[5] = {4.0848f, 3.9505f, 3.7418f, 2.8769f, 2.8366f};
  const float NB[5] = {-6.8946f, -6.3029f, -5.5913f, -3.1427f, -3.0525f};
  const float NC[5] = {2.927f, 2.6377f, 2.3037f, 1.2046f, 1.2012f};
  float* Gm = DW + (size_t)blockIdx.x * 16384;
  const int tid = threadIdx.x;
  const int ty = tid >> 5, tx = tid & 31;

  float psum = 0.0f;
#pragma unroll
  for (int r = 0; r < 16; ++r) {
    int idx = tid + r * 1024;
    float v = Gm[idx];
    Xs[idx] = v;
    psum = fmaf(v, v, psum);
  }
  psum = wave_sum64(psum);
  if ((tid & 63) == 0) Aw[tid >> 6] = psum;
  __syncthreads();
  if (tid == 0) {
    float tot = 0.0f;
    for (int i = 0; i < 16; ++i) tot += Aw[i];
    Aw[0] = 1.0f / (sqrtf(tot) + 1e-7f);
  }
  __syncthreads();
  float scl = Aw[0];
#pragma unroll
  for (int r = 0; r < 16; ++r) {
    int idx = tid + r * 1024;
    Xs[idx] *= scl;
  }
  __syncthreads();

#pragma unroll 1
  for (int it = 0; it < 5; ++it) {
    float ac = NA[it], bc = NB[it], cc = NC[it];
    // Aw = X^T
#pragma unroll
    for (int ii = 0; ii < 4; ++ii)
#pragma unroll
      for (int jj = 0; jj < 4; ++jj)
        Aw[(tx * 4 + jj) * 128 + ty * 4 + ii] = Xs[(ty * 4 + ii) * 128 + tx * 4 + jj];
    __syncthreads();
    // Ar = X @ X^T
    float Ar[4][4];
#pragma unroll
    for (int ii = 0; ii < 4; ++ii)
#pragma unroll
      for (int jj = 0; jj < 4; ++jj) Ar[ii][jj] = 0.0f;
    for (int k = 0; k < 128; ++k) {
      float a[4], b[4];
#pragma unroll
      for (int ii = 0; ii < 4; ++ii) a[ii] = Xs[(ty * 4 + ii) * 128 + k];
#pragma unroll
      for (int jj = 0; jj < 4; ++jj) b[jj] = Aw[k * 128 + tx * 4 + jj];
#pragma unroll
      for (int ii = 0; ii < 4; ++ii)
#pragma unroll
        for (int jj = 0; jj < 4; ++jj) Ar[ii][jj] = fmaf(a[ii], b[jj], Ar[ii][jj]);
    }
    __syncthreads();
    // Aw = A
#pragma unroll
    for (int ii = 0; ii < 4; ++ii)
#pragma unroll
      for (int jj = 0; jj < 4; ++jj)
        Aw[(ty * 4 + ii) * 128 + tx * 4 + jj] = Ar[ii][jj];
    __syncthreads();
    // Bm = bc*A + cc*(A@A)
    float Bm[4][4];
#pragma unroll
    for (int ii = 0; ii < 4; ++ii)
#pragma unroll
      for (int jj = 0; jj < 4; ++jj) Bm[ii][jj] = 0.0f;
    for (int k = 0; k < 128; ++k) {
      float a[4], b[4];
#pragma unroll
      for (int ii = 0; ii < 4; ++ii) a[ii] = Aw[(ty * 4 + ii) * 128 + k];
#pragma unroll
      for (int jj = 0; jj < 4; ++jj) b[jj] = Aw[k * 128 + tx * 4 + jj];
#pragma unroll
      for (int ii = 0; ii < 4; ++ii)
#pragma unroll
        for (int jj = 0; jj < 4; ++jj) Bm[ii][jj] = fmaf(a[ii], b[jj], Bm[ii][jj]);
    }
#pragma unroll
    for (int ii = 0; ii < 4; ++ii)
#pragma unroll
      for (int jj = 0; jj < 4; ++jj) Bm[ii][jj] = fmaf(bc, Ar[ii][jj], cc * Bm[ii][jj]);
    __syncthreads();
    // Aw = Bm
#pragma unroll
    for (int ii = 0; ii < 4; ++ii)
#pragma unroll
      for (int jj = 0; jj < 4; ++jj)
        Aw[(ty * 4 + ii) * 128 + tx * 4 + jj] = Bm[ii][jj];
    __syncthreads();
    // Xn = ac*X + Bm@X
    float Xn[4][4];
#pragma unroll
    for (int ii = 0; ii < 4; ++ii)
#pragma unroll
      for (int jj = 0; jj < 4; ++jj)
        Xn[ii][jj] = ac * Xs[(ty * 4 + ii) * 128 + tx * 4 + jj];
    for (int k = 0; k < 128; ++k) {
      float a[4], b[4];
#pragma unroll
      for (int ii = 0; ii < 4; ++ii) a[ii] = Aw[(ty * 4 + ii) * 128 + k];
#pragma unroll
      for (int jj = 0; jj < 4; ++jj) b[jj] = Xs[k * 128 + tx * 4 + jj];
#pragma unroll
      for (int ii = 0; ii < 4; ++ii)
#pragma unroll
        for (int jj = 0; jj < 4; ++jj) Xn[ii][jj] = fmaf(a[ii], b[jj], Xn[ii][jj]);
    }
    __syncthreads();
#pragma unroll
    for (int ii = 0; ii < 4; ++ii)
#pragma unroll
      for (int jj = 0; jj < 4; ++jj)
        Xs[(ty * 4 + ii) * 128 + tx * 4 + jj] = Xn[ii][jj];
    __syncthreads();
  }
#pragma unroll
  for (int r = 0; r < 16; ++r) {
    int idx = tid + r * 1024;
    Gm[idx] = Xs[idx];
  }
}

// w += dw; renormalize rows to original norms. grid 3*NH*HD blocks of 64.
__global__ void k_apply(float* __restrict__ WW, const float* __restrict__ DW,
                        const float* __restrict__ WN0) {
  int rid = blockIdx.x;
  int l = threadIdx.x;
  float* wrow = WW + (size_t)rid * 128;
  const float* drow = DW + (size_t)rid * 128;
  float v0 = wrow[l] + drow[l];
  float v1 = wrow[l + 64] + drow[l + 64];
  float s = wave_sum64(v0 * v0 + v1 * v1);
  float f = WN0[rid] / (sqrtf(s) + 1e-5f);
  wrow[l] = v0 * f;
  wrow[l + 64] = v1 * f;
}

// ---------------------------------------------------------------- final projection

// grid (64, 16), block 256: out = U @ W_o
__global__ __launch_bounds__(256) void k_final(const float* __restrict__ U,
                                               const float* __restrict__ Wo,
                                               float* __restrict__ out) {
  __shared__ float As[32][132];
  __shared__ float Bs[32][132];
  const int t0 = blockIdx.x * 128;
  const int col0 = blockIdx.y * 128;
  const int tid = threadIdx.x;
  const int ty = tid >> 4, tx = tid & 15;
  const int kk = tid & 31, sub = tid >> 5;
  float acc[8][8];
#pragma unroll
  for (int i = 0; i < 8; ++i)
#pragma unroll
    for (int j = 0; j < 8; ++j) acc[i][j] = 0.0f;

  for (int ks = 0; ks < DMODEL; ks += 32) {
#pragma unroll
    for (int r = 0; r < 16; ++r) {
      int t = sub + r * 8;
      As[kk][t] = U[(size_t)(t0 + t) * DMODEL + ks + kk];
    }
#pragma unroll
    for (int r = 0; r < 16; ++r) {
      int idx = tid + r * 256;
      int k2 = idx >> 7, c = idx & 127;
      Bs[k2][c] = Wo[(size_t)(ks + k2) * DMODEL + col0 + c];
    }
    __syncthreads();
    mm8x8(As, Bs, ty, tx, acc);
    __syncthreads();
  }
#pragma unroll
  for (int i = 0; i < 8; ++i)
#pragma unroll
    for (int j = 0; j < 8; ++j)
      out[(size_t)(t0 + ty * 8 + i) * DMODEL + col0 + tx * 8 + j] = acc[i][j];
}

// ---------------------------------------------------------------- launch

extern "C" void kernel_launch(void* const* d_in, const int* in_sizes, int n_in,
                              void* d_out, int out_size, void* d_ws, size_t ws_size,
                              hipStream_t stream) {
  (void)in_sizes; (void)n_in; (void)out_size;
  const float* x    = (const float*)d_in[0];
  const float* Wqkv = (const float*)d_in[1];
  const float* Wlr  = (const float*)d_in[2];
  const float* Wo   = (const float*)d_in[3];
  const float* Wm   = (const float*)d_in[4];
  const float* bm   = (const float*)d_in[5];
  const float* Wsc  = (const float*)d_in[6];
  const float* bs   = (const float*)d_in[7];
  const float* lng  = (const float*)d_in[8];
  const float* lnb  = (const float*)d_in[9];
  const float* w0   = (const float*)d_in[10];
  const float* w1   = (const float*)d_in[11];
  const float* w2   = (const float*)d_in[12];

  // Q lives in d_out (exactly LSEQ*DMODEL floats); its last read (k_out, chunk 3)
  // strictly precedes k_final's write of d_out on the same stream.
  float* Q = (float*)d_out;

  float* ws = (float*)d_ws;
  size_t off = 0;
  auto alloc = [&](size_t n) { float* p = ws + off; off += n; return p; };
  float* Km  = alloc((size_t)NH * LSEQ * HD);       // 16.7M floats
  float* V   = alloc((size_t)NH * LSEQ * HD);
  float* U   = alloc((size_t)LSEQ * DMODEL);        // LN'd+scaled output, token-major
  float* LR  = alloc((size_t)3 * NH * LSEQ);
  float* MOM = alloc((size_t)NH * LSEQ);
  float* SCL = alloc((size_t)NH * LSEQ);
  float* WW  = alloc((size_t)3 * NH * HD * HD);
  float* WN0 = alloc((size_t)3 * NH * HD);
  float* BUF = alloc((size_t)3 * NH * HD * CH);     // Gb/Hb/Dh -> hid/dgb/dhb
  float* DW  = alloc((size_t)3 * NH * HD * HD);
  float* DWP = alloc((size_t)3 * NH * 2 * HD * HD);
  float* MI  = alloc((size_t)16);

  // Diagnostic guard: if workspace is too small, do nothing (d_out stays zeroed
  // -> clean absmax failure instead of an OOB memory fault).
  if (off * sizeof(float) > ws_size) return;

  k_init_w<<<3 * NH * HD, 64, 0, stream>>>(w0, w1, w2, WW, WN0);
  k_qkv<<<dim3(LSEQ / 128, 48), 256, 0, stream>>>(x, Wqkv, Q, Km, V);
  k_l2norm<<<2 * NH * LSEQ / 4, 256, 0, stream>>>(Q, Km);
  k_lrms<<<LSEQ, 128, 0, stream>>>(x, Wlr, Wm, bm, Wsc, bs, LR, MOM, SCL);

  for (int c = 0; c < 4; ++c) {
    int s = c * CH;
    k_out<<<dim3(CH / 64, NH), 256, 0, stream>>>(WW, Q, SCL, lng, lnb, U, s);
    if (c < 3) {
      k_front<<<dim3(CH / 128, NH, 3), 256, 0, stream>>>(WW, Km, V, BUF, s);
      k_elem<<<(NH * HD * CH) / (256 * 4), 256, 0, stream>>>(
          BUF, BUF + (size_t)NH * HD * CH, BUF + (size_t)2 * NH * HD * CH);
      k_mom_mean<<<NH, 256, 0, stream>>>(MOM, MI, s);
      k_dwp<<<dim3(2, NH, 3), 256, 0, stream>>>(BUF, Km, V, LR, DWP, s);
      k_dwred<<<3 * NH, 256, 0, stream>>>(DWP, MI, DW);
      k_ns5<<<3 * NH, 1024, 0, stream>>>(DW);
      k_apply<<<3 * NH * HD, 64, 0, stream>>>(WW, DW, WN0);
    }
  }
  k_final<<<dim3(LSEQ / 128, DMODEL / 128), 256, 0, stream>>>(U, Wo, (float*)d_out);
}

// Round 3
// 2280.309 us; speedup vs baseline: 2.6305x; 2.6305x over previous
//
#include <hip/hip_runtime.h>
#include <hip/hip_bf16.h>
#include <cstdint>
#include <cstddef>

#define LSEQ   8192
#define DMODEL 2048
#define NH     16      // heads == groups
#define HD     128     // head dim == hidden dim
#define CH     2048    // chunk length (group-space positions)

typedef __attribute__((ext_vector_type(8))) __bf16 bf16x8;
typedef __attribute__((ext_vector_type(4))) float f32x4;

// ---------------------------------------------------------------- helpers

__device__ __forceinline__ float wave_sum64(float v) {
#pragma unroll
  for (int m = 32; m; m >>= 1) v += __shfl_xor(v, m, 64);
  return v;
}

__device__ __forceinline__ float sigm(float x) { return 1.0f / (1.0f + expf(-x)); }

// RTNE float -> bf16 bits
__device__ __forceinline__ unsigned short f2bf(float f) {
  unsigned int u = __float_as_uint(f);
  u += 0x7FFFu + ((u >> 16) & 1u);
  return (unsigned short)(u >> 16);
}

// async global->LDS, 16B per lane. lds dest is wave-uniform base; HW adds lane*16.
__device__ __forceinline__ void gload_lds16(const void* g, void* l) {
  __builtin_amdgcn_global_load_lds((__attribute__((address_space(1))) void*)(g),
                                   (__attribute__((address_space(3))) void*)(l), 16, 0, 0);
}

// 8x8 microtile inner product over a 32-deep LDS K-slice (fp32 path).
__device__ __forceinline__ void mm8x8(const float (*__restrict__ As)[132],
                                      const float (*__restrict__ Bs)[132],
                                      int ty, int tx, float acc[8][8]) {
#pragma unroll
  for (int k2 = 0; k2 < 32; ++k2) {
    float a[8], b[8];
#pragma unroll
    for (int i = 0; i < 8; ++i) a[i] = As[k2][ty * 8 + i];
#pragma unroll
    for (int j = 0; j < 8; ++j) b[j] = Bs[k2][tx * 8 + j];
#pragma unroll
    for (int i = 0; i < 8; ++i)
#pragma unroll
      for (int j = 0; j < 8; ++j) acc[i][j] = fmaf(a[i], b[j], acc[i][j]);
  }
}

// ---------------------------------------------------------------- casts

// float -> bf16, vectorized. n4 = count of float4s.
__global__ void k_cast(const float* __restrict__ X, unsigned short* __restrict__ Xb, int n4) {
  int i = blockIdx.x * 256 + threadIdx.x;
  int stride = gridDim.x * 256;
  for (; i < n4; i += stride) {
    float4 v = ((const float4*)X)[i];
    ushort4 o;
    o.x = f2bf(v.x); o.y = f2bf(v.y); o.z = f2bf(v.z); o.w = f2bf(v.w);
    ((ushort4*)Xb)[i] = o;
  }
}

// W (K x N, fp32) -> Wt (N x K, bf16). grid (N/64, K/64), block 256.
__global__ void k_tcast(const float* __restrict__ W, unsigned short* __restrict__ Wt,
                        int K, int N) {
  __shared__ float t[64][65];
  const int n0 = blockIdx.x * 64, k0 = blockIdx.y * 64;
  const int tid = threadIdx.x;
  const int cx = tid & 63, ry = tid >> 6;
#pragma unroll
  for (int r = 0; r < 16; ++r) {
    int row = ry + r * 4;
    t[row][cx] = W[(size_t)(k0 + row) * N + n0 + cx];
  }
  __syncthreads();
#pragma unroll
  for (int r = 0; r < 16; ++r) {
    int nn = ry + r * 4;
    Wt[(size_t)(n0 + nn) * K + k0 + cx] = f2bf(t[cx][nn]);
  }
}

// ---------------------------------------------------------------- bf16 MFMA GEMM core
// C[128x128] tile at (row0, col0). A: [M][K] bf16 row-major; B: [N][K] bf16 row-major
// (i.e. pre-transposed weights). 256 threads = 4 waves in 2x2; each wave 64x64 via
// 4x4 grid of 16x16x32 MFMA frags. BK=32, single-buffered LDS, global_load_lds x16.
__device__ __forceinline__ void gemm_core(const unsigned short* __restrict__ A,
                                          const unsigned short* __restrict__ B,
                                          int K, int ldA, int ldB, int row0, int col0,
                                          unsigned short* Al, unsigned short* Bl,
                                          f32x4 acc[4][4]) {
  const int tid = threadIdx.x;
  const int w = tid >> 6, l = tid & 63;
  const int lrow = l & 15, lk = (l >> 4) * 8;
  const int wr = (w >> 1) * 64, wc = (w & 1) * 64;
  const int srow = l >> 2, skk = (l & 3) * 8;  // staging: 16 rows/KB chunk, 8 bf16/lane

  for (int kk = 0; kk < K; kk += 32) {
#pragma unroll
    for (int q = 0; q < 2; ++q) {
      int c = w * 2 + q;  // chunk 0..7, 16 rows each
      gload_lds16(A + (size_t)(row0 + c * 16 + srow) * ldA + kk + skk, &Al[c * 512]);
      gload_lds16(B + (size_t)(col0 + c * 16 + srow) * ldB + kk + skk, &Bl[c * 512]);
    }
    __syncthreads();
    bf16x8 af[4], bfr[4];
#pragma unroll
    for (int m = 0; m < 4; ++m)
      af[m] = *(const bf16x8*)&Al[(wr + m * 16 + lrow) * 32 + lk];
#pragma unroll
    for (int n = 0; n < 4; ++n)
      bfr[n] = *(const bf16x8*)&Bl[(wc + n * 16 + lrow) * 32 + lk];
#pragma unroll
    for (int m = 0; m < 4; ++m)
#pragma unroll
      for (int n = 0; n < 4; ++n)
        acc[m][n] = __builtin_amdgcn_mfma_f32_16x16x32_bf16(af[m], bfr[n], acc[m][n], 0, 0, 0);
    __syncthreads();
  }
}

// ---------------------------------------------------------------- init w + row norms

__global__ void k_init_w(const float* __restrict__ w0, const float* __restrict__ w1,
                         const float* __restrict__ w2, float* __restrict__ WW,
                         float* __restrict__ WN0) {
  int rid = blockIdx.x;
  int m = rid >> 11;
  int gr = rid & 2047;
  const float* src = (m == 0) ? w0 : (m == 1) ? w1 : w2;
  const float* row = src + (size_t)gr * HD;
  float* drow = WW + ((size_t)m * 2048 + gr) * HD;
  int l = threadIdx.x;
  float v0 = row[l], v1 = row[l + 64];
  drow[l] = v0; drow[l + 64] = v1;
  float s = wave_sum64(v0 * v0 + v1 * v1);
  if (l == 0) WN0[rid] = sqrtf(s);
}

// ---------------------------------------------------------------- qkv projection (bf16 MFMA)

// grid (64, 48), block 256. silu + scatter to group layout (fp32 out).
__global__ __launch_bounds__(256) void k_qkv_mfma(const unsigned short* __restrict__ xb,
                                                  const unsigned short* __restrict__ Wqt,
                                                  float* __restrict__ Q, float* __restrict__ Km,
                                                  float* __restrict__ V) {
  __shared__ unsigned short Al[128 * 32];
  __shared__ unsigned short Bl[128 * 32];
  f32x4 acc[4][4];
#pragma unroll
  for (int m = 0; m < 4; ++m)
#pragma unroll
    for (int n = 0; n < 4; ++n) acc[m][n] = {};

  gemm_core(xb, Wqt, DMODEL, DMODEL, DMODEL, blockIdx.x * 128, blockIdx.y * 128, Al, Bl, acc);

  const int ct = blockIdx.y, hh = ct / 3, which = ct % 3;
  float* dst = (which == 0) ? Q : (which == 1) ? Km : V;
  const int tid = threadIdx.x, w = tid >> 6, l = tid & 63;
  const int wr = (w >> 1) * 64, wc = (w & 1) * 64;
#pragma unroll
  for (int m = 0; m < 4; ++m)
#pragma unroll
    for (int j = 0; j < 4; ++j) {
      int t = blockIdx.x * 128 + wr + m * 16 + (l >> 4) * 4 + j;
      int fth = t * NH + hh;
      int g = fth >> 13, tp = fth & 8191;
      float* drow = dst + ((size_t)g * LSEQ + tp) * HD;
#pragma unroll
      for (int n = 0; n < 4; ++n) {
        float v = acc[m][n][j];
        drow[wc + n * 16 + (l & 15)] = v * sigm(v);
      }
    }
}

// normalize Q and K rows in place.
__global__ void k_l2norm(float* __restrict__ Q, float* __restrict__ Km) {
  int rid = blockIdx.x * 4 + (threadIdx.x >> 6);
  int l = threadIdx.x & 63;
  float* base = (rid < NH * LSEQ) ? Q : Km;
  int r = (rid < NH * LSEQ) ? rid : rid - NH * LSEQ;
  float* row = base + (size_t)r * HD;
  float v0 = row[l], v1 = row[l + 64];
  float s = wave_sum64(v0 * v0 + v1 * v1);
  float f = 1.0f / (sqrtf(s) + 1e-5f);
  row[l] = v0 * f;
  row[l + 64] = v1 * f;
}

// ---------------------------------------------------------------- lr / momentum / scale

__global__ __launch_bounds__(128) void k_lrms(const float* __restrict__ x,
                                              const float* __restrict__ Wlr,
                                              const float* __restrict__ Wm, const float* __restrict__ bm,
                                              const float* __restrict__ Wsc, const float* __restrict__ bs,
                                              float* __restrict__ LR, float* __restrict__ MOM,
                                              float* __restrict__ SCL) {
  __shared__ float xs[DMODEL];
  const int t = blockIdx.x;
  const int tid = threadIdx.x;
  for (int i = tid; i < DMODEL; i += 128) xs[i] = x[(size_t)t * DMODEL + i];
  __syncthreads();
  const int c = tid;
  if (c >= 80) return;
  const float* Wcol;
  int stride;
  float bias = 0.0f;
  if (c < 48) { Wcol = Wlr + c; stride = 48; }
  else if (c < 64) { Wcol = Wm + (c - 48); stride = 16; bias = bm[c - 48]; }
  else { Wcol = Wsc + (c - 64); stride = 16; bias = bs[c - 64]; }
  float s0 = 0, s1 = 0, s2 = 0, s3 = 0;
  for (int k = 0; k < DMODEL; k += 4) {
    s0 = fmaf(xs[k], Wcol[(size_t)k * stride], s0);
    s1 = fmaf(xs[k + 1], Wcol[(size_t)(k + 1) * stride], s1);
    s2 = fmaf(xs[k + 2], Wcol[(size_t)(k + 2) * stride], s2);
    s3 = fmaf(xs[k + 3], Wcol[(size_t)(k + 3) * stride], s3);
  }
  float dot = (s0 + s1) + (s2 + s3);
  if (c < 48) {
    float base_lr_inv = 0.01f + logf(-expm1f(-0.01f));
    float v = dot + base_lr_inv;
    float sp = fmaxf(v, 0.0f) + log1pf(expf(-fabsf(v)));
    int j = c >> 4, hh = c & 15;
    LR[((size_t)(j * NH + hh)) * LSEQ + t] = sp;
  } else if (c < 64) {
    MOM[(size_t)(c - 48) * LSEQ + t] = sigm(dot + bias);
  } else {
    float v = dot + bias;
    SCL[(size_t)(c - 64) * LSEQ + t] = v * sigm(v);
  }
}

// ---------------------------------------------------------------- per-chunk output (+ fused LN/scale)

// grid (CH/64, NH), block 256. U written as bf16 token-major [LSEQ][DMODEL].
__global__ __launch_bounds__(256) void k_out(const float* __restrict__ WW,
                                             const float* __restrict__ Q,
                                             const float* __restrict__ SCL,
                                             const float* __restrict__ lng,
                                             const float* __restrict__ lnb,
                                             unsigned short* __restrict__ U, int s) {
  __shared__ float A0s[32][132];
  __shared__ float A1s[32][132];
  __shared__ float Bs[32][132];
  __shared__ float gh[128][68];
  const int tt0 = blockIdx.x * 64;
  const int g = blockIdx.y;
  const int tid = threadIdx.x;
  const int ty = tid >> 4, tx = tid & 15;
  const int kk = tid & 31, sub = tid >> 5;
  const float* w0g = WW + ((size_t)0 * 2048 + g * 128) * 128;
  const float* w1g = WW + ((size_t)1 * 2048 + g * 128) * 128;
  const float* w2g = WW + ((size_t)2 * 2048 + g * 128) * 128;

  float acc1[8][4], acc2[8][4];
#pragma unroll
  for (int i = 0; i < 8; ++i)
#pragma unroll
    for (int j = 0; j < 4; ++j) { acc1[i][j] = 0.0f; acc2[i][j] = 0.0f; }

  for (int ks = 0; ks < 128; ks += 32) {
#pragma unroll
    for (int r = 0; r < 16; ++r) {
      int e = sub + r * 8;
      A0s[kk][e] = w0g[(size_t)e * 128 + ks + kk];
      A1s[kk][e] = w2g[(size_t)e * 128 + ks + kk];
    }
#pragma unroll
    for (int r = 0; r < 8; ++r) {
      int tc = sub + r * 8;
      Bs[kk][tc] = Q[((size_t)g * LSEQ + s + tt0 + tc) * HD + ks + kk];
    }
    __syncthreads();
#pragma unroll
    for (int k2 = 0; k2 < 32; ++k2) {
      float a0[8], a1[8], b[4];
#pragma unroll
      for (int i = 0; i < 8; ++i) { a0[i] = A0s[k2][ty * 8 + i]; a1[i] = A1s[k2][ty * 8 + i]; }
#pragma unroll
      for (int j = 0; j < 4; ++j) b[j] = Bs[k2][tx * 4 + j];
#pragma unroll
      for (int i = 0; i < 8; ++i)
#pragma unroll
        for (int j = 0; j < 4; ++j) {
          acc1[i][j] = fmaf(a0[i], b[j], acc1[i][j]);
          acc2[i][j] = fmaf(a1[i], b[j], acc2[i][j]);
        }
    }
    __syncthreads();
  }
#pragma unroll
  for (int i = 0; i < 8; ++i)
#pragma unroll
    for (int j = 0; j < 4; ++j) {
      float gv = acc1[i][j];
      gh[ty * 8 + i][tx * 4 + j] = gv * sigm(gv) * acc2[i][j];
    }
  __syncthreads();

  float acco[8][4];
#pragma unroll
  for (int i = 0; i < 8; ++i)
#pragma unroll
    for (int j = 0; j < 4; ++j) acco[i][j] = 0.0f;

  for (int es = 0; es < 128; es += 32) {
#pragma unroll
    for (int r = 0; r < 16; ++r) {
      int d = sub + r * 8;
      A0s[kk][d] = w1g[(size_t)d * 128 + es + kk];
    }
    __syncthreads();
#pragma unroll
    for (int k2 = 0; k2 < 32; ++k2) {
      float a[8], b[4];
#pragma unroll
      for (int i = 0; i < 8; ++i) a[i] = A0s[k2][ty * 8 + i];
#pragma unroll
      for (int j = 0; j < 4; ++j) b[j] = gh[es + k2][tx * 4 + j];
#pragma unroll
      for (int i = 0; i < 8; ++i)
#pragma unroll
        for (int j = 0; j < 4; ++j) acco[i][j] = fmaf(a[i], b[j], acco[i][j]);
    }
    __syncthreads();
  }
#pragma unroll
  for (int i = 0; i < 8; ++i)
#pragma unroll
    for (int j = 0; j < 4; ++j) gh[ty * 8 + i][tx * 4 + j] = acco[i][j];
  __syncthreads();

  const int tok = tid >> 2;
  const int part = tid & 3;
  float sum = 0.0f;
#pragma unroll
  for (int dd = 0; dd < 32; ++dd) sum += gh[part * 32 + dd][tok];
  sum += __shfl_xor(sum, 1, 64);
  sum += __shfl_xor(sum, 2, 64);
  float mu = sum * (1.0f / 128.0f);
  float vs = 0.0f;
#pragma unroll
  for (int dd = 0; dd < 32; ++dd) {
    float dv = gh[part * 32 + dd][tok] - mu;
    vs = fmaf(dv, dv, vs);
  }
  vs += __shfl_xor(vs, 1, 64);
  vs += __shfl_xor(vs, 2, 64);
  float rstd = rsqrtf(vs * (1.0f / 128.0f) + 1e-6f);
  int tabs = s + tt0 + tok;
  float sc = SCL[(size_t)g * LSEQ + tabs];
  unsigned short* urow = U + (size_t)tabs * DMODEL + g * HD + part * 32;
#pragma unroll
  for (int dd = 0; dd < 32; ++dd) {
    int d = part * 32 + dd;
    float o = (gh[d][tok] - mu) * rstd * lng[d] + lnb[d];
    urow[dd] = f2bf(o * sc);
  }
}

// ---------------------------------------------------------------- chunk backward front GEMMs

__global__ __launch_bounds__(256) void k_front(const float* __restrict__ WW,
                                               const float* __restrict__ Km,
                                               const float* __restrict__ V,
                                               float* __restrict__ BUF, int s) {
  __shared__ float As[32][132];
  __shared__ float Bs[32][132];
  const int tt0 = blockIdx.x * 128;
  const int g = blockIdx.y;
  const int z = blockIdx.z;
  const int tid = threadIdx.x;
  const int ty = tid >> 4, tx = tid & 15;
  const int kk = tid & 31, sub = tid >> 5;
  const int wsel = (z == 0) ? 0 : (z == 1) ? 2 : 1;
  const float* wg = WW + ((size_t)wsel * 2048 + g * 128) * 128;
  const float* X = (z == 2) ? V : Km;
  float* out = BUF + (size_t)z * (NH * 128 * CH) + (size_t)g * 128 * CH;

  float acc[8][8];
#pragma unroll
  for (int i = 0; i < 8; ++i)
#pragma unroll
    for (int j = 0; j < 8; ++j) acc[i][j] = 0.0f;

  for (int ks = 0; ks < 128; ks += 32) {
    if (z != 2) {
#pragma unroll
      for (int r = 0; r < 16; ++r) {
        int e = sub + r * 8;
        As[kk][e] = wg[(size_t)e * 128 + ks + kk];
      }
    } else {
#pragma unroll
      for (int r = 0; r < 16; ++r) {
        int idx = tid + r * 256;
        int k2 = idx >> 7, e = idx & 127;
        As[k2][e] = wg[(size_t)(ks + k2) * 128 + e];
      }
    }
#pragma unroll
    for (int r = 0; r < 16; ++r) {
      int t = sub + r * 8;
      Bs[kk][t] = X[((size_t)g * LSEQ + s + tt0 + t) * HD + ks + kk];
    }
    __syncthreads();
    mm8x8(As, Bs, ty, tx, acc);
    __syncthreads();
  }
#pragma unroll
  for (int i = 0; i < 8; ++i)
#pragma unroll
    for (int j = 0; j < 8; ++j)
      out[(size_t)(ty * 8 + i) * CH + tt0 + tx * 8 + j] = acc[i][j];
}

// elementwise: (Gb,Hb,Dh) -> (hid, dgate_before, dhidden_before) in place
__global__ void k_elem(float* __restrict__ BA, float* __restrict__ BB, float* __restrict__ BC) {
  size_t i = ((size_t)blockIdx.x * 256 + threadIdx.x) * 4;
  float4 a = *(const float4*)(BA + i);
  float4 b = *(const float4*)(BB + i);
  float4 c = *(const float4*)(BC + i);
  float4 ha, hb2, hc;
  float* pa = (float*)&a; float* pb = (float*)&b; float* pc = (float*)&c;
  float* oa = (float*)&ha; float* ob = (float*)&hb2; float* oc = (float*)&hc;
#pragma unroll
  for (int k = 0; k < 4; ++k) {
    float gb = pa[k], hb = pb[k], dh = pc[k];
    float sg = sigm(gb);
    float sgb = gb * sg;
    float hid = sgb * hb;
    float dgate = dh * hb;
    float dgb = dgate * sg * (1.0f + gb * (1.0f - sg));
    float dhb = dh * sgb;
    oa[k] = hid; ob[k] = dgb; oc[k] = dhb;
  }
  *(float4*)(BA + i) = ha;
  *(float4*)(BB + i) = hb2;
  *(float4*)(BC + i) = hc;
}

__global__ void k_mom_mean(const float* __restrict__ MOM, float* __restrict__ MI, int s) {
  __shared__ float red[4];
  int g = blockIdx.x;
  int tid = threadIdx.x;
  float sum = 0.0f;
  for (int i = tid; i < CH; i += 256) sum += MOM[(size_t)g * LSEQ + s + i];
  sum = wave_sum64(sum);
  if ((tid & 63) == 0) red[tid >> 6] = sum;
  __syncthreads();
  if (tid == 0) MI[g] = (red[0] + red[1] + red[2] + red[3]) * (1.0f / (float)CH);
}

__global__ __launch_bounds__(256) void k_dwp(const float* __restrict__ BUF,
                                             const float* __restrict__ Km,
                                             const float* __restrict__ V,
                                             const float* __restrict__ LR,
                                             float* __restrict__ DWP, int s) {
  __shared__ float As[32][132];
  __shared__ float Bs[32][132];
  const int p = blockIdx.x;
  const int g = blockIdx.y;
  const int z = blockIdx.z;
  const int tid = threadIdx.x;
  const int ty = tid >> 4, tx = tid & 15;
  const int kk = tid & 31, sub = tid >> 5;
  const int msel = (z == 0) ? 1 : (z == 1) ? 0 : 2;
  const float* M = BUF + (size_t)msel * (NH * 128 * CH) + (size_t)g * 128 * CH;
  const float* N = (z == 1) ? V : Km;
  const float* lr = LR + (size_t)(z * NH + g) * LSEQ;
  const int ts = p * 1024;

  float acc[8][8];
#pragma unroll
  for (int i = 0; i < 8; ++i)
#pragma unroll
    for (int j = 0; j < 8; ++j) acc[i][j] = 0.0f;

  for (int ks = 0; ks < 1024; ks += 32) {
#pragma unroll
    for (int r = 0; r < 16; ++r) {
      int o1 = sub + r * 8;
      As[kk][o1] = M[(size_t)o1 * CH + ts + ks + kk];
    }
#pragma unroll
    for (int r = 0; r < 16; ++r) {
      int idx = tid + r * 256;
      int k2 = idx >> 7, o2 = idx & 127;
      int tok = s + ts + ks + k2;
      Bs[k2][o2] = N[((size_t)g * LSEQ + tok) * HD + o2] * lr[tok];
    }
    __syncthreads();
    mm8x8(As, Bs, ty, tx, acc);
    __syncthreads();
  }
  float* outp = DWP + (((size_t)(z * NH + g)) * 2 + p) * 16384;
#pragma unroll
  for (int i = 0; i < 8; ++i)
#pragma unroll
    for (int j = 0; j < 8; ++j)
      outp[(ty * 8 + i) * 128 + tx * 8 + j] = acc[i][j];
}

__global__ void k_dwred(const float* __restrict__ DWP, const float* __restrict__ MI,
                        float* __restrict__ DW) {
  int zg = blockIdx.x;
  int g = zg & 15, z = zg >> 4;
  float mi = 1.0f + MI[g];
  const float* base = DWP + (size_t)zg * 2 * 16384;
  float* out = DW + (size_t)zg * 16384;
  for (int idx = threadIdx.x; idx < 16384; idx += 256) {
    float sv = base[idx] + base[(size_t)16384 + idx];
    sv *= mi;
    int oidx = (z == 1) ? ((idx & 127) * 128 + (idx >> 7)) : idx;
    out[oidx] = sv;
  }
}

// ---------------------------------------------------------------- Newton-Schulz 5

__global__ __launch_bounds__(1024) void k_ns5(float* __restrict__ DW) {
  __shared__ float Xs[128 * 128];
  __shared__ float Aw[128 * 128];
  const float NA[5] = {4.0848f, 3.9505f, 3.7418f, 2.8769f, 2.8366f};
  const float NB[5] = {-6.8946f, -6.3029f, -5.5913f, -3.1427f, -3.0525f};
  const float NC[5] = {2.927f, 2.6377f, 2.3037f, 1.2046f, 1.2012f};
  float* Gm = DW + (size_t)blockIdx.x * 16384;
  const int tid = threadIdx.x;
  const int ty = tid >> 5, tx = tid & 31;

  float psum = 0.0f;
#pragma unroll
  for (int r = 0; r < 16; ++r) {
    int idx = tid + r * 1024;
    float v = Gm[idx];
    Xs[idx] = v;
    psum = fmaf(v, v, psum);
  }
  psum = wave_sum64(psum);
  if ((tid & 63) == 0) Aw[tid >> 6] = psum;
  __syncthreads();
  if (tid == 0) {
    float tot = 0.0f;
    for (int i = 0; i < 16; ++i) tot += Aw[i];
    Aw[0] = 1.0f / (sqrtf(tot) + 1e-7f);
  }
  __syncthreads();
  float scl = Aw[0];
#pragma unroll
  for (int r = 0; r < 16; ++r) {
    int idx = tid + r * 1024;
    Xs[idx] *= scl;
  }
  __syncthreads();

#pragma unroll 1
  for (int it = 0; it < 5; ++it) {
    float ac = NA[it], bc = NB[it], cc = NC[it];
#pragma unroll
    for (int ii = 0; ii < 4; ++ii)
#pragma unroll
      for (int jj = 0; jj < 4; ++jj)
        Aw[(tx * 4 + jj) * 128 + ty * 4 + ii] = Xs[(ty * 4 + ii) * 128 + tx * 4 + jj];
    __syncthreads();
    float Ar[4][4];
#pragma unroll
    for (int ii = 0; ii < 4; ++ii)
#pragma unroll
      for (int jj = 0; jj < 4; ++jj) Ar[ii][jj] = 0.0f;
    for (int k = 0; k < 128; ++k) {
      float a[4], b[4];
#pragma unroll
      for (int ii = 0; ii < 4; ++ii) a[ii] = Xs[(ty * 4 + ii) * 128 + k];
#pragma unroll
      for (int jj = 0; jj < 4; ++jj) b[jj] = Aw[k * 128 + tx * 4 + jj];
#pragma unroll
      for (int ii = 0; ii < 4; ++ii)
#pragma unroll
        for (int jj = 0; jj < 4; ++jj) Ar[ii][jj] = fmaf(a[ii], b[jj], Ar[ii][jj]);
    }
    __syncthreads();
#pragma unroll
    for (int ii = 0; ii < 4; ++ii)
#pragma unroll
      for (int jj = 0; jj < 4; ++jj)
        Aw[(ty * 4 + ii) * 128 + tx * 4 + jj] = Ar[ii][jj];
    __syncthreads();
    float Bm[4][4];
#pragma unroll
    for (int ii = 0; ii < 4; ++ii)
#pragma unroll
      for (int jj = 0; jj < 4; ++jj) Bm[ii][jj] = 0.0f;
    for (int k = 0; k < 128; ++k) {
      float a[4], b[4];
#pragma unroll
      for (int ii = 0; ii < 4; ++ii) a[ii] = Aw[(ty * 4 + ii) * 128 + k];
#pragma unroll
      for (int jj = 0; jj < 4; ++jj) b[jj] = Aw[k * 128 + tx * 4 + jj];
#pragma unroll
      for (int ii = 0; ii < 4; ++ii)
#pragma unroll
        for (int jj = 0; jj < 4; ++jj) Bm[ii][jj] = fmaf(a[ii], b[jj], Bm[ii][jj]);
    }
#pragma unroll
    for (int ii = 0; ii < 4; ++ii)
#pragma unroll
      for (int jj = 0; jj < 4; ++jj) Bm[ii][jj] = fmaf(bc, Ar[ii][jj], cc * Bm[ii][jj]);
    __syncthreads();
#pragma unroll
    for (int ii = 0; ii < 4; ++ii)
#pragma unroll
      for (int jj = 0; jj < 4; ++jj)
        Aw[(ty * 4 + ii) * 128 + tx * 4 + jj] = Bm[ii][jj];
    __syncthreads();
    float Xn[4][4];
#pragma unroll
    for (int ii = 0; ii < 4; ++ii)
#pragma unroll
      for (int jj = 0; jj < 4; ++jj)
        Xn[ii][jj] = ac * Xs[(ty * 4 + ii) * 128 + tx * 4 + jj];
    for (int k = 0; k < 128; ++k) {
      float a[4], b[4];
#pragma unroll
      for (int ii = 0; ii < 4; ++ii) a[ii] = Aw[(ty * 4 + ii) * 128 + k];
#pragma unroll
      for (int jj = 0; jj < 4; ++jj) b[jj] = Xs[k * 128 + tx * 4 + jj];
#pragma unroll
      for (int ii = 0; ii < 4; ++ii)
#pragma unroll
        for (int jj = 0; jj < 4; ++jj) Xn[ii][jj] = fmaf(a[ii], b[jj], Xn[ii][jj]);
    }
    __syncthreads();
#pragma unroll
    for (int ii = 0; ii < 4; ++ii)
#pragma unroll
      for (int jj = 0; jj < 4; ++jj)
        Xs[(ty * 4 + ii) * 128 + tx * 4 + jj] = Xn[ii][jj];
    __syncthreads();
  }
#pragma unroll
  for (int r = 0; r < 16; ++r) {
    int idx = tid + r * 1024;
    Gm[idx] = Xs[idx];
  }
}

__global__ void k_apply(float* __restrict__ WW, const float* __restrict__ DW,
                        const float* __restrict__ WN0) {
  int rid = blockIdx.x;
  int l = threadIdx.x;
  float* wrow = WW + (size_t)rid * 128;
  const float* drow = DW + (size_t)rid * 128;
  float v0 = wrow[l] + drow[l];
  float v1 = wrow[l + 64] + drow[l + 64];
  float s = wave_sum64(v0 * v0 + v1 * v1);
  float f = WN0[rid] / (sqrtf(s) + 1e-5f);
  wrow[l] = v0 * f;
  wrow[l + 64] = v1 * f;
}

// ---------------------------------------------------------------- final projection (bf16 MFMA)

// grid (64, 16), block 256: out = U(bf16) @ Wo (via Wot bf16), fp32 out.
__global__ __launch_bounds__(256) void k_final_mfma(const unsigned short* __restrict__ U,
                                                    const unsigned short* __restrict__ Wot,
                                                    float* __restrict__ out) {
  __shared__ unsigned short Al[128 * 32];
  __shared__ unsigned short Bl[128 * 32];
  f32x4 acc[4][4];
#pragma unroll
  for (int m = 0; m < 4; ++m)
#pragma unroll
    for (int n = 0; n < 4; ++n) acc[m][n] = {};

  const int row0 = blockIdx.x * 128, col0 = blockIdx.y * 128;
  gemm_core(U, Wot, DMODEL, DMODEL, DMODEL, row0, col0, Al, Bl, acc);

  const int tid = threadIdx.x, w = tid >> 6, l = tid & 63;
  const int wr = (w >> 1) * 64, wc = (w & 1) * 64;
#pragma unroll
  for (int m = 0; m < 4; ++m)
#pragma unroll
    for (int j = 0; j < 4; ++j) {
      int t = row0 + wr + m * 16 + (l >> 4) * 4 + j;
      float* orow = out + (size_t)t * DMODEL + col0;
#pragma unroll
      for (int n = 0; n < 4; ++n)
        orow[wc + n * 16 + (l & 15)] = acc[m][n][j];
    }
}

// ---------------------------------------------------------------- launch

extern "C" void kernel_launch(void* const* d_in, const int* in_sizes, int n_in,
                              void* d_out, int out_size, void* d_ws, size_t ws_size,
                              hipStream_t stream) {
  (void)in_sizes; (void)n_in; (void)out_size;
  const float* x    = (const float*)d_in[0];
  const float* Wqkv = (const float*)d_in[1];
  const float* Wlr  = (const float*)d_in[2];
  const float* Wo   = (const float*)d_in[3];
  const float* Wm   = (const float*)d_in[4];
  const float* bm   = (const float*)d_in[5];
  const float* Wsc  = (const float*)d_in[6];
  const float* bs   = (const float*)d_in[7];
  const float* lng  = (const float*)d_in[8];
  const float* lnb  = (const float*)d_in[9];
  const float* w0   = (const float*)d_in[10];
  const float* w1   = (const float*)d_in[11];
  const float* w2   = (const float*)d_in[12];

  // Q lives in d_out (fp32); its last read (k_out, chunk 3) precedes k_final's write.
  float* Q = (float*)d_out;

  float* ws = (float*)d_ws;
  size_t off = 0;
  auto alloc = [&](size_t n) { float* p = ws + off; off += n; return p; };
  float* Km   = alloc((size_t)NH * LSEQ * HD);
  float* V    = alloc((size_t)NH * LSEQ * HD);
  float* Uf   = alloc((size_t)LSEQ * DMODEL / 2);   // U stored as bf16
  float* LR   = alloc((size_t)3 * NH * LSEQ);
  float* MOM  = alloc((size_t)NH * LSEQ);
  float* SCL  = alloc((size_t)NH * LSEQ);
  float* WW   = alloc((size_t)3 * NH * HD * HD);
  float* WN0  = alloc((size_t)3 * NH * HD);
  float* BUF  = alloc((size_t)3 * NH * HD * CH);    // chunk loop scratch
  float* DW   = alloc((size_t)3 * NH * HD * HD);
  float* DWP  = alloc((size_t)3 * NH * 2 * HD * HD);
  float* MI   = alloc((size_t)16);
  if (off * sizeof(float) > ws_size) return;        // clean failure instead of OOB

  unsigned short* U = (unsigned short*)Uf;
  // xb/Wqt alias BUF..DWP (dead until chunk loop); Wot aliases BUF (dead after loop).
  unsigned short* xb  = (unsigned short*)BUF;                                   // 16.78M u16
  unsigned short* Wqt = (unsigned short*)(BUF + (size_t)LSEQ * DMODEL / 2);     // 12.58M u16
  unsigned short* Wot = (unsigned short*)BUF;                                   // 4.19M u16

  k_init_w<<<3 * NH * HD, 64, 0, stream>>>(w0, w1, w2, WW, WN0);
  k_cast<<<2048, 256, 0, stream>>>(x, xb, LSEQ * DMODEL / 4);
  k_tcast<<<dim3(3 * DMODEL / 64, DMODEL / 64), 256, 0, stream>>>(Wqkv, Wqt, DMODEL, 3 * DMODEL);
  k_qkv_mfma<<<dim3(LSEQ / 128, 48), 256, 0, stream>>>(xb, Wqt, Q, Km, V);
  k_l2norm<<<2 * NH * LSEQ / 4, 256, 0, stream>>>(Q, Km);
  k_lrms<<<LSEQ, 128, 0, stream>>>(x, Wlr, Wm, bm, Wsc, bs, LR, MOM, SCL);

  for (int c = 0; c < 4; ++c) {
    int s = c * CH;
    k_out<<<dim3(CH / 64, NH), 256, 0, stream>>>(WW, Q, SCL, lng, lnb, U, s);
    if (c < 3) {
      k_front<<<dim3(CH / 128, NH, 3), 256, 0, stream>>>(WW, Km, V, BUF, s);
      k_elem<<<(NH * HD * CH) / (256 * 4), 256, 0, stream>>>(
          BUF, BUF + (size_t)NH * HD * CH, BUF + (size_t)2 * NH * HD * CH);
      k_mom_mean<<<NH, 256, 0, stream>>>(MOM, MI, s);
      k_dwp<<<dim3(2, NH, 3), 256, 0, stream>>>(BUF, Km, V, LR, DWP, s);
      k_dwred<<<3 * NH, 256, 0, stream>>>(DWP, MI, DW);
      k_ns5<<<3 * NH, 1024, 0, stream>>>(DW);
      k_apply<<<3 * NH * HD, 64, 0, stream>>>(WW, DW, WN0);
    }
  }
  k_tcast<<<dim3(DMODEL / 64, DMODEL / 64), 256, 0, stream>>>(Wo, Wot, DMODEL, DMODEL);
  k_final_mfma<<<dim3(LSEQ / 128, DMODEL / 16 / 8), 256, 0, stream>>>(U, Wot, (float*)d_out);
}

// Round 4
// 2178.704 us; speedup vs baseline: 2.7532x; 1.0466x over previous
//
#include <hip/hip_runtime.h>
#include <hip/hip_bf16.h>
#include <cstdint>
#include <cstddef>

#define LSEQ   8192
#define DMODEL 2048
#define NH     16      // heads == groups
#define HD     128     // head dim == hidden dim
#define CH     2048    // chunk length (group-space positions)

typedef __attribute__((ext_vector_type(8))) __bf16 bf16x8;
typedef __attribute__((ext_vector_type(4))) float f32x4;

// ---------------------------------------------------------------- helpers

__device__ __forceinline__ float wave_sum64(float v) {
#pragma unroll
  for (int m = 32; m; m >>= 1) v += __shfl_xor(v, m, 64);
  return v;
}

__device__ __forceinline__ float sigm(float x) { return 1.0f / (1.0f + expf(-x)); }

// RTNE float -> bf16 bits
__device__ __forceinline__ unsigned short f2bf(float f) {
  unsigned int u = __float_as_uint(f);
  u += 0x7FFFu + ((u >> 16) & 1u);
  return (unsigned short)(u >> 16);
}

// async global->LDS, 16B per lane. lds dest is wave-uniform base; HW adds lane*16.
__device__ __forceinline__ void gload_lds16(const void* g, void* l) {
  __builtin_amdgcn_global_load_lds((__attribute__((address_space(1))) void*)(g),
                                   (__attribute__((address_space(3))) void*)(l), 16, 0, 0);
}

// 8x8 microtile inner product over a 32-deep LDS K-slice (fp32 path).
__device__ __forceinline__ void mm8x8(const float (*__restrict__ As)[132],
                                      const float (*__restrict__ Bs)[132],
                                      int ty, int tx, float acc[8][8]) {
#pragma unroll
  for (int k2 = 0; k2 < 32; ++k2) {
    float a[8], b[8];
#pragma unroll
    for (int i = 0; i < 8; ++i) a[i] = As[k2][ty * 8 + i];
#pragma unroll
    for (int j = 0; j < 8; ++j) b[j] = Bs[k2][tx * 8 + j];
#pragma unroll
    for (int i = 0; i < 8; ++i)
#pragma unroll
      for (int j = 0; j < 8; ++j) acc[i][j] = fmaf(a[i], b[j], acc[i][j]);
  }
}

// ---------------------------------------------------------------- casts

__global__ void k_cast(const float* __restrict__ X, unsigned short* __restrict__ Xb, int n4) {
  int i = blockIdx.x * 256 + threadIdx.x;
  int stride = gridDim.x * 256;
  for (; i < n4; i += stride) {
    float4 v = ((const float4*)X)[i];
    ushort4 o;
    o.x = f2bf(v.x); o.y = f2bf(v.y); o.z = f2bf(v.z); o.w = f2bf(v.w);
    ((ushort4*)Xb)[i] = o;
  }
}

// W (K x N, fp32) -> Wt (N x K, bf16). grid (N/64, K/64), block 256.
__global__ void k_tcast(const float* __restrict__ W, unsigned short* __restrict__ Wt,
                        int K, int N) {
  __shared__ float t[64][65];
  const int n0 = blockIdx.x * 64, k0 = blockIdx.y * 64;
  const int tid = threadIdx.x;
  const int cx = tid & 63, ry = tid >> 6;
#pragma unroll
  for (int r = 0; r < 16; ++r) {
    int row = ry + r * 4;
    t[row][cx] = W[(size_t)(k0 + row) * N + n0 + cx];
  }
  __syncthreads();
#pragma unroll
  for (int r = 0; r < 16; ++r) {
    int nn = ry + r * 4;
    Wt[(size_t)(n0 + nn) * K + k0 + cx] = f2bf(t[cx][nn]);
  }
}

// ---------------------------------------------------------------- bf16 MFMA GEMM core (m97 style)

__device__ __forceinline__ void gemm_core(const unsigned short* __restrict__ A,
                                          const unsigned short* __restrict__ B,
                                          int K, int ldA, int ldB, int row0, int col0,
                                          unsigned short* Al, unsigned short* Bl,
                                          f32x4 acc[4][4]) {
  const int tid = threadIdx.x;
  const int w = tid >> 6, l = tid & 63;
  const int lrow = l & 15, lk = (l >> 4) * 8;
  const int wr = (w >> 1) * 64, wc = (w & 1) * 64;
  const int srow = l >> 2, skk = (l & 3) * 8;

  for (int kk = 0; kk < K; kk += 32) {
#pragma unroll
    for (int q = 0; q < 2; ++q) {
      int c = w * 2 + q;
      gload_lds16(A + (size_t)(row0 + c * 16 + srow) * ldA + kk + skk, &Al[c * 512]);
      gload_lds16(B + (size_t)(col0 + c * 16 + srow) * ldB + kk + skk, &Bl[c * 512]);
    }
    __syncthreads();
    bf16x8 af[4], bfr[4];
#pragma unroll
    for (int m = 0; m < 4; ++m)
      af[m] = *(const bf16x8*)&Al[(wr + m * 16 + lrow) * 32 + lk];
#pragma unroll
    for (int n = 0; n < 4; ++n)
      bfr[n] = *(const bf16x8*)&Bl[(wc + n * 16 + lrow) * 32 + lk];
#pragma unroll
    for (int m = 0; m < 4; ++m)
#pragma unroll
      for (int n = 0; n < 4; ++n)
        acc[m][n] = __builtin_amdgcn_mfma_f32_16x16x32_bf16(af[m], bfr[n], acc[m][n], 0, 0, 0);
    __syncthreads();
  }
}

// ---------------------------------------------------------------- init w + row norms

__global__ void k_init_w(const float* __restrict__ w0, const float* __restrict__ w1,
                         const float* __restrict__ w2, float* __restrict__ WW,
                         float* __restrict__ WN0) {
  int rid = blockIdx.x;
  int m = rid >> 11;
  int gr = rid & 2047;
  const float* src = (m == 0) ? w0 : (m == 1) ? w1 : w2;
  const float* row = src + (size_t)gr * HD;
  float* drow = WW + ((size_t)m * 2048 + gr) * HD;
  int l = threadIdx.x;
  float v0 = row[l], v1 = row[l + 64];
  drow[l] = v0; drow[l + 64] = v1;
  float s = wave_sum64(v0 * v0 + v1 * v1);
  if (l == 0) WN0[rid] = sqrtf(s);
}

// ---------------------------------------------------------------- qkv projection (bf16 MFMA)

__global__ __launch_bounds__(256) void k_qkv_mfma(const unsigned short* __restrict__ xb,
                                                  const unsigned short* __restrict__ Wqt,
                                                  float* __restrict__ Q, float* __restrict__ Km,
                                                  float* __restrict__ V) {
  __shared__ unsigned short Al[128 * 32];
  __shared__ unsigned short Bl[128 * 32];
  f32x4 acc[4][4];
#pragma unroll
  for (int m = 0; m < 4; ++m)
#pragma unroll
    for (int n = 0; n < 4; ++n) acc[m][n] = {};

  gemm_core(xb, Wqt, DMODEL, DMODEL, DMODEL, blockIdx.x * 128, blockIdx.y * 128, Al, Bl, acc);

  const int ct = blockIdx.y, hh = ct / 3, which = ct % 3;
  float* dst = (which == 0) ? Q : (which == 1) ? Km : V;
  const int tid = threadIdx.x, w = tid >> 6, l = tid & 63;
  const int wr = (w >> 1) * 64, wc = (w & 1) * 64;
#pragma unroll
  for (int m = 0; m < 4; ++m)
#pragma unroll
    for (int j = 0; j < 4; ++j) {
      int t = blockIdx.x * 128 + wr + m * 16 + (l >> 4) * 4 + j;
      int fth = t * NH + hh;
      int g = fth >> 13, tp = fth & 8191;
      float* drow = dst + ((size_t)g * LSEQ + tp) * HD;
#pragma unroll
      for (int n = 0; n < 4; ++n) {
        float v = acc[m][n][j];
        drow[wc + n * 16 + (l & 15)] = v * sigm(v);
      }
    }
}

// normalize Q and K rows in place.
__global__ void k_l2norm(float* __restrict__ Q, float* __restrict__ Km) {
  int rid = blockIdx.x * 4 + (threadIdx.x >> 6);
  int l = threadIdx.x & 63;
  float* base = (rid < NH * LSEQ) ? Q : Km;
  int r = (rid < NH * LSEQ) ? rid : rid - NH * LSEQ;
  float* row = base + (size_t)r * HD;
  float v0 = row[l], v1 = row[l + 64];
  float s = wave_sum64(v0 * v0 + v1 * v1);
  float f = 1.0f / (sqrtf(s) + 1e-5f);
  row[l] = v0 * f;
  row[l + 64] = v1 * f;
}

// ---------------------------------------------------------------- lr / momentum / scale (tiled fp32 GEMM)

// grid 256 (32 tokens each), block 256 = (tok 0..31) x (colgroup 0..7, 10 cols each).
__global__ __launch_bounds__(256) void k_lrms2(const float* __restrict__ x,
                                               const float* __restrict__ Wlr,
                                               const float* __restrict__ Wm, const float* __restrict__ bm,
                                               const float* __restrict__ Wsc, const float* __restrict__ bs,
                                               float* __restrict__ LR, float* __restrict__ MOM,
                                               float* __restrict__ SCL) {
  // col c lives at Ws[k2][(c/10)*12 + c%10] -> 16B-aligned group bases
  __shared__ float Ws[32][96];
  const int t0 = blockIdx.x * 32;
  const int tid = threadIdx.x;
  const int tok = tid & 31, cg = tid >> 5;
  const float* xrow = x + (size_t)(t0 + tok) * DMODEL;
  float acc[10];
#pragma unroll
  for (int j = 0; j < 10; ++j) acc[j] = 0.0f;

  for (int ks = 0; ks < DMODEL; ks += 32) {
#pragma unroll
    for (int r = 0; r < 10; ++r) {
      int idx = tid + r * 256;          // 0..2559
      int k2 = idx / 80, c = idx - k2 * 80;
      float wv;
      if (c < 48) wv = Wlr[(size_t)(ks + k2) * 48 + c];
      else if (c < 64) wv = Wm[(size_t)(ks + k2) * 16 + (c - 48)];
      else wv = Wsc[(size_t)(ks + k2) * 16 + (c - 64)];
      Ws[k2][(c / 10) * 12 + c % 10] = wv;
    }
    float4 xf[8];
#pragma unroll
    for (int q = 0; q < 8; ++q) xf[q] = *(const float4*)(xrow + ks + q * 4);
    __syncthreads();
#pragma unroll
    for (int k2 = 0; k2 < 32; ++k2) {
      float a = ((const float*)xf)[k2];
      const float* bb = &Ws[k2][cg * 12];
      float4 b0 = *(const float4*)(bb);
      float4 b1 = *(const float4*)(bb + 4);
      float2 b2 = *(const float2*)(bb + 8);
      acc[0] = fmaf(a, b0.x, acc[0]); acc[1] = fmaf(a, b0.y, acc[1]);
      acc[2] = fmaf(a, b0.z, acc[2]); acc[3] = fmaf(a, b0.w, acc[3]);
      acc[4] = fmaf(a, b1.x, acc[4]); acc[5] = fmaf(a, b1.y, acc[5]);
      acc[6] = fmaf(a, b1.z, acc[6]); acc[7] = fmaf(a, b1.w, acc[7]);
      acc[8] = fmaf(a, b2.x, acc[8]); acc[9] = fmaf(a, b2.y, acc[9]);
    }
    __syncthreads();
  }

  const int t = t0 + tok;
  const float base_lr_inv = 0.01f + logf(-expm1f(-0.01f));
#pragma unroll
  for (int j = 0; j < 10; ++j) {
    int c = cg * 10 + j;
    float dot = acc[j];
    if (c < 48) {
      float v = dot + base_lr_inv;
      float sp = fmaxf(v, 0.0f) + log1pf(expf(-fabsf(v)));
      int jj = c >> 4, hh = c & 15;
      LR[((size_t)(jj * NH + hh)) * LSEQ + t] = sp;
    } else if (c < 64) {
      MOM[(size_t)(c - 48) * LSEQ + t] = sigm(dot + bm[c - 48]);
    } else {
      float v = dot + bs[c - 64];
      SCL[(size_t)(c - 64) * LSEQ + t] = v * sigm(v);
    }
  }
}

// ---------------------------------------------------------------- per-chunk output (bf16 MFMA + fused LN/scale)

// swizzled bf16 LDS tile helpers: element (row, col) of a 128x128 tile,
// byte = row*256 + col*2, swizzled with ((row&7)<<4) to kill bank conflicts.
__device__ __forceinline__ void st_sw(unsigned short* base, int row, int col, unsigned short v) {
  int byte = (row * 256 + col * 2) ^ ((row & 7) << 4);
  *(unsigned short*)((char*)base + byte) = v;
}
__device__ __forceinline__ bf16x8 ld_sw(const unsigned short* base, int row, int kcol) {
  int byte = (row * 256 + kcol * 2) ^ ((row & 7) << 4);
  return *(const bf16x8*)((const char*)base + byte);
}

// stage 128x128 fp32 tile -> swizzled bf16 LDS
__device__ __forceinline__ void stage_sw(const float* __restrict__ src, int ld,
                                         unsigned short* dst, int tid) {
#pragma unroll
  for (int p = 0; p < 16; ++p) {
    int row = p * 8 + (tid >> 5);
    int col = (tid & 31) * 4;
    float4 v = *(const float4*)(src + (size_t)row * ld + col);
    int byte = (row * 256 + col * 2) ^ ((row & 7) << 4);
    unsigned short* d = (unsigned short*)((char*)dst + byte);
    d[0] = f2bf(v.x); d[1] = f2bf(v.y); d[2] = f2bf(v.z); d[3] = f2bf(v.w);
  }
}

// grid (CH/128, NH), block 256. o = w1 @ (silu(w0@q^T) * (w2@q^T)), LN, scale -> U (bf16)
__global__ __launch_bounds__(256) void k_out2(const float* __restrict__ WW,
                                              const float* __restrict__ Q,
                                              const float* __restrict__ SCL,
                                              const float* __restrict__ lng,
                                              const float* __restrict__ lnb,
                                              unsigned short* __restrict__ U, int s) {
  __shared__ __align__(16) char smem[131072];
  unsigned short* Qs  = (unsigned short*)smem;            // 32KB
  unsigned short* W0s = (unsigned short*)(smem + 32768);  // W0, then W1
  unsigned short* W2s = (unsigned short*)(smem + 65536);
  unsigned short* GHs = (unsigned short*)(smem + 98304);
  float* Os = (float*)smem;                               // [128][132] post-pass2

  const int g = blockIdx.y;
  const int t0 = blockIdx.x * 128;
  const int tid = threadIdx.x;
  const int w = tid >> 6, l = tid & 63;
  const int lrow = l & 15, lk8 = (l >> 4) * 8;
  const int wr = (w >> 1) * 64, wc = (w & 1) * 64;

  const float* Qg  = Q + ((size_t)g * LSEQ + s + t0) * HD;
  const float* w0g = WW + ((size_t)0 * 2048 + g * 128) * 128;
  const float* w1g = WW + ((size_t)1 * 2048 + g * 128) * 128;
  const float* w2g = WW + ((size_t)2 * 2048 + g * 128) * 128;

  stage_sw(Qg, HD, Qs, tid);
  stage_sw(w0g, 128, W0s, tid);
  stage_sw(w2g, 128, W2s, tid);
  __syncthreads();

  // pass 1: G = Q@W0^T, H = Q@W2^T
  f32x4 ga[4][4], ha[4][4];
#pragma unroll
  for (int m = 0; m < 4; ++m)
#pragma unroll
    for (int n = 0; n < 4; ++n) { ga[m][n] = {}; ha[m][n] = {}; }
#pragma unroll
  for (int kk = 0; kk < 128; kk += 32) {
    bf16x8 af[4], b0[4], b2[4];
#pragma unroll
    for (int m = 0; m < 4; ++m) af[m] = ld_sw(Qs, wr + m * 16 + lrow, kk + lk8);
#pragma unroll
    for (int n = 0; n < 4; ++n) {
      b0[n] = ld_sw(W0s, wc + n * 16 + lrow, kk + lk8);
      b2[n] = ld_sw(W2s, wc + n * 16 + lrow, kk + lk8);
    }
#pragma unroll
    for (int m = 0; m < 4; ++m)
#pragma unroll
      for (int n = 0; n < 4; ++n) {
        ga[m][n] = __builtin_amdgcn_mfma_f32_16x16x32_bf16(af[m], b0[n], ga[m][n], 0, 0, 0);
        ha[m][n] = __builtin_amdgcn_mfma_f32_16x16x32_bf16(af[m], b2[n], ha[m][n], 0, 0, 0);
      }
  }
  // gh = silu(g)*h -> GHs (bf16, swizzled)
#pragma unroll
  for (int m = 0; m < 4; ++m)
#pragma unroll
    for (int n = 0; n < 4; ++n)
#pragma unroll
      for (int j = 0; j < 4; ++j) {
        int row = wr + m * 16 + (l >> 4) * 4 + j;
        int col = wc + n * 16 + (l & 15);
        float gv = ga[m][n][j];
        st_sw(GHs, row, col, f2bf(gv * sigm(gv) * ha[m][n][j]));
      }
  __syncthreads();
  stage_sw(w1g, 128, W0s, tid);  // W1 replaces W0
  __syncthreads();

  // pass 2: O = GH @ W1^T
  f32x4 oa[4][4];
#pragma unroll
  for (int m = 0; m < 4; ++m)
#pragma unroll
    for (int n = 0; n < 4; ++n) oa[m][n] = {};
#pragma unroll
  for (int kk = 0; kk < 128; kk += 32) {
    bf16x8 af[4], b1[4];
#pragma unroll
    for (int m = 0; m < 4; ++m) af[m] = ld_sw(GHs, wr + m * 16 + lrow, kk + lk8);
#pragma unroll
    for (int n = 0; n < 4; ++n) b1[n] = ld_sw(W0s, wc + n * 16 + lrow, kk + lk8);
#pragma unroll
    for (int m = 0; m < 4; ++m)
#pragma unroll
      for (int n = 0; n < 4; ++n)
        oa[m][n] = __builtin_amdgcn_mfma_f32_16x16x32_bf16(af[m], b1[n], oa[m][n], 0, 0, 0);
  }
  __syncthreads();  // all LDS reads done; Os may overlay Qs/W0s/W2s
#pragma unroll
  for (int m = 0; m < 4; ++m)
#pragma unroll
    for (int n = 0; n < 4; ++n)
#pragma unroll
      for (int j = 0; j < 4; ++j) {
        int row = wr + m * 16 + (l >> 4) * 4 + j;
        int col = wc + n * 16 + (l & 15);
        Os[row * 132 + col] = oa[m][n][j];
      }
  __syncthreads();

  // LN + scale, write U bf16. 2 threads per token.
  const int tok = tid >> 1, part = tid & 1;
  const float* orow = Os + tok * 132 + part * 64;
  float sum = 0.0f;
#pragma unroll
  for (int q = 0; q < 16; ++q) {
    float4 v = *(const float4*)(orow + q * 4);
    sum += (v.x + v.y) + (v.z + v.w);
  }
  sum += __shfl_xor(sum, 1, 64);
  float mu = sum * (1.0f / 128.0f);
  float vs = 0.0f;
#pragma unroll
  for (int q = 0; q < 16; ++q) {
    float4 v = *(const float4*)(orow + q * 4);
    float d0 = v.x - mu, d1 = v.y - mu, d2 = v.z - mu, d3 = v.w - mu;
    vs += d0 * d0 + d1 * d1 + d2 * d2 + d3 * d3;
  }
  vs += __shfl_xor(vs, 1, 64);
  float rstd = rsqrtf(vs * (1.0f / 128.0f) + 1e-6f);
  int tabs = s + t0 + tok;
  float sc = SCL[(size_t)g * LSEQ + tabs];
  unsigned short* urow = U + (size_t)tabs * DMODEL + g * HD + part * 64;
#pragma unroll
  for (int q = 0; q < 16; ++q) {
    float4 v = *(const float4*)(orow + q * 4);
    int d = part * 64 + q * 4;
    ushort4 o;
    o.x = f2bf(((v.x - mu) * rstd * lng[d + 0] + lnb[d + 0]) * sc);
    o.y = f2bf(((v.y - mu) * rstd * lng[d + 1] + lnb[d + 1]) * sc);
    o.z = f2bf(((v.z - mu) * rstd * lng[d + 2] + lnb[d + 2]) * sc);
    o.w = f2bf(((v.w - mu) * rstd * lng[d + 3] + lnb[d + 3]) * sc);
    *(ushort4*)(urow + q * 4) = o;
  }
}

// ---------------------------------------------------------------- chunk backward front GEMMs (fp32)

__global__ __launch_bounds__(256) void k_front(const float* __restrict__ WW,
                                               const float* __restrict__ Km,
                                               const float* __restrict__ V,
                                               float* __restrict__ BUF, int s) {
  __shared__ float As[32][132];
  __shared__ float Bs[32][132];
  const int tt0 = blockIdx.x * 128;
  const int g = blockIdx.y;
  const int z = blockIdx.z;
  const int tid = threadIdx.x;
  const int ty = tid >> 4, tx = tid & 15;
  const int kk = tid & 31, sub = tid >> 5;
  const int wsel = (z == 0) ? 0 : (z == 1) ? 2 : 1;
  const float* wg = WW + ((size_t)wsel * 2048 + g * 128) * 128;
  const float* X = (z == 2) ? V : Km;
  float* out = BUF + (size_t)z * (NH * 128 * CH) + (size_t)g * 128 * CH;

  float acc[8][8];
#pragma unroll
  for (int i = 0; i < 8; ++i)
#pragma unroll
    for (int j = 0; j < 8; ++j) acc[i][j] = 0.0f;

  for (int ks = 0; ks < 128; ks += 32) {
    if (z != 2) {
#pragma unroll
      for (int r = 0; r < 16; ++r) {
        int e = sub + r * 8;
        As[kk][e] = wg[(size_t)e * 128 + ks + kk];
      }
    } else {
#pragma unroll
      for (int r = 0; r < 16; ++r) {
        int idx = tid + r * 256;
        int k2 = idx >> 7, e = idx & 127;
        As[k2][e] = wg[(size_t)(ks + k2) * 128 + e];
      }
    }
#pragma unroll
    for (int r = 0; r < 16; ++r) {
      int t = sub + r * 8;
      Bs[kk][t] = X[((size_t)g * LSEQ + s + tt0 + t) * HD + ks + kk];
    }
    __syncthreads();
    mm8x8(As, Bs, ty, tx, acc);
    __syncthreads();
  }
#pragma unroll
  for (int i = 0; i < 8; ++i)
#pragma unroll
    for (int j = 0; j < 8; ++j)
      out[(size_t)(ty * 8 + i) * CH + tt0 + tx * 8 + j] = acc[i][j];
}

__global__ void k_elem(float* __restrict__ BA, float* __restrict__ BB, float* __restrict__ BC) {
  size_t i = ((size_t)blockIdx.x * 256 + threadIdx.x) * 4;
  float4 a = *(const float4*)(BA + i);
  float4 b = *(const float4*)(BB + i);
  float4 c = *(const float4*)(BC + i);
  float4 ha, hb2, hc;
  float* pa = (float*)&a; float* pb = (float*)&b; float* pc = (float*)&c;
  float* oa = (float*)&ha; float* ob = (float*)&hb2; float* oc = (float*)&hc;
#pragma unroll
  for (int k = 0; k < 4; ++k) {
    float gb = pa[k], hb = pb[k], dh = pc[k];
    float sg = sigm(gb);
    float sgb = gb * sg;
    float hid = sgb * hb;
    float dgate = dh * hb;
    float dgb = dgate * sg * (1.0f + gb * (1.0f - sg));
    float dhb = dh * sgb;
    oa[k] = hid; ob[k] = dgb; oc[k] = dhb;
  }
  *(float4*)(BA + i) = ha;
  *(float4*)(BB + i) = hb2;
  *(float4*)(BC + i) = hc;
}

__global__ void k_mom_mean(const float* __restrict__ MOM, float* __restrict__ MI, int s) {
  __shared__ float red[4];
  int g = blockIdx.x;
  int tid = threadIdx.x;
  float sum = 0.0f;
  for (int i = tid; i < CH; i += 256) sum += MOM[(size_t)g * LSEQ + s + i];
  sum = wave_sum64(sum);
  if ((tid & 63) == 0) red[tid >> 6] = sum;
  __syncthreads();
  if (tid == 0) MI[g] = (red[0] + red[1] + red[2] + red[3]) * (1.0f / (float)CH);
}

__global__ __launch_bounds__(256) void k_dwp(const float* __restrict__ BUF,
                                             const float* __restrict__ Km,
                                             const float* __restrict__ V,
                                             const float* __restrict__ LR,
                                             float* __restrict__ DWP, int s) {
  __shared__ float As[32][132];
  __shared__ float Bs[32][132];
  const int p = blockIdx.x;
  const int g = blockIdx.y;
  const int z = blockIdx.z;
  const int tid = threadIdx.x;
  const int ty = tid >> 4, tx = tid & 15;
  const int kk = tid & 31, sub = tid >> 5;
  const int msel = (z == 0) ? 1 : (z == 1) ? 0 : 2;
  const float* M = BUF + (size_t)msel * (NH * 128 * CH) + (size_t)g * 128 * CH;
  const float* N = (z == 1) ? V : Km;
  const float* lr = LR + (size_t)(z * NH + g) * LSEQ;
  const int ts = p * 1024;

  float acc[8][8];
#pragma unroll
  for (int i = 0; i < 8; ++i)
#pragma unroll
    for (int j = 0; j < 8; ++j) acc[i][j] = 0.0f;

  for (int ks = 0; ks < 1024; ks += 32) {
#pragma unroll
    for (int r = 0; r < 16; ++r) {
      int o1 = sub + r * 8;
      As[kk][o1] = M[(size_t)o1 * CH + ts + ks + kk];
    }
#pragma unroll
    for (int r = 0; r < 16; ++r) {
      int idx = tid + r * 256;
      int k2 = idx >> 7, o2 = idx & 127;
      int tok = s + ts + ks + k2;
      Bs[k2][o2] = N[((size_t)g * LSEQ + tok) * HD + o2] * lr[tok];
    }
    __syncthreads();
    mm8x8(As, Bs, ty, tx, acc);
    __syncthreads();
  }
  float* outp = DWP + (((size_t)(z * NH + g)) * 2 + p) * 16384;
#pragma unroll
  for (int i = 0; i < 8; ++i)
#pragma unroll
    for (int j = 0; j < 8; ++j)
      outp[(ty * 8 + i) * 128 + tx * 8 + j] = acc[i][j];
}

__global__ void k_dwred(const float* __restrict__ DWP, const float* __restrict__ MI,
                        float* __restrict__ DW) {
  int zg = blockIdx.x;
  int g = zg & 15, z = zg >> 4;
  float mi = 1.0f + MI[g];
  const float* base = DWP + (size_t)zg * 2 * 16384;
  float* out = DW + (size_t)zg * 16384;
  for (int idx = threadIdx.x; idx < 16384; idx += 256) {
    float sv = base[idx] + base[(size_t)16384 + idx];
    sv *= mi;
    int oidx = (z == 1) ? ((idx & 127) * 128 + (idx >> 7)) : idx;
    out[oidx] = sv;
  }
}

// ---------------------------------------------------------------- Newton-Schulz 5

__global__ __launch_bounds__(1024) void k_ns5(float* __restrict__ DW) {
  __shared__ float Xs[128 * 128];
  __shared__ float Aw[128 * 128];
  const float NA[5] = {4.0848f, 3.9505f, 3.7418f, 2.8769f, 2.8366f};
  const float NB[5] = {-6.8946f, -6.3029f, -5.5913f, -3.1427f, -3.0525f};
  const float NC[5] = {2.927f, 2.6377f, 2.3037f, 1.2046f, 1.2012f};
  float* Gm = DW + (size_t)blockIdx.x * 16384;
  const int tid = threadIdx.x;
  const int ty = tid >> 5, tx = tid & 31;

  float psum = 0.0f;
#pragma unroll
  for (int r = 0; r < 16; ++r) {
    int idx = tid + r * 1024;
    float v = Gm[idx];
    Xs[idx] = v;
    psum = fmaf(v, v, psum);
  }
  psum = wave_sum64(psum);
  if ((tid & 63) == 0) Aw[tid >> 6] = psum;
  __syncthreads();
  if (tid == 0) {
    float tot = 0.0f;
    for (int i = 0; i < 16; ++i) tot += Aw[i];
    Aw[0] = 1.0f / (sqrtf(tot) + 1e-7f);
  }
  __syncthreads();
  float scl = Aw[0];
#pragma unroll
  for (int r = 0; r < 16; ++r) {
    int idx = tid + r * 1024;
    Xs[idx] *= scl;
  }
  __syncthreads();

#pragma unroll 1
  for (int it = 0; it < 5; ++it) {
    float ac = NA[it], bc = NB[it], cc = NC[it];
#pragma unroll
    for (int ii = 0; ii < 4; ++ii)
#pragma unroll
      for (int jj = 0; jj < 4; ++jj)
        Aw[(tx * 4 + jj) * 128 + ty * 4 + ii] = Xs[(ty * 4 + ii) * 128 + tx * 4 + jj];
    __syncthreads();
    float Ar[4][4];
#pragma unroll
    for (int ii = 0; ii < 4; ++ii)
#pragma unroll
      for (int jj = 0; jj < 4; ++jj) Ar[ii][jj] = 0.0f;
    for (int k = 0; k < 128; ++k) {
      float a[4], b[4];
#pragma unroll
      for (int ii = 0; ii < 4; ++ii) a[ii] = Xs[(ty * 4 + ii) * 128 + k];
#pragma unroll
      for (int jj = 0; jj < 4; ++jj) b[jj] = Aw[k * 128 + tx * 4 + jj];
#pragma unroll
      for (int ii = 0; ii < 4; ++ii)
#pragma unroll
        for (int jj = 0; jj < 4; ++jj) Ar[ii][jj] = fmaf(a[ii], b[jj], Ar[ii][jj]);
    }
    __syncthreads();
#pragma unroll
    for (int ii = 0; ii < 4; ++ii)
#pragma unroll
      for (int jj = 0; jj < 4; ++jj)
        Aw[(ty * 4 + ii) * 128 + tx * 4 + jj] = Ar[ii][jj];
    __syncthreads();
    float Bm[4][4];
#pragma unroll
    for (int ii = 0; ii < 4; ++ii)
#pragma unroll
      for (int jj = 0; jj < 4; ++jj) Bm[ii][jj] = 0.0f;
    for (int k = 0; k < 128; ++k) {
      float a[4], b[4];
#pragma unroll
      for (int ii = 0; ii < 4; ++ii) a[ii] = Aw[(ty * 4 + ii) * 128 + k];
#pragma unroll
      for (int jj = 0; jj < 4; ++jj) b[jj] = Aw[k * 128 + tx * 4 + jj];
#pragma unroll
      for (int ii = 0; ii < 4; ++ii)
#pragma unroll
        for (int jj = 0; jj < 4; ++jj) Bm[ii][jj] = fmaf(a[ii], b[jj], Bm[ii][jj]);
    }
#pragma unroll
    for (int ii = 0; ii < 4; ++ii)
#pragma unroll
      for (int jj = 0; jj < 4; ++jj) Bm[ii][jj] = fmaf(bc, Ar[ii][jj], cc * Bm[ii][jj]);
    __syncthreads();
#pragma unroll
    for (int ii = 0; ii < 4; ++ii)
#pragma unroll
      for (int jj = 0; jj < 4; ++jj)
        Aw[(ty * 4 + ii) * 128 + tx * 4 + jj] = Bm[ii][jj];
    __syncthreads();
    float Xn[4][4];
#pragma unroll
    for (int ii = 0; ii < 4; ++ii)
#pragma unroll
      for (int jj = 0; jj < 4; ++jj)
        Xn[ii][jj] = ac * Xs[(ty * 4 + ii) * 128 + tx * 4 + jj];
    for (int k = 0; k < 128; ++k) {
      float a[4], b[4];
#pragma unroll
      for (int ii = 0; ii < 4; ++ii) a[ii] = Aw[(ty * 4 + ii) * 128 + k];
#pragma unroll
      for (int jj = 0; jj < 4; ++jj) b[jj] = Xs[k * 128 + tx * 4 + jj];
#pragma unroll
      for (int ii = 0; ii < 4; ++ii)
#pragma unroll
        for (int jj = 0; jj < 4; ++jj) Xn[ii][jj] = fmaf(a[ii], b[jj], Xn[ii][jj]);
    }
    __syncthreads();
#pragma unroll
    for (int ii = 0; ii < 4; ++ii)
#pragma unroll
      for (int jj = 0; jj < 4; ++jj)
        Xs[(ty * 4 + ii) * 128 + tx * 4 + jj] = Xn[ii][jj];
    __syncthreads();
  }
#pragma unroll
  for (int r = 0; r < 16; ++r) {
    int idx = tid + r * 1024;
    Gm[idx] = Xs[idx];
  }
}

__global__ void k_apply(float* __restrict__ WW, const float* __restrict__ DW,
                        const float* __restrict__ WN0) {
  int rid = blockIdx.x;
  int l = threadIdx.x;
  float* wrow = WW + (size_t)rid * 128;
  const float* drow = DW + (size_t)rid * 128;
  float v0 = wrow[l] + drow[l];
  float v1 = wrow[l + 64] + drow[l + 64];
  float s = wave_sum64(v0 * v0 + v1 * v1);
  float f = WN0[rid] / (sqrtf(s) + 1e-5f);
  wrow[l] = v0 * f;
  wrow[l + 64] = v1 * f;
}

// ---------------------------------------------------------------- final projection (bf16 MFMA)

__global__ __launch_bounds__(256) void k_final_mfma(const unsigned short* __restrict__ U,
                                                    const unsigned short* __restrict__ Wot,
                                                    float* __restrict__ out) {
  __shared__ unsigned short Al[128 * 32];
  __shared__ unsigned short Bl[128 * 32];
  f32x4 acc[4][4];
#pragma unroll
  for (int m = 0; m < 4; ++m)
#pragma unroll
    for (int n = 0; n < 4; ++n) acc[m][n] = {};

  const int row0 = blockIdx.x * 128, col0 = blockIdx.y * 128;
  gemm_core(U, Wot, DMODEL, DMODEL, DMODEL, row0, col0, Al, Bl, acc);

  const int tid = threadIdx.x, w = tid >> 6, l = tid & 63;
  const int wr = (w >> 1) * 64, wc = (w & 1) * 64;
#pragma unroll
  for (int m = 0; m < 4; ++m)
#pragma unroll
    for (int j = 0; j < 4; ++j) {
      int t = row0 + wr + m * 16 + (l >> 4) * 4 + j;
      float* orow = out + (size_t)t * DMODEL + col0;
#pragma unroll
      for (int n = 0; n < 4; ++n)
        orow[wc + n * 16 + (l & 15)] = acc[m][n][j];
    }
}

// ---------------------------------------------------------------- launch

extern "C" void kernel_launch(void* const* d_in, const int* in_sizes, int n_in,
                              void* d_out, int out_size, void* d_ws, size_t ws_size,
                              hipStream_t stream) {
  (void)in_sizes; (void)n_in; (void)out_size;
  const float* x    = (const float*)d_in[0];
  const float* Wqkv = (const float*)d_in[1];
  const float* Wlr  = (const float*)d_in[2];
  const float* Wo   = (const float*)d_in[3];
  const float* Wm   = (const float*)d_in[4];
  const float* bm   = (const float*)d_in[5];
  const float* Wsc  = (const float*)d_in[6];
  const float* bs   = (const float*)d_in[7];
  const float* lng  = (const float*)d_in[8];
  const float* lnb  = (const float*)d_in[9];
  const float* w0   = (const float*)d_in[10];
  const float* w1   = (const float*)d_in[11];
  const float* w2   = (const float*)d_in[12];

  // Q lives in d_out (fp32); its last read (k_out2, chunk 3) precedes k_final's write.
  float* Q = (float*)d_out;

  float* ws = (float*)d_ws;
  size_t off = 0;
  auto alloc = [&](size_t n) { float* p = ws + off; off += n; return p; };
  float* Km   = alloc((size_t)NH * LSEQ * HD);
  float* V    = alloc((size_t)NH * LSEQ * HD);
  float* Uf   = alloc((size_t)LSEQ * DMODEL / 2);   // U stored as bf16
  float* LR   = alloc((size_t)3 * NH * LSEQ);
  float* MOM  = alloc((size_t)NH * LSEQ);
  float* SCL  = alloc((size_t)NH * LSEQ);
  float* WW   = alloc((size_t)3 * NH * HD * HD);
  float* WN0  = alloc((size_t)3 * NH * HD);
  float* BUF  = alloc((size_t)3 * NH * HD * CH);    // chunk loop scratch
  float* DW   = alloc((size_t)3 * NH * HD * HD);
  float* DWP  = alloc((size_t)3 * NH * 2 * HD * HD);
  float* MI   = alloc((size_t)16);
  if (off * sizeof(float) > ws_size) return;        // clean failure instead of OOB

  unsigned short* U = (unsigned short*)Uf;
  unsigned short* xb  = (unsigned short*)BUF;                                   // aliases BUF (dead until loop)
  unsigned short* Wqt = (unsigned short*)(BUF + (size_t)LSEQ * DMODEL / 2);
  unsigned short* Wot = (unsigned short*)BUF;                                   // aliases BUF (dead after loop)

  k_init_w<<<3 * NH * HD, 64, 0, stream>>>(w0, w1, w2, WW, WN0);
  k_cast<<<2048, 256, 0, stream>>>(x, xb, LSEQ * DMODEL / 4);
  k_tcast<<<dim3(3 * DMODEL / 64, DMODEL / 64), 256, 0, stream>>>(Wqkv, Wqt, DMODEL, 3 * DMODEL);
  k_qkv_mfma<<<dim3(LSEQ / 128, 48), 256, 0, stream>>>(xb, Wqt, Q, Km, V);
  k_l2norm<<<2 * NH * LSEQ / 4, 256, 0, stream>>>(Q, Km);
  k_lrms2<<<LSEQ / 32, 256, 0, stream>>>(x, Wlr, Wm, bm, Wsc, bs, LR, MOM, SCL);

  for (int c = 0; c < 4; ++c) {
    int s = c * CH;
    k_out2<<<dim3(CH / 128, NH), 256, 0, stream>>>(WW, Q, SCL, lng, lnb, U, s);
    if (c < 3) {
      k_front<<<dim3(CH / 128, NH, 3), 256, 0, stream>>>(WW, Km, V, BUF, s);
      k_elem<<<(NH * HD * CH) / (256 * 4), 256, 0, stream>>>(
          BUF, BUF + (size_t)NH * HD * CH, BUF + (size_t)2 * NH * HD * CH);
      k_mom_mean<<<NH, 256, 0, stream>>>(MOM, MI, s);
      k_dwp<<<dim3(2, NH, 3), 256, 0, stream>>>(BUF, Km, V, LR, DWP, s);
      k_dwred<<<3 * NH, 256, 0, stream>>>(DWP, MI, DW);
      k_ns5<<<3 * NH, 1024, 0, stream>>>(DW);
      k_apply<<<3 * NH * HD, 64, 0, stream>>>(WW, DW, WN0);
    }
  }
  k_tcast<<<dim3(DMODEL / 64, DMODEL / 64), 256, 0, stream>>>(Wo, Wot, DMODEL, DMODEL);
  k_final_mfma<<<dim3(LSEQ / 128, DMODEL / 128), 256, 0, stream>>>(U, Wot, (float*)d_out);
}

// Round 5
// 1922.477 us; speedup vs baseline: 3.1201x; 1.1333x over previous
//
#include <hip/hip_runtime.h>
#include <hip/hip_bf16.h>
#include <cstdint>
#include <cstddef>

#define LSEQ   8192
#define DMODEL 2048
#define NH     16      // heads == groups
#define HD     128     // head dim == hidden dim
#define CH     2048    // chunk length (group-space positions)

typedef __attribute__((ext_vector_type(8))) __bf16 bf16x8;
typedef __attribute__((ext_vector_type(4))) float f32x4;

// ---------------------------------------------------------------- helpers

__device__ __forceinline__ float wave_sum64(float v) {
#pragma unroll
  for (int m = 32; m; m >>= 1) v += __shfl_xor(v, m, 64);
  return v;
}

__device__ __forceinline__ float sigm(float x) { return 1.0f / (1.0f + expf(-x)); }

// RTNE float -> bf16 bits
__device__ __forceinline__ unsigned short f2bf(float f) {
  unsigned int u = __float_as_uint(f);
  u += 0x7FFFu + ((u >> 16) & 1u);
  return (unsigned short)(u >> 16);
}

// async global->LDS, 16B per lane. lds dest is wave-uniform base; HW adds lane*16.
__device__ __forceinline__ void gload_lds16(const void* g, void* l) {
  __builtin_amdgcn_global_load_lds((__attribute__((address_space(1))) void*)(g),
                                   (__attribute__((address_space(3))) void*)(l), 16, 0, 0);
}

// 8x8 microtile inner product over a 32-deep LDS K-slice (fp32 path).
__device__ __forceinline__ void mm8x8(const float (*__restrict__ As)[132],
                                      const float (*__restrict__ Bs)[132],
                                      int ty, int tx, float acc[8][8]) {
#pragma unroll
  for (int k2 = 0; k2 < 32; ++k2) {
    float a[8], b[8];
#pragma unroll
    for (int i = 0; i < 8; ++i) a[i] = As[k2][ty * 8 + i];
#pragma unroll
    for (int j = 0; j < 8; ++j) b[j] = Bs[k2][tx * 8 + j];
#pragma unroll
    for (int i = 0; i < 8; ++i)
#pragma unroll
      for (int j = 0; j < 8; ++j) acc[i][j] = fmaf(a[i], b[j], acc[i][j]);
  }
}

// ---------------------------------------------------------------- casts

__global__ void k_cast(const float* __restrict__ X, unsigned short* __restrict__ Xb, int n4) {
  int i = blockIdx.x * 256 + threadIdx.x;
  int stride = gridDim.x * 256;
  for (; i < n4; i += stride) {
    float4 v = ((const float4*)X)[i];
    ushort4 o;
    o.x = f2bf(v.x); o.y = f2bf(v.y); o.z = f2bf(v.z); o.w = f2bf(v.w);
    ((ushort4*)Xb)[i] = o;
  }
}

// W (K x N, fp32) -> Wt (N x K, bf16). grid (N/64, K/64), block 256.
__global__ void k_tcast(const float* __restrict__ W, unsigned short* __restrict__ Wt,
                        int K, int N) {
  __shared__ float t[64][65];
  const int n0 = blockIdx.x * 64, k0 = blockIdx.y * 64;
  const int tid = threadIdx.x;
  const int cx = tid & 63, ry = tid >> 6;
#pragma unroll
  for (int r = 0; r < 16; ++r) {
    int row = ry + r * 4;
    t[row][cx] = W[(size_t)(k0 + row) * N + n0 + cx];
  }
  __syncthreads();
#pragma unroll
  for (int r = 0; r < 16; ++r) {
    int nn = ry + r * 4;
    Wt[(size_t)(n0 + nn) * K + k0 + cx] = f2bf(t[cx][nn]);
  }
}

// ---------------------------------------------------------------- bf16 MFMA GEMM core (m97 style)

__device__ __forceinline__ void gemm_core(const unsigned short* __restrict__ A,
                                          const unsigned short* __restrict__ B,
                                          int K, int ldA, int ldB, int row0, int col0,
                                          unsigned short* Al, unsigned short* Bl,
                                          f32x4 acc[4][4]) {
  const int tid = threadIdx.x;
  const int w = tid >> 6, l = tid & 63;
  const int lrow = l & 15, lk = (l >> 4) * 8;
  const int wr = (w >> 1) * 64, wc = (w & 1) * 64;
  const int srow = l >> 2, skk = (l & 3) * 8;

  for (int kk = 0; kk < K; kk += 32) {
#pragma unroll
    for (int q = 0; q < 2; ++q) {
      int c = w * 2 + q;
      gload_lds16(A + (size_t)(row0 + c * 16 + srow) * ldA + kk + skk, &Al[c * 512]);
      gload_lds16(B + (size_t)(col0 + c * 16 + srow) * ldB + kk + skk, &Bl[c * 512]);
    }
    __syncthreads();
    bf16x8 af[4], bfr[4];
#pragma unroll
    for (int m = 0; m < 4; ++m)
      af[m] = *(const bf16x8*)&Al[(wr + m * 16 + lrow) * 32 + lk];
#pragma unroll
    for (int n = 0; n < 4; ++n)
      bfr[n] = *(const bf16x8*)&Bl[(wc + n * 16 + lrow) * 32 + lk];
#pragma unroll
    for (int m = 0; m < 4; ++m)
#pragma unroll
      for (int n = 0; n < 4; ++n)
        acc[m][n] = __builtin_amdgcn_mfma_f32_16x16x32_bf16(af[m], bfr[n], acc[m][n], 0, 0, 0);
    __syncthreads();
  }
}

// ---------------------------------------------------------------- init w + row norms

__global__ void k_init_w(const float* __restrict__ w0, const float* __restrict__ w1,
                         const float* __restrict__ w2, float* __restrict__ WW,
                         float* __restrict__ WN0) {
  int rid = blockIdx.x;
  int m = rid >> 11;
  int gr = rid & 2047;
  const float* src = (m == 0) ? w0 : (m == 1) ? w1 : w2;
  const float* row = src + (size_t)gr * HD;
  float* drow = WW + ((size_t)m * 2048 + gr) * HD;
  int l = threadIdx.x;
  float v0 = row[l], v1 = row[l + 64];
  drow[l] = v0; drow[l + 64] = v1;
  float s = wave_sum64(v0 * v0 + v1 * v1);
  if (l == 0) WN0[rid] = sqrtf(s);
}

// ---------------------------------------------------------------- qkv projection (bf16 MFMA)

__global__ __launch_bounds__(256) void k_qkv_mfma(const unsigned short* __restrict__ xb,
                                                  const unsigned short* __restrict__ Wqt,
                                                  float* __restrict__ Q, float* __restrict__ Km,
                                                  float* __restrict__ V) {
  __shared__ unsigned short Al[128 * 32];
  __shared__ unsigned short Bl[128 * 32];
  f32x4 acc[4][4];
#pragma unroll
  for (int m = 0; m < 4; ++m)
#pragma unroll
    for (int n = 0; n < 4; ++n) acc[m][n] = {};

  gemm_core(xb, Wqt, DMODEL, DMODEL, DMODEL, blockIdx.x * 128, blockIdx.y * 128, Al, Bl, acc);

  const int ct = blockIdx.y, hh = ct / 3, which = ct % 3;
  float* dst = (which == 0) ? Q : (which == 1) ? Km : V;
  const int tid = threadIdx.x, w = tid >> 6, l = tid & 63;
  const int wr = (w >> 1) * 64, wc = (w & 1) * 64;
#pragma unroll
  for (int m = 0; m < 4; ++m)
#pragma unroll
    for (int j = 0; j < 4; ++j) {
      int t = blockIdx.x * 128 + wr + m * 16 + (l >> 4) * 4 + j;
      int fth = t * NH + hh;
      int g = fth >> 13, tp = fth & 8191;
      float* drow = dst + ((size_t)g * LSEQ + tp) * HD;
#pragma unroll
      for (int n = 0; n < 4; ++n) {
        float v = acc[m][n][j];
        drow[wc + n * 16 + (l & 15)] = v * sigm(v);
      }
    }
}

// normalize Q and K rows in place.
__global__ void k_l2norm(float* __restrict__ Q, float* __restrict__ Km) {
  int rid = blockIdx.x * 4 + (threadIdx.x >> 6);
  int l = threadIdx.x & 63;
  float* base = (rid < NH * LSEQ) ? Q : Km;
  int r = (rid < NH * LSEQ) ? rid : rid - NH * LSEQ;
  float* row = base + (size_t)r * HD;
  float v0 = row[l], v1 = row[l + 64];
  float s = wave_sum64(v0 * v0 + v1 * v1);
  float f = 1.0f / (sqrtf(s) + 1e-5f);
  row[l] = v0 * f;
  row[l + 64] = v1 * f;
}

// ---------------------------------------------------------------- lr / scale (tiled fp32 GEMM)
// 64 output cols: 0..47 -> lr (softplus), 48..63 -> scale (silu + bias).
// momentum dropped: dw *= (1+m_i) is a per-matrix positive scalar, cancelled by
// NS5's Frobenius normalization (eps 1e-7 vs ||dw||~26 -> relative 4e-9).
// grid 128 (64 tokens each), block 256 = 16x16 threads, 4x4 microtile.
__global__ __launch_bounds__(256) void k_lrms4(const float* __restrict__ x,
                                               const float* __restrict__ Wlr,
                                               const float* __restrict__ Wsc, const float* __restrict__ bs,
                                               float* __restrict__ LR, float* __restrict__ SCL) {
  __shared__ float Xs[32][68];   // [k][tok]
  __shared__ float Ws[32][68];   // [k][col]
  const int t0 = blockIdx.x * 64;
  const int tid = threadIdx.x;
  const int kk = tid & 31, sub = tid >> 5;
  const int c64 = tid & 63, k0 = tid >> 6;
  const int ty = tid >> 4, tx = tid & 15;
  float acc[4][4];
#pragma unroll
  for (int i = 0; i < 4; ++i)
#pragma unroll
    for (int j = 0; j < 4; ++j) acc[i][j] = 0.0f;

  for (int ks = 0; ks < DMODEL; ks += 32) {
#pragma unroll
    for (int r = 0; r < 8; ++r) {
      int t = sub + r * 8;
      Xs[kk][t] = x[(size_t)(t0 + t) * DMODEL + ks + kk];
    }
#pragma unroll
    for (int r = 0; r < 8; ++r) {
      int k2 = k0 + r * 4;
      float wv = (c64 < 48) ? Wlr[(size_t)(ks + k2) * 48 + c64]
                            : Wsc[(size_t)(ks + k2) * 16 + (c64 - 48)];
      Ws[k2][c64] = wv;
    }
    __syncthreads();
#pragma unroll
    for (int k2 = 0; k2 < 32; ++k2) {
      float4 a = *(const float4*)&Xs[k2][ty * 4];
      float4 b = *(const float4*)&Ws[k2][tx * 4];
      const float* ap = (const float*)&a;
      const float* bp = (const float*)&b;
#pragma unroll
      for (int i = 0; i < 4; ++i)
#pragma unroll
        for (int j = 0; j < 4; ++j) acc[i][j] = fmaf(ap[i], bp[j], acc[i][j]);
    }
    __syncthreads();
  }

  const float base_lr_inv = 0.01f + logf(-expm1f(-0.01f));
#pragma unroll
  for (int i = 0; i < 4; ++i) {
    int t = t0 + ty * 4 + i;
#pragma unroll
    for (int j = 0; j < 4; ++j) {
      int c = tx * 4 + j;
      float dot = acc[i][j];
      if (c < 48) {
        float v = dot + base_lr_inv;
        float sp = fmaxf(v, 0.0f) + log1pf(expf(-fabsf(v)));
        LR[(size_t)c * LSEQ + t] = sp;      // (c>>4)*NH + (c&15) == c
      } else {
        float v = dot + bs[c - 48];
        SCL[(size_t)(c - 48) * LSEQ + t] = v * sigm(v);
      }
    }
  }
}

// ---------------------------------------------------------------- per-chunk output (bf16 MFMA + fused LN/scale)

__device__ __forceinline__ void st_sw(unsigned short* base, int row, int col, unsigned short v) {
  int byte = (row * 256 + col * 2) ^ ((row & 7) << 4);
  *(unsigned short*)((char*)base + byte) = v;
}
__device__ __forceinline__ bf16x8 ld_sw(const unsigned short* base, int row, int kcol) {
  int byte = (row * 256 + kcol * 2) ^ ((row & 7) << 4);
  return *(const bf16x8*)((const char*)base + byte);
}

__device__ __forceinline__ void stage_sw(const float* __restrict__ src, int ld,
                                         unsigned short* dst, int tid) {
#pragma unroll
  for (int p = 0; p < 16; ++p) {
    int row = p * 8 + (tid >> 5);
    int col = (tid & 31) * 4;
    float4 v = *(const float4*)(src + (size_t)row * ld + col);
    int byte = (row * 256 + col * 2) ^ ((row & 7) << 4);
    unsigned short* d = (unsigned short*)((char*)dst + byte);
    d[0] = f2bf(v.x); d[1] = f2bf(v.y); d[2] = f2bf(v.z); d[3] = f2bf(v.w);
  }
}

// grid (CH/128, NH), block 256. o = w1 @ (silu(w0@q^T) * (w2@q^T)), LN, scale -> U (bf16)
__global__ __launch_bounds__(256) void k_out2(const float* __restrict__ WW,
                                              const float* __restrict__ Q,
                                              const float* __restrict__ SCL,
                                              const float* __restrict__ lng,
                                              const float* __restrict__ lnb,
                                              unsigned short* __restrict__ U, int s) {
  __shared__ __align__(16) char smem[131072];
  unsigned short* Qs  = (unsigned short*)smem;            // 32KB
  unsigned short* W0s = (unsigned short*)(smem + 32768);  // W0, then W1
  unsigned short* W2s = (unsigned short*)(smem + 65536);
  unsigned short* GHs = (unsigned short*)(smem + 98304);
  float* Os = (float*)smem;                               // [128][132] post-pass2

  const int g = blockIdx.y;
  const int t0 = blockIdx.x * 128;
  const int tid = threadIdx.x;
  const int w = tid >> 6, l = tid & 63;
  const int lrow = l & 15, lk8 = (l >> 4) * 8;
  const int wr = (w >> 1) * 64, wc = (w & 1) * 64;

  const float* Qg  = Q + ((size_t)g * LSEQ + s + t0) * HD;
  const float* w0g = WW + ((size_t)0 * 2048 + g * 128) * 128;
  const float* w1g = WW + ((size_t)1 * 2048 + g * 128) * 128;
  const float* w2g = WW + ((size_t)2 * 2048 + g * 128) * 128;

  stage_sw(Qg, HD, Qs, tid);
  stage_sw(w0g, 128, W0s, tid);
  stage_sw(w2g, 128, W2s, tid);
  __syncthreads();

  f32x4 ga[4][4], ha[4][4];
#pragma unroll
  for (int m = 0; m < 4; ++m)
#pragma unroll
    for (int n = 0; n < 4; ++n) { ga[m][n] = {}; ha[m][n] = {}; }
#pragma unroll
  for (int kk = 0; kk < 128; kk += 32) {
    bf16x8 af[4], b0[4], b2[4];
#pragma unroll
    for (int m = 0; m < 4; ++m) af[m] = ld_sw(Qs, wr + m * 16 + lrow, kk + lk8);
#pragma unroll
    for (int n = 0; n < 4; ++n) {
      b0[n] = ld_sw(W0s, wc + n * 16 + lrow, kk + lk8);
      b2[n] = ld_sw(W2s, wc + n * 16 + lrow, kk + lk8);
    }
#pragma unroll
    for (int m = 0; m < 4; ++m)
#pragma unroll
      for (int n = 0; n < 4; ++n) {
        ga[m][n] = __builtin_amdgcn_mfma_f32_16x16x32_bf16(af[m], b0[n], ga[m][n], 0, 0, 0);
        ha[m][n] = __builtin_amdgcn_mfma_f32_16x16x32_bf16(af[m], b2[n], ha[m][n], 0, 0, 0);
      }
  }
#pragma unroll
  for (int m = 0; m < 4; ++m)
#pragma unroll
    for (int n = 0; n < 4; ++n)
#pragma unroll
      for (int j = 0; j < 4; ++j) {
        int row = wr + m * 16 + (l >> 4) * 4 + j;
        int col = wc + n * 16 + (l & 15);
        float gv = ga[m][n][j];
        st_sw(GHs, row, col, f2bf(gv * sigm(gv) * ha[m][n][j]));
      }
  __syncthreads();
  stage_sw(w1g, 128, W0s, tid);
  __syncthreads();

  f32x4 oa[4][4];
#pragma unroll
  for (int m = 0; m < 4; ++m)
#pragma unroll
    for (int n = 0; n < 4; ++n) oa[m][n] = {};
#pragma unroll
  for (int kk = 0; kk < 128; kk += 32) {
    bf16x8 af[4], b1[4];
#pragma unroll
    for (int m = 0; m < 4; ++m) af[m] = ld_sw(GHs, wr + m * 16 + lrow, kk + lk8);
#pragma unroll
    for (int n = 0; n < 4; ++n) b1[n] = ld_sw(W0s, wc + n * 16 + lrow, kk + lk8);
#pragma unroll
    for (int m = 0; m < 4; ++m)
#pragma unroll
      for (int n = 0; n < 4; ++n)
        oa[m][n] = __builtin_amdgcn_mfma_f32_16x16x32_bf16(af[m], b1[n], oa[m][n], 0, 0, 0);
  }
  __syncthreads();
#pragma unroll
  for (int m = 0; m < 4; ++m)
#pragma unroll
    for (int n = 0; n < 4; ++n)
#pragma unroll
      for (int j = 0; j < 4; ++j) {
        int row = wr + m * 16 + (l >> 4) * 4 + j;
        int col = wc + n * 16 + (l & 15);
        Os[row * 132 + col] = oa[m][n][j];
      }
  __syncthreads();

  const int tok = tid >> 1, part = tid & 1;
  const float* orow = Os + tok * 132 + part * 64;
  float sum = 0.0f;
#pragma unroll
  for (int q = 0; q < 16; ++q) {
    float4 v = *(const float4*)(orow + q * 4);
    sum += (v.x + v.y) + (v.z + v.w);
  }
  sum += __shfl_xor(sum, 1, 64);
  float mu = sum * (1.0f / 128.0f);
  float vs = 0.0f;
#pragma unroll
  for (int q = 0; q < 16; ++q) {
    float4 v = *(const float4*)(orow + q * 4);
    float d0 = v.x - mu, d1 = v.y - mu, d2 = v.z - mu, d3 = v.w - mu;
    vs += d0 * d0 + d1 * d1 + d2 * d2 + d3 * d3;
  }
  vs += __shfl_xor(vs, 1, 64);
  float rstd = rsqrtf(vs * (1.0f / 128.0f) + 1e-6f);
  int tabs = s + t0 + tok;
  float sc = SCL[(size_t)g * LSEQ + tabs];
  unsigned short* urow = U + (size_t)tabs * DMODEL + g * HD + part * 64;
#pragma unroll
  for (int q = 0; q < 16; ++q) {
    float4 v = *(const float4*)(orow + q * 4);
    int d = part * 64 + q * 4;
    ushort4 o;
    o.x = f2bf(((v.x - mu) * rstd * lng[d + 0] + lnb[d + 0]) * sc);
    o.y = f2bf(((v.y - mu) * rstd * lng[d + 1] + lnb[d + 1]) * sc);
    o.z = f2bf(((v.z - mu) * rstd * lng[d + 2] + lnb[d + 2]) * sc);
    o.w = f2bf(((v.w - mu) * rstd * lng[d + 3] + lnb[d + 3]) * sc);
    *(ushort4*)(urow + q * 4) = o;
  }
}

// ---------------------------------------------------------------- chunk backward front GEMMs (fp32)

__global__ __launch_bounds__(256) void k_front(const float* __restrict__ WW,
                                               const float* __restrict__ Km,
                                               const float* __restrict__ V,
                                               float* __restrict__ BUF, int s) {
  __shared__ float As[32][132];
  __shared__ float Bs[32][132];
  const int tt0 = blockIdx.x * 128;
  const int g = blockIdx.y;
  const int z = blockIdx.z;
  const int tid = threadIdx.x;
  const int ty = tid >> 4, tx = tid & 15;
  const int kk = tid & 31, sub = tid >> 5;
  const int wsel = (z == 0) ? 0 : (z == 1) ? 2 : 1;
  const float* wg = WW + ((size_t)wsel * 2048 + g * 128) * 128;
  const float* X = (z == 2) ? V : Km;
  float* out = BUF + (size_t)z * (NH * 128 * CH) + (size_t)g * 128 * CH;

  float acc[8][8];
#pragma unroll
  for (int i = 0; i < 8; ++i)
#pragma unroll
    for (int j = 0; j < 8; ++j) acc[i][j] = 0.0f;

  for (int ks = 0; ks < 128; ks += 32) {
    if (z != 2) {
#pragma unroll
      for (int r = 0; r < 16; ++r) {
        int e = sub + r * 8;
        As[kk][e] = wg[(size_t)e * 128 + ks + kk];
      }
    } else {
#pragma unroll
      for (int r = 0; r < 16; ++r) {
        int idx = tid + r * 256;
        int k2 = idx >> 7, e = idx & 127;
        As[k2][e] = wg[(size_t)(ks + k2) * 128 + e];
      }
    }
#pragma unroll
    for (int r = 0; r < 16; ++r) {
      int t = sub + r * 8;
      Bs[kk][t] = X[((size_t)g * LSEQ + s + tt0 + t) * HD + ks + kk];
    }
    __syncthreads();
    mm8x8(As, Bs, ty, tx, acc);
    __syncthreads();
  }
#pragma unroll
  for (int i = 0; i < 8; ++i)
#pragma unroll
    for (int j = 0; j < 8; ++j)
      out[(size_t)(ty * 8 + i) * CH + tt0 + tx * 8 + j] = acc[i][j];
}

__global__ void k_elem(float* __restrict__ BA, float* __restrict__ BB, float* __restrict__ BC) {
  size_t i = ((size_t)blockIdx.x * 256 + threadIdx.x) * 4;
  float4 a = *(const float4*)(BA + i);
  float4 b = *(const float4*)(BB + i);
  float4 c = *(const float4*)(BC + i);
  float4 ha, hb2, hc;
  float* pa = (float*)&a; float* pb = (float*)&b; float* pc = (float*)&c;
  float* oa = (float*)&ha; float* ob = (float*)&hb2; float* oc = (float*)&hc;
#pragma unroll
  for (int k = 0; k < 4; ++k) {
    float gb = pa[k], hb = pb[k], dh = pc[k];
    float sg = sigm(gb);
    float sgb = gb * sg;
    float hid = sgb * hb;
    float dgate = dh * hb;
    float dgb = dgate * sg * (1.0f + gb * (1.0f - sg));
    float dhb = dh * sgb;
    oa[k] = hid; ob[k] = dgb; oc[k] = dhb;
  }
  *(float4*)(BA + i) = ha;
  *(float4*)(BB + i) = hb2;
  *(float4*)(BC + i) = hc;
}

// partial dW GEMMs over 256-token slices. grid (8, NH, 3).
__global__ __launch_bounds__(256) void k_dwp(const float* __restrict__ BUF,
                                             const float* __restrict__ Km,
                                             const float* __restrict__ V,
                                             const float* __restrict__ LR,
                                             float* __restrict__ DWP, int s) {
  __shared__ float As[32][132];
  __shared__ float Bs[32][132];
  const int p = blockIdx.x;
  const int g = blockIdx.y;
  const int z = blockIdx.z;
  const int tid = threadIdx.x;
  const int ty = tid >> 4, tx = tid & 15;
  const int kk = tid & 31, sub = tid >> 5;
  const int msel = (z == 0) ? 1 : (z == 1) ? 0 : 2;
  const float* M = BUF + (size_t)msel * (NH * 128 * CH) + (size_t)g * 128 * CH;
  const float* N = (z == 1) ? V : Km;
  const float* lr = LR + (size_t)(z * NH + g) * LSEQ;
  const int ts = p * 256;

  float acc[8][8];
#pragma unroll
  for (int i = 0; i < 8; ++i)
#pragma unroll
    for (int j = 0; j < 8; ++j) acc[i][j] = 0.0f;

  for (int ks = 0; ks < 256; ks += 32) {
#pragma unroll
    for (int r = 0; r < 16; ++r) {
      int o1 = sub + r * 8;
      As[kk][o1] = M[(size_t)o1 * CH + ts + ks + kk];
    }
#pragma unroll
    for (int r = 0; r < 16; ++r) {
      int idx = tid + r * 256;
      int k2 = idx >> 7, o2 = idx & 127;
      int tok = s + ts + ks + k2;
      Bs[k2][o2] = N[((size_t)g * LSEQ + tok) * HD + o2] * lr[tok];
    }
    __syncthreads();
    mm8x8(As, Bs, ty, tx, acc);
    __syncthreads();
  }
  float* outp = DWP + (((size_t)(z * NH + g)) * 8 + p) * 16384;
#pragma unroll
  for (int i = 0; i < 8; ++i)
#pragma unroll
    for (int j = 0; j < 8; ++j)
      outp[(ty * 8 + i) * 128 + tx * 8 + j] = acc[i][j];
}

// reduce 8 partials; transpose dw1 (z==1).
__global__ void k_dwred(const float* __restrict__ DWP, float* __restrict__ DW) {
  int zg = blockIdx.x;
  int z = zg >> 4;
  const float* base = DWP + (size_t)zg * 8 * 16384;
  float* out = DW + (size_t)zg * 16384;
  for (int idx = threadIdx.x; idx < 16384; idx += 256) {
    float sv = 0.0f;
#pragma unroll
    for (int pp = 0; pp < 8; ++pp) sv += base[(size_t)pp * 16384 + idx];
    int oidx = (z == 1) ? ((idx & 127) * 128 + (idx >> 7)) : idx;
    out[oidx] = sv;
  }
}

// ---------------------------------------------------------------- Newton-Schulz 5

__global__ __launch_bounds__(1024) void k_ns5(float* __restrict__ DW) {
  __shared__ float Xs[128 * 128];
  __shared__ float Aw[128 * 128];
  const float NA[5] = {4.0848f, 3.9505f, 3.7418f, 2.8769f, 2.8366f};
  const float NB[5] = {-6.8946f, -6.3029f, -5.5913f, -3.1427f, -3.0525f};
  const float NC[5] = {2.927f, 2.6377f, 2.3037f, 1.2046f, 1.2012f};
  float* Gm = DW + (size_t)blockIdx.x * 16384;
  const int tid = threadIdx.x;
  const int ty = tid >> 5, tx = tid & 31;

  float psum = 0.0f;
#pragma unroll
  for (int r = 0; r < 16; ++r) {
    int idx = tid + r * 1024;
    float v = Gm[idx];
    Xs[idx] = v;
    psum = fmaf(v, v, psum);
  }
  psum = wave_sum64(psum);
  if ((tid & 63) == 0) Aw[tid >> 6] = psum;
  __syncthreads();
  if (tid == 0) {
    float tot = 0.0f;
    for (int i = 0; i < 16; ++i) tot += Aw[i];
    Aw[0] = 1.0f / (sqrtf(tot) + 1e-7f);
  }
  __syncthreads();
  float scl = Aw[0];
#pragma unroll
  for (int r = 0; r < 16; ++r) {
    int idx = tid + r * 1024;
    Xs[idx] *= scl;
  }
  __syncthreads();

#pragma unroll 1
  for (int it = 0; it < 5; ++it) {
    float ac = NA[it], bc = NB[it], cc = NC[it];
#pragma unroll
    for (int ii = 0; ii < 4; ++ii)
#pragma unroll
      for (int jj = 0; jj < 4; ++jj)
        Aw[(tx * 4 + jj) * 128 + ty * 4 + ii] = Xs[(ty * 4 + ii) * 128 + tx * 4 + jj];
    __syncthreads();
    float Ar[4][4];
#pragma unroll
    for (int ii = 0; ii < 4; ++ii)
#pragma unroll
      for (int jj = 0; jj < 4; ++jj) Ar[ii][jj] = 0.0f;
    for (int k = 0; k < 128; ++k) {
      float a[4], b[4];
#pragma unroll
      for (int ii = 0; ii < 4; ++ii) a[ii] = Xs[(ty * 4 + ii) * 128 + k];
#pragma unroll
      for (int jj = 0; jj < 4; ++jj) b[jj] = Aw[k * 128 + tx * 4 + jj];
#pragma unroll
      for (int ii = 0; ii < 4; ++ii)
#pragma unroll
        for (int jj = 0; jj < 4; ++jj) Ar[ii][jj] = fmaf(a[ii], b[jj], Ar[ii][jj]);
    }
    __syncthreads();
#pragma unroll
    for (int ii = 0; ii < 4; ++ii)
#pragma unroll
      for (int jj = 0; jj < 4; ++jj)
        Aw[(ty * 4 + ii) * 128 + tx * 4 + jj] = Ar[ii][jj];
    __syncthreads();
    float Bm[4][4];
#pragma unroll
    for (int ii = 0; ii < 4; ++ii)
#pragma unroll
      for (int jj = 0; jj < 4; ++jj) Bm[ii][jj] = 0.0f;
    for (int k = 0; k < 128; ++k) {
      float a[4], b[4];
#pragma unroll
      for (int ii = 0; ii < 4; ++ii) a[ii] = Aw[(ty * 4 + ii) * 128 + k];
#pragma unroll
      for (int jj = 0; jj < 4; ++jj) b[jj] = Aw[k * 128 + tx * 4 + jj];
#pragma unroll
      for (int ii = 0; ii < 4; ++ii)
#pragma unroll
        for (int jj = 0; jj < 4; ++jj) Bm[ii][jj] = fmaf(a[ii], b[jj], Bm[ii][jj]);
    }
#pragma unroll
    for (int ii = 0; ii < 4; ++ii)
#pragma unroll
      for (int jj = 0; jj < 4; ++jj) Bm[ii][jj] = fmaf(bc, Ar[ii][jj], cc * Bm[ii][jj]);
    __syncthreads();
#pragma unroll
    for (int ii = 0; ii < 4; ++ii)
#pragma unroll
      for (int jj = 0; jj < 4; ++jj)
        Aw[(ty * 4 + ii) * 128 + tx * 4 + jj] = Bm[ii][jj];
    __syncthreads();
    float Xn[4][4];
#pragma unroll
    for (int ii = 0; ii < 4; ++ii)
#pragma unroll
      for (int jj = 0; jj < 4; ++jj)
        Xn[ii][jj] = ac * Xs[(ty * 4 + ii) * 128 + tx * 4 + jj];
    for (int k = 0; k < 128; ++k) {
      float a[4], b[4];
#pragma unroll
      for (int ii = 0; ii < 4; ++ii) a[ii] = Aw[(ty * 4 + ii) * 128 + k];
#pragma unroll
      for (int jj = 0; jj < 4; ++jj) b[jj] = Xs[k * 128 + tx * 4 + jj];
#pragma unroll
      for (int ii = 0; ii < 4; ++ii)
#pragma unroll
        for (int jj = 0; jj < 4; ++jj) Xn[ii][jj] = fmaf(a[ii], b[jj], Xn[ii][jj]);
    }
    __syncthreads();
#pragma unroll
    for (int ii = 0; ii < 4; ++ii)
#pragma unroll
      for (int jj = 0; jj < 4; ++jj)
        Xs[(ty * 4 + ii) * 128 + tx * 4 + jj] = Xn[ii][jj];
    __syncthreads();
  }
#pragma unroll
  for (int r = 0; r < 16; ++r) {
    int idx = tid + r * 1024;
    Gm[idx] = Xs[idx];
  }
}

__global__ void k_apply(float* __restrict__ WW, const float* __restrict__ DW,
                        const float* __restrict__ WN0) {
  int rid = blockIdx.x;
  int l = threadIdx.x;
  float* wrow = WW + (size_t)rid * 128;
  const float* drow = DW + (size_t)rid * 128;
  float v0 = wrow[l] + drow[l];
  float v1 = wrow[l + 64] + drow[l + 64];
  float s = wave_sum64(v0 * v0 + v1 * v1);
  float f = WN0[rid] / (sqrtf(s) + 1e-5f);
  wrow[l] = v0 * f;
  wrow[l + 64] = v1 * f;
}

// ---------------------------------------------------------------- final projection (bf16 MFMA)

__global__ __launch_bounds__(256) void k_final_mfma(const unsigned short* __restrict__ U,
                                                    const unsigned short* __restrict__ Wot,
                                                    float* __restrict__ out) {
  __shared__ unsigned short Al[128 * 32];
  __shared__ unsigned short Bl[128 * 32];
  f32x4 acc[4][4];
#pragma unroll
  for (int m = 0; m < 4; ++m)
#pragma unroll
    for (int n = 0; n < 4; ++n) acc[m][n] = {};

  const int row0 = blockIdx.x * 128, col0 = blockIdx.y * 128;
  gemm_core(U, Wot, DMODEL, DMODEL, DMODEL, row0, col0, Al, Bl, acc);

  const int tid = threadIdx.x, w = tid >> 6, l = tid & 63;
  const int wr = (w >> 1) * 64, wc = (w & 1) * 64;
#pragma unroll
  for (int m = 0; m < 4; ++m)
#pragma unroll
    for (int j = 0; j < 4; ++j) {
      int t = row0 + wr + m * 16 + (l >> 4) * 4 + j;
      float* orow = out + (size_t)t * DMODEL + col0;
#pragma unroll
      for (int n = 0; n < 4; ++n)
        orow[wc + n * 16 + (l & 15)] = acc[m][n][j];
    }
}

// ---------------------------------------------------------------- launch

extern "C" void kernel_launch(void* const* d_in, const int* in_sizes, int n_in,
                              void* d_out, int out_size, void* d_ws, size_t ws_size,
                              hipStream_t stream) {
  (void)in_sizes; (void)n_in; (void)out_size;
  const float* x    = (const float*)d_in[0];
  const float* Wqkv = (const float*)d_in[1];
  const float* Wlr  = (const float*)d_in[2];
  const float* Wo   = (const float*)d_in[3];
  const float* lng  = (const float*)d_in[8];
  const float* lnb  = (const float*)d_in[9];
  const float* Wsc  = (const float*)d_in[6];
  const float* bs   = (const float*)d_in[7];
  const float* w0   = (const float*)d_in[10];
  const float* w1   = (const float*)d_in[11];
  const float* w2   = (const float*)d_in[12];

  // Q lives in d_out (fp32); its last read (k_out2, chunk 3) precedes k_final's write.
  float* Q = (float*)d_out;

  float* ws = (float*)d_ws;
  size_t off = 0;
  auto alloc = [&](size_t n) { float* p = ws + off; off += n; return p; };
  float* Km   = alloc((size_t)NH * LSEQ * HD);
  float* V    = alloc((size_t)NH * LSEQ * HD);
  float* Uf   = alloc((size_t)LSEQ * DMODEL / 2);   // U stored as bf16
  float* LR   = alloc((size_t)3 * NH * LSEQ);
  float* SCL  = alloc((size_t)NH * LSEQ);
  float* WW   = alloc((size_t)3 * NH * HD * HD);
  float* WN0  = alloc((size_t)3 * NH * HD);
  float* BUF  = alloc((size_t)3 * NH * HD * CH);    // chunk loop scratch
  float* DW   = alloc((size_t)3 * NH * HD * HD);
  float* DWP  = alloc((size_t)3 * NH * 8 * HD * HD);
  if (off * sizeof(float) > ws_size) return;        // clean failure instead of OOB

  unsigned short* U = (unsigned short*)Uf;
  unsigned short* xb  = (unsigned short*)BUF;                                   // aliases BUF (dead until loop)
  unsigned short* Wqt = (unsigned short*)(BUF + (size_t)LSEQ * DMODEL / 2);
  unsigned short* Wot = (unsigned short*)BUF;                                   // aliases BUF (dead after loop)

  k_init_w<<<3 * NH * HD, 64, 0, stream>>>(w0, w1, w2, WW, WN0);
  k_cast<<<2048, 256, 0, stream>>>(x, xb, LSEQ * DMODEL / 4);
  k_tcast<<<dim3(3 * DMODEL / 64, DMODEL / 64), 256, 0, stream>>>(Wqkv, Wqt, DMODEL, 3 * DMODEL);
  k_qkv_mfma<<<dim3(LSEQ / 128, 48), 256, 0, stream>>>(xb, Wqt, Q, Km, V);
  k_l2norm<<<2 * NH * LSEQ / 4, 256, 0, stream>>>(Q, Km);
  k_lrms4<<<LSEQ / 64, 256, 0, stream>>>(x, Wlr, Wsc, bs, LR, SCL);

  for (int c = 0; c < 4; ++c) {
    int s = c * CH;
    k_out2<<<dim3(CH / 128, NH), 256, 0, stream>>>(WW, Q, SCL, lng, lnb, U, s);
    if (c < 3) {
      k_front<<<dim3(CH / 128, NH, 3), 256, 0, stream>>>(WW, Km, V, BUF, s);
      k_elem<<<(NH * HD * CH) / (256 * 4), 256, 0, stream>>>(
          BUF, BUF + (size_t)NH * HD * CH, BUF + (size_t)2 * NH * HD * CH);
      k_dwp<<<dim3(8, NH, 3), 256, 0, stream>>>(BUF, Km, V, LR, DWP, s);
      k_dwred<<<3 * NH, 256, 0, stream>>>(DWP, DW);
      k_ns5<<<3 * NH, 1024, 0, stream>>>(DW);
      k_apply<<<3 * NH * HD, 64, 0, stream>>>(WW, DW, WN0);
    }
  }
  k_tcast<<<dim3(DMODEL / 64, DMODEL / 64), 256, 0, stream>>>(Wo, Wot, DMODEL, DMODEL);
  k_final_mfma<<<dim3(LSEQ / 128, DMODEL / 128), 256, 0, stream>>>(U, Wot, (float*)d_out);
}

// Round 6
// 1594.436 us; speedup vs baseline: 3.7620x; 1.2057x over previous
//
#include <hip/hip_runtime.h>
#include <hip/hip_bf16.h>
#include <cstdint>
#include <cstddef>

#define LSEQ   8192
#define DMODEL 2048
#define NH     16      // heads == groups
#define HD     128     // head dim == hidden dim
#define CH     2048    // chunk length (group-space positions)

typedef __attribute__((ext_vector_type(8))) __bf16 bf16x8;
typedef __attribute__((ext_vector_type(4))) float f32x4;

// ---------------------------------------------------------------- helpers

__device__ __forceinline__ float wave_sum64(float v) {
#pragma unroll
  for (int m = 32; m; m >>= 1) v += __shfl_xor(v, m, 64);
  return v;
}

__device__ __forceinline__ float sigm(float x) { return 1.0f / (1.0f + expf(-x)); }

// RTNE float -> bf16 bits
__device__ __forceinline__ unsigned short f2bf(float f) {
  unsigned int u = __float_as_uint(f);
  u += 0x7FFFu + ((u >> 16) & 1u);
  return (unsigned short)(u >> 16);
}
__device__ __forceinline__ float bf2f(unsigned short h) {
  return __uint_as_float((unsigned int)h << 16);
}

// async global->LDS, 16B per lane. lds dest is wave-uniform base; HW adds lane*16.
__device__ __forceinline__ void gload_lds16(const void* g, void* l) {
  __builtin_amdgcn_global_load_lds((__attribute__((address_space(1))) void*)(g),
                                   (__attribute__((address_space(3))) void*)(l), 16, 0, 0);
}

// ---------------------------------------------------------------- casts

__global__ void k_cast(const float* __restrict__ X, unsigned short* __restrict__ Xb, int n4) {
  int i = blockIdx.x * 256 + threadIdx.x;
  int stride = gridDim.x * 256;
  for (; i < n4; i += stride) {
    float4 v = ((const float4*)X)[i];
    ushort4 o;
    o.x = f2bf(v.x); o.y = f2bf(v.y); o.z = f2bf(v.z); o.w = f2bf(v.w);
    ((ushort4*)Xb)[i] = o;
  }
}

// W (K x N, fp32) -> Wt (N x K, bf16). grid (N/64, K/64), block 256.
__global__ void k_tcast(const float* __restrict__ W, unsigned short* __restrict__ Wt,
                        int K, int N) {
  __shared__ float t[64][65];
  const int n0 = blockIdx.x * 64, k0 = blockIdx.y * 64;
  const int tid = threadIdx.x;
  const int cx = tid & 63, ry = tid >> 6;
#pragma unroll
  for (int r = 0; r < 16; ++r) {
    int row = ry + r * 4;
    t[row][cx] = W[(size_t)(k0 + row) * N + n0 + cx];
  }
  __syncthreads();
#pragma unroll
  for (int r = 0; r < 16; ++r) {
    int nn = ry + r * 4;
    Wt[(size_t)(n0 + nn) * K + k0 + cx] = f2bf(t[cx][nn]);
  }
}

// ---------------------------------------------------------------- bf16 MFMA GEMM core (m97 style)

__device__ __forceinline__ void gemm_core(const unsigned short* __restrict__ A,
                                          const unsigned short* __restrict__ B,
                                          int K, int ldA, int ldB, int row0, int col0,
                                          unsigned short* Al, unsigned short* Bl,
                                          f32x4 acc[4][4]) {
  const int tid = threadIdx.x;
  const int w = tid >> 6, l = tid & 63;
  const int lrow = l & 15, lk = (l >> 4) * 8;
  const int wr = (w >> 1) * 64, wc = (w & 1) * 64;
  const int srow = l >> 2, skk = (l & 3) * 8;

  for (int kk = 0; kk < K; kk += 32) {
#pragma unroll
    for (int q = 0; q < 2; ++q) {
      int c = w * 2 + q;
      gload_lds16(A + (size_t)(row0 + c * 16 + srow) * ldA + kk + skk, &Al[c * 512]);
      gload_lds16(B + (size_t)(col0 + c * 16 + srow) * ldB + kk + skk, &Bl[c * 512]);
    }
    __syncthreads();
    bf16x8 af[4], bfr[4];
#pragma unroll
    for (int m = 0; m < 4; ++m)
      af[m] = *(const bf16x8*)&Al[(wr + m * 16 + lrow) * 32 + lk];
#pragma unroll
    for (int n = 0; n < 4; ++n)
      bfr[n] = *(const bf16x8*)&Bl[(wc + n * 16 + lrow) * 32 + lk];
#pragma unroll
    for (int m = 0; m < 4; ++m)
#pragma unroll
      for (int n = 0; n < 4; ++n)
        acc[m][n] = __builtin_amdgcn_mfma_f32_16x16x32_bf16(af[m], bfr[n], acc[m][n], 0, 0, 0);
    __syncthreads();
  }
}

// ---------------------------------------------------------------- swizzled hi/lo LDS staging

__device__ __forceinline__ bf16x8 ld_sw(const unsigned short* base, int row, int kcol) {
  int byte = (row * 256 + kcol * 2) ^ ((row & 7) << 4);
  return *(const bf16x8*)((const char*)base + byte);
}
__device__ __forceinline__ void st_sw(unsigned short* base, int row, int col, unsigned short v) {
  int byte = (row * 256 + col * 2) ^ ((row & 7) << 4);
  *(unsigned short*)((char*)base + byte) = v;
}

// direct: fp32 [128 rows][>=128 cols] -> swizzled bf16 [128][128]
__device__ __forceinline__ void stage_sw(const float* __restrict__ src, int ld,
                                         unsigned short* dst, int tid) {
#pragma unroll
  for (int p = 0; p < 16; ++p) {
    int row = p * 8 + (tid >> 5);
    int col = (tid & 31) * 4;
    float4 v = *(const float4*)(src + (size_t)row * ld + col);
    int byte = (row * 256 + col * 2) ^ ((row & 7) << 4);
    unsigned short* d = (unsigned short*)((char*)dst + byte);
    d[0] = f2bf(v.x); d[1] = f2bf(v.y); d[2] = f2bf(v.z); d[3] = f2bf(v.w);
  }
}

// direct hi/lo: fp32 -> (H, L) swizzled bf16 pair
__device__ __forceinline__ void stage_hl(const float* __restrict__ src, int ld,
                                         unsigned short* H, unsigned short* L, int tid) {
#pragma unroll
  for (int p = 0; p < 16; ++p) {
    int row = p * 8 + (tid >> 5);
    int col = (tid & 31) * 4;
    float4 v = *(const float4*)(src + (size_t)row * ld + col);
    int byte = (row * 256 + col * 2) ^ ((row & 7) << 4);
    unsigned short* h = (unsigned short*)((char*)H + byte);
    unsigned short* l = (unsigned short*)((char*)L + byte);
    const float* pv = (const float*)&v;
#pragma unroll
    for (int i = 0; i < 4; ++i) {
      unsigned short hi = f2bf(pv[i]);
      h[i] = hi;
      l[i] = f2bf(pv[i] - bf2f(hi));
    }
  }
}

// transposed hi/lo: src fp32 [128 k][128 c] row-major -> LDS[c][k] hi/lo
__device__ __forceinline__ void stage_hl_t(const float* __restrict__ src, int ld,
                                           unsigned short* H, unsigned short* L, int tid) {
#pragma unroll
  for (int p = 0; p < 16; ++p) {
    int k = p * 8 + (tid >> 5);
    int c = (tid & 31) * 4;
    float4 v = *(const float4*)(src + (size_t)k * ld + c);
    const float* pv = (const float*)&v;
#pragma unroll
    for (int i = 0; i < 4; ++i) {
      unsigned short hi = f2bf(pv[i]);
      st_sw(H, c + i, k, hi);
      st_sw(L, c + i, k, f2bf(pv[i] - bf2f(hi)));
    }
  }
}

// transposed + per-row scale: src [128 t][HD d], scale lr[t] -> LDS[d][t] hi/lo
__device__ __forceinline__ void stage_hl_ts(const float* __restrict__ src, int ld,
                                            const float* __restrict__ lr,
                                            unsigned short* H, unsigned short* L, int tid) {
#pragma unroll
  for (int p = 0; p < 16; ++p) {
    int t = p * 8 + (tid >> 5);
    int d = (tid & 31) * 4;
    float4 v = *(const float4*)(src + (size_t)t * ld + d);
    float sc = lr[t];
    const float* pv = (const float*)&v;
#pragma unroll
    for (int i = 0; i < 4; ++i) {
      float x = pv[i] * sc;
      unsigned short hi = f2bf(x);
      st_sw(H, d + i, t, hi);
      st_sw(L, d + i, t, f2bf(x - bf2f(hi)));
    }
  }
}

// ---------------------------------------------------------------- init w + row norms

__global__ void k_init_w(const float* __restrict__ w0, const float* __restrict__ w1,
                         const float* __restrict__ w2, float* __restrict__ WW,
                         float* __restrict__ WN0) {
  int rid = blockIdx.x;
  int m = rid >> 11;
  int gr = rid & 2047;
  const float* src = (m == 0) ? w0 : (m == 1) ? w1 : w2;
  const float* row = src + (size_t)gr * HD;
  float* drow = WW + ((size_t)m * 2048 + gr) * HD;
  int l = threadIdx.x;
  float v0 = row[l], v1 = row[l + 64];
  drow[l] = v0; drow[l + 64] = v1;
  float s = wave_sum64(v0 * v0 + v1 * v1);
  if (l == 0) WN0[rid] = sqrtf(s);
}

// ---------------------------------------------------------------- qkv projection (bf16 MFMA)

__global__ __launch_bounds__(256) void k_qkv_mfma(const unsigned short* __restrict__ xb,
                                                  const unsigned short* __restrict__ Wqt,
                                                  float* __restrict__ Q, float* __restrict__ Km,
                                                  float* __restrict__ V) {
  __shared__ unsigned short Al[128 * 32];
  __shared__ unsigned short Bl[128 * 32];
  f32x4 acc[4][4];
#pragma unroll
  for (int m = 0; m < 4; ++m)
#pragma unroll
    for (int n = 0; n < 4; ++n) acc[m][n] = {};

  gemm_core(xb, Wqt, DMODEL, DMODEL, DMODEL, blockIdx.x * 128, blockIdx.y * 128, Al, Bl, acc);

  const int ct = blockIdx.y, hh = ct / 3, which = ct % 3;
  float* dst = (which == 0) ? Q : (which == 1) ? Km : V;
  const int tid = threadIdx.x, w = tid >> 6, l = tid & 63;
  const int wr = (w >> 1) * 64, wc = (w & 1) * 64;
#pragma unroll
  for (int m = 0; m < 4; ++m)
#pragma unroll
    for (int j = 0; j < 4; ++j) {
      int t = blockIdx.x * 128 + wr + m * 16 + (l >> 4) * 4 + j;
      int fth = t * NH + hh;
      int g = fth >> 13, tp = fth & 8191;
      float* drow = dst + ((size_t)g * LSEQ + tp) * HD;
#pragma unroll
      for (int n = 0; n < 4; ++n) {
        float v = acc[m][n][j];
        drow[wc + n * 16 + (l & 15)] = v * sigm(v);
      }
    }
}

// normalize Q and K rows in place.
__global__ void k_l2norm(float* __restrict__ Q, float* __restrict__ Km) {
  int rid = blockIdx.x * 4 + (threadIdx.x >> 6);
  int l = threadIdx.x & 63;
  float* base = (rid < NH * LSEQ) ? Q : Km;
  int r = (rid < NH * LSEQ) ? rid : rid - NH * LSEQ;
  float* row = base + (size_t)r * HD;
  float v0 = row[l], v1 = row[l + 64];
  float s = wave_sum64(v0 * v0 + v1 * v1);
  float f = 1.0f / (sqrtf(s) + 1e-5f);
  row[l] = v0 * f;
  row[l + 64] = v1 * f;
}

// ---------------------------------------------------------------- lr / scale: K-split GEMM + reduce
// momentum dropped: dw *= (1+m_i) is a per-matrix positive scalar, cancelled by
// NS5's Frobenius normalization.

// grid (128, 16): 64 tokens x 64 cols x 128-K slice per block. Partials -> P.
__global__ __launch_bounds__(256) void k_lrms5(const float* __restrict__ x,
                                               const float* __restrict__ Wlr,
                                               const float* __restrict__ Wsc,
                                               float* __restrict__ P) {
  __shared__ float Xs[128][67];
  __shared__ float Ws[128][68];
  const int tb = blockIdx.x;
  const int kp = blockIdx.y;
  const int tid = threadIdx.x;
  // stage W slice [128 k][64 c]
  for (int i = tid; i < 128 * 64; i += 256) {
    int k = i >> 6, c = i & 63;
    float wv = (c < 48) ? Wlr[(size_t)(kp * 128 + k) * 48 + c]
                        : Wsc[(size_t)(kp * 128 + k) * 16 + (c - 48)];
    Ws[k][c] = wv;
  }
  // stage x transposed [128 k][64 t]
  const int t8 = tid >> 5, kk = tid & 31;
#pragma unroll
  for (int r = 0; r < 8; ++r) {
    int t = t8 + r * 8;
    float4 v = *(const float4*)(x + (size_t)(tb * 64 + t) * DMODEL + kp * 128 + kk * 4);
    Xs[kk * 4 + 0][t] = v.x; Xs[kk * 4 + 1][t] = v.y;
    Xs[kk * 4 + 2][t] = v.z; Xs[kk * 4 + 3][t] = v.w;
  }
  __syncthreads();
  const int ty = tid >> 4, tx = tid & 15;
  float acc[4][4];
#pragma unroll
  for (int i = 0; i < 4; ++i)
#pragma unroll
    for (int j = 0; j < 4; ++j) acc[i][j] = 0.0f;
  for (int k = 0; k < 128; ++k) {
    float a[4], b[4];
#pragma unroll
    for (int i = 0; i < 4; ++i) a[i] = Xs[k][ty * 4 + i];
#pragma unroll
    for (int j = 0; j < 4; ++j) b[j] = Ws[k][tx * 4 + j];
#pragma unroll
    for (int i = 0; i < 4; ++i)
#pragma unroll
      for (int j = 0; j < 4; ++j) acc[i][j] = fmaf(a[i], b[j], acc[i][j]);
  }
  float* o = P + ((size_t)tb * 16 + kp) * 4096;
#pragma unroll
  for (int i = 0; i < 4; ++i)
#pragma unroll
    for (int j = 0; j < 4; ++j)
      o[(ty * 4 + i) * 64 + tx * 4 + j] = acc[i][j];
}

// reduce 16 K-partials + activations. grid 2048, block 256: one (t,c) per thread.
__global__ void k_lrsum(const float* __restrict__ P, const float* __restrict__ bs,
                        float* __restrict__ LR, float* __restrict__ SCL) {
  int e = blockIdx.x * 256 + threadIdx.x;   // e < 8192*64
  int t = e >> 6, c = e & 63;
  const float* base = P + ((size_t)(t >> 6) * 16) * 4096 + (t & 63) * 64 + c;
  float sum = 0.0f;
#pragma unroll
  for (int kp = 0; kp < 16; ++kp) sum += base[(size_t)kp * 4096];
  if (c < 48) {
    float base_lr_inv = 0.01f + logf(-expm1f(-0.01f));
    float v = sum + base_lr_inv;
    float sp = fmaxf(v, 0.0f) + log1pf(expf(-fabsf(v)));
    LR[(size_t)c * LSEQ + t] = sp;
  } else {
    float v = sum + bs[c - 48];
    SCL[(size_t)(c - 48) * LSEQ + t] = v * sigm(v);
  }
}

// ---------------------------------------------------------------- per-chunk output (bf16 MFMA + fused LN/scale)

// grid (CH/128, NH), block 256.
__global__ __launch_bounds__(256) void k_out2(const float* __restrict__ WW,
                                              const float* __restrict__ Q,
                                              const float* __restrict__ SCL,
                                              const float* __restrict__ lng,
                                              const float* __restrict__ lnb,
                                              unsigned short* __restrict__ U, int s) {
  __shared__ __align__(16) char smem[131072];
  unsigned short* Qs  = (unsigned short*)smem;
  unsigned short* W0s = (unsigned short*)(smem + 32768);
  unsigned short* W2s = (unsigned short*)(smem + 65536);
  unsigned short* GHs = (unsigned short*)(smem + 98304);
  float* Os = (float*)smem;

  const int g = blockIdx.y;
  const int t0 = blockIdx.x * 128;
  const int tid = threadIdx.x;
  const int w = tid >> 6, l = tid & 63;
  const int lrow = l & 15, lk8 = (l >> 4) * 8;
  const int wr = (w >> 1) * 64, wc = (w & 1) * 64;

  const float* Qg  = Q + ((size_t)g * LSEQ + s + t0) * HD;
  const float* w0g = WW + ((size_t)0 * 2048 + g * 128) * 128;
  const float* w1g = WW + ((size_t)1 * 2048 + g * 128) * 128;
  const float* w2g = WW + ((size_t)2 * 2048 + g * 128) * 128;

  stage_sw(Qg, HD, Qs, tid);
  stage_sw(w0g, 128, W0s, tid);
  stage_sw(w2g, 128, W2s, tid);
  __syncthreads();

  f32x4 ga[4][4], ha[4][4];
#pragma unroll
  for (int m = 0; m < 4; ++m)
#pragma unroll
    for (int n = 0; n < 4; ++n) { ga[m][n] = {}; ha[m][n] = {}; }
#pragma unroll
  for (int kk = 0; kk < 128; kk += 32) {
    bf16x8 af[4], b0[4], b2[4];
#pragma unroll
    for (int m = 0; m < 4; ++m) af[m] = ld_sw(Qs, wr + m * 16 + lrow, kk + lk8);
#pragma unroll
    for (int n = 0; n < 4; ++n) {
      b0[n] = ld_sw(W0s, wc + n * 16 + lrow, kk + lk8);
      b2[n] = ld_sw(W2s, wc + n * 16 + lrow, kk + lk8);
    }
#pragma unroll
    for (int m = 0; m < 4; ++m)
#pragma unroll
      for (int n = 0; n < 4; ++n) {
        ga[m][n] = __builtin_amdgcn_mfma_f32_16x16x32_bf16(af[m], b0[n], ga[m][n], 0, 0, 0);
        ha[m][n] = __builtin_amdgcn_mfma_f32_16x16x32_bf16(af[m], b2[n], ha[m][n], 0, 0, 0);
      }
  }
#pragma unroll
  for (int m = 0; m < 4; ++m)
#pragma unroll
    for (int n = 0; n < 4; ++n)
#pragma unroll
      for (int j = 0; j < 4; ++j) {
        int row = wr + m * 16 + (l >> 4) * 4 + j;
        int col = wc + n * 16 + (l & 15);
        float gv = ga[m][n][j];
        st_sw(GHs, row, col, f2bf(gv * sigm(gv) * ha[m][n][j]));
      }
  __syncthreads();
  stage_sw(w1g, 128, W0s, tid);
  __syncthreads();

  f32x4 oa[4][4];
#pragma unroll
  for (int m = 0; m < 4; ++m)
#pragma unroll
    for (int n = 0; n < 4; ++n) oa[m][n] = {};
#pragma unroll
  for (int kk = 0; kk < 128; kk += 32) {
    bf16x8 af[4], b1[4];
#pragma unroll
    for (int m = 0; m < 4; ++m) af[m] = ld_sw(GHs, wr + m * 16 + lrow, kk + lk8);
#pragma unroll
    for (int n = 0; n < 4; ++n) b1[n] = ld_sw(W0s, wc + n * 16 + lrow, kk + lk8);
#pragma unroll
    for (int m = 0; m < 4; ++m)
#pragma unroll
      for (int n = 0; n < 4; ++n)
        oa[m][n] = __builtin_amdgcn_mfma_f32_16x16x32_bf16(af[m], b1[n], oa[m][n], 0, 0, 0);
  }
  __syncthreads();
#pragma unroll
  for (int m = 0; m < 4; ++m)
#pragma unroll
    for (int n = 0; n < 4; ++n)
#pragma unroll
      for (int j = 0; j < 4; ++j) {
        int row = wr + m * 16 + (l >> 4) * 4 + j;
        int col = wc + n * 16 + (l & 15);
        Os[row * 132 + col] = oa[m][n][j];
      }
  __syncthreads();

  const int tok = tid >> 1, part = tid & 1;
  const float* orow = Os + tok * 132 + part * 64;
  float sum = 0.0f;
#pragma unroll
  for (int q = 0; q < 16; ++q) {
    float4 v = *(const float4*)(orow + q * 4);
    sum += (v.x + v.y) + (v.z + v.w);
  }
  sum += __shfl_xor(sum, 1, 64);
  float mu = sum * (1.0f / 128.0f);
  float vs = 0.0f;
#pragma unroll
  for (int q = 0; q < 16; ++q) {
    float4 v = *(const float4*)(orow + q * 4);
    float d0 = v.x - mu, d1 = v.y - mu, d2 = v.z - mu, d3 = v.w - mu;
    vs += d0 * d0 + d1 * d1 + d2 * d2 + d3 * d3;
  }
  vs += __shfl_xor(vs, 1, 64);
  float rstd = rsqrtf(vs * (1.0f / 128.0f) + 1e-6f);
  int tabs = s + t0 + tok;
  float sc = SCL[(size_t)g * LSEQ + tabs];
  unsigned short* urow = U + (size_t)tabs * DMODEL + g * HD + part * 64;
#pragma unroll
  for (int q = 0; q < 16; ++q) {
    float4 v = *(const float4*)(orow + q * 4);
    int d = part * 64 + q * 4;
    ushort4 o;
    o.x = f2bf(((v.x - mu) * rstd * lng[d + 0] + lnb[d + 0]) * sc);
    o.y = f2bf(((v.y - mu) * rstd * lng[d + 1] + lnb[d + 1]) * sc);
    o.z = f2bf(((v.z - mu) * rstd * lng[d + 2] + lnb[d + 2]) * sc);
    o.w = f2bf(((v.w - mu) * rstd * lng[d + 3] + lnb[d + 3]) * sc);
    *(ushort4*)(urow + q * 4) = o;
  }
}

// ---------------------------------------------------------------- chunk backward front GEMMs (split-bf16 MFMA)
// z=0: Gb=w0@K^T  z=1: Hb=w2@K^T  z=2: Dh=w1^T@V^T.  fp32-class accuracy via hi/lo split.

__global__ __launch_bounds__(256) void k_front_mx(const float* __restrict__ WW,
                                                  const float* __restrict__ Km,
                                                  const float* __restrict__ V,
                                                  float* __restrict__ BUF, int s) {
  __shared__ __align__(16) char smem[131072];
  unsigned short* AH = (unsigned short*)smem;
  unsigned short* AL = (unsigned short*)(smem + 32768);
  unsigned short* BH = (unsigned short*)(smem + 65536);
  unsigned short* BL = (unsigned short*)(smem + 98304);

  const int tt0 = blockIdx.x * 128;
  const int g = blockIdx.y;
  const int z = blockIdx.z;
  const int tid = threadIdx.x;
  const int w = tid >> 6, l = tid & 63;
  const int lrow = l & 15, lk8 = (l >> 4) * 8;
  const int wr = (w >> 1) * 64, wc = (w & 1) * 64;

  const int wsel = (z == 0) ? 0 : (z == 1) ? 2 : 1;
  const float* wg = WW + ((size_t)wsel * 2048 + g * 128) * 128;
  const float* X = (z == 2) ? V : Km;

  if (z != 2) stage_hl(wg, 128, AH, AL, tid);     // rows e, k=d contiguous
  else        stage_hl_t(wg, 128, AH, AL, tid);   // A[e][d] = w1[d][e]
  stage_hl(X + ((size_t)g * LSEQ + s + tt0) * HD, HD, BH, BL, tid);  // rows t, k=d
  __syncthreads();

  f32x4 acc[4][4];
#pragma unroll
  for (int m = 0; m < 4; ++m)
#pragma unroll
    for (int n = 0; n < 4; ++n) acc[m][n] = {};
#pragma unroll
  for (int kk = 0; kk < 128; kk += 32) {
    bf16x8 ah[4], al4[4], bh[4], bl4[4];
#pragma unroll
    for (int m = 0; m < 4; ++m) {
      ah[m] = ld_sw(AH, wr + m * 16 + lrow, kk + lk8);
      al4[m] = ld_sw(AL, wr + m * 16 + lrow, kk + lk8);
    }
#pragma unroll
    for (int n = 0; n < 4; ++n) {
      bh[n] = ld_sw(BH, wc + n * 16 + lrow, kk + lk8);
      bl4[n] = ld_sw(BL, wc + n * 16 + lrow, kk + lk8);
    }
#pragma unroll
    for (int m = 0; m < 4; ++m)
#pragma unroll
      for (int n = 0; n < 4; ++n) {
        acc[m][n] = __builtin_amdgcn_mfma_f32_16x16x32_bf16(ah[m], bh[n], acc[m][n], 0, 0, 0);
        acc[m][n] = __builtin_amdgcn_mfma_f32_16x16x32_bf16(ah[m], bl4[n], acc[m][n], 0, 0, 0);
        acc[m][n] = __builtin_amdgcn_mfma_f32_16x16x32_bf16(al4[m], bh[n], acc[m][n], 0, 0, 0);
      }
  }

  float* out = BUF + (size_t)z * (NH * 128 * CH) + (size_t)g * 128 * CH;
#pragma unroll
  for (int m = 0; m < 4; ++m)
#pragma unroll
    for (int n = 0; n < 4; ++n)
#pragma unroll
      for (int j = 0; j < 4; ++j) {
        int row = wr + m * 16 + (l >> 4) * 4 + j;
        int col = wc + n * 16 + (l & 15);
        out[(size_t)row * CH + tt0 + col] = acc[m][n][j];
      }
}

// elementwise: (Gb,Hb,Dh) -> (hid, dgate_before, dhidden_before) in place
__global__ void k_elem(float* __restrict__ BA, float* __restrict__ BB, float* __restrict__ BC) {
  size_t i = ((size_t)blockIdx.x * 256 + threadIdx.x) * 4;
  float4 a = *(const float4*)(BA + i);
  float4 b = *(const float4*)(BB + i);
  float4 c = *(const float4*)(BC + i);
  float4 ha, hb2, hc;
  float* pa = (float*)&a; float* pb = (float*)&b; float* pc = (float*)&c;
  float* oa = (float*)&ha; float* ob = (float*)&hb2; float* oc = (float*)&hc;
#pragma unroll
  for (int k = 0; k < 4; ++k) {
    float gb = pa[k], hb = pb[k], dh = pc[k];
    float sg = sigm(gb);
    float sgb = gb * sg;
    float hid = sgb * hb;
    float dgate = dh * hb;
    float dgb = dgate * sg * (1.0f + gb * (1.0f - sg));
    float dhb = dh * sgb;
    oa[k] = hid; ob[k] = dgb; oc[k] = dhb;
  }
  *(float4*)(BA + i) = ha;
  *(float4*)(BB + i) = hb2;
  *(float4*)(BC + i) = hc;
}

// partial dW GEMMs over 256-token slices (split-bf16). grid (8, NH, 3).
__global__ __launch_bounds__(256) void k_dwp_mx(const float* __restrict__ BUF,
                                                const float* __restrict__ Km,
                                                const float* __restrict__ V,
                                                const float* __restrict__ LR,
                                                float* __restrict__ DWP, int s) {
  __shared__ __align__(16) char smem[131072];
  unsigned short* AH = (unsigned short*)smem;
  unsigned short* AL = (unsigned short*)(smem + 32768);
  unsigned short* BH = (unsigned short*)(smem + 65536);
  unsigned short* BL = (unsigned short*)(smem + 98304);

  const int p = blockIdx.x;
  const int g = blockIdx.y;
  const int z = blockIdx.z;
  const int tid = threadIdx.x;
  const int w = tid >> 6, l = tid & 63;
  const int lrow = l & 15, lk8 = (l >> 4) * 8;
  const int wr = (w >> 1) * 64, wc = (w & 1) * 64;

  const int msel = (z == 0) ? 1 : (z == 1) ? 0 : 2;
  const float* M = BUF + (size_t)msel * (NH * 128 * CH) + (size_t)g * 128 * CH;
  const float* N = (z == 1) ? V : Km;
  const float* lr = LR + (size_t)(z * NH + g) * LSEQ;
  const int ts = p * 256;

  f32x4 acc[4][4];
#pragma unroll
  for (int m = 0; m < 4; ++m)
#pragma unroll
    for (int n = 0; n < 4; ++n) acc[m][n] = {};

  for (int h = 0; h < 2; ++h) {
    if (h) __syncthreads();
    // A: M[e][ts + h*128 + k], k contiguous (row stride CH)
    stage_hl(M + ts + h * 128, CH, AH, AL, tid);
    // B: B[d][t] = N[tok][d] * lr[tok]
    stage_hl_ts(N + ((size_t)g * LSEQ + s + ts + h * 128) * HD, HD,
                lr + s + ts + h * 128, BH, BL, tid);
    __syncthreads();
#pragma unroll
    for (int kk = 0; kk < 128; kk += 32) {
      bf16x8 ah[4], al4[4], bh[4], bl4[4];
#pragma unroll
      for (int m = 0; m < 4; ++m) {
        ah[m] = ld_sw(AH, wr + m * 16 + lrow, kk + lk8);
        al4[m] = ld_sw(AL, wr + m * 16 + lrow, kk + lk8);
      }
#pragma unroll
      for (int n = 0; n < 4; ++n) {
        bh[n] = ld_sw(BH, wc + n * 16 + lrow, kk + lk8);
        bl4[n] = ld_sw(BL, wc + n * 16 + lrow, kk + lk8);
      }
#pragma unroll
      for (int m = 0; m < 4; ++m)
#pragma unroll
        for (int n = 0; n < 4; ++n) {
          acc[m][n] = __builtin_amdgcn_mfma_f32_16x16x32_bf16(ah[m], bh[n], acc[m][n], 0, 0, 0);
          acc[m][n] = __builtin_amdgcn_mfma_f32_16x16x32_bf16(ah[m], bl4[n], acc[m][n], 0, 0, 0);
          acc[m][n] = __builtin_amdgcn_mfma_f32_16x16x32_bf16(al4[m], bh[n], acc[m][n], 0, 0, 0);
        }
    }
  }

  float* outp = DWP + (((size_t)(z * NH + g)) * 8 + p) * 16384;
#pragma unroll
  for (int m = 0; m < 4; ++m)
#pragma unroll
    for (int n = 0; n < 4; ++n)
#pragma unroll
      for (int j = 0; j < 4; ++j) {
        int row = wr + m * 16 + (l >> 4) * 4 + j;
        int col = wc + n * 16 + (l & 15);
        outp[row * 128 + col] = acc[m][n][j];
      }
}

// reduce 8 partials; transpose dw1 (z==1).
__global__ void k_dwred(const float* __restrict__ DWP, float* __restrict__ DW) {
  int zg = blockIdx.x;
  int z = zg >> 4;
  const float* base = DWP + (size_t)zg * 8 * 16384;
  float* out = DW + (size_t)zg * 16384;
  for (int idx = threadIdx.x; idx < 16384; idx += 256) {
    float sv = 0.0f;
#pragma unroll
    for (int pp = 0; pp < 8; ++pp) sv += base[(size_t)pp * 16384 + idx];
    int oidx = (z == 1) ? ((idx & 127) * 128 + (idx >> 7)) : idx;
    out[oidx] = sv;
  }
}

// ---------------------------------------------------------------- Newton-Schulz 5 (fp32)

__global__ __launch_bounds__(1024) void k_ns5(float* __restrict__ DW) {
  __shared__ float Xs[128 * 128];
  __shared__ float Aw[128 * 128];
  const float NA[5] = {4.0848f, 3.9505f, 3.7418f, 2.8769f, 2.8366f};
  const float NB[5] = {-6.8946f, -6.3029f, -5.5913f, -3.1427f, -3.0525f};
  const float NC[5] = {2.927f, 2.6377f, 2.3037f, 1.2046f, 1.2012f};
  float* Gm = DW + (size_t)blockIdx.x * 16384;
  const int tid = threadIdx.x;
  const int ty = tid >> 5, tx = tid & 31;

  float psum = 0.0f;
#pragma unroll
  for (int r = 0; r < 16; ++r) {
    int idx = tid + r * 1024;
    float v = Gm[idx];
    Xs[idx] = v;
    psum = fmaf(v, v, psum);
  }
  psum = wave_sum64(psum);
  if ((tid & 63) == 0) Aw[tid >> 6] = psum;
  __syncthreads();
  if (tid == 0) {
    float tot = 0.0f;
    for (int i = 0; i < 16; ++i) tot += Aw[i];
    Aw[0] = 1.0f / (sqrtf(tot) + 1e-7f);
  }
  __syncthreads();
  float scl = Aw[0];
#pragma unroll
  for (int r = 0; r < 16; ++r) {
    int idx = tid + r * 1024;
    Xs[idx] *= scl;
  }
  __syncthreads();

#pragma unroll 1
  for (int it = 0; it < 5; ++it) {
    float ac = NA[it], bc = NB[it], cc = NC[it];
#pragma unroll
    for (int ii = 0; ii < 4; ++ii)
#pragma unroll
      for (int jj = 0; jj < 4; ++jj)
        Aw[(tx * 4 + jj) * 128 + ty * 4 + ii] = Xs[(ty * 4 + ii) * 128 + tx * 4 + jj];
    __syncthreads();
    float Ar[4][4];
#pragma unroll
    for (int ii = 0; ii < 4; ++ii)
#pragma unroll
      for (int jj = 0; jj < 4; ++jj) Ar[ii][jj] = 0.0f;
    for (int k = 0; k < 128; ++k) {
      float a[4], b[4];
#pragma unroll
      for (int ii = 0; ii < 4; ++ii) a[ii] = Xs[(ty * 4 + ii) * 128 + k];
#pragma unroll
      for (int jj = 0; jj < 4; ++jj) b[jj] = Aw[k * 128 + tx * 4 + jj];
#pragma unroll
      for (int ii = 0; ii < 4; ++ii)
#pragma unroll
        for (int jj = 0; jj < 4; ++jj) Ar[ii][jj] = fmaf(a[ii], b[jj], Ar[ii][jj]);
    }
    __syncthreads();
#pragma unroll
    for (int ii = 0; ii < 4; ++ii)
#pragma unroll
      for (int jj = 0; jj < 4; ++jj)
        Aw[(ty * 4 + ii) * 128 + tx * 4 + jj] = Ar[ii][jj];
    __syncthreads();
    float Bm[4][4];
#pragma unroll
    for (int ii = 0; ii < 4; ++ii)
#pragma unroll
      for (int jj = 0; jj < 4; ++jj) Bm[ii][jj] = 0.0f;
    for (int k = 0; k < 128; ++k) {
      float a[4], b[4];
#pragma unroll
      for (int ii = 0; ii < 4; ++ii) a[ii] = Aw[(ty * 4 + ii) * 128 + k];
#pragma unroll
      for (int jj = 0; jj < 4; ++jj) b[jj] = Aw[k * 128 + tx * 4 + jj];
#pragma unroll
      for (int ii = 0; ii < 4; ++ii)
#pragma unroll
        for (int jj = 0; jj < 4; ++jj) Bm[ii][jj] = fmaf(a[ii], b[jj], Bm[ii][jj]);
    }
#pragma unroll
    for (int ii = 0; ii < 4; ++ii)
#pragma unroll
      for (int jj = 0; jj < 4; ++jj) Bm[ii][jj] = fmaf(bc, Ar[ii][jj], cc * Bm[ii][jj]);
    __syncthreads();
#pragma unroll
    for (int ii = 0; ii < 4; ++ii)
#pragma unroll
      for (int jj = 0; jj < 4; ++jj)
        Aw[(ty * 4 + ii) * 128 + tx * 4 + jj] = Bm[ii][jj];
    __syncthreads();
    float Xn[4][4];
#pragma unroll
    for (int ii = 0; ii < 4; ++ii)
#pragma unroll
      for (int jj = 0; jj < 4; ++jj)
        Xn[ii][jj] = ac * Xs[(ty * 4 + ii) * 128 + tx * 4 + jj];
    for (int k = 0; k < 128; ++k) {
      float a[4], b[4];
#pragma unroll
      for (int ii = 0; ii < 4; ++ii) a[ii] = Aw[(ty * 4 + ii) * 128 + k];
#pragma unroll
      for (int jj = 0; jj < 4; ++jj) b[jj] = Xs[k * 128 + tx * 4 + jj];
#pragma unroll
      for (int ii = 0; ii < 4; ++ii)
#pragma unroll
        for (int jj = 0; jj < 4; ++jj) Xn[ii][jj] = fmaf(a[ii], b[jj], Xn[ii][jj]);
    }
    __syncthreads();
#pragma unroll
    for (int ii = 0; ii < 4; ++ii)
#pragma unroll
      for (int jj = 0; jj < 4; ++jj)
        Xs[(ty * 4 + ii) * 128 + tx * 4 + jj] = Xn[ii][jj];
    __syncthreads();
  }
#pragma unroll
  for (int r = 0; r < 16; ++r) {
    int idx = tid + r * 1024;
    Gm[idx] = Xs[idx];
  }
}

__global__ void k_apply(float* __restrict__ WW, const float* __restrict__ DW,
                        const float* __restrict__ WN0) {
  int rid = blockIdx.x;
  int l = threadIdx.x;
  float* wrow = WW + (size_t)rid * 128;
  const float* drow = DW + (size_t)rid * 128;
  float v0 = wrow[l] + drow[l];
  float v1 = wrow[l + 64] + drow[l + 64];
  float s = wave_sum64(v0 * v0 + v1 * v1);
  float f = WN0[rid] / (sqrtf(s) + 1e-5f);
  wrow[l] = v0 * f;
  wrow[l + 64] = v1 * f;
}

// ---------------------------------------------------------------- final projection (bf16 MFMA)

__global__ __launch_bounds__(256) void k_final_mfma(const unsigned short* __restrict__ U,
                                                    const unsigned short* __restrict__ Wot,
                                                    float* __restrict__ out) {
  __shared__ unsigned short Al[128 * 32];
  __shared__ unsigned short Bl[128 * 32];
  f32x4 acc[4][4];
#pragma unroll
  for (int m = 0; m < 4; ++m)
#pragma unroll
    for (int n = 0; n < 4; ++n) acc[m][n] = {};

  const int row0 = blockIdx.x * 128, col0 = blockIdx.y * 128;
  gemm_core(U, Wot, DMODEL, DMODEL, DMODEL, row0, col0, Al, Bl, acc);

  const int tid = threadIdx.x, w = tid >> 6, l = tid & 63;
  const int wr = (w >> 1) * 64, wc = (w & 1) * 64;
#pragma unroll
  for (int m = 0; m < 4; ++m)
#pragma unroll
    for (int j = 0; j < 4; ++j) {
      int t = row0 + wr + m * 16 + (l >> 4) * 4 + j;
      float* orow = out + (size_t)t * DMODEL + col0;
#pragma unroll
      for (int n = 0; n < 4; ++n)
        orow[wc + n * 16 + (l & 15)] = acc[m][n][j];
    }
}

// ---------------------------------------------------------------- launch

extern "C" void kernel_launch(void* const* d_in, const int* in_sizes, int n_in,
                              void* d_out, int out_size, void* d_ws, size_t ws_size,
                              hipStream_t stream) {
  (void)in_sizes; (void)n_in; (void)out_size;
  const float* x    = (const float*)d_in[0];
  const float* Wqkv = (const float*)d_in[1];
  const float* Wlr  = (const float*)d_in[2];
  const float* Wo   = (const float*)d_in[3];
  const float* Wsc  = (const float*)d_in[6];
  const float* bs   = (const float*)d_in[7];
  const float* lng  = (const float*)d_in[8];
  const float* lnb  = (const float*)d_in[9];
  const float* w0   = (const float*)d_in[10];
  const float* w1   = (const float*)d_in[11];
  const float* w2   = (const float*)d_in[12];

  // Q lives in d_out (fp32); its last read (k_out2, chunk 3) precedes k_final's write.
  float* Q = (float*)d_out;

  float* ws = (float*)d_ws;
  size_t off = 0;
  auto alloc = [&](size_t n) { float* p = ws + off; off += n; return p; };
  float* Km   = alloc((size_t)NH * LSEQ * HD);
  float* V    = alloc((size_t)NH * LSEQ * HD);
  float* Uf   = alloc((size_t)LSEQ * DMODEL / 2);   // U stored as bf16
  float* LR   = alloc((size_t)3 * NH * LSEQ);
  float* SCL  = alloc((size_t)NH * LSEQ);
  float* WW   = alloc((size_t)3 * NH * HD * HD);
  float* WN0  = alloc((size_t)3 * NH * HD);
  float* BUF  = alloc((size_t)3 * NH * HD * CH);    // chunk loop scratch
  float* DW   = alloc((size_t)3 * NH * HD * HD);
  float* DWP  = alloc((size_t)3 * NH * 8 * HD * HD);
  if (off * sizeof(float) > ws_size) return;        // clean failure instead of OOB

  unsigned short* U = (unsigned short*)Uf;
  // BUF aliases (each dead before the next use):
  unsigned short* xb  = (unsigned short*)BUF;                                   // pre-qkv
  unsigned short* Wqt = (unsigned short*)(BUF + (size_t)LSEQ * DMODEL / 2);
  float* Plr = BUF;                                                             // lrms partials (post-qkv)
  unsigned short* Wot = (unsigned short*)BUF;                                   // post-loop

  k_init_w<<<3 * NH * HD, 64, 0, stream>>>(w0, w1, w2, WW, WN0);
  k_cast<<<2048, 256, 0, stream>>>(x, xb, LSEQ * DMODEL / 4);
  k_tcast<<<dim3(3 * DMODEL / 64, DMODEL / 64), 256, 0, stream>>>(Wqkv, Wqt, DMODEL, 3 * DMODEL);
  k_qkv_mfma<<<dim3(LSEQ / 128, 48), 256, 0, stream>>>(xb, Wqt, Q, Km, V);
  k_l2norm<<<2 * NH * LSEQ / 4, 256, 0, stream>>>(Q, Km);
  k_lrms5<<<dim3(LSEQ / 64, 16), 256, 0, stream>>>(x, Wlr, Wsc, Plr);
  k_lrsum<<<LSEQ * 64 / 256, 256, 0, stream>>>(Plr, bs, LR, SCL);

  for (int c = 0; c < 4; ++c) {
    int s = c * CH;
    k_out2<<<dim3(CH / 128, NH), 256, 0, stream>>>(WW, Q, SCL, lng, lnb, U, s);
    if (c < 3) {
      k_front_mx<<<dim3(CH / 128, NH, 3), 256, 0, stream>>>(WW, Km, V, BUF, s);
      k_elem<<<(NH * HD * CH) / (256 * 4), 256, 0, stream>>>(
          BUF, BUF + (size_t)NH * HD * CH, BUF + (size_t)2 * NH * HD * CH);
      k_dwp_mx<<<dim3(8, NH, 3), 256, 0, stream>>>(BUF, Km, V, LR, DWP, s);
      k_dwred<<<3 * NH, 256, 0, stream>>>(DWP, DW);
      k_ns5<<<3 * NH, 1024, 0, stream>>>(DW);
      k_apply<<<3 * NH * HD, 64, 0, stream>>>(WW, DW, WN0);
    }
  }
  k_tcast<<<dim3(DMODEL / 64, DMODEL / 64), 256, 0, stream>>>(Wo, Wot, DMODEL, DMODEL);
  k_final_mfma<<<dim3(LSEQ / 128, DMODEL / 128), 256, 0, stream>>>(U, Wot, (float*)d_out);
}

// Round 7
// 1402.228 us; speedup vs baseline: 4.2777x; 1.1371x over previous
//
#include <hip/hip_runtime.h>
#include <hip/hip_bf16.h>
#include <cstdint>
#include <cstddef>

#define LSEQ   8192
#define DMODEL 2048
#define NH     16      // heads == groups
#define HD     128     // head dim == hidden dim
#define CH     2048    // chunk length (group-space positions)

typedef __attribute__((ext_vector_type(8))) __bf16 bf16x8;
typedef __attribute__((ext_vector_type(4))) float f32x4;

// ---------------------------------------------------------------- helpers

__device__ __forceinline__ float wave_sum64(float v) {
#pragma unroll
  for (int m = 32; m; m >>= 1) v += __shfl_xor(v, m, 64);
  return v;
}

__device__ __forceinline__ float sigm(float x) { return 1.0f / (1.0f + expf(-x)); }

// RTNE float -> bf16 bits
__device__ __forceinline__ unsigned short f2bf(float f) {
  unsigned int u = __float_as_uint(f);
  u += 0x7FFFu + ((u >> 16) & 1u);
  return (unsigned short)(u >> 16);
}
__device__ __forceinline__ float bf2f(unsigned short h) {
  return __uint_as_float((unsigned int)h << 16);
}

// async global->LDS, 16B per lane.
__device__ __forceinline__ void gload_lds16(const void* g, void* l) {
  __builtin_amdgcn_global_load_lds((__attribute__((address_space(1))) void*)(g),
                                   (__attribute__((address_space(3))) void*)(l), 16, 0, 0);
}

union bfu8 { bf16x8 v; unsigned short u[8]; };

// ---------------------------------------------------------------- casts

__global__ void k_cast(const float* __restrict__ X, unsigned short* __restrict__ Xb, int n4) {
  int i = blockIdx.x * 256 + threadIdx.x;
  int stride = gridDim.x * 256;
  for (; i < n4; i += stride) {
    float4 v = ((const float4*)X)[i];
    ushort4 o;
    o.x = f2bf(v.x); o.y = f2bf(v.y); o.z = f2bf(v.z); o.w = f2bf(v.w);
    ((ushort4*)Xb)[i] = o;
  }
}

// W (K x N, fp32) -> Wt (N x K, bf16). grid (N/64, K/64), block 256.
__global__ void k_tcast(const float* __restrict__ W, unsigned short* __restrict__ Wt,
                        int K, int N) {
  __shared__ float t[64][65];
  const int n0 = blockIdx.x * 64, k0 = blockIdx.y * 64;
  const int tid = threadIdx.x;
  const int cx = tid & 63, ry = tid >> 6;
#pragma unroll
  for (int r = 0; r < 16; ++r) {
    int row = ry + r * 4;
    t[row][cx] = W[(size_t)(k0 + row) * N + n0 + cx];
  }
  __syncthreads();
#pragma unroll
  for (int r = 0; r < 16; ++r) {
    int nn = ry + r * 4;
    Wt[(size_t)(n0 + nn) * K + k0 + cx] = f2bf(t[cx][nn]);
  }
}

// ---------------------------------------------------------------- bf16 MFMA GEMM core (m97 style)

__device__ __forceinline__ void gemm_core(const unsigned short* __restrict__ A,
                                          const unsigned short* __restrict__ B,
                                          int K, int ldA, int ldB, int row0, int col0,
                                          unsigned short* Al, unsigned short* Bl,
                                          f32x4 acc[4][4]) {
  const int tid = threadIdx.x;
  const int w = tid >> 6, l = tid & 63;
  const int lrow = l & 15, lk = (l >> 4) * 8;
  const int wr = (w >> 1) * 64, wc = (w & 1) * 64;
  const int srow = l >> 2, skk = (l & 3) * 8;

  for (int kk = 0; kk < K; kk += 32) {
#pragma unroll
    for (int q = 0; q < 2; ++q) {
      int c = w * 2 + q;
      gload_lds16(A + (size_t)(row0 + c * 16 + srow) * ldA + kk + skk, &Al[c * 512]);
      gload_lds16(B + (size_t)(col0 + c * 16 + srow) * ldB + kk + skk, &Bl[c * 512]);
    }
    __syncthreads();
    bf16x8 af[4], bfr[4];
#pragma unroll
    for (int m = 0; m < 4; ++m)
      af[m] = *(const bf16x8*)&Al[(wr + m * 16 + lrow) * 32 + lk];
#pragma unroll
    for (int n = 0; n < 4; ++n)
      bfr[n] = *(const bf16x8*)&Bl[(wc + n * 16 + lrow) * 32 + lk];
#pragma unroll
    for (int m = 0; m < 4; ++m)
#pragma unroll
      for (int n = 0; n < 4; ++n)
        acc[m][n] = __builtin_amdgcn_mfma_f32_16x16x32_bf16(af[m], bfr[n], acc[m][n], 0, 0, 0);
    __syncthreads();
  }
}

// ---------------------------------------------------------------- swizzled LDS helpers (bf16 128x128)

__device__ __forceinline__ bf16x8 ld_sw(const unsigned short* base, int row, int kcol) {
  int byte = (row * 256 + kcol * 2) ^ ((row & 7) << 4);
  return *(const bf16x8*)((const char*)base + byte);
}
__device__ __forceinline__ void st_sw(unsigned short* base, int row, int col, unsigned short v) {
  int byte = (row * 256 + col * 2) ^ ((row & 7) << 4);
  *(unsigned short*)((char*)base + byte) = v;
}
__device__ __forceinline__ unsigned short ld_sw1(const unsigned short* base, int row, int col) {
  int byte = (row * 256 + col * 2) ^ ((row & 7) << 4);
  return *(const unsigned short*)((const char*)base + byte);
}

// fp32 [128 rows][ld] -> swizzled bf16 (256-thread version)
__device__ __forceinline__ void stage_sw(const float* __restrict__ src, int ld,
                                         unsigned short* dst, int tid) {
#pragma unroll
  for (int p = 0; p < 16; ++p) {
    int row = p * 8 + (tid >> 5);
    int col = (tid & 31) * 4;
    float4 v = *(const float4*)(src + (size_t)row * ld + col);
    int byte = (row * 256 + col * 2) ^ ((row & 7) << 4);
    unsigned short* d = (unsigned short*)((char*)dst + byte);
    d[0] = f2bf(v.x); d[1] = f2bf(v.y); d[2] = f2bf(v.z); d[3] = f2bf(v.w);
  }
}

// fp32 -> swizzled hi/lo pair (256-thread version)
__device__ __forceinline__ void stage_hl(const float* __restrict__ src, int ld,
                                         unsigned short* H, unsigned short* L, int tid) {
#pragma unroll
  for (int p = 0; p < 16; ++p) {
    int row = p * 8 + (tid >> 5);
    int col = (tid & 31) * 4;
    float4 v = *(const float4*)(src + (size_t)row * ld + col);
    int byte = (row * 256 + col * 2) ^ ((row & 7) << 4);
    unsigned short* h = (unsigned short*)((char*)H + byte);
    unsigned short* l = (unsigned short*)((char*)L + byte);
    const float* pv = (const float*)&v;
#pragma unroll
    for (int i = 0; i < 4; ++i) {
      unsigned short hi = f2bf(pv[i]);
      h[i] = hi;
      l[i] = f2bf(pv[i] - bf2f(hi));
    }
  }
}

// fp32 -> swizzled hi/lo pair (1024-thread version)
__device__ __forceinline__ void stage_hl_1024(const float* __restrict__ src, int ld,
                                              unsigned short* H, unsigned short* L, int tid) {
#pragma unroll
  for (int p = 0; p < 4; ++p) {
    int row = p * 32 + (tid >> 5);
    int col = (tid & 31) * 4;
    float4 v = *(const float4*)(src + (size_t)row * ld + col);
    int byte = (row * 256 + col * 2) ^ ((row & 7) << 4);
    unsigned short* h = (unsigned short*)((char*)H + byte);
    unsigned short* l = (unsigned short*)((char*)L + byte);
    const float* pv = (const float*)&v;
#pragma unroll
    for (int i = 0; i < 4; ++i) {
      unsigned short hi = f2bf(pv[i]);
      h[i] = hi;
      l[i] = f2bf(pv[i] - bf2f(hi));
    }
  }
}

// transposed + per-row scale: src [128 t][ld], scale lr[t] -> LDS[d][t] hi/lo
__device__ __forceinline__ void stage_hl_ts(const float* __restrict__ src, int ld,
                                            const float* __restrict__ lr,
                                            unsigned short* H, unsigned short* L, int tid) {
#pragma unroll
  for (int p = 0; p < 16; ++p) {
    int t = p * 8 + (tid >> 5);
    int d = (tid & 31) * 4;
    float4 v = *(const float4*)(src + (size_t)t * ld + d);
    float sc = lr[t];
    const float* pv = (const float*)&v;
#pragma unroll
    for (int i = 0; i < 4; ++i) {
      float x = pv[i] * sc;
      unsigned short hi = f2bf(x);
      st_sw(H, d + i, t, hi);
      st_sw(L, d + i, t, f2bf(x - bf2f(hi)));
    }
  }
}

// ---------------------------------------------------------------- init w + row norms (+ w1^T copy)

__global__ void k_init_w(const float* __restrict__ w0, const float* __restrict__ w1,
                         const float* __restrict__ w2, float* __restrict__ WW,
                         float* __restrict__ WN0, float* __restrict__ W1T) {
  int rid = blockIdx.x;
  int m = rid >> 11;
  int gr = rid & 2047;
  const float* src = (m == 0) ? w0 : (m == 1) ? w1 : w2;
  const float* row = src + (size_t)gr * HD;
  float* drow = WW + ((size_t)m * 2048 + gr) * HD;
  int l = threadIdx.x;
  float v0 = row[l], v1 = row[l + 64];
  drow[l] = v0; drow[l + 64] = v1;
  if (m == 1) {
    int g = gr >> 7, r = gr & 127;
    W1T[((size_t)g * 128 + l) * 128 + r] = v0;
    W1T[((size_t)g * 128 + l + 64) * 128 + r] = v1;
  }
  float s = wave_sum64(v0 * v0 + v1 * v1);
  if (l == 0) WN0[rid] = sqrtf(s);
}

// ---------------------------------------------------------------- qkv projection (bf16 MFMA)

__global__ __launch_bounds__(256) void k_qkv_mfma(const unsigned short* __restrict__ xb,
                                                  const unsigned short* __restrict__ Wqt,
                                                  float* __restrict__ Q, float* __restrict__ Km,
                                                  float* __restrict__ V) {
  __shared__ unsigned short Al[128 * 32];
  __shared__ unsigned short Bl[128 * 32];
  f32x4 acc[4][4];
#pragma unroll
  for (int m = 0; m < 4; ++m)
#pragma unroll
    for (int n = 0; n < 4; ++n) acc[m][n] = {};

  gemm_core(xb, Wqt, DMODEL, DMODEL, DMODEL, blockIdx.x * 128, blockIdx.y * 128, Al, Bl, acc);

  const int ct = blockIdx.y, hh = ct / 3, which = ct % 3;
  float* dst = (which == 0) ? Q : (which == 1) ? Km : V;
  const int tid = threadIdx.x, w = tid >> 6, l = tid & 63;
  const int wr = (w >> 1) * 64, wc = (w & 1) * 64;
#pragma unroll
  for (int m = 0; m < 4; ++m)
#pragma unroll
    for (int j = 0; j < 4; ++j) {
      int t = blockIdx.x * 128 + wr + m * 16 + (l >> 4) * 4 + j;
      int fth = t * NH + hh;
      int g = fth >> 13, tp = fth & 8191;
      float* drow = dst + ((size_t)g * LSEQ + tp) * HD;
#pragma unroll
      for (int n = 0; n < 4; ++n) {
        float v = acc[m][n][j];
        drow[wc + n * 16 + (l & 15)] = v * sigm(v);
      }
    }
}

// normalize Q and K rows in place.
__global__ void k_l2norm(float* __restrict__ Q, float* __restrict__ Km) {
  int rid = blockIdx.x * 4 + (threadIdx.x >> 6);
  int l = threadIdx.x & 63;
  float* base = (rid < NH * LSEQ) ? Q : Km;
  int r = (rid < NH * LSEQ) ? rid : rid - NH * LSEQ;
  float* row = base + (size_t)r * HD;
  float v0 = row[l], v1 = row[l + 64];
  float s = wave_sum64(v0 * v0 + v1 * v1);
  float f = 1.0f / (sqrtf(s) + 1e-5f);
  row[l] = v0 * f;
  row[l + 64] = v1 * f;
}

// ---------------------------------------------------------------- lr / scale: K-split GEMM + reduce

// grid (128, 16): 64 tokens x 64 cols x 128-K slice per block.
__global__ __launch_bounds__(256) void k_lrms5(const float* __restrict__ x,
                                               const float* __restrict__ Wlr,
                                               const float* __restrict__ Wsc,
                                               float* __restrict__ P) {
  __shared__ float Xs[128][67];
  __shared__ float Ws[128][68];
  const int tb = blockIdx.x;
  const int kp = blockIdx.y;
  const int tid = threadIdx.x;
  for (int i = tid; i < 128 * 64; i += 256) {
    int k = i >> 6, c = i & 63;
    float wv = (c < 48) ? Wlr[(size_t)(kp * 128 + k) * 48 + c]
                        : Wsc[(size_t)(kp * 128 + k) * 16 + (c - 48)];
    Ws[k][c] = wv;
  }
  const int t8 = tid >> 5, kk = tid & 31;
#pragma unroll
  for (int r = 0; r < 8; ++r) {
    int t = t8 + r * 8;
    float4 v = *(const float4*)(x + (size_t)(tb * 64 + t) * DMODEL + kp * 128 + kk * 4);
    Xs[kk * 4 + 0][t] = v.x; Xs[kk * 4 + 1][t] = v.y;
    Xs[kk * 4 + 2][t] = v.z; Xs[kk * 4 + 3][t] = v.w;
  }
  __syncthreads();
  const int ty = tid >> 4, tx = tid & 15;
  float acc[4][4];
#pragma unroll
  for (int i = 0; i < 4; ++i)
#pragma unroll
    for (int j = 0; j < 4; ++j) acc[i][j] = 0.0f;
  for (int k = 0; k < 128; ++k) {
    float a[4], b[4];
#pragma unroll
    for (int i = 0; i < 4; ++i) a[i] = Xs[k][ty * 4 + i];
#pragma unroll
    for (int j = 0; j < 4; ++j) b[j] = Ws[k][tx * 4 + j];
#pragma unroll
    for (int i = 0; i < 4; ++i)
#pragma unroll
      for (int j = 0; j < 4; ++j) acc[i][j] = fmaf(a[i], b[j], acc[i][j]);
  }
  float* o = P + ((size_t)tb * 16 + kp) * 4096;
#pragma unroll
  for (int i = 0; i < 4; ++i)
#pragma unroll
    for (int j = 0; j < 4; ++j)
      o[(ty * 4 + i) * 64 + tx * 4 + j] = acc[i][j];
}

__global__ void k_lrsum(const float* __restrict__ P, const float* __restrict__ bs,
                        float* __restrict__ LR, float* __restrict__ SCL) {
  int e = blockIdx.x * 256 + threadIdx.x;
  int t = e >> 6, c = e & 63;
  const float* base = P + ((size_t)(t >> 6) * 16) * 4096 + (t & 63) * 64 + c;
  float sum = 0.0f;
#pragma unroll
  for (int kp = 0; kp < 16; ++kp) sum += base[(size_t)kp * 4096];
  if (c < 48) {
    float base_lr_inv = 0.01f + logf(-expm1f(-0.01f));
    float v = sum + base_lr_inv;
    float sp = fmaxf(v, 0.0f) + log1pf(expf(-fabsf(v)));
    LR[(size_t)c * LSEQ + t] = sp;
  } else {
    float v = sum + bs[c - 48];
    SCL[(size_t)(c - 48) * LSEQ + t] = v * sigm(v);
  }
}

// ---------------------------------------------------------------- per-chunk output (bf16 MFMA + fused LN/scale)

__global__ __launch_bounds__(256) void k_out2(const float* __restrict__ WW,
                                              const float* __restrict__ Q,
                                              const float* __restrict__ SCL,
                                              const float* __restrict__ lng,
                                              const float* __restrict__ lnb,
                                              unsigned short* __restrict__ U, int s) {
  __shared__ __align__(16) char smem[131072];
  unsigned short* Qs  = (unsigned short*)smem;
  unsigned short* W0s = (unsigned short*)(smem + 32768);
  unsigned short* W2s = (unsigned short*)(smem + 65536);
  unsigned short* GHs = (unsigned short*)(smem + 98304);
  float* Os = (float*)smem;

  const int g = blockIdx.y;
  const int t0 = blockIdx.x * 128;
  const int tid = threadIdx.x;
  const int w = tid >> 6, l = tid & 63;
  const int lrow = l & 15, lk8 = (l >> 4) * 8;
  const int wr = (w >> 1) * 64, wc = (w & 1) * 64;

  const float* Qg  = Q + ((size_t)g * LSEQ + s + t0) * HD;
  const float* w0g = WW + ((size_t)0 * 2048 + g * 128) * 128;
  const float* w1g = WW + ((size_t)1 * 2048 + g * 128) * 128;
  const float* w2g = WW + ((size_t)2 * 2048 + g * 128) * 128;

  stage_sw(Qg, HD, Qs, tid);
  stage_sw(w0g, 128, W0s, tid);
  stage_sw(w2g, 128, W2s, tid);
  __syncthreads();

  f32x4 ga[4][4], ha[4][4];
#pragma unroll
  for (int m = 0; m < 4; ++m)
#pragma unroll
    for (int n = 0; n < 4; ++n) { ga[m][n] = {}; ha[m][n] = {}; }
#pragma unroll
  for (int kk = 0; kk < 128; kk += 32) {
    bf16x8 af[4], b0[4], b2[4];
#pragma unroll
    for (int m = 0; m < 4; ++m) af[m] = ld_sw(Qs, wr + m * 16 + lrow, kk + lk8);
#pragma unroll
    for (int n = 0; n < 4; ++n) {
      b0[n] = ld_sw(W0s, wc + n * 16 + lrow, kk + lk8);
      b2[n] = ld_sw(W2s, wc + n * 16 + lrow, kk + lk8);
    }
#pragma unroll
    for (int m = 0; m < 4; ++m)
#pragma unroll
      for (int n = 0; n < 4; ++n) {
        ga[m][n] = __builtin_amdgcn_mfma_f32_16x16x32_bf16(af[m], b0[n], ga[m][n], 0, 0, 0);
        ha[m][n] = __builtin_amdgcn_mfma_f32_16x16x32_bf16(af[m], b2[n], ha[m][n], 0, 0, 0);
      }
  }
#pragma unroll
  for (int m = 0; m < 4; ++m)
#pragma unroll
    for (int n = 0; n < 4; ++n)
#pragma unroll
      for (int j = 0; j < 4; ++j) {
        int row = wr + m * 16 + (l >> 4) * 4 + j;
        int col = wc + n * 16 + (l & 15);
        float gv = ga[m][n][j];
        st_sw(GHs, row, col, f2bf(gv * sigm(gv) * ha[m][n][j]));
      }
  __syncthreads();
  stage_sw(w1g, 128, W0s, tid);
  __syncthreads();

  f32x4 oa[4][4];
#pragma unroll
  for (int m = 0; m < 4; ++m)
#pragma unroll
    for (int n = 0; n < 4; ++n) oa[m][n] = {};
#pragma unroll
  for (int kk = 0; kk < 128; kk += 32) {
    bf16x8 af[4], b1[4];
#pragma unroll
    for (int m = 0; m < 4; ++m) af[m] = ld_sw(GHs, wr + m * 16 + lrow, kk + lk8);
#pragma unroll
    for (int n = 0; n < 4; ++n) b1[n] = ld_sw(W0s, wc + n * 16 + lrow, kk + lk8);
#pragma unroll
    for (int m = 0; m < 4; ++m)
#pragma unroll
      for (int n = 0; n < 4; ++n)
        oa[m][n] = __builtin_amdgcn_mfma_f32_16x16x32_bf16(af[m], b1[n], oa[m][n], 0, 0, 0);
  }
  __syncthreads();
#pragma unroll
  for (int m = 0; m < 4; ++m)
#pragma unroll
    for (int n = 0; n < 4; ++n)
#pragma unroll
      for (int j = 0; j < 4; ++j) {
        int row = wr + m * 16 + (l >> 4) * 4 + j;
        int col = wc + n * 16 + (l & 15);
        Os[row * 132 + col] = oa[m][n][j];
      }
  __syncthreads();

  const int tok = tid >> 1, part = tid & 1;
  const float* orow = Os + tok * 132 + part * 64;
  float sum = 0.0f;
#pragma unroll
  for (int q = 0; q < 16; ++q) {
    float4 v = *(const float4*)(orow + q * 4);
    sum += (v.x + v.y) + (v.z + v.w);
  }
  sum += __shfl_xor(sum, 1, 64);
  float mu = sum * (1.0f / 128.0f);
  float vs = 0.0f;
#pragma unroll
  for (int q = 0; q < 16; ++q) {
    float4 v = *(const float4*)(orow + q * 4);
    float d0 = v.x - mu, d1 = v.y - mu, d2 = v.z - mu, d3 = v.w - mu;
    vs += d0 * d0 + d1 * d1 + d2 * d2 + d3 * d3;
  }
  vs += __shfl_xor(vs, 1, 64);
  float rstd = rsqrtf(vs * (1.0f / 128.0f) + 1e-6f);
  int tabs = s + t0 + tok;
  float sc = SCL[(size_t)g * LSEQ + tabs];
  unsigned short* urow = U + (size_t)tabs * DMODEL + g * HD + part * 64;
#pragma unroll
  for (int q = 0; q < 16; ++q) {
    float4 v = *(const float4*)(orow + q * 4);
    int d = part * 64 + q * 4;
    ushort4 o;
    o.x = f2bf(((v.x - mu) * rstd * lng[d + 0] + lnb[d + 0]) * sc);
    o.y = f2bf(((v.y - mu) * rstd * lng[d + 1] + lnb[d + 1]) * sc);
    o.z = f2bf(((v.z - mu) * rstd * lng[d + 2] + lnb[d + 2]) * sc);
    o.w = f2bf(((v.w - mu) * rstd * lng[d + 3] + lnb[d + 3]) * sc);
    *(ushort4*)(urow + q * 4) = o;
  }
}

// ---------------------------------------------------------------- fused front GEMMs + elementwise
// grid (CH/128, NH), block 1024 (16 waves, 4x4, 32x32 tiles).
// Computes Gb=w0@K^T, Hb=w2@K^T, Dh=w1^T@V^T at identical frag coords (split-bf16,
// K/V staged hi/lo in LDS; w operand frags read from global L2), applies silu
// backprop in regs, writes hid/dgb/dhb to BUF.
__global__ __launch_bounds__(1024) void k_fe(const float* __restrict__ WW,
                                             const float* __restrict__ W1T,
                                             const float* __restrict__ Km,
                                             const float* __restrict__ V,
                                             float* __restrict__ BUF, int s) {
  __shared__ __align__(16) char smem[131072];
  unsigned short* KH = (unsigned short*)smem;
  unsigned short* KL = (unsigned short*)(smem + 32768);
  unsigned short* VH = (unsigned short*)(smem + 65536);
  unsigned short* VL = (unsigned short*)(smem + 98304);

  const int tt0 = blockIdx.x * 128;
  const int g = blockIdx.y;
  const int tid = threadIdx.x;
  const int w = tid >> 6, l = tid & 63;
  const int ww = w >> 2, wv = w & 3;
  const int lrow = l & 15, lk8 = (l >> 4) * 8;
  const int frow = (l >> 4) * 4, fcol = l & 15;

  stage_hl_1024(Km + ((size_t)g * LSEQ + s + tt0) * HD, HD, KH, KL, tid);
  stage_hl_1024(V + ((size_t)g * LSEQ + s + tt0) * HD, HD, VH, VL, tid);
  __syncthreads();

  const float* Asrc[3];
  Asrc[0] = WW + ((size_t)0 * 2048 + g * 128) * 128;  // w0 rows
  Asrc[1] = WW + ((size_t)2 * 2048 + g * 128) * 128;  // w2 rows
  Asrc[2] = W1T + (size_t)g * 16384;                  // w1^T rows

  f32x4 acc[3][2][2];
#pragma unroll
  for (int q = 0; q < 3; ++q)
#pragma unroll
    for (int m = 0; m < 2; ++m)
#pragma unroll
      for (int n = 0; n < 2; ++n) acc[q][m][n] = {};

#pragma unroll 1
  for (int q = 0; q < 3; ++q) {
    const float* src = Asrc[q];
    const unsigned short* BH = (q == 2) ? VH : KH;
    const unsigned short* BL = (q == 2) ? VL : KL;
#pragma unroll
    for (int kk = 0; kk < 128; kk += 32) {
      bf16x8 ah[2], al[2], bh[2], bl[2];
#pragma unroll
      for (int m = 0; m < 2; ++m) {
        int row = ww * 32 + m * 16 + lrow;
        float4 v0 = *(const float4*)(src + (size_t)row * 128 + kk + lk8);
        float4 v1 = *(const float4*)(src + (size_t)row * 128 + kk + lk8 + 4);
        bfu8 h, lo;
        const float* p0 = (const float*)&v0;
        const float* p1 = (const float*)&v1;
#pragma unroll
        for (int i = 0; i < 4; ++i) {
          unsigned short hb0 = f2bf(p0[i]);
          h.u[i] = hb0; lo.u[i] = f2bf(p0[i] - bf2f(hb0));
          unsigned short hb1 = f2bf(p1[i]);
          h.u[i + 4] = hb1; lo.u[i + 4] = f2bf(p1[i] - bf2f(hb1));
        }
        ah[m] = h.v; al[m] = lo.v;
      }
#pragma unroll
      for (int n = 0; n < 2; ++n) {
        int row = wv * 32 + n * 16 + lrow;
        bh[n] = ld_sw(BH, row, kk + lk8);
        bl[n] = ld_sw(BL, row, kk + lk8);
      }
#pragma unroll
      for (int m = 0; m < 2; ++m)
#pragma unroll
        for (int n = 0; n < 2; ++n) {
          acc[q][m][n] = __builtin_amdgcn_mfma_f32_16x16x32_bf16(ah[m], bh[n], acc[q][m][n], 0, 0, 0);
          acc[q][m][n] = __builtin_amdgcn_mfma_f32_16x16x32_bf16(ah[m], bl[n], acc[q][m][n], 0, 0, 0);
          acc[q][m][n] = __builtin_amdgcn_mfma_f32_16x16x32_bf16(al[m], bh[n], acc[q][m][n], 0, 0, 0);
        }
    }
  }

  float* out0 = BUF + (size_t)0 * (NH * 128 * CH) + (size_t)g * 128 * CH;  // hid
  float* out1 = BUF + (size_t)1 * (NH * 128 * CH) + (size_t)g * 128 * CH;  // dgb
  float* out2 = BUF + (size_t)2 * (NH * 128 * CH) + (size_t)g * 128 * CH;  // dhb
#pragma unroll
  for (int m = 0; m < 2; ++m)
#pragma unroll
    for (int n = 0; n < 2; ++n)
#pragma unroll
      for (int j = 0; j < 4; ++j) {
        int row = ww * 32 + m * 16 + frow + j;
        int col = wv * 32 + n * 16 + fcol;
        float gb = acc[0][m][n][j];
        float hb = acc[1][m][n][j];
        float dh = acc[2][m][n][j];
        float sg = sigm(gb);
        float sgb = gb * sg;
        float hid = sgb * hb;
        float dgate = dh * hb;
        float dgb = dgate * sg * (1.0f + gb * (1.0f - sg));
        float dhb = dh * sgb;
        size_t o = (size_t)row * CH + tt0 + col;
        out0[o] = hid; out1[o] = dgb; out2[o] = dhb;
      }
}

// partial dW GEMMs over 256-token slices (split-bf16). grid (8, NH, 3).
__global__ __launch_bounds__(256) void k_dwp_mx(const float* __restrict__ BUF,
                                                const float* __restrict__ Km,
                                                const float* __restrict__ V,
                                                const float* __restrict__ LR,
                                                float* __restrict__ DWP, int s) {
  __shared__ __align__(16) char smem[131072];
  unsigned short* AH = (unsigned short*)smem;
  unsigned short* AL = (unsigned short*)(smem + 32768);
  unsigned short* BH = (unsigned short*)(smem + 65536);
  unsigned short* BL = (unsigned short*)(smem + 98304);

  const int p = blockIdx.x;
  const int g = blockIdx.y;
  const int z = blockIdx.z;
  const int tid = threadIdx.x;
  const int w = tid >> 6, l = tid & 63;
  const int lrow = l & 15, lk8 = (l >> 4) * 8;
  const int wr = (w >> 1) * 64, wc = (w & 1) * 64;

  const int msel = (z == 0) ? 1 : (z == 1) ? 0 : 2;
  const float* M = BUF + (size_t)msel * (NH * 128 * CH) + (size_t)g * 128 * CH;
  const float* N = (z == 1) ? V : Km;
  const float* lr = LR + (size_t)(z * NH + g) * LSEQ;
  const int ts = p * 256;

  f32x4 acc[4][4];
#pragma unroll
  for (int m = 0; m < 4; ++m)
#pragma unroll
    for (int n = 0; n < 4; ++n) acc[m][n] = {};

  for (int h = 0; h < 2; ++h) {
    if (h) __syncthreads();
    stage_hl(M + ts + h * 128, CH, AH, AL, tid);
    stage_hl_ts(N + ((size_t)g * LSEQ + s + ts + h * 128) * HD, HD,
                lr + s + ts + h * 128, BH, BL, tid);
    __syncthreads();
#pragma unroll
    for (int kk = 0; kk < 128; kk += 32) {
      bf16x8 ah[4], al4[4], bh[4], bl4[4];
#pragma unroll
      for (int m = 0; m < 4; ++m) {
        ah[m] = ld_sw(AH, wr + m * 16 + lrow, kk + lk8);
        al4[m] = ld_sw(AL, wr + m * 16 + lrow, kk + lk8);
      }
#pragma unroll
      for (int n = 0; n < 4; ++n) {
        bh[n] = ld_sw(BH, wc + n * 16 + lrow, kk + lk8);
        bl4[n] = ld_sw(BL, wc + n * 16 + lrow, kk + lk8);
      }
#pragma unroll
      for (int m = 0; m < 4; ++m)
#pragma unroll
        for (int n = 0; n < 4; ++n) {
          acc[m][n] = __builtin_amdgcn_mfma_f32_16x16x32_bf16(ah[m], bh[n], acc[m][n], 0, 0, 0);
          acc[m][n] = __builtin_amdgcn_mfma_f32_16x16x32_bf16(ah[m], bl4[n], acc[m][n], 0, 0, 0);
          acc[m][n] = __builtin_amdgcn_mfma_f32_16x16x32_bf16(al4[m], bh[n], acc[m][n], 0, 0, 0);
        }
    }
  }

  float* outp = DWP + (((size_t)(z * NH + g)) * 8 + p) * 16384;
#pragma unroll
  for (int m = 0; m < 4; ++m)
#pragma unroll
    for (int n = 0; n < 4; ++n)
#pragma unroll
      for (int j = 0; j < 4; ++j) {
        int row = wr + m * 16 + (l >> 4) * 4 + j;
        int col = wc + n * 16 + (l & 15);
        outp[row * 128 + col] = acc[m][n][j];
      }
}

// reduce 8 partials; transpose dw1 (z==1).
__global__ void k_dwred(const float* __restrict__ DWP, float* __restrict__ DW) {
  int zg = blockIdx.x;
  int z = zg >> 4;
  const float* base = DWP + (size_t)zg * 8 * 16384;
  float* out = DW + (size_t)zg * 16384;
  for (int idx = threadIdx.x; idx < 16384; idx += 256) {
    float sv = 0.0f;
#pragma unroll
    for (int pp = 0; pp < 8; ++pp) sv += base[(size_t)pp * 16384 + idx];
    int oidx = (z == 1) ? ((idx & 127) * 128 + (idx >> 7)) : idx;
    out[oidx] = sv;
  }
}

// ---------------------------------------------------------------- Newton-Schulz 5 (split-bf16 MFMA)
// One 128x128 matrix per block, 1024 threads = 16 waves (4x4 of 32x32 tiles).
// P holds the iterate (possibly transposed; f(Y^T)=f(Y)^T makes this exact),
// Q holds A then Bm. All matmuls use row-operands; the Bm@X step computes
// Xn^T = a*Y^T + Y^T@Bm after an in-LDS transpose of Y. After 5 iterations
// P = X5^T; the global writeback un-transposes.
__global__ __launch_bounds__(1024) void k_ns5_mfma(float* __restrict__ DW) {
  __shared__ __align__(16) char smem[131072];
  unsigned short* PH = (unsigned short*)smem;
  unsigned short* PL = (unsigned short*)(smem + 32768);
  unsigned short* QH = (unsigned short*)(smem + 65536);
  unsigned short* QL = (unsigned short*)(smem + 98304);
  float* red = (float*)(smem + 65536);  // norm scratch (pre-loop only)

  const float NA[5] = {4.0848f, 3.9505f, 3.7418f, 2.8769f, 2.8366f};
  const float NB[5] = {-6.8946f, -6.3029f, -5.5913f, -3.1427f, -3.0525f};
  const float NC[5] = {2.927f, 2.6377f, 2.3037f, 1.2046f, 1.2012f};
  float* Gm = DW + (size_t)blockIdx.x * 16384;
  const int tid = threadIdx.x;
  const int w = tid >> 6, l = tid & 63;
  const int ww = w >> 2, wv = w & 3;
  const int lrow = l & 15, lk8 = (l >> 4) * 8;
  const int frow = (l >> 4) * 4, fcol = l & 15;

  // load + Frobenius norm + split into P
  float vals[16];
  float psum = 0.0f;
#pragma unroll
  for (int r = 0; r < 16; ++r) {
    vals[r] = Gm[tid + r * 1024];
    psum = fmaf(vals[r], vals[r], psum);
  }
  psum = wave_sum64(psum);
  if (l == 0) red[w] = psum;
  __syncthreads();
  float tot = 0.0f;
#pragma unroll
  for (int i = 0; i < 16; ++i) tot += red[i];
  float scl = 1.0f / (sqrtf(tot) + 1e-7f);
  __syncthreads();
#pragma unroll
  for (int r = 0; r < 16; ++r) {
    int idx = tid + r * 1024;
    int rr = idx >> 7, cc = idx & 127;
    float v = vals[r] * scl;
    unsigned short hi = f2bf(v);
    st_sw(PH, rr, cc, hi);
    st_sw(PL, rr, cc, f2bf(v - bf2f(hi)));
  }
  __syncthreads();

#pragma unroll 1
  for (int it = 0; it < 5; ++it) {
    const float ac = NA[it], bc = NB[it], cc2 = NC[it];

    // Step A: accA = Y @ Y^T (both operands = rows of P)
    f32x4 accA[2][2];
#pragma unroll
    for (int m = 0; m < 2; ++m)
#pragma unroll
      for (int n = 0; n < 2; ++n) accA[m][n] = {};
#pragma unroll
    for (int kk = 0; kk < 128; kk += 32) {
      bf16x8 ah[2], al[2], bh[2], bl[2];
#pragma unroll
      for (int m = 0; m < 2; ++m) {
        ah[m] = ld_sw(PH, ww * 32 + m * 16 + lrow, kk + lk8);
        al[m] = ld_sw(PL, ww * 32 + m * 16 + lrow, kk + lk8);
      }
#pragma unroll
      for (int n = 0; n < 2; ++n) {
        bh[n] = ld_sw(PH, wv * 32 + n * 16 + lrow, kk + lk8);
        bl[n] = ld_sw(PL, wv * 32 + n * 16 + lrow, kk + lk8);
      }
#pragma unroll
      for (int m = 0; m < 2; ++m)
#pragma unroll
        for (int n = 0; n < 2; ++n) {
          accA[m][n] = __builtin_amdgcn_mfma_f32_16x16x32_bf16(ah[m], bh[n], accA[m][n], 0, 0, 0);
          accA[m][n] = __builtin_amdgcn_mfma_f32_16x16x32_bf16(ah[m], bl[n], accA[m][n], 0, 0, 0);
          accA[m][n] = __builtin_amdgcn_mfma_f32_16x16x32_bf16(al[m], bh[n], accA[m][n], 0, 0, 0);
        }
    }
    // write A -> Q
#pragma unroll
    for (int m = 0; m < 2; ++m)
#pragma unroll
      for (int n = 0; n < 2; ++n)
#pragma unroll
        for (int j = 0; j < 4; ++j) {
          int row = ww * 32 + m * 16 + frow + j;
          int col = wv * 32 + n * 16 + fcol;
          float v = accA[m][n][j];
          unsigned short hi = f2bf(v);
          st_sw(QH, row, col, hi);
          st_sw(QL, row, col, f2bf(v - bf2f(hi)));
        }
    __syncthreads();

    // Step B: accB = A @ A (A symmetric; operands = rows of Q)
    f32x4 accB[2][2];
#pragma unroll
    for (int m = 0; m < 2; ++m)
#pragma unroll
      for (int n = 0; n < 2; ++n) accB[m][n] = {};
#pragma unroll
    for (int kk = 0; kk < 128; kk += 32) {
      bf16x8 ah[2], al[2], bh[2], bl[2];
#pragma unroll
      for (int m = 0; m < 2; ++m) {
        ah[m] = ld_sw(QH, ww * 32 + m * 16 + lrow, kk + lk8);
        al[m] = ld_sw(QL, ww * 32 + m * 16 + lrow, kk + lk8);
      }
#pragma unroll
      for (int n = 0; n < 2; ++n) {
        bh[n] = ld_sw(QH, wv * 32 + n * 16 + lrow, kk + lk8);
        bl[n] = ld_sw(QL, wv * 32 + n * 16 + lrow, kk + lk8);
      }
#pragma unroll
      for (int m = 0; m < 2; ++m)
#pragma unroll
        for (int n = 0; n < 2; ++n) {
          accB[m][n] = __builtin_amdgcn_mfma_f32_16x16x32_bf16(ah[m], bh[n], accB[m][n], 0, 0, 0);
          accB[m][n] = __builtin_amdgcn_mfma_f32_16x16x32_bf16(ah[m], bl[n], accB[m][n], 0, 0, 0);
          accB[m][n] = __builtin_amdgcn_mfma_f32_16x16x32_bf16(al[m], bh[n], accB[m][n], 0, 0, 0);
        }
    }
    // Bm = bc*A + cc*A2 in regs (accA still live, same coords)
#pragma unroll
    for (int m = 0; m < 2; ++m)
#pragma unroll
      for (int n = 0; n < 2; ++n)
#pragma unroll
        for (int j = 0; j < 4; ++j)
          accB[m][n][j] = fmaf(bc, accA[m][n][j], cc2 * accB[m][n][j]);
    __syncthreads();  // all reads of A done
    // write Bm -> Q; read P for transpose
#pragma unroll
    for (int m = 0; m < 2; ++m)
#pragma unroll
      for (int n = 0; n < 2; ++n)
#pragma unroll
        for (int j = 0; j < 4; ++j) {
          int row = ww * 32 + m * 16 + frow + j;
          int col = wv * 32 + n * 16 + fcol;
          float v = accB[m][n][j];
          unsigned short hi = f2bf(v);
          st_sw(QH, row, col, hi);
          st_sw(QL, row, col, f2bf(v - bf2f(hi)));
        }
    unsigned short th[16], tl[16];
#pragma unroll
    for (int r = 0; r < 16; ++r) {
      int idx = tid + r * 1024;
      int rr = idx >> 7, ccx = idx & 127;
      th[r] = ld_sw1(PH, rr, ccx);
      tl[r] = ld_sw1(PL, rr, ccx);
    }
    __syncthreads();  // Bm visible; transpose reads complete
#pragma unroll
    for (int r = 0; r < 16; ++r) {
      int idx = tid + r * 1024;
      int rr = idx >> 7, ccx = idx & 127;
      st_sw(PH, ccx, rr, th[r]);
      st_sw(PL, ccx, rr, tl[r]);
    }
    __syncthreads();  // P now holds Y^T

    // Step C: accC = Y^T @ Bm + ac*Y^T  -> Xn^T
    f32x4 accC[2][2];
#pragma unroll
    for (int m = 0; m < 2; ++m)
#pragma unroll
      for (int n = 0; n < 2; ++n) accC[m][n] = {};
#pragma unroll
    for (int kk = 0; kk < 128; kk += 32) {
      bf16x8 ah[2], al[2], bh[2], bl[2];
#pragma unroll
      for (int m = 0; m < 2; ++m) {
        ah[m] = ld_sw(PH, ww * 32 + m * 16 + lrow, kk + lk8);
        al[m] = ld_sw(PL, ww * 32 + m * 16 + lrow, kk + lk8);
      }
#pragma unroll
      for (int n = 0; n < 2; ++n) {
        bh[n] = ld_sw(QH, wv * 32 + n * 16 + lrow, kk + lk8);
        bl[n] = ld_sw(QL, wv * 32 + n * 16 + lrow, kk + lk8);
      }
#pragma unroll
      for (int m = 0; m < 2; ++m)
#pragma unroll
        for (int n = 0; n < 2; ++n) {
          accC[m][n] = __builtin_amdgcn_mfma_f32_16x16x32_bf16(ah[m], bh[n], accC[m][n], 0, 0, 0);
          accC[m][n] = __builtin_amdgcn_mfma_f32_16x16x32_bf16(ah[m], bl[n], accC[m][n], 0, 0, 0);
          accC[m][n] = __builtin_amdgcn_mfma_f32_16x16x32_bf16(al[m], bh[n], accC[m][n], 0, 0, 0);
        }
    }
#pragma unroll
    for (int m = 0; m < 2; ++m)
#pragma unroll
      for (int n = 0; n < 2; ++n)
#pragma unroll
        for (int j = 0; j < 4; ++j) {
          int row = ww * 32 + m * 16 + frow + j;
          int col = wv * 32 + n * 16 + fcol;
          float yv = bf2f(ld_sw1(PH, row, col)) + bf2f(ld_sw1(PL, row, col));
          accC[m][n][j] = fmaf(ac, yv, accC[m][n][j]);
        }
    __syncthreads();  // all reads of P done
#pragma unroll
    for (int m = 0; m < 2; ++m)
#pragma unroll
      for (int n = 0; n < 2; ++n)
#pragma unroll
        for (int j = 0; j < 4; ++j) {
          int row = ww * 32 + m * 16 + frow + j;
          int col = wv * 32 + n * 16 + fcol;
          float v = accC[m][n][j];
          unsigned short hi = f2bf(v);
          st_sw(PH, row, col, hi);
          st_sw(PL, row, col, f2bf(v - bf2f(hi)));
        }
    __syncthreads();
  }

  // P = X5^T; write back transposed.
#pragma unroll
  for (int r = 0; r < 16; ++r) {
    int idx = tid + r * 1024;
    int rr = idx >> 7, ccx = idx & 127;
    Gm[idx] = bf2f(ld_sw1(PH, ccx, rr)) + bf2f(ld_sw1(PL, ccx, rr));
  }
}

// w += dw; renormalize; maintain W1T.
__global__ void k_apply(float* __restrict__ WW, const float* __restrict__ DW,
                        const float* __restrict__ WN0, float* __restrict__ W1T) {
  int rid = blockIdx.x;
  int m = rid >> 11;
  int gr = rid & 2047;
  int l = threadIdx.x;
  float* wrow = WW + (size_t)rid * 128;
  const float* drow = DW + (size_t)rid * 128;
  float v0 = wrow[l] + drow[l];
  float v1 = wrow[l + 64] + drow[l + 64];
  float s = wave_sum64(v0 * v0 + v1 * v1);
  float f = WN0[rid] / (sqrtf(s) + 1e-5f);
  v0 *= f; v1 *= f;
  wrow[l] = v0;
  wrow[l + 64] = v1;
  if (m == 1) {
    int g = gr >> 7, r = gr & 127;
    W1T[((size_t)g * 128 + l) * 128 + r] = v0;
    W1T[((size_t)g * 128 + l + 64) * 128 + r] = v1;
  }
}

// ---------------------------------------------------------------- final projection (bf16 MFMA)

__global__ __launch_bounds__(256) void k_final_mfma(const unsigned short* __restrict__ U,
                                                    const unsigned short* __restrict__ Wot,
                                                    float* __restrict__ out) {
  __shared__ unsigned short Al[128 * 32];
  __shared__ unsigned short Bl[128 * 32];
  f32x4 acc[4][4];
#pragma unroll
  for (int m = 0; m < 4; ++m)
#pragma unroll
    for (int n = 0; n < 4; ++n) acc[m][n] = {};

  const int row0 = blockIdx.x * 128, col0 = blockIdx.y * 128;
  gemm_core(U, Wot, DMODEL, DMODEL, DMODEL, row0, col0, Al, Bl, acc);

  const int tid = threadIdx.x, w = tid >> 6, l = tid & 63;
  const int wr = (w >> 1) * 64, wc = (w & 1) * 64;
#pragma unroll
  for (int m = 0; m < 4; ++m)
#pragma unroll
    for (int j = 0; j < 4; ++j) {
      int t = row0 + wr + m * 16 + (l >> 4) * 4 + j;
      float* orow = out + (size_t)t * DMODEL + col0;
#pragma unroll
      for (int n = 0; n < 4; ++n)
        orow[wc + n * 16 + (l & 15)] = acc[m][n][j];
    }
}

// ---------------------------------------------------------------- launch

extern "C" void kernel_launch(void* const* d_in, const int* in_sizes, int n_in,
                              void* d_out, int out_size, void* d_ws, size_t ws_size,
                              hipStream_t stream) {
  (void)in_sizes; (void)n_in; (void)out_size;
  const float* x    = (const float*)d_in[0];
  const float* Wqkv = (const float*)d_in[1];
  const float* Wlr  = (const float*)d_in[2];
  const float* Wo   = (const float*)d_in[3];
  const float* Wsc  = (const float*)d_in[6];
  const float* bs   = (const float*)d_in[7];
  const float* lng  = (const float*)d_in[8];
  const float* lnb  = (const float*)d_in[9];
  const float* w0   = (const float*)d_in[10];
  const float* w1   = (const float*)d_in[11];
  const float* w2   = (const float*)d_in[12];

  float* Q = (float*)d_out;  // last read (k_out2 chunk 3) precedes k_final's write

  float* ws = (float*)d_ws;
  size_t off = 0;
  auto alloc = [&](size_t n) { float* p = ws + off; off += n; return p; };
  float* Km   = alloc((size_t)NH * LSEQ * HD);
  float* V    = alloc((size_t)NH * LSEQ * HD);
  float* Uf   = alloc((size_t)LSEQ * DMODEL / 2);   // U stored as bf16
  float* LR   = alloc((size_t)3 * NH * LSEQ);
  float* SCL  = alloc((size_t)NH * LSEQ);
  float* WW   = alloc((size_t)3 * NH * HD * HD);
  float* WN0  = alloc((size_t)3 * NH * HD);
  float* W1T  = alloc((size_t)NH * HD * HD);
  float* BUF  = alloc((size_t)3 * NH * HD * CH);    // chunk loop scratch
  float* DW   = alloc((size_t)3 * NH * HD * HD);
  float* DWP  = alloc((size_t)3 * NH * 8 * HD * HD);
  if (off * sizeof(float) > ws_size) return;        // clean failure instead of OOB

  unsigned short* U = (unsigned short*)Uf;
  unsigned short* xb  = (unsigned short*)BUF;                                   // pre-qkv
  unsigned short* Wqt = (unsigned short*)(BUF + (size_t)LSEQ * DMODEL / 2);
  float* Plr = BUF;                                                             // lrms partials
  unsigned short* Wot = (unsigned short*)BUF;                                   // post-loop

  k_init_w<<<3 * NH * HD, 64, 0, stream>>>(w0, w1, w2, WW, WN0, W1T);
  k_cast<<<2048, 256, 0, stream>>>(x, xb, LSEQ * DMODEL / 4);
  k_tcast<<<dim3(3 * DMODEL / 64, DMODEL / 64), 256, 0, stream>>>(Wqkv, Wqt, DMODEL, 3 * DMODEL);
  k_qkv_mfma<<<dim3(LSEQ / 128, 48), 256, 0, stream>>>(xb, Wqt, Q, Km, V);
  k_l2norm<<<2 * NH * LSEQ / 4, 256, 0, stream>>>(Q, Km);
  k_lrms5<<<dim3(LSEQ / 64, 16), 256, 0, stream>>>(x, Wlr, Wsc, Plr);
  k_lrsum<<<LSEQ * 64 / 256, 256, 0, stream>>>(Plr, bs, LR, SCL);

  for (int c = 0; c < 4; ++c) {
    int s = c * CH;
    k_out2<<<dim3(CH / 128, NH), 256, 0, stream>>>(WW, Q, SCL, lng, lnb, U, s);
    if (c < 3) {
      k_fe<<<dim3(CH / 128, NH), 1024, 0, stream>>>(WW, W1T, Km, V, BUF, s);
      k_dwp_mx<<<dim3(8, NH, 3), 256, 0, stream>>>(BUF, Km, V, LR, DWP, s);
      k_dwred<<<3 * NH, 256, 0, stream>>>(DWP, DW);
      k_ns5_mfma<<<3 * NH, 1024, 0, stream>>>(DW);
      k_apply<<<3 * NH * HD, 64, 0, stream>>>(WW, DW, WN0, W1T);
    }
  }
  k_tcast<<<dim3(DMODEL / 64, DMODEL / 64), 256, 0, stream>>>(Wo, Wot, DMODEL, DMODEL);
  k_final_mfma<<<dim3(LSEQ / 128, DMODEL / 128), 256, 0, stream>>>(U, Wot, (float*)d_out);
}

// Round 8
// 1375.185 us; speedup vs baseline: 4.3618x; 1.0197x over previous
//
#include <hip/hip_runtime.h>
#include <hip/hip_bf16.h>
#include <cstdint>
#include <cstddef>

#define LSEQ   8192
#define DMODEL 2048
#define NH     16      // heads == groups
#define HD     128     // head dim == hidden dim
#define CH     2048    // chunk length (group-space positions)

typedef __attribute__((ext_vector_type(8))) __bf16 bf16x8;
typedef __attribute__((ext_vector_type(4))) float f32x4;

// ---------------------------------------------------------------- helpers

__device__ __forceinline__ float wave_sum64(float v) {
#pragma unroll
  for (int m = 32; m; m >>= 1) v += __shfl_xor(v, m, 64);
  return v;
}

__device__ __forceinline__ float sigm(float x) { return 1.0f / (1.0f + expf(-x)); }

// RTNE float -> bf16 bits
__device__ __forceinline__ unsigned short f2bf(float f) {
  unsigned int u = __float_as_uint(f);
  u += 0x7FFFu + ((u >> 16) & 1u);
  return (unsigned short)(u >> 16);
}
__device__ __forceinline__ float bf2f(unsigned short h) {
  return __uint_as_float((unsigned int)h << 16);
}

// async global->LDS, 16B per lane.
__device__ __forceinline__ void gload_lds16(const void* g, void* l) {
  __builtin_amdgcn_global_load_lds((__attribute__((address_space(1))) void*)(g),
                                   (__attribute__((address_space(3))) void*)(l), 16, 0, 0);
}

union bfu8 { bf16x8 v; unsigned short u[8]; };

// ---------------------------------------------------------------- casts

__global__ void k_cast(const float* __restrict__ X, unsigned short* __restrict__ Xb, int n4) {
  int i = blockIdx.x * 256 + threadIdx.x;
  int stride = gridDim.x * 256;
  for (; i < n4; i += stride) {
    float4 v = ((const float4*)X)[i];
    ushort4 o;
    o.x = f2bf(v.x); o.y = f2bf(v.y); o.z = f2bf(v.z); o.w = f2bf(v.w);
    ((ushort4*)Xb)[i] = o;
  }
}

// W (K x N, fp32) -> Wt (N x K, bf16). grid (N/64, K/64), block 256.
__global__ void k_tcast(const float* __restrict__ W, unsigned short* __restrict__ Wt,
                        int K, int N) {
  __shared__ float t[64][65];
  const int n0 = blockIdx.x * 64, k0 = blockIdx.y * 64;
  const int tid = threadIdx.x;
  const int cx = tid & 63, ry = tid >> 6;
#pragma unroll
  for (int r = 0; r < 16; ++r) {
    int row = ry + r * 4;
    t[row][cx] = W[(size_t)(k0 + row) * N + n0 + cx];
  }
  __syncthreads();
#pragma unroll
  for (int r = 0; r < 16; ++r) {
    int nn = ry + r * 4;
    Wt[(size_t)(n0 + nn) * K + k0 + cx] = f2bf(t[cx][nn]);
  }
}

// ---------------------------------------------------------------- bf16 MFMA GEMM core (m97 style)

__device__ __forceinline__ void gemm_core(const unsigned short* __restrict__ A,
                                          const unsigned short* __restrict__ B,
                                          int K, int ldA, int ldB, int row0, int col0,
                                          unsigned short* Al, unsigned short* Bl,
                                          f32x4 acc[4][4]) {
  const int tid = threadIdx.x;
  const int w = tid >> 6, l = tid & 63;
  const int lrow = l & 15, lk = (l >> 4) * 8;
  const int wr = (w >> 1) * 64, wc = (w & 1) * 64;
  const int srow = l >> 2, skk = (l & 3) * 8;

  for (int kk = 0; kk < K; kk += 32) {
#pragma unroll
    for (int q = 0; q < 2; ++q) {
      int c = w * 2 + q;
      gload_lds16(A + (size_t)(row0 + c * 16 + srow) * ldA + kk + skk, &Al[c * 512]);
      gload_lds16(B + (size_t)(col0 + c * 16 + srow) * ldB + kk + skk, &Bl[c * 512]);
    }
    __syncthreads();
    bf16x8 af[4], bfr[4];
#pragma unroll
    for (int m = 0; m < 4; ++m)
      af[m] = *(const bf16x8*)&Al[(wr + m * 16 + lrow) * 32 + lk];
#pragma unroll
    for (int n = 0; n < 4; ++n)
      bfr[n] = *(const bf16x8*)&Bl[(wc + n * 16 + lrow) * 32 + lk];
#pragma unroll
    for (int m = 0; m < 4; ++m)
#pragma unroll
      for (int n = 0; n < 4; ++n)
        acc[m][n] = __builtin_amdgcn_mfma_f32_16x16x32_bf16(af[m], bfr[n], acc[m][n], 0, 0, 0);
    __syncthreads();
  }
}

// ---------------------------------------------------------------- swizzled LDS helpers (bf16 128x128)

__device__ __forceinline__ bf16x8 ld_sw(const unsigned short* base, int row, int kcol) {
  int byte = (row * 256 + kcol * 2) ^ ((row & 7) << 4);
  return *(const bf16x8*)((const char*)base + byte);
}
__device__ __forceinline__ void st_sw(unsigned short* base, int row, int col, unsigned short v) {
  int byte = (row * 256 + col * 2) ^ ((row & 7) << 4);
  *(unsigned short*)((char*)base + byte) = v;
}
__device__ __forceinline__ unsigned short ld_sw1(const unsigned short* base, int row, int col) {
  int byte = (row * 256 + col * 2) ^ ((row & 7) << 4);
  return *(const unsigned short*)((const char*)base + byte);
}

// fp32 [128 rows][ld] -> swizzled bf16 (256-thread version)
__device__ __forceinline__ void stage_sw(const float* __restrict__ src, int ld,
                                         unsigned short* dst, int tid) {
#pragma unroll
  for (int p = 0; p < 16; ++p) {
    int row = p * 8 + (tid >> 5);
    int col = (tid & 31) * 4;
    float4 v = *(const float4*)(src + (size_t)row * ld + col);
    int byte = (row * 256 + col * 2) ^ ((row & 7) << 4);
    unsigned short* d = (unsigned short*)((char*)dst + byte);
    d[0] = f2bf(v.x); d[1] = f2bf(v.y); d[2] = f2bf(v.z); d[3] = f2bf(v.w);
  }
}

// fp32 -> swizzled hi/lo pair (256-thread version)
__device__ __forceinline__ void stage_hl(const float* __restrict__ src, int ld,
                                         unsigned short* H, unsigned short* L, int tid) {
#pragma unroll
  for (int p = 0; p < 16; ++p) {
    int row = p * 8 + (tid >> 5);
    int col = (tid & 31) * 4;
    float4 v = *(const float4*)(src + (size_t)row * ld + col);
    int byte = (row * 256 + col * 2) ^ ((row & 7) << 4);
    unsigned short* h = (unsigned short*)((char*)H + byte);
    unsigned short* l = (unsigned short*)((char*)L + byte);
    const float* pv = (const float*)&v;
#pragma unroll
    for (int i = 0; i < 4; ++i) {
      unsigned short hi = f2bf(pv[i]);
      h[i] = hi;
      l[i] = f2bf(pv[i] - bf2f(hi));
    }
  }
}

// fp32 -> swizzled hi/lo pair (1024-thread version)
__device__ __forceinline__ void stage_hl_1024(const float* __restrict__ src, int ld,
                                              unsigned short* H, unsigned short* L, int tid) {
#pragma unroll
  for (int p = 0; p < 4; ++p) {
    int row = p * 32 + (tid >> 5);
    int col = (tid & 31) * 4;
    float4 v = *(const float4*)(src + (size_t)row * ld + col);
    int byte = (row * 256 + col * 2) ^ ((row & 7) << 4);
    unsigned short* h = (unsigned short*)((char*)H + byte);
    unsigned short* l = (unsigned short*)((char*)L + byte);
    const float* pv = (const float*)&v;
#pragma unroll
    for (int i = 0; i < 4; ++i) {
      unsigned short hi = f2bf(pv[i]);
      h[i] = hi;
      l[i] = f2bf(pv[i] - bf2f(hi));
    }
  }
}

// transposed + per-row scale: src [128 t][ld], scale lr[t] -> LDS[d][t] hi/lo
__device__ __forceinline__ void stage_hl_ts(const float* __restrict__ src, int ld,
                                            const float* __restrict__ lr,
                                            unsigned short* H, unsigned short* L, int tid) {
#pragma unroll
  for (int p = 0; p < 16; ++p) {
    int t = p * 8 + (tid >> 5);
    int d = (tid & 31) * 4;
    float4 v = *(const float4*)(src + (size_t)t * ld + d);
    float sc = lr[t];
    const float* pv = (const float*)&v;
#pragma unroll
    for (int i = 0; i < 4; ++i) {
      float x = pv[i] * sc;
      unsigned short hi = f2bf(x);
      st_sw(H, d + i, t, hi);
      st_sw(L, d + i, t, f2bf(x - bf2f(hi)));
    }
  }
}

// ---------------------------------------------------------------- init w + row norms (+ w1^T copy)

__global__ void k_init_w(const float* __restrict__ w0, const float* __restrict__ w1,
                         const float* __restrict__ w2, float* __restrict__ WW,
                         float* __restrict__ WN0, float* __restrict__ W1T) {
  int rid = blockIdx.x;
  int m = rid >> 11;
  int gr = rid & 2047;
  const float* src = (m == 0) ? w0 : (m == 1) ? w1 : w2;
  const float* row = src + (size_t)gr * HD;
  float* drow = WW + ((size_t)m * 2048 + gr) * HD;
  int l = threadIdx.x;
  float v0 = row[l], v1 = row[l + 64];
  drow[l] = v0; drow[l + 64] = v1;
  if (m == 1) {
    int g = gr >> 7, r = gr & 127;
    W1T[((size_t)g * 128 + l) * 128 + r] = v0;
    W1T[((size_t)g * 128 + l + 64) * 128 + r] = v1;
  }
  float s = wave_sum64(v0 * v0 + v1 * v1);
  if (l == 0) WN0[rid] = sqrtf(s);
}

// ---------------------------------------------------------------- qkv projection (bf16 MFMA + fused silu/l2norm)
// 1D grid 3072 blocks, XCD-swizzled. which!=2 rows (Q,K) l2-normalized in-epilogue.

__global__ __launch_bounds__(256) void k_qkv_mfma(const unsigned short* __restrict__ xb,
                                                  const unsigned short* __restrict__ Wqt,
                                                  float* __restrict__ Q, float* __restrict__ Km,
                                                  float* __restrict__ V) {
  __shared__ unsigned short Al[128 * 32];
  __shared__ unsigned short Bl[128 * 32];
  __shared__ float nrm[128][2];
  const int flat = blockIdx.x;
  const int swz = (flat & 7) * 384 + (flat >> 3);   // bijective: 3072 % 8 == 0
  const int bx = swz & 63, ct = swz >> 6;

  f32x4 acc[4][4];
#pragma unroll
  for (int m = 0; m < 4; ++m)
#pragma unroll
    for (int n = 0; n < 4; ++n) acc[m][n] = {};

  gemm_core(xb, Wqt, DMODEL, DMODEL, DMODEL, bx * 128, ct * 128, Al, Bl, acc);

  const int hh = ct / 3, which = ct % 3;
  float* dst = (which == 0) ? Q : (which == 1) ? Km : V;
  const int tid = threadIdx.x, w = tid >> 6, l = tid & 63;
  const int wr = (w >> 1) * 64, wc = (w & 1) * 64;

  // silu in place
#pragma unroll
  for (int m = 0; m < 4; ++m)
#pragma unroll
    for (int n = 0; n < 4; ++n)
#pragma unroll
      for (int j = 0; j < 4; ++j) {
        float v = acc[m][n][j];
        acc[m][n][j] = v * sigm(v);
      }

  float f[4][4];
  if (which != 2) {
    // per-(m,j) partial sq-sum over this lane's 4 cols, then 16-lane reduce
#pragma unroll
    for (int m = 0; m < 4; ++m)
#pragma unroll
      for (int j = 0; j < 4; ++j) {
        float p = 0.0f;
#pragma unroll
        for (int n = 0; n < 4; ++n) p = fmaf(acc[m][n][j], acc[m][n][j], p);
        p += __shfl_xor(p, 1, 64);
        p += __shfl_xor(p, 2, 64);
        p += __shfl_xor(p, 4, 64);
        p += __shfl_xor(p, 8, 64);
        f[m][j] = p;  // stash partial
      }
    if ((l & 15) == 0) {
#pragma unroll
      for (int m = 0; m < 4; ++m)
#pragma unroll
        for (int j = 0; j < 4; ++j)
          nrm[wr + m * 16 + (l >> 4) * 4 + j][w & 1] = f[m][j];
    }
    __syncthreads();
#pragma unroll
    for (int m = 0; m < 4; ++m)
#pragma unroll
      for (int j = 0; j < 4; ++j) {
        int row = wr + m * 16 + (l >> 4) * 4 + j;
        f[m][j] = 1.0f / (sqrtf(nrm[row][0] + nrm[row][1]) + 1e-5f);
      }
  } else {
#pragma unroll
    for (int m = 0; m < 4; ++m)
#pragma unroll
      for (int j = 0; j < 4; ++j) f[m][j] = 1.0f;
  }

#pragma unroll
  for (int m = 0; m < 4; ++m)
#pragma unroll
    for (int j = 0; j < 4; ++j) {
      int t = bx * 128 + wr + m * 16 + (l >> 4) * 4 + j;
      int fth = t * NH + hh;
      int g = fth >> 13, tp = fth & 8191;
      float* drow = dst + ((size_t)g * LSEQ + tp) * HD;
#pragma unroll
      for (int n = 0; n < 4; ++n)
        drow[wc + n * 16 + (l & 15)] = acc[m][n][j] * f[m][j];
    }
}

// ---------------------------------------------------------------- lr / scale: K-split GEMM + reduce

// grid (128, 16): 64 tokens x 64 cols x 128-K slice per block.
__global__ __launch_bounds__(256) void k_lrms5(const float* __restrict__ x,
                                               const float* __restrict__ Wlr,
                                               const float* __restrict__ Wsc,
                                               float* __restrict__ P) {
  __shared__ float Xs[128][67];
  __shared__ float Ws[128][68];
  const int tb = blockIdx.x;
  const int kp = blockIdx.y;
  const int tid = threadIdx.x;
  for (int i = tid; i < 128 * 64; i += 256) {
    int k = i >> 6, c = i & 63;
    float wv = (c < 48) ? Wlr[(size_t)(kp * 128 + k) * 48 + c]
                        : Wsc[(size_t)(kp * 128 + k) * 16 + (c - 48)];
    Ws[k][c] = wv;
  }
  const int t8 = tid >> 5, kk = tid & 31;
#pragma unroll
  for (int r = 0; r < 8; ++r) {
    int t = t8 + r * 8;
    float4 v = *(const float4*)(x + (size_t)(tb * 64 + t) * DMODEL + kp * 128 + kk * 4);
    Xs[kk * 4 + 0][t] = v.x; Xs[kk * 4 + 1][t] = v.y;
    Xs[kk * 4 + 2][t] = v.z; Xs[kk * 4 + 3][t] = v.w;
  }
  __syncthreads();
  const int ty = tid >> 4, tx = tid & 15;
  float acc[4][4];
#pragma unroll
  for (int i = 0; i < 4; ++i)
#pragma unroll
    for (int j = 0; j < 4; ++j) acc[i][j] = 0.0f;
  for (int k = 0; k < 128; ++k) {
    float a[4], b[4];
#pragma unroll
    for (int i = 0; i < 4; ++i) a[i] = Xs[k][ty * 4 + i];
#pragma unroll
    for (int j = 0; j < 4; ++j) b[j] = Ws[k][tx * 4 + j];
#pragma unroll
    for (int i = 0; i < 4; ++i)
#pragma unroll
      for (int j = 0; j < 4; ++j) acc[i][j] = fmaf(a[i], b[j], acc[i][j]);
  }
  float* o = P + ((size_t)tb * 16 + kp) * 4096;
#pragma unroll
  for (int i = 0; i < 4; ++i)
#pragma unroll
    for (int j = 0; j < 4; ++j)
      o[(ty * 4 + i) * 64 + tx * 4 + j] = acc[i][j];
}

__global__ void k_lrsum(const float* __restrict__ P, const float* __restrict__ bs,
                        float* __restrict__ LR, float* __restrict__ SCL) {
  int e = blockIdx.x * 256 + threadIdx.x;
  int t = e >> 6, c = e & 63;
  const float* base = P + ((size_t)(t >> 6) * 16) * 4096 + (t & 63) * 64 + c;
  float sum = 0.0f;
#pragma unroll
  for (int kp = 0; kp < 16; ++kp) sum += base[(size_t)kp * 4096];
  if (c < 48) {
    float base_lr_inv = 0.01f + logf(-expm1f(-0.01f));
    float v = sum + base_lr_inv;
    float sp = fmaxf(v, 0.0f) + log1pf(expf(-fabsf(v)));
    LR[(size_t)c * LSEQ + t] = sp;
  } else {
    float v = sum + bs[c - 48];
    SCL[(size_t)(c - 48) * LSEQ + t] = v * sigm(v);
  }
}

// ---------------------------------------------------------------- per-chunk output (bf16 MFMA + fused LN/scale)

__global__ __launch_bounds__(256) void k_out2(const float* __restrict__ WW,
                                              const float* __restrict__ Q,
                                              const float* __restrict__ SCL,
                                              const float* __restrict__ lng,
                                              const float* __restrict__ lnb,
                                              unsigned short* __restrict__ U, int s) {
  __shared__ __align__(16) char smem[131072];
  unsigned short* Qs  = (unsigned short*)smem;
  unsigned short* W0s = (unsigned short*)(smem + 32768);
  unsigned short* W2s = (unsigned short*)(smem + 65536);
  unsigned short* GHs = (unsigned short*)(smem + 98304);
  float* Os = (float*)smem;

  const int g = blockIdx.y;
  const int t0 = blockIdx.x * 128;
  const int tid = threadIdx.x;
  const int w = tid >> 6, l = tid & 63;
  const int lrow = l & 15, lk8 = (l >> 4) * 8;
  const int wr = (w >> 1) * 64, wc = (w & 1) * 64;

  const float* Qg  = Q + ((size_t)g * LSEQ + s + t0) * HD;
  const float* w0g = WW + ((size_t)0 * 2048 + g * 128) * 128;
  const float* w1g = WW + ((size_t)1 * 2048 + g * 128) * 128;
  const float* w2g = WW + ((size_t)2 * 2048 + g * 128) * 128;

  stage_sw(Qg, HD, Qs, tid);
  stage_sw(w0g, 128, W0s, tid);
  stage_sw(w2g, 128, W2s, tid);
  __syncthreads();

  f32x4 ga[4][4], ha[4][4];
#pragma unroll
  for (int m = 0; m < 4; ++m)
#pragma unroll
    for (int n = 0; n < 4; ++n) { ga[m][n] = {}; ha[m][n] = {}; }
#pragma unroll
  for (int kk = 0; kk < 128; kk += 32) {
    bf16x8 af[4], b0[4], b2[4];
#pragma unroll
    for (int m = 0; m < 4; ++m) af[m] = ld_sw(Qs, wr + m * 16 + lrow, kk + lk8);
#pragma unroll
    for (int n = 0; n < 4; ++n) {
      b0[n] = ld_sw(W0s, wc + n * 16 + lrow, kk + lk8);
      b2[n] = ld_sw(W2s, wc + n * 16 + lrow, kk + lk8);
    }
#pragma unroll
    for (int m = 0; m < 4; ++m)
#pragma unroll
      for (int n = 0; n < 4; ++n) {
        ga[m][n] = __builtin_amdgcn_mfma_f32_16x16x32_bf16(af[m], b0[n], ga[m][n], 0, 0, 0);
        ha[m][n] = __builtin_amdgcn_mfma_f32_16x16x32_bf16(af[m], b2[n], ha[m][n], 0, 0, 0);
      }
  }
#pragma unroll
  for (int m = 0; m < 4; ++m)
#pragma unroll
    for (int n = 0; n < 4; ++n)
#pragma unroll
      for (int j = 0; j < 4; ++j) {
        int row = wr + m * 16 + (l >> 4) * 4 + j;
        int col = wc + n * 16 + (l & 15);
        float gv = ga[m][n][j];
        st_sw(GHs, row, col, f2bf(gv * sigm(gv) * ha[m][n][j]));
      }
  __syncthreads();
  stage_sw(w1g, 128, W0s, tid);
  __syncthreads();

  f32x4 oa[4][4];
#pragma unroll
  for (int m = 0; m < 4; ++m)
#pragma unroll
    for (int n = 0; n < 4; ++n) oa[m][n] = {};
#pragma unroll
  for (int kk = 0; kk < 128; kk += 32) {
    bf16x8 af[4], b1[4];
#pragma unroll
    for (int m = 0; m < 4; ++m) af[m] = ld_sw(GHs, wr + m * 16 + lrow, kk + lk8);
#pragma unroll
    for (int n = 0; n < 4; ++n) b1[n] = ld_sw(W0s, wc + n * 16 + lrow, kk + lk8);
#pragma unroll
    for (int m = 0; m < 4; ++m)
#pragma unroll
      for (int n = 0; n < 4; ++n)
        oa[m][n] = __builtin_amdgcn_mfma_f32_16x16x32_bf16(af[m], b1[n], oa[m][n], 0, 0, 0);
  }
  __syncthreads();
#pragma unroll
  for (int m = 0; m < 4; ++m)
#pragma unroll
    for (int n = 0; n < 4; ++n)
#pragma unroll
      for (int j = 0; j < 4; ++j) {
        int row = wr + m * 16 + (l >> 4) * 4 + j;
        int col = wc + n * 16 + (l & 15);
        Os[row * 132 + col] = oa[m][n][j];
      }
  __syncthreads();

  const int tok = tid >> 1, part = tid & 1;
  const float* orow = Os + tok * 132 + part * 64;
  float sum = 0.0f;
#pragma unroll
  for (int q = 0; q < 16; ++q) {
    float4 v = *(const float4*)(orow + q * 4);
    sum += (v.x + v.y) + (v.z + v.w);
  }
  sum += __shfl_xor(sum, 1, 64);
  float mu = sum * (1.0f / 128.0f);
  float vs = 0.0f;
#pragma unroll
  for (int q = 0; q < 16; ++q) {
    float4 v = *(const float4*)(orow + q * 4);
    float d0 = v.x - mu, d1 = v.y - mu, d2 = v.z - mu, d3 = v.w - mu;
    vs += d0 * d0 + d1 * d1 + d2 * d2 + d3 * d3;
  }
  vs += __shfl_xor(vs, 1, 64);
  float rstd = rsqrtf(vs * (1.0f / 128.0f) + 1e-6f);
  int tabs = s + t0 + tok;
  float sc = SCL[(size_t)g * LSEQ + tabs];
  unsigned short* urow = U + (size_t)tabs * DMODEL + g * HD + part * 64;
#pragma unroll
  for (int q = 0; q < 16; ++q) {
    float4 v = *(const float4*)(orow + q * 4);
    int d = part * 64 + q * 4;
    ushort4 o;
    o.x = f2bf(((v.x - mu) * rstd * lng[d + 0] + lnb[d + 0]) * sc);
    o.y = f2bf(((v.y - mu) * rstd * lng[d + 1] + lnb[d + 1]) * sc);
    o.z = f2bf(((v.z - mu) * rstd * lng[d + 2] + lnb[d + 2]) * sc);
    o.w = f2bf(((v.w - mu) * rstd * lng[d + 3] + lnb[d + 3]) * sc);
    *(ushort4*)(urow + q * 4) = o;
  }
}

// ---------------------------------------------------------------- fused front GEMMs + elementwise

__global__ __launch_bounds__(1024) void k_fe(const float* __restrict__ WW,
                                             const float* __restrict__ W1T,
                                             const float* __restrict__ Km,
                                             const float* __restrict__ V,
                                             float* __restrict__ BUF, int s) {
  __shared__ __align__(16) char smem[131072];
  unsigned short* KH = (unsigned short*)smem;
  unsigned short* KL = (unsigned short*)(smem + 32768);
  unsigned short* VH = (unsigned short*)(smem + 65536);
  unsigned short* VL = (unsigned short*)(smem + 98304);

  const int tt0 = blockIdx.x * 128;
  const int g = blockIdx.y;
  const int tid = threadIdx.x;
  const int w = tid >> 6, l = tid & 63;
  const int ww = w >> 2, wv = w & 3;
  const int lrow = l & 15, lk8 = (l >> 4) * 8;
  const int frow = (l >> 4) * 4, fcol = l & 15;

  stage_hl_1024(Km + ((size_t)g * LSEQ + s + tt0) * HD, HD, KH, KL, tid);
  stage_hl_1024(V + ((size_t)g * LSEQ + s + tt0) * HD, HD, VH, VL, tid);
  __syncthreads();

  const float* Asrc[3];
  Asrc[0] = WW + ((size_t)0 * 2048 + g * 128) * 128;  // w0 rows
  Asrc[1] = WW + ((size_t)2 * 2048 + g * 128) * 128;  // w2 rows
  Asrc[2] = W1T + (size_t)g * 16384;                  // w1^T rows

  f32x4 acc[3][2][2];
#pragma unroll
  for (int q = 0; q < 3; ++q)
#pragma unroll
    for (int m = 0; m < 2; ++m)
#pragma unroll
      for (int n = 0; n < 2; ++n) acc[q][m][n] = {};

#pragma unroll 1
  for (int q = 0; q < 3; ++q) {
    const float* src = Asrc[q];
    const unsigned short* BH = (q == 2) ? VH : KH;
    const unsigned short* BL = (q == 2) ? VL : KL;
#pragma unroll
    for (int kk = 0; kk < 128; kk += 32) {
      bf16x8 ah[2], al[2], bh[2], bl[2];
#pragma unroll
      for (int m = 0; m < 2; ++m) {
        int row = ww * 32 + m * 16 + lrow;
        float4 v0 = *(const float4*)(src + (size_t)row * 128 + kk + lk8);
        float4 v1 = *(const float4*)(src + (size_t)row * 128 + kk + lk8 + 4);
        bfu8 h, lo;
        const float* p0 = (const float*)&v0;
        const float* p1 = (const float*)&v1;
#pragma unroll
        for (int i = 0; i < 4; ++i) {
          unsigned short hb0 = f2bf(p0[i]);
          h.u[i] = hb0; lo.u[i] = f2bf(p0[i] - bf2f(hb0));
          unsigned short hb1 = f2bf(p1[i]);
          h.u[i + 4] = hb1; lo.u[i + 4] = f2bf(p1[i] - bf2f(hb1));
        }
        ah[m] = h.v; al[m] = lo.v;
      }
#pragma unroll
      for (int n = 0; n < 2; ++n) {
        int row = wv * 32 + n * 16 + lrow;
        bh[n] = ld_sw(BH, row, kk + lk8);
        bl[n] = ld_sw(BL, row, kk + lk8);
      }
#pragma unroll
      for (int m = 0; m < 2; ++m)
#pragma unroll
        for (int n = 0; n < 2; ++n) {
          acc[q][m][n] = __builtin_amdgcn_mfma_f32_16x16x32_bf16(ah[m], bh[n], acc[q][m][n], 0, 0, 0);
          acc[q][m][n] = __builtin_amdgcn_mfma_f32_16x16x32_bf16(ah[m], bl[n], acc[q][m][n], 0, 0, 0);
          acc[q][m][n] = __builtin_amdgcn_mfma_f32_16x16x32_bf16(al[m], bh[n], acc[q][m][n], 0, 0, 0);
        }
    }
  }

  float* out0 = BUF + (size_t)0 * (NH * 128 * CH) + (size_t)g * 128 * CH;  // hid
  float* out1 = BUF + (size_t)1 * (NH * 128 * CH) + (size_t)g * 128 * CH;  // dgb
  float* out2 = BUF + (size_t)2 * (NH * 128 * CH) + (size_t)g * 128 * CH;  // dhb
#pragma unroll
  for (int m = 0; m < 2; ++m)
#pragma unroll
    for (int n = 0; n < 2; ++n)
#pragma unroll
      for (int j = 0; j < 4; ++j) {
        int row = ww * 32 + m * 16 + frow + j;
        int col = wv * 32 + n * 16 + fcol;
        float gb = acc[0][m][n][j];
        float hb = acc[1][m][n][j];
        float dh = acc[2][m][n][j];
        float sg = sigm(gb);
        float sgb = gb * sg;
        float hid = sgb * hb;
        float dgate = dh * hb;
        float dgb = dgate * sg * (1.0f + gb * (1.0f - sg));
        float dhb = dh * sgb;
        size_t o = (size_t)row * CH + tt0 + col;
        out0[o] = hid; out1[o] = dgb; out2[o] = dhb;
      }
}

// partial dW GEMMs over 256-token slices (split-bf16). grid (8, NH, 3).
__global__ __launch_bounds__(256) void k_dwp_mx(const float* __restrict__ BUF,
                                                const float* __restrict__ Km,
                                                const float* __restrict__ V,
                                                const float* __restrict__ LR,
                                                float* __restrict__ DWP, int s) {
  __shared__ __align__(16) char smem[131072];
  unsigned short* AH = (unsigned short*)smem;
  unsigned short* AL = (unsigned short*)(smem + 32768);
  unsigned short* BH = (unsigned short*)(smem + 65536);
  unsigned short* BL = (unsigned short*)(smem + 98304);

  const int p = blockIdx.x;
  const int g = blockIdx.y;
  const int z = blockIdx.z;
  const int tid = threadIdx.x;
  const int w = tid >> 6, l = tid & 63;
  const int lrow = l & 15, lk8 = (l >> 4) * 8;
  const int wr = (w >> 1) * 64, wc = (w & 1) * 64;

  const int msel = (z == 0) ? 1 : (z == 1) ? 0 : 2;
  const float* M = BUF + (size_t)msel * (NH * 128 * CH) + (size_t)g * 128 * CH;
  const float* N = (z == 1) ? V : Km;
  const float* lr = LR + (size_t)(z * NH + g) * LSEQ;
  const int ts = p * 256;

  f32x4 acc[4][4];
#pragma unroll
  for (int m = 0; m < 4; ++m)
#pragma unroll
    for (int n = 0; n < 4; ++n) acc[m][n] = {};

  for (int h = 0; h < 2; ++h) {
    if (h) __syncthreads();
    stage_hl(M + ts + h * 128, CH, AH, AL, tid);
    stage_hl_ts(N + ((size_t)g * LSEQ + s + ts + h * 128) * HD, HD,
                lr + s + ts + h * 128, BH, BL, tid);
    __syncthreads();
#pragma unroll
    for (int kk = 0; kk < 128; kk += 32) {
      bf16x8 ah[4], al4[4], bh[4], bl4[4];
#pragma unroll
      for (int m = 0; m < 4; ++m) {
        ah[m] = ld_sw(AH, wr + m * 16 + lrow, kk + lk8);
        al4[m] = ld_sw(AL, wr + m * 16 + lrow, kk + lk8);
      }
#pragma unroll
      for (int n = 0; n < 4; ++n) {
        bh[n] = ld_sw(BH, wc + n * 16 + lrow, kk + lk8);
        bl4[n] = ld_sw(BL, wc + n * 16 + lrow, kk + lk8);
      }
#pragma unroll
      for (int m = 0; m < 4; ++m)
#pragma unroll
        for (int n = 0; n < 4; ++n) {
          acc[m][n] = __builtin_amdgcn_mfma_f32_16x16x32_bf16(ah[m], bh[n], acc[m][n], 0, 0, 0);
          acc[m][n] = __builtin_amdgcn_mfma_f32_16x16x32_bf16(ah[m], bl4[n], acc[m][n], 0, 0, 0);
          acc[m][n] = __builtin_amdgcn_mfma_f32_16x16x32_bf16(al4[m], bh[n], acc[m][n], 0, 0, 0);
        }
    }
  }

  float* outp = DWP + (((size_t)(z * NH + g)) * 8 + p) * 16384;
#pragma unroll
  for (int m = 0; m < 4; ++m)
#pragma unroll
    for (int n = 0; n < 4; ++n)
#pragma unroll
      for (int j = 0; j < 4; ++j) {
        int row = wr + m * 16 + (l >> 4) * 4 + j;
        int col = wc + n * 16 + (l & 15);
        outp[row * 128 + col] = acc[m][n][j];
      }
}

// ---------------------------------------------------------------- Newton-Schulz 5 (split-bf16 MFMA, fused partial-reduce)
// Input: DWP partials (8 per matrix). z==1 input is dw1^T; NS5(G^T)=NS5(G)^T, so
// the final writeback transposes for z!=1 (P=X5^T) and writes P directly for z==1.
__global__ __launch_bounds__(1024) void k_ns5_mfma(const float* __restrict__ DWP,
                                                   float* __restrict__ DW) {
  __shared__ __align__(16) char smem[131072];
  unsigned short* PH = (unsigned short*)smem;
  unsigned short* PL = (unsigned short*)(smem + 32768);
  unsigned short* QH = (unsigned short*)(smem + 65536);
  unsigned short* QL = (unsigned short*)(smem + 98304);
  float* red = (float*)(smem + 65536);  // norm scratch (pre-loop only)

  const float NA[5] = {4.0848f, 3.9505f, 3.7418f, 2.8769f, 2.8366f};
  const float NB[5] = {-6.8946f, -6.3029f, -5.5913f, -3.1427f, -3.0525f};
  const float NC[5] = {2.927f, 2.6377f, 2.3037f, 1.2046f, 1.2012f};
  const int zg = blockIdx.x;
  const int z = zg >> 4;
  const float* base = DWP + (size_t)zg * 8 * 16384;
  float* Gout = DW + (size_t)zg * 16384;
  const int tid = threadIdx.x;
  const int w = tid >> 6, l = tid & 63;
  const int ww = w >> 2, wv = w & 3;
  const int lrow = l & 15, lk8 = (l >> 4) * 8;
  const int frow = (l >> 4) * 4, fcol = l & 15;

  // fused partial-reduce + Frobenius norm + split into P
  float vals[16];
  float psum = 0.0f;
#pragma unroll
  for (int r = 0; r < 16; ++r) {
    int idx = tid + r * 1024;
    float sv = 0.0f;
#pragma unroll
    for (int p = 0; p < 8; ++p) sv += base[(size_t)p * 16384 + idx];
    vals[r] = sv;
    psum = fmaf(sv, sv, psum);
  }
  psum = wave_sum64(psum);
  if (l == 0) red[w] = psum;
  __syncthreads();
  float tot = 0.0f;
#pragma unroll
  for (int i = 0; i < 16; ++i) tot += red[i];
  float scl = 1.0f / (sqrtf(tot) + 1e-7f);
  __syncthreads();
#pragma unroll
  for (int r = 0; r < 16; ++r) {
    int idx = tid + r * 1024;
    int rr = idx >> 7, cc = idx & 127;
    float v = vals[r] * scl;
    unsigned short hi = f2bf(v);
    st_sw(PH, rr, cc, hi);
    st_sw(PL, rr, cc, f2bf(v - bf2f(hi)));
  }
  __syncthreads();

#pragma unroll 1
  for (int it = 0; it < 5; ++it) {
    const float ac = NA[it], bc = NB[it], cc2 = NC[it];

    // Step A: accA = Y @ Y^T
    f32x4 accA[2][2];
#pragma unroll
    for (int m = 0; m < 2; ++m)
#pragma unroll
      for (int n = 0; n < 2; ++n) accA[m][n] = {};
#pragma unroll
    for (int kk = 0; kk < 128; kk += 32) {
      bf16x8 ah[2], al[2], bh[2], bl[2];
#pragma unroll
      for (int m = 0; m < 2; ++m) {
        ah[m] = ld_sw(PH, ww * 32 + m * 16 + lrow, kk + lk8);
        al[m] = ld_sw(PL, ww * 32 + m * 16 + lrow, kk + lk8);
      }
#pragma unroll
      for (int n = 0; n < 2; ++n) {
        bh[n] = ld_sw(PH, wv * 32 + n * 16 + lrow, kk + lk8);
        bl[n] = ld_sw(PL, wv * 32 + n * 16 + lrow, kk + lk8);
      }
#pragma unroll
      for (int m = 0; m < 2; ++m)
#pragma unroll
        for (int n = 0; n < 2; ++n) {
          accA[m][n] = __builtin_amdgcn_mfma_f32_16x16x32_bf16(ah[m], bh[n], accA[m][n], 0, 0, 0);
          accA[m][n] = __builtin_amdgcn_mfma_f32_16x16x32_bf16(ah[m], bl[n], accA[m][n], 0, 0, 0);
          accA[m][n] = __builtin_amdgcn_mfma_f32_16x16x32_bf16(al[m], bh[n], accA[m][n], 0, 0, 0);
        }
    }
#pragma unroll
    for (int m = 0; m < 2; ++m)
#pragma unroll
      for (int n = 0; n < 2; ++n)
#pragma unroll
        for (int j = 0; j < 4; ++j) {
          int row = ww * 32 + m * 16 + frow + j;
          int col = wv * 32 + n * 16 + fcol;
          float v = accA[m][n][j];
          unsigned short hi = f2bf(v);
          st_sw(QH, row, col, hi);
          st_sw(QL, row, col, f2bf(v - bf2f(hi)));
        }
    __syncthreads();

    // Step B: accB = A @ A
    f32x4 accB[2][2];
#pragma unroll
    for (int m = 0; m < 2; ++m)
#pragma unroll
      for (int n = 0; n < 2; ++n) accB[m][n] = {};
#pragma unroll
    for (int kk = 0; kk < 128; kk += 32) {
      bf16x8 ah[2], al[2], bh[2], bl[2];
#pragma unroll
      for (int m = 0; m < 2; ++m) {
        ah[m] = ld_sw(QH, ww * 32 + m * 16 + lrow, kk + lk8);
        al[m] = ld_sw(QL, ww * 32 + m * 16 + lrow, kk + lk8);
      }
#pragma unroll
      for (int n = 0; n < 2; ++n) {
        bh[n] = ld_sw(QH, wv * 32 + n * 16 + lrow, kk + lk8);
        bl[n] = ld_sw(QL, wv * 32 + n * 16 + lrow, kk + lk8);
      }
#pragma unroll
      for (int m = 0; m < 2; ++m)
#pragma unroll
        for (int n = 0; n < 2; ++n) {
          accB[m][n] = __builtin_amdgcn_mfma_f32_16x16x32_bf16(ah[m], bh[n], accB[m][n], 0, 0, 0);
          accB[m][n] = __builtin_amdgcn_mfma_f32_16x16x32_bf16(ah[m], bl[n], accB[m][n], 0, 0, 0);
          accB[m][n] = __builtin_amdgcn_mfma_f32_16x16x32_bf16(al[m], bh[n], accB[m][n], 0, 0, 0);
        }
    }
#pragma unroll
    for (int m = 0; m < 2; ++m)
#pragma unroll
      for (int n = 0; n < 2; ++n)
#pragma unroll
        for (int j = 0; j < 4; ++j)
          accB[m][n][j] = fmaf(bc, accA[m][n][j], cc2 * accB[m][n][j]);
    __syncthreads();
#pragma unroll
    for (int m = 0; m < 2; ++m)
#pragma unroll
      for (int n = 0; n < 2; ++n)
#pragma unroll
        for (int j = 0; j < 4; ++j) {
          int row = ww * 32 + m * 16 + frow + j;
          int col = wv * 32 + n * 16 + fcol;
          float v = accB[m][n][j];
          unsigned short hi = f2bf(v);
          st_sw(QH, row, col, hi);
          st_sw(QL, row, col, f2bf(v - bf2f(hi)));
        }
    unsigned short th[16], tl[16];
#pragma unroll
    for (int r = 0; r < 16; ++r) {
      int idx = tid + r * 1024;
      int rr = idx >> 7, ccx = idx & 127;
      th[r] = ld_sw1(PH, rr, ccx);
      tl[r] = ld_sw1(PL, rr, ccx);
    }
    __syncthreads();
#pragma unroll
    for (int r = 0; r < 16; ++r) {
      int idx = tid + r * 1024;
      int rr = idx >> 7, ccx = idx & 127;
      st_sw(PH, ccx, rr, th[r]);
      st_sw(PL, ccx, rr, tl[r]);
    }
    __syncthreads();  // P now holds Y^T

    // Step C: accC = Y^T @ Bm + ac*Y^T
    f32x4 accC[2][2];
#pragma unroll
    for (int m = 0; m < 2; ++m)
#pragma unroll
      for (int n = 0; n < 2; ++n) accC[m][n] = {};
#pragma unroll
    for (int kk = 0; kk < 128; kk += 32) {
      bf16x8 ah[2], al[2], bh[2], bl[2];
#pragma unroll
      for (int m = 0; m < 2; ++m) {
        ah[m] = ld_sw(PH, ww * 32 + m * 16 + lrow, kk + lk8);
        al[m] = ld_sw(PL, ww * 32 + m * 16 + lrow, kk + lk8);
      }
#pragma unroll
      for (int n = 0; n < 2; ++n) {
        bh[n] = ld_sw(QH, wv * 32 + n * 16 + lrow, kk + lk8);
        bl[n] = ld_sw(QL, wv * 32 + n * 16 + lrow, kk + lk8);
      }
#pragma unroll
      for (int m = 0; m < 2; ++m)
#pragma unroll
        for (int n = 0; n < 2; ++n) {
          accC[m][n] = __builtin_amdgcn_mfma_f32_16x16x32_bf16(ah[m], bh[n], accC[m][n], 0, 0, 0);
          accC[m][n] = __builtin_amdgcn_mfma_f32_16x16x32_bf16(ah[m], bl[n], accC[m][n], 0, 0, 0);
          accC[m][n] = __builtin_amdgcn_mfma_f32_16x16x32_bf16(al[m], bh[n], accC[m][n], 0, 0, 0);
        }
    }
#pragma unroll
    for (int m = 0; m < 2; ++m)
#pragma unroll
      for (int n = 0; n < 2; ++n)
#pragma unroll
        for (int j = 0; j < 4; ++j) {
          int row = ww * 32 + m * 16 + frow + j;
          int col = wv * 32 + n * 16 + fcol;
          float yv = bf2f(ld_sw1(PH, row, col)) + bf2f(ld_sw1(PL, row, col));
          accC[m][n][j] = fmaf(ac, yv, accC[m][n][j]);
        }
    __syncthreads();
#pragma unroll
    for (int m = 0; m < 2; ++m)
#pragma unroll
      for (int n = 0; n < 2; ++n)
#pragma unroll
        for (int j = 0; j < 4; ++j) {
          int row = ww * 32 + m * 16 + frow + j;
          int col = wv * 32 + n * 16 + fcol;
          float v = accC[m][n][j];
          unsigned short hi = f2bf(v);
          st_sw(PH, row, col, hi);
          st_sw(PL, row, col, f2bf(v - bf2f(hi)));
        }
    __syncthreads();
  }

  // P = NS5(input)^T. z!=1: un-transpose. z==1 (input was dw1^T): write P directly.
#pragma unroll
  for (int r = 0; r < 16; ++r) {
    int idx = tid + r * 1024;
    int rr = idx >> 7, ccx = idx & 127;
    if (z == 1)
      Gout[idx] = bf2f(ld_sw1(PH, rr, ccx)) + bf2f(ld_sw1(PL, rr, ccx));
    else
      Gout[idx] = bf2f(ld_sw1(PH, ccx, rr)) + bf2f(ld_sw1(PL, ccx, rr));
  }
}

// w += dw; renormalize; maintain W1T.
__global__ void k_apply(float* __restrict__ WW, const float* __restrict__ DW,
                        const float* __restrict__ WN0, float* __restrict__ W1T) {
  int rid = blockIdx.x;
  int m = rid >> 11;
  int gr = rid & 2047;
  int l = threadIdx.x;
  float* wrow = WW + (size_t)rid * 128;
  const float* drow = DW + (size_t)rid * 128;
  float v0 = wrow[l] + drow[l];
  float v1 = wrow[l + 64] + drow[l + 64];
  float s = wave_sum64(v0 * v0 + v1 * v1);
  float f = WN0[rid] / (sqrtf(s) + 1e-5f);
  v0 *= f; v1 *= f;
  wrow[l] = v0;
  wrow[l + 64] = v1;
  if (m == 1) {
    int g = gr >> 7, r = gr & 127;
    W1T[((size_t)g * 128 + l) * 128 + r] = v0;
    W1T[((size_t)g * 128 + l + 64) * 128 + r] = v1;
  }
}

// ---------------------------------------------------------------- final projection (bf16 MFMA, XCD-swizzled)

__global__ __launch_bounds__(256) void k_final_mfma(const unsigned short* __restrict__ U,
                                                    const unsigned short* __restrict__ Wot,
                                                    float* __restrict__ out) {
  __shared__ unsigned short Al[128 * 32];
  __shared__ unsigned short Bl[128 * 32];
  f32x4 acc[4][4];
#pragma unroll
  for (int m = 0; m < 4; ++m)
#pragma unroll
    for (int n = 0; n < 4; ++n) acc[m][n] = {};

  const int flat = blockIdx.x;
  const int swz = (flat & 7) * 128 + (flat >> 3);   // bijective: 1024 % 8 == 0
  const int row0 = (swz & 63) * 128, col0 = (swz >> 6) * 128;
  gemm_core(U, Wot, DMODEL, DMODEL, DMODEL, row0, col0, Al, Bl, acc);

  const int tid = threadIdx.x, w = tid >> 6, l = tid & 63;
  const int wr = (w >> 1) * 64, wc = (w & 1) * 64;
#pragma unroll
  for (int m = 0; m < 4; ++m)
#pragma unroll
    for (int j = 0; j < 4; ++j) {
      int t = row0 + wr + m * 16 + (l >> 4) * 4 + j;
      float* orow = out + (size_t)t * DMODEL + col0;
#pragma unroll
      for (int n = 0; n < 4; ++n)
        orow[wc + n * 16 + (l & 15)] = acc[m][n][j];
    }
}

// ---------------------------------------------------------------- launch

extern "C" void kernel_launch(void* const* d_in, const int* in_sizes, int n_in,
                              void* d_out, int out_size, void* d_ws, size_t ws_size,
                              hipStream_t stream) {
  (void)in_sizes; (void)n_in; (void)out_size;
  const float* x    = (const float*)d_in[0];
  const float* Wqkv = (const float*)d_in[1];
  const float* Wlr  = (const float*)d_in[2];
  const float* Wo   = (const float*)d_in[3];
  const float* Wsc  = (const float*)d_in[6];
  const float* bs   = (const float*)d_in[7];
  const float* lng  = (const float*)d_in[8];
  const float* lnb  = (const float*)d_in[9];
  const float* w0   = (const float*)d_in[10];
  const float* w1   = (const float*)d_in[11];
  const float* w2   = (const float*)d_in[12];

  float* Q = (float*)d_out;  // last read (k_out2 chunk 3) precedes k_final's write

  float* ws = (float*)d_ws;
  size_t off = 0;
  auto alloc = [&](size_t n) { float* p = ws + off; off += n; return p; };
  float* Km   = alloc((size_t)NH * LSEQ * HD);
  float* V    = alloc((size_t)NH * LSEQ * HD);
  float* Uf   = alloc((size_t)LSEQ * DMODEL / 2);   // U stored as bf16
  float* LR   = alloc((size_t)3 * NH * LSEQ);
  float* SCL  = alloc((size_t)NH * LSEQ);
  float* WW   = alloc((size_t)3 * NH * HD * HD);
  float* WN0  = alloc((size_t)3 * NH * HD);
  float* W1T  = alloc((size_t)NH * HD * HD);
  float* BUF  = alloc((size_t)3 * NH * HD * CH);    // chunk loop scratch
  float* DW   = alloc((size_t)3 * NH * HD * HD);
  float* DWP  = alloc((size_t)3 * NH * 8 * HD * HD);
  if (off * sizeof(float) > ws_size) return;        // clean failure instead of OOB

  unsigned short* U = (unsigned short*)Uf;
  unsigned short* xb  = (unsigned short*)BUF;                                   // pre-qkv
  unsigned short* Wqt = (unsigned short*)(BUF + (size_t)LSEQ * DMODEL / 2);
  float* Plr = BUF;                                                             // lrms partials
  unsigned short* Wot = (unsigned short*)BUF;                                   // post-loop

  k_init_w<<<3 * NH * HD, 64, 0, stream>>>(w0, w1, w2, WW, WN0, W1T);
  k_cast<<<2048, 256, 0, stream>>>(x, xb, LSEQ * DMODEL / 4);
  k_tcast<<<dim3(3 * DMODEL / 64, DMODEL / 64), 256, 0, stream>>>(Wqkv, Wqt, DMODEL, 3 * DMODEL);
  k_qkv_mfma<<<3072, 256, 0, stream>>>(xb, Wqt, Q, Km, V);
  k_lrms5<<<dim3(LSEQ / 64, 16), 256, 0, stream>>>(x, Wlr, Wsc, Plr);
  k_lrsum<<<LSEQ * 64 / 256, 256, 0, stream>>>(Plr, bs, LR, SCL);

  for (int c = 0; c < 4; ++c) {
    int s = c * CH;
    k_out2<<<dim3(CH / 128, NH), 256, 0, stream>>>(WW, Q, SCL, lng, lnb, U, s);
    if (c < 3) {
      k_fe<<<dim3(CH / 128, NH), 1024, 0, stream>>>(WW, W1T, Km, V, BUF, s);
      k_dwp_mx<<<dim3(8, NH, 3), 256, 0, stream>>>(BUF, Km, V, LR, DWP, s);
      k_ns5_mfma<<<3 * NH, 1024, 0, stream>>>(DWP, DW);
      k_apply<<<3 * NH * HD, 64, 0, stream>>>(WW, DW, WN0, W1T);
    }
  }
  k_tcast<<<dim3(DMODEL / 64, DMODEL / 64), 256, 0, stream>>>(Wo, Wot, DMODEL, DMODEL);
  k_final_mfma<<<1024, 256, 0, stream>>>(U, Wot, (float*)d_out);
}

// Round 9
// 1346.892 us; speedup vs baseline: 4.4534x; 1.0210x over previous
//
#include <hip/hip_runtime.h>
#include <hip/hip_bf16.h>
#include <cstdint>
#include <cstddef>

#define LSEQ   8192
#define DMODEL 2048
#define NH     16      // heads == groups
#define HD     128     // head dim == hidden dim
#define CH     2048    // chunk length (group-space positions)

typedef __attribute__((ext_vector_type(8))) __bf16 bf16x8;
typedef __attribute__((ext_vector_type(4))) float f32x4;

// ---------------------------------------------------------------- helpers

__device__ __forceinline__ float wave_sum64(float v) {
#pragma unroll
  for (int m = 32; m; m >>= 1) v += __shfl_xor(v, m, 64);
  return v;
}

__device__ __forceinline__ float sigm(float x) { return 1.0f / (1.0f + expf(-x)); }

// RTNE float -> bf16 bits
__device__ __forceinline__ unsigned short f2bf(float f) {
  unsigned int u = __float_as_uint(f);
  u += 0x7FFFu + ((u >> 16) & 1u);
  return (unsigned short)(u >> 16);
}
__device__ __forceinline__ float bf2f(unsigned short h) {
  return __uint_as_float((unsigned int)h << 16);
}

// async global->LDS, 16B per lane.
__device__ __forceinline__ void gload_lds16(const void* g, void* l) {
  __builtin_amdgcn_global_load_lds((__attribute__((address_space(1))) void*)(g),
                                   (__attribute__((address_space(3))) void*)(l), 16, 0, 0);
}

union bfu8 { bf16x8 v; unsigned short u[8]; };

// ---------------------------------------------------------------- casts

__global__ void k_cast(const float* __restrict__ X, unsigned short* __restrict__ Xb, int n4) {
  int i = blockIdx.x * 256 + threadIdx.x;
  int stride = gridDim.x * 256;
  for (; i < n4; i += stride) {
    float4 v = ((const float4*)X)[i];
    ushort4 o;
    o.x = f2bf(v.x); o.y = f2bf(v.y); o.z = f2bf(v.z); o.w = f2bf(v.w);
    ((ushort4*)Xb)[i] = o;
  }
}

// W (K x N, fp32) -> Wt (N x K, bf16). grid (N/64, K/64), block 256.
__global__ void k_tcast(const float* __restrict__ W, unsigned short* __restrict__ Wt,
                        int K, int N) {
  __shared__ float t[64][65];
  const int n0 = blockIdx.x * 64, k0 = blockIdx.y * 64;
  const int tid = threadIdx.x;
  const int cx = tid & 63, ry = tid >> 6;
#pragma unroll
  for (int r = 0; r < 16; ++r) {
    int row = ry + r * 4;
    t[row][cx] = W[(size_t)(k0 + row) * N + n0 + cx];
  }
  __syncthreads();
#pragma unroll
  for (int r = 0; r < 16; ++r) {
    int nn = ry + r * 4;
    Wt[(size_t)(n0 + nn) * K + k0 + cx] = f2bf(t[cx][nn]);
  }
}

// ---------------------------------------------------------------- bf16 MFMA GEMM core (m97 style)

__device__ __forceinline__ void gemm_core(const unsigned short* __restrict__ A,
                                          const unsigned short* __restrict__ B,
                                          int K, int ldA, int ldB, int row0, int col0,
                                          unsigned short* Al, unsigned short* Bl,
                                          f32x4 acc[4][4]) {
  const int tid = threadIdx.x;
  const int w = tid >> 6, l = tid & 63;
  const int lrow = l & 15, lk = (l >> 4) * 8;
  const int wr = (w >> 1) * 64, wc = (w & 1) * 64;
  const int srow = l >> 2, skk = (l & 3) * 8;

  for (int kk = 0; kk < K; kk += 32) {
#pragma unroll
    for (int q = 0; q < 2; ++q) {
      int c = w * 2 + q;
      gload_lds16(A + (size_t)(row0 + c * 16 + srow) * ldA + kk + skk, &Al[c * 512]);
      gload_lds16(B + (size_t)(col0 + c * 16 + srow) * ldB + kk + skk, &Bl[c * 512]);
    }
    __syncthreads();
    bf16x8 af[4], bfr[4];
#pragma unroll
    for (int m = 0; m < 4; ++m)
      af[m] = *(const bf16x8*)&Al[(wr + m * 16 + lrow) * 32 + lk];
#pragma unroll
    for (int n = 0; n < 4; ++n)
      bfr[n] = *(const bf16x8*)&Bl[(wc + n * 16 + lrow) * 32 + lk];
#pragma unroll
    for (int m = 0; m < 4; ++m)
#pragma unroll
      for (int n = 0; n < 4; ++n)
        acc[m][n] = __builtin_amdgcn_mfma_f32_16x16x32_bf16(af[m], bfr[n], acc[m][n], 0, 0, 0);
    __syncthreads();
  }
}

// ---------------------------------------------------------------- swizzled LDS helpers (bf16, 128-col rows)

__device__ __forceinline__ bf16x8 ld_sw(const unsigned short* base, int row, int kcol) {
  int byte = (row * 256 + kcol * 2) ^ ((row & 7) << 4);
  return *(const bf16x8*)((const char*)base + byte);
}
__device__ __forceinline__ void st_sw(unsigned short* base, int row, int col, unsigned short v) {
  int byte = (row * 256 + col * 2) ^ ((row & 7) << 4);
  *(unsigned short*)((char*)base + byte) = v;
}
__device__ __forceinline__ unsigned short ld_sw1(const unsigned short* base, int row, int col) {
  int byte = (row * 256 + col * 2) ^ ((row & 7) << 4);
  return *(const unsigned short*)((const char*)base + byte);
}

// fp32 [128 rows][ld] -> swizzled bf16 (256-thread version)
__device__ __forceinline__ void stage_sw(const float* __restrict__ src, int ld,
                                         unsigned short* dst, int tid) {
#pragma unroll
  for (int p = 0; p < 16; ++p) {
    int row = p * 8 + (tid >> 5);
    int col = (tid & 31) * 4;
    float4 v = *(const float4*)(src + (size_t)row * ld + col);
    int byte = (row * 256 + col * 2) ^ ((row & 7) << 4);
    unsigned short* d = (unsigned short*)((char*)dst + byte);
    d[0] = f2bf(v.x); d[1] = f2bf(v.y); d[2] = f2bf(v.z); d[3] = f2bf(v.w);
  }
}

// fp32 [64 rows][ld] -> swizzled bf16 (256-thread version)
__device__ __forceinline__ void stage_sw64(const float* __restrict__ src, int ld,
                                           unsigned short* dst, int tid) {
#pragma unroll
  for (int p = 0; p < 8; ++p) {
    int row = p * 8 + (tid >> 5);
    int col = (tid & 31) * 4;
    float4 v = *(const float4*)(src + (size_t)row * ld + col);
    int byte = (row * 256 + col * 2) ^ ((row & 7) << 4);
    unsigned short* d = (unsigned short*)((char*)dst + byte);
    d[0] = f2bf(v.x); d[1] = f2bf(v.y); d[2] = f2bf(v.z); d[3] = f2bf(v.w);
  }
}

// fp32 -> swizzled hi/lo pair (256-thread version)
__device__ __forceinline__ void stage_hl(const float* __restrict__ src, int ld,
                                         unsigned short* H, unsigned short* L, int tid) {
#pragma unroll
  for (int p = 0; p < 16; ++p) {
    int row = p * 8 + (tid >> 5);
    int col = (tid & 31) * 4;
    float4 v = *(const float4*)(src + (size_t)row * ld + col);
    int byte = (row * 256 + col * 2) ^ ((row & 7) << 4);
    unsigned short* h = (unsigned short*)((char*)H + byte);
    unsigned short* l = (unsigned short*)((char*)L + byte);
    const float* pv = (const float*)&v;
#pragma unroll
    for (int i = 0; i < 4; ++i) {
      unsigned short hi = f2bf(pv[i]);
      h[i] = hi;
      l[i] = f2bf(pv[i] - bf2f(hi));
    }
  }
}

// fp32 -> swizzled hi/lo pair (1024-thread version)
__device__ __forceinline__ void stage_hl_1024(const float* __restrict__ src, int ld,
                                              unsigned short* H, unsigned short* L, int tid) {
#pragma unroll
  for (int p = 0; p < 4; ++p) {
    int row = p * 32 + (tid >> 5);
    int col = (tid & 31) * 4;
    float4 v = *(const float4*)(src + (size_t)row * ld + col);
    int byte = (row * 256 + col * 2) ^ ((row & 7) << 4);
    unsigned short* h = (unsigned short*)((char*)H + byte);
    unsigned short* l = (unsigned short*)((char*)L + byte);
    const float* pv = (const float*)&v;
#pragma unroll
    for (int i = 0; i < 4; ++i) {
      unsigned short hi = f2bf(pv[i]);
      h[i] = hi;
      l[i] = f2bf(pv[i] - bf2f(hi));
    }
  }
}

// transposed + per-row scale: src [128 t][ld], scale lr[t] -> LDS[d][t] hi/lo
__device__ __forceinline__ void stage_hl_ts(const float* __restrict__ src, int ld,
                                            const float* __restrict__ lr,
                                            unsigned short* H, unsigned short* L, int tid) {
#pragma unroll
  for (int p = 0; p < 16; ++p) {
    int t = p * 8 + (tid >> 5);
    int d = (tid & 31) * 4;
    float4 v = *(const float4*)(src + (size_t)t * ld + d);
    float sc = lr[t];
    const float* pv = (const float*)&v;
#pragma unroll
    for (int i = 0; i < 4; ++i) {
      float x = pv[i] * sc;
      unsigned short hi = f2bf(x);
      st_sw(H, d + i, t, hi);
      st_sw(L, d + i, t, f2bf(x - bf2f(hi)));
    }
  }
}

// ---------------------------------------------------------------- init w + row norms (+ w1^T copy)

__global__ void k_init_w(const float* __restrict__ w0, const float* __restrict__ w1,
                         const float* __restrict__ w2, float* __restrict__ WW,
                         float* __restrict__ WN0, float* __restrict__ W1T) {
  int rid = blockIdx.x;
  int m = rid >> 11;
  int gr = rid & 2047;
  const float* src = (m == 0) ? w0 : (m == 1) ? w1 : w2;
  const float* row = src + (size_t)gr * HD;
  float* drow = WW + ((size_t)m * 2048 + gr) * HD;
  int l = threadIdx.x;
  float v0 = row[l], v1 = row[l + 64];
  drow[l] = v0; drow[l + 64] = v1;
  if (m == 1) {
    int g = gr >> 7, r = gr & 127;
    W1T[((size_t)g * 128 + l) * 128 + r] = v0;
    W1T[((size_t)g * 128 + l + 64) * 128 + r] = v1;
  }
  float s = wave_sum64(v0 * v0 + v1 * v1);
  if (l == 0) WN0[rid] = sqrtf(s);
}

// ---------------------------------------------------------------- qkv projection (bf16 MFMA + fused silu/l2norm)
// 2D grid (64, 48) — natural dispatch order (XCD swizzle reverted: R8 showed 4.4x FETCH blowup).

__global__ __launch_bounds__(256) void k_qkv_mfma(const unsigned short* __restrict__ xb,
                                                  const unsigned short* __restrict__ Wqt,
                                                  float* __restrict__ Q, float* __restrict__ Km,
                                                  float* __restrict__ V) {
  __shared__ unsigned short Al[128 * 32];
  __shared__ unsigned short Bl[128 * 32];
  __shared__ float nrm[128][2];
  const int bx = blockIdx.x, ct = blockIdx.y;

  f32x4 acc[4][4];
#pragma unroll
  for (int m = 0; m < 4; ++m)
#pragma unroll
    for (int n = 0; n < 4; ++n) acc[m][n] = {};

  gemm_core(xb, Wqt, DMODEL, DMODEL, DMODEL, bx * 128, ct * 128, Al, Bl, acc);

  const int hh = ct / 3, which = ct % 3;
  float* dst = (which == 0) ? Q : (which == 1) ? Km : V;
  const int tid = threadIdx.x, w = tid >> 6, l = tid & 63;
  const int wr = (w >> 1) * 64, wc = (w & 1) * 64;

  // silu in place
#pragma unroll
  for (int m = 0; m < 4; ++m)
#pragma unroll
    for (int n = 0; n < 4; ++n)
#pragma unroll
      for (int j = 0; j < 4; ++j) {
        float v = acc[m][n][j];
        acc[m][n][j] = v * sigm(v);
      }

  float f[4][4];
  if (which != 2) {
#pragma unroll
    for (int m = 0; m < 4; ++m)
#pragma unroll
      for (int j = 0; j < 4; ++j) {
        float p = 0.0f;
#pragma unroll
        for (int n = 0; n < 4; ++n) p = fmaf(acc[m][n][j], acc[m][n][j], p);
        p += __shfl_xor(p, 1, 64);
        p += __shfl_xor(p, 2, 64);
        p += __shfl_xor(p, 4, 64);
        p += __shfl_xor(p, 8, 64);
        f[m][j] = p;
      }
    if ((l & 15) == 0) {
#pragma unroll
      for (int m = 0; m < 4; ++m)
#pragma unroll
        for (int j = 0; j < 4; ++j)
          nrm[wr + m * 16 + (l >> 4) * 4 + j][w & 1] = f[m][j];
    }
    __syncthreads();
#pragma unroll
    for (int m = 0; m < 4; ++m)
#pragma unroll
      for (int j = 0; j < 4; ++j) {
        int row = wr + m * 16 + (l >> 4) * 4 + j;
        f[m][j] = 1.0f / (sqrtf(nrm[row][0] + nrm[row][1]) + 1e-5f);
      }
  } else {
#pragma unroll
    for (int m = 0; m < 4; ++m)
#pragma unroll
      for (int j = 0; j < 4; ++j) f[m][j] = 1.0f;
  }

#pragma unroll
  for (int m = 0; m < 4; ++m)
#pragma unroll
    for (int j = 0; j < 4; ++j) {
      int t = bx * 128 + wr + m * 16 + (l >> 4) * 4 + j;
      int fth = t * NH + hh;
      int g = fth >> 13, tp = fth & 8191;
      float* drow = dst + ((size_t)g * LSEQ + tp) * HD;
#pragma unroll
      for (int n = 0; n < 4; ++n)
        drow[wc + n * 16 + (l & 15)] = acc[m][n][j] * f[m][j];
    }
}

// ---------------------------------------------------------------- lr / scale: K-split GEMM + reduce

// grid (128, 16): 64 tokens x 64 cols x 128-K slice per block.
__global__ __launch_bounds__(256) void k_lrms5(const float* __restrict__ x,
                                               const float* __restrict__ Wlr,
                                               const float* __restrict__ Wsc,
                                               float* __restrict__ P) {
  __shared__ float Xs[128][67];
  __shared__ float Ws[128][68];
  const int tb = blockIdx.x;
  const int kp = blockIdx.y;
  const int tid = threadIdx.x;
  for (int i = tid; i < 128 * 64; i += 256) {
    int k = i >> 6, c = i & 63;
    float wv = (c < 48) ? Wlr[(size_t)(kp * 128 + k) * 48 + c]
                        : Wsc[(size_t)(kp * 128 + k) * 16 + (c - 48)];
    Ws[k][c] = wv;
  }
  const int t8 = tid >> 5, kk = tid & 31;
#pragma unroll
  for (int r = 0; r < 8; ++r) {
    int t = t8 + r * 8;
    float4 v = *(const float4*)(x + (size_t)(tb * 64 + t) * DMODEL + kp * 128 + kk * 4);
    Xs[kk * 4 + 0][t] = v.x; Xs[kk * 4 + 1][t] = v.y;
    Xs[kk * 4 + 2][t] = v.z; Xs[kk * 4 + 3][t] = v.w;
  }
  __syncthreads();
  const int ty = tid >> 4, tx = tid & 15;
  float acc[4][4];
#pragma unroll
  for (int i = 0; i < 4; ++i)
#pragma unroll
    for (int j = 0; j < 4; ++j) acc[i][j] = 0.0f;
  for (int k = 0; k < 128; ++k) {
    float a[4], b[4];
#pragma unroll
    for (int i = 0; i < 4; ++i) a[i] = Xs[k][ty * 4 + i];
#pragma unroll
    for (int j = 0; j < 4; ++j) b[j] = Ws[k][tx * 4 + j];
#pragma unroll
    for (int i = 0; i < 4; ++i)
#pragma unroll
      for (int j = 0; j < 4; ++j) acc[i][j] = fmaf(a[i], b[j], acc[i][j]);
  }
  float* o = P + ((size_t)tb * 16 + kp) * 4096;
#pragma unroll
  for (int i = 0; i < 4; ++i)
#pragma unroll
    for (int j = 0; j < 4; ++j)
      o[(ty * 4 + i) * 64 + tx * 4 + j] = acc[i][j];
}

__global__ void k_lrsum(const float* __restrict__ P, const float* __restrict__ bs,
                        float* __restrict__ LR, float* __restrict__ SCL) {
  int e = blockIdx.x * 256 + threadIdx.x;
  int t = e >> 6, c = e & 63;
  const float* base = P + ((size_t)(t >> 6) * 16) * 4096 + (t & 63) * 64 + c;
  float sum = 0.0f;
#pragma unroll
  for (int kp = 0; kp < 16; ++kp) sum += base[(size_t)kp * 4096];
  if (c < 48) {
    float base_lr_inv = 0.01f + logf(-expm1f(-0.01f));
    float v = sum + base_lr_inv;
    float sp = fmaxf(v, 0.0f) + log1pf(expf(-fabsf(v)));
    LR[(size_t)c * LSEQ + t] = sp;
  } else {
    float v = sum + bs[c - 48];
    SCL[(size_t)(c - 48) * LSEQ + t] = v * sigm(v);
  }
}

// ---------------------------------------------------------------- per-chunk output (bf16 MFMA + fused LN/scale)
// 64-token tiles, 80 KB LDS (GH aliases dead Q region) -> 2 blocks/CU.
// grid (CH/64, NH), block 256 (4 waves in 2x2 over M=64 x N=128).

__global__ __launch_bounds__(256) void k_out2(const float* __restrict__ WW,
                                              const float* __restrict__ Q,
                                              const float* __restrict__ SCL,
                                              const float* __restrict__ lng,
                                              const float* __restrict__ lnb,
                                              unsigned short* __restrict__ U, int s) {
  __shared__ __align__(16) char smem[81920];
  unsigned short* Qs  = (unsigned short*)smem;            // 16KB; GH aliases after pass 1
  unsigned short* W0s = (unsigned short*)(smem + 16384);  // 32KB; W1 after pass 1
  unsigned short* W2s = (unsigned short*)(smem + 49152);  // 32KB
  float* Os = (float*)(smem + 16384);                     // [64][132] fp32, post-pass2

  const int g = blockIdx.y;
  const int t0 = blockIdx.x * 64;
  const int tid = threadIdx.x;
  const int w = tid >> 6, l = tid & 63;
  const int lrow = l & 15, lk8 = (l >> 4) * 8;
  const int wr = (w >> 1) * 32, wc = (w & 1) * 64;

  const float* Qg  = Q + ((size_t)g * LSEQ + s + t0) * HD;
  const float* w0g = WW + ((size_t)0 * 2048 + g * 128) * 128;
  const float* w1g = WW + ((size_t)1 * 2048 + g * 128) * 128;
  const float* w2g = WW + ((size_t)2 * 2048 + g * 128) * 128;

  stage_sw64(Qg, HD, Qs, tid);
  stage_sw(w0g, 128, W0s, tid);
  stage_sw(w2g, 128, W2s, tid);
  __syncthreads();

  // pass 1: G = Q@W0^T, H = Q@W2^T (each wave: 32 rows x 64 cols)
  f32x4 ga[2][4], ha[2][4];
#pragma unroll
  for (int m = 0; m < 2; ++m)
#pragma unroll
    for (int n = 0; n < 4; ++n) { ga[m][n] = {}; ha[m][n] = {}; }
#pragma unroll
  for (int kk = 0; kk < 128; kk += 32) {
    bf16x8 af[2], b0[4], b2[4];
#pragma unroll
    for (int m = 0; m < 2; ++m) af[m] = ld_sw(Qs, wr + m * 16 + lrow, kk + lk8);
#pragma unroll
    for (int n = 0; n < 4; ++n) {
      b0[n] = ld_sw(W0s, wc + n * 16 + lrow, kk + lk8);
      b2[n] = ld_sw(W2s, wc + n * 16 + lrow, kk + lk8);
    }
#pragma unroll
    for (int m = 0; m < 2; ++m)
#pragma unroll
      for (int n = 0; n < 4; ++n) {
        ga[m][n] = __builtin_amdgcn_mfma_f32_16x16x32_bf16(af[m], b0[n], ga[m][n], 0, 0, 0);
        ha[m][n] = __builtin_amdgcn_mfma_f32_16x16x32_bf16(af[m], b2[n], ha[m][n], 0, 0, 0);
      }
  }
  __syncthreads();  // all pass-1 LDS reads done (Qs, W0s free)
  // GH -> Qs region; W1 -> W0s region
#pragma unroll
  for (int m = 0; m < 2; ++m)
#pragma unroll
    for (int n = 0; n < 4; ++n)
#pragma unroll
      for (int j = 0; j < 4; ++j) {
        int row = wr + m * 16 + (l >> 4) * 4 + j;
        int col = wc + n * 16 + (l & 15);
        float gv = ga[m][n][j];
        st_sw(Qs, row, col, f2bf(gv * sigm(gv) * ha[m][n][j]));
      }
  stage_sw(w1g, 128, W0s, tid);
  __syncthreads();

  // pass 2: O = GH @ W1^T
  f32x4 oa[2][4];
#pragma unroll
  for (int m = 0; m < 2; ++m)
#pragma unroll
    for (int n = 0; n < 4; ++n) oa[m][n] = {};
#pragma unroll
  for (int kk = 0; kk < 128; kk += 32) {
    bf16x8 af[2], b1[4];
#pragma unroll
    for (int m = 0; m < 2; ++m) af[m] = ld_sw(Qs, wr + m * 16 + lrow, kk + lk8);
#pragma unroll
    for (int n = 0; n < 4; ++n) b1[n] = ld_sw(W0s, wc + n * 16 + lrow, kk + lk8);
#pragma unroll
    for (int m = 0; m < 2; ++m)
#pragma unroll
      for (int n = 0; n < 4; ++n)
        oa[m][n] = __builtin_amdgcn_mfma_f32_16x16x32_bf16(af[m], b1[n], oa[m][n], 0, 0, 0);
  }
  __syncthreads();  // all LDS reads done; Os overlays W0s/W2s
#pragma unroll
  for (int m = 0; m < 2; ++m)
#pragma unroll
    for (int n = 0; n < 4; ++n)
#pragma unroll
      for (int j = 0; j < 4; ++j) {
        int row = wr + m * 16 + (l >> 4) * 4 + j;
        int col = wc + n * 16 + (l & 15);
        Os[row * 132 + col] = oa[m][n][j];
      }
  __syncthreads();

  // LN + scale, write U bf16. 4 threads per token (32 cols each).
  const int tok = tid >> 2, part = tid & 3;
  const float* orow = Os + tok * 132 + part * 32;
  float sum = 0.0f;
#pragma unroll
  for (int q = 0; q < 8; ++q) {
    float4 v = *(const float4*)(orow + q * 4);
    sum += (v.x + v.y) + (v.z + v.w);
  }
  sum += __shfl_xor(sum, 1, 64);
  sum += __shfl_xor(sum, 2, 64);
  float mu = sum * (1.0f / 128.0f);
  float vs = 0.0f;
#pragma unroll
  for (int q = 0; q < 8; ++q) {
    float4 v = *(const float4*)(orow + q * 4);
    float d0 = v.x - mu, d1 = v.y - mu, d2 = v.z - mu, d3 = v.w - mu;
    vs += d0 * d0 + d1 * d1 + d2 * d2 + d3 * d3;
  }
  vs += __shfl_xor(vs, 1, 64);
  vs += __shfl_xor(vs, 2, 64);
  float rstd = rsqrtf(vs * (1.0f / 128.0f) + 1e-6f);
  int tabs = s + t0 + tok;
  float sc = SCL[(size_t)g * LSEQ + tabs];
  unsigned short* urow = U + (size_t)tabs * DMODEL + g * HD + part * 32;
#pragma unroll
  for (int q = 0; q < 8; ++q) {
    float4 v = *(const float4*)(orow + q * 4);
    int d = part * 32 + q * 4;
    ushort4 o;
    o.x = f2bf(((v.x - mu) * rstd * lng[d + 0] + lnb[d + 0]) * sc);
    o.y = f2bf(((v.y - mu) * rstd * lng[d + 1] + lnb[d + 1]) * sc);
    o.z = f2bf(((v.z - mu) * rstd * lng[d + 2] + lnb[d + 2]) * sc);
    o.w = f2bf(((v.w - mu) * rstd * lng[d + 3] + lnb[d + 3]) * sc);
    *(ushort4*)(urow + q * 4) = o;
  }
}

// ---------------------------------------------------------------- fused front GEMMs + elementwise

__global__ __launch_bounds__(1024) void k_fe(const float* __restrict__ WW,
                                             const float* __restrict__ W1T,
                                             const float* __restrict__ Km,
                                             const float* __restrict__ V,
                                             float* __restrict__ BUF, int s) {
  __shared__ __align__(16) char smem[131072];
  unsigned short* KH = (unsigned short*)smem;
  unsigned short* KL = (unsigned short*)(smem + 32768);
  unsigned short* VH = (unsigned short*)(smem + 65536);
  unsigned short* VL = (unsigned short*)(smem + 98304);

  const int tt0 = blockIdx.x * 128;
  const int g = blockIdx.y;
  const int tid = threadIdx.x;
  const int w = tid >> 6, l = tid & 63;
  const int ww = w >> 2, wv = w & 3;
  const int lrow = l & 15, lk8 = (l >> 4) * 8;
  const int frow = (l >> 4) * 4, fcol = l & 15;

  stage_hl_1024(Km + ((size_t)g * LSEQ + s + tt0) * HD, HD, KH, KL, tid);
  stage_hl_1024(V + ((size_t)g * LSEQ + s + tt0) * HD, HD, VH, VL, tid);
  __syncthreads();

  const float* Asrc[3];
  Asrc[0] = WW + ((size_t)0 * 2048 + g * 128) * 128;  // w0 rows
  Asrc[1] = WW + ((size_t)2 * 2048 + g * 128) * 128;  // w2 rows
  Asrc[2] = W1T + (size_t)g * 16384;                  // w1^T rows

  f32x4 acc[3][2][2];
#pragma unroll
  for (int q = 0; q < 3; ++q)
#pragma unroll
    for (int m = 0; m < 2; ++m)
#pragma unroll
      for (int n = 0; n < 2; ++n) acc[q][m][n] = {};

#pragma unroll 1
  for (int q = 0; q < 3; ++q) {
    const float* src = Asrc[q];
    const unsigned short* BH = (q == 2) ? VH : KH;
    const unsigned short* BL = (q == 2) ? VL : KL;
#pragma unroll
    for (int kk = 0; kk < 128; kk += 32) {
      bf16x8 ah[2], al[2], bh[2], bl[2];
#pragma unroll
      for (int m = 0; m < 2; ++m) {
        int row = ww * 32 + m * 16 + lrow;
        float4 v0 = *(const float4*)(src + (size_t)row * 128 + kk + lk8);
        float4 v1 = *(const float4*)(src + (size_t)row * 128 + kk + lk8 + 4);
        bfu8 h, lo;
        const float* p0 = (const float*)&v0;
        const float* p1 = (const float*)&v1;
#pragma unroll
        for (int i = 0; i < 4; ++i) {
          unsigned short hb0 = f2bf(p0[i]);
          h.u[i] = hb0; lo.u[i] = f2bf(p0[i] - bf2f(hb0));
          unsigned short hb1 = f2bf(p1[i]);
          h.u[i + 4] = hb1; lo.u[i + 4] = f2bf(p1[i] - bf2f(hb1));
        }
        ah[m] = h.v; al[m] = lo.v;
      }
#pragma unroll
      for (int n = 0; n < 2; ++n) {
        int row = wv * 32 + n * 16 + lrow;
        bh[n] = ld_sw(BH, row, kk + lk8);
        bl[n] = ld_sw(BL, row, kk + lk8);
      }
#pragma unroll
      for (int m = 0; m < 2; ++m)
#pragma unroll
        for (int n = 0; n < 2; ++n) {
          acc[q][m][n] = __builtin_amdgcn_mfma_f32_16x16x32_bf16(ah[m], bh[n], acc[q][m][n], 0, 0, 0);
          acc[q][m][n] = __builtin_amdgcn_mfma_f32_16x16x32_bf16(ah[m], bl[n], acc[q][m][n], 0, 0, 0);
          acc[q][m][n] = __builtin_amdgcn_mfma_f32_16x16x32_bf16(al[m], bh[n], acc[q][m][n], 0, 0, 0);
        }
    }
  }

  float* out0 = BUF + (size_t)0 * (NH * 128 * CH) + (size_t)g * 128 * CH;  // hid
  float* out1 = BUF + (size_t)1 * (NH * 128 * CH) + (size_t)g * 128 * CH;  // dgb
  float* out2 = BUF + (size_t)2 * (NH * 128 * CH) + (size_t)g * 128 * CH;  // dhb
#pragma unroll
  for (int m = 0; m < 2; ++m)
#pragma unroll
    for (int n = 0; n < 2; ++n)
#pragma unroll
      for (int j = 0; j < 4; ++j) {
        int row = ww * 32 + m * 16 + frow + j;
        int col = wv * 32 + n * 16 + fcol;
        float gb = acc[0][m][n][j];
        float hb = acc[1][m][n][j];
        float dh = acc[2][m][n][j];
        float sg = sigm(gb);
        float sgb = gb * sg;
        float hid = sgb * hb;
        float dgate = dh * hb;
        float dgb = dgate * sg * (1.0f + gb * (1.0f - sg));
        float dhb = dh * sgb;
        size_t o = (size_t)row * CH + tt0 + col;
        out0[o] = hid; out1[o] = dgb; out2[o] = dhb;
      }
}

// partial dW GEMMs over 256-token slices (split-bf16). grid (8, NH, 3).
__global__ __launch_bounds__(256) void k_dwp_mx(const float* __restrict__ BUF,
                                                const float* __restrict__ Km,
                                                const float* __restrict__ V,
                                                const float* __restrict__ LR,
                                                float* __restrict__ DWP, int s) {
  __shared__ __align__(16) char smem[131072];
  unsigned short* AH = (unsigned short*)smem;
  unsigned short* AL = (unsigned short*)(smem + 32768);
  unsigned short* BH = (unsigned short*)(smem + 65536);
  unsigned short* BL = (unsigned short*)(smem + 98304);

  const int p = blockIdx.x;
  const int g = blockIdx.y;
  const int z = blockIdx.z;
  const int tid = threadIdx.x;
  const int w = tid >> 6, l = tid & 63;
  const int lrow = l & 15, lk8 = (l >> 4) * 8;
  const int wr = (w >> 1) * 64, wc = (w & 1) * 64;

  const int msel = (z == 0) ? 1 : (z == 1) ? 0 : 2;
  const float* M = BUF + (size_t)msel * (NH * 128 * CH) + (size_t)g * 128 * CH;
  const float* N = (z == 1) ? V : Km;
  const float* lr = LR + (size_t)(z * NH + g) * LSEQ;
  const int ts = p * 256;

  f32x4 acc[4][4];
#pragma unroll
  for (int m = 0; m < 4; ++m)
#pragma unroll
    for (int n = 0; n < 4; ++n) acc[m][n] = {};

  for (int h = 0; h < 2; ++h) {
    if (h) __syncthreads();
    stage_hl(M + ts + h * 128, CH, AH, AL, tid);
    stage_hl_ts(N + ((size_t)g * LSEQ + s + ts + h * 128) * HD, HD,
                lr + s + ts + h * 128, BH, BL, tid);
    __syncthreads();
#pragma unroll
    for (int kk = 0; kk < 128; kk += 32) {
      bf16x8 ah[4], al4[4], bh[4], bl4[4];
#pragma unroll
      for (int m = 0; m < 4; ++m) {
        ah[m] = ld_sw(AH, wr + m * 16 + lrow, kk + lk8);
        al4[m] = ld_sw(AL, wr + m * 16 + lrow, kk + lk8);
      }
#pragma unroll
      for (int n = 0; n < 4; ++n) {
        bh[n] = ld_sw(BH, wc + n * 16 + lrow, kk + lk8);
        bl4[n] = ld_sw(BL, wc + n * 16 + lrow, kk + lk8);
      }
#pragma unroll
      for (int m = 0; m < 4; ++m)
#pragma unroll
        for (int n = 0; n < 4; ++n) {
          acc[m][n] = __builtin_amdgcn_mfma_f32_16x16x32_bf16(ah[m], bh[n], acc[m][n], 0, 0, 0);
          acc[m][n] = __builtin_amdgcn_mfma_f32_16x16x32_bf16(ah[m], bl4[n], acc[m][n], 0, 0, 0);
          acc[m][n] = __builtin_amdgcn_mfma_f32_16x16x32_bf16(al4[m], bh[n], acc[m][n], 0, 0, 0);
        }
    }
  }

  float* outp = DWP + (((size_t)(z * NH + g)) * 8 + p) * 16384;
#pragma unroll
  for (int m = 0; m < 4; ++m)
#pragma unroll
    for (int n = 0; n < 4; ++n)
#pragma unroll
      for (int j = 0; j < 4; ++j) {
        int row = wr + m * 16 + (l >> 4) * 4 + j;
        int col = wc + n * 16 + (l & 15);
        outp[row * 128 + col] = acc[m][n][j];
      }
}

// ---------------------------------------------------------------- Newton-Schulz 5 (split-bf16 MFMA, fused partial-reduce)
// z==1 input is dw1^T; NS5(G^T)=NS5(G)^T, so z==1 writes P directly (un-transposed
// result IS dw1), z!=1 un-transposes.
__global__ __launch_bounds__(1024) void k_ns5_mfma(const float* __restrict__ DWP,
                                                   float* __restrict__ DW) {
  __shared__ __align__(16) char smem[131072];
  unsigned short* PH = (unsigned short*)smem;
  unsigned short* PL = (unsigned short*)(smem + 32768);
  unsigned short* QH = (unsigned short*)(smem + 65536);
  unsigned short* QL = (unsigned short*)(smem + 98304);
  float* red = (float*)(smem + 65536);

  const float NA[5] = {4.0848f, 3.9505f, 3.7418f, 2.8769f, 2.8366f};
  const float NB[5] = {-6.8946f, -6.3029f, -5.5913f, -3.1427f, -3.0525f};
  const float NC[5] = {2.927f, 2.6377f, 2.3037f, 1.2046f, 1.2012f};
  const int zg = blockIdx.x;
  const int z = zg >> 4;
  const float* base = DWP + (size_t)zg * 8 * 16384;
  float* Gout = DW + (size_t)zg * 16384;
  const int tid = threadIdx.x;
  const int w = tid >> 6, l = tid & 63;
  const int ww = w >> 2, wv = w & 3;
  const int lrow = l & 15, lk8 = (l >> 4) * 8;
  const int frow = (l >> 4) * 4, fcol = l & 15;

  float vals[16];
  float psum = 0.0f;
#pragma unroll
  for (int r = 0; r < 16; ++r) {
    int idx = tid + r * 1024;
    float sv = 0.0f;
#pragma unroll
    for (int p = 0; p < 8; ++p) sv += base[(size_t)p * 16384 + idx];
    vals[r] = sv;
    psum = fmaf(sv, sv, psum);
  }
  psum = wave_sum64(psum);
  if (l == 0) red[w] = psum;
  __syncthreads();
  float tot = 0.0f;
#pragma unroll
  for (int i = 0; i < 16; ++i) tot += red[i];
  float scl = 1.0f / (sqrtf(tot) + 1e-7f);
  __syncthreads();
#pragma unroll
  for (int r = 0; r < 16; ++r) {
    int idx = tid + r * 1024;
    int rr = idx >> 7, cc = idx & 127;
    float v = vals[r] * scl;
    unsigned short hi = f2bf(v);
    st_sw(PH, rr, cc, hi);
    st_sw(PL, rr, cc, f2bf(v - bf2f(hi)));
  }
  __syncthreads();

#pragma unroll 1
  for (int it = 0; it < 5; ++it) {
    const float ac = NA[it], bc = NB[it], cc2 = NC[it];

    f32x4 accA[2][2];
#pragma unroll
    for (int m = 0; m < 2; ++m)
#pragma unroll
      for (int n = 0; n < 2; ++n) accA[m][n] = {};
#pragma unroll
    for (int kk = 0; kk < 128; kk += 32) {
      bf16x8 ah[2], al[2], bh[2], bl[2];
#pragma unroll
      for (int m = 0; m < 2; ++m) {
        ah[m] = ld_sw(PH, ww * 32 + m * 16 + lrow, kk + lk8);
        al[m] = ld_sw(PL, ww * 32 + m * 16 + lrow, kk + lk8);
      }
#pragma unroll
      for (int n = 0; n < 2; ++n) {
        bh[n] = ld_sw(PH, wv * 32 + n * 16 + lrow, kk + lk8);
        bl[n] = ld_sw(PL, wv * 32 + n * 16 + lrow, kk + lk8);
      }
#pragma unroll
      for (int m = 0; m < 2; ++m)
#pragma unroll
        for (int n = 0; n < 2; ++n) {
          accA[m][n] = __builtin_amdgcn_mfma_f32_16x16x32_bf16(ah[m], bh[n], accA[m][n], 0, 0, 0);
          accA[m][n] = __builtin_amdgcn_mfma_f32_16x16x32_bf16(ah[m], bl[n], accA[m][n], 0, 0, 0);
          accA[m][n] = __builtin_amdgcn_mfma_f32_16x16x32_bf16(al[m], bh[n], accA[m][n], 0, 0, 0);
        }
    }
#pragma unroll
    for (int m = 0; m < 2; ++m)
#pragma unroll
      for (int n = 0; n < 2; ++n)
#pragma unroll
        for (int j = 0; j < 4; ++j) {
          int row = ww * 32 + m * 16 + frow + j;
          int col = wv * 32 + n * 16 + fcol;
          float v = accA[m][n][j];
          unsigned short hi = f2bf(v);
          st_sw(QH, row, col, hi);
          st_sw(QL, row, col, f2bf(v - bf2f(hi)));
        }
    __syncthreads();

    f32x4 accB[2][2];
#pragma unroll
    for (int m = 0; m < 2; ++m)
#pragma unroll
      for (int n = 0; n < 2; ++n) accB[m][n] = {};
#pragma unroll
    for (int kk = 0; kk < 128; kk += 32) {
      bf16x8 ah[2], al[2], bh[2], bl[2];
#pragma unroll
      for (int m = 0; m < 2; ++m) {
        ah[m] = ld_sw(QH, ww * 32 + m * 16 + lrow, kk + lk8);
        al[m] = ld_sw(QL, ww * 32 + m * 16 + lrow, kk + lk8);
      }
#pragma unroll
      for (int n = 0; n < 2; ++n) {
        bh[n] = ld_sw(QH, wv * 32 + n * 16 + lrow, kk + lk8);
        bl[n] = ld_sw(QL, wv * 32 + n * 16 + lrow, kk + lk8);
      }
#pragma unroll
      for (int m = 0; m < 2; ++m)
#pragma unroll
        for (int n = 0; n < 2; ++n) {
          accB[m][n] = __builtin_amdgcn_mfma_f32_16x16x32_bf16(ah[m], bh[n], accB[m][n], 0, 0, 0);
          accB[m][n] = __builtin_amdgcn_mfma_f32_16x16x32_bf16(ah[m], bl[n], accB[m][n], 0, 0, 0);
          accB[m][n] = __builtin_amdgcn_mfma_f32_16x16x32_bf16(al[m], bh[n], accB[m][n], 0, 0, 0);
        }
    }
#pragma unroll
    for (int m = 0; m < 2; ++m)
#pragma unroll
      for (int n = 0; n < 2; ++n)
#pragma unroll
        for (int j = 0; j < 4; ++j)
          accB[m][n][j] = fmaf(bc, accA[m][n][j], cc2 * accB[m][n][j]);
    __syncthreads();
#pragma unroll
    for (int m = 0; m < 2; ++m)
#pragma unroll
      for (int n = 0; n < 2; ++n)
#pragma unroll
        for (int j = 0; j < 4; ++j) {
          int row = ww * 32 + m * 16 + frow + j;
          int col = wv * 32 + n * 16 + fcol;
          float v = accB[m][n][j];
          unsigned short hi = f2bf(v);
          st_sw(QH, row, col, hi);
          st_sw(QL, row, col, f2bf(v - bf2f(hi)));
        }
    unsigned short th[16], tl[16];
#pragma unroll
    for (int r = 0; r < 16; ++r) {
      int idx = tid + r * 1024;
      int rr = idx >> 7, ccx = idx & 127;
      th[r] = ld_sw1(PH, rr, ccx);
      tl[r] = ld_sw1(PL, rr, ccx);
    }
    __syncthreads();
#pragma unroll
    for (int r = 0; r < 16; ++r) {
      int idx = tid + r * 1024;
      int rr = idx >> 7, ccx = idx & 127;
      st_sw(PH, ccx, rr, th[r]);
      st_sw(PL, ccx, rr, tl[r]);
    }
    __syncthreads();  // P now holds Y^T

    f32x4 accC[2][2];
#pragma unroll
    for (int m = 0; m < 2; ++m)
#pragma unroll
      for (int n = 0; n < 2; ++n) accC[m][n] = {};
#pragma unroll
    for (int kk = 0; kk < 128; kk += 32) {
      bf16x8 ah[2], al[2], bh[2], bl[2];
#pragma unroll
      for (int m = 0; m < 2; ++m) {
        ah[m] = ld_sw(PH, ww * 32 + m * 16 + lrow, kk + lk8);
        al[m] = ld_sw(PL, ww * 32 + m * 16 + lrow, kk + lk8);
      }
#pragma unroll
      for (int n = 0; n < 2; ++n) {
        bh[n] = ld_sw(QH, wv * 32 + n * 16 + lrow, kk + lk8);
        bl[n] = ld_sw(QL, wv * 32 + n * 16 + lrow, kk + lk8);
      }
#pragma unroll
      for (int m = 0; m < 2; ++m)
#pragma unroll
        for (int n = 0; n < 2; ++n) {
          accC[m][n] = __builtin_amdgcn_mfma_f32_16x16x32_bf16(ah[m], bh[n], accC[m][n], 0, 0, 0);
          accC[m][n] = __builtin_amdgcn_mfma_f32_16x16x32_bf16(ah[m], bl[n], accC[m][n], 0, 0, 0);
          accC[m][n] = __builtin_amdgcn_mfma_f32_16x16x32_bf16(al[m], bh[n], accC[m][n], 0, 0, 0);
        }
    }
#pragma unroll
    for (int m = 0; m < 2; ++m)
#pragma unroll
      for (int n = 0; n < 2; ++n)
#pragma unroll
        for (int j = 0; j < 4; ++j) {
          int row = ww * 32 + m * 16 + frow + j;
          int col = wv * 32 + n * 16 + fcol;
          float yv = bf2f(ld_sw1(PH, row, col)) + bf2f(ld_sw1(PL, row, col));
          accC[m][n][j] = fmaf(ac, yv, accC[m][n][j]);
        }
    __syncthreads();
#pragma unroll
    for (int m = 0; m < 2; ++m)
#pragma unroll
      for (int n = 0; n < 2; ++n)
#pragma unroll
        for (int j = 0; j < 4; ++j) {
          int row = ww * 32 + m * 16 + frow + j;
          int col = wv * 32 + n * 16 + fcol;
          float v = accC[m][n][j];
          unsigned short hi = f2bf(v);
          st_sw(PH, row, col, hi);
          st_sw(PL, row, col, f2bf(v - bf2f(hi)));
        }
    __syncthreads();
  }

#pragma unroll
  for (int r = 0; r < 16; ++r) {
    int idx = tid + r * 1024;
    int rr = idx >> 7, ccx = idx & 127;
    if (z == 1)
      Gout[idx] = bf2f(ld_sw1(PH, rr, ccx)) + bf2f(ld_sw1(PL, rr, ccx));
    else
      Gout[idx] = bf2f(ld_sw1(PH, ccx, rr)) + bf2f(ld_sw1(PL, ccx, rr));
  }
}

// w += dw; renormalize; maintain W1T.
__global__ void k_apply(float* __restrict__ WW, const float* __restrict__ DW,
                        const float* __restrict__ WN0, float* __restrict__ W1T) {
  int rid = blockIdx.x;
  int m = rid >> 11;
  int gr = rid & 2047;
  int l = threadIdx.x;
  float* wrow = WW + (size_t)rid * 128;
  const float* drow = DW + (size_t)rid * 128;
  float v0 = wrow[l] + drow[l];
  float v1 = wrow[l + 64] + drow[l + 64];
  float s = wave_sum64(v0 * v0 + v1 * v1);
  float f = WN0[rid] / (sqrtf(s) + 1e-5f);
  v0 *= f; v1 *= f;
  wrow[l] = v0;
  wrow[l + 64] = v1;
  if (m == 1) {
    int g = gr >> 7, r = gr & 127;
    W1T[((size_t)g * 128 + l) * 128 + r] = v0;
    W1T[((size_t)g * 128 + l + 64) * 128 + r] = v1;
  }
}

// ---------------------------------------------------------------- final projection (bf16 MFMA, natural 2D grid)

__global__ __launch_bounds__(256) void k_final_mfma(const unsigned short* __restrict__ U,
                                                    const unsigned short* __restrict__ Wot,
                                                    float* __restrict__ out) {
  __shared__ unsigned short Al[128 * 32];
  __shared__ unsigned short Bl[128 * 32];
  f32x4 acc[4][4];
#pragma unroll
  for (int m = 0; m < 4; ++m)
#pragma unroll
    for (int n = 0; n < 4; ++n) acc[m][n] = {};

  const int row0 = blockIdx.x * 128, col0 = blockIdx.y * 128;
  gemm_core(U, Wot, DMODEL, DMODEL, DMODEL, row0, col0, Al, Bl, acc);

  const int tid = threadIdx.x, w = tid >> 6, l = tid & 63;
  const int wr = (w >> 1) * 64, wc = (w & 1) * 64;
#pragma unroll
  for (int m = 0; m < 4; ++m)
#pragma unroll
    for (int j = 0; j < 4; ++j) {
      int t = row0 + wr + m * 16 + (l >> 4) * 4 + j;
      float* orow = out + (size_t)t * DMODEL + col0;
#pragma unroll
      for (int n = 0; n < 4; ++n)
        orow[wc + n * 16 + (l & 15)] = acc[m][n][j];
    }
}

// ---------------------------------------------------------------- launch

extern "C" void kernel_launch(void* const* d_in, const int* in_sizes, int n_in,
                              void* d_out, int out_size, void* d_ws, size_t ws_size,
                              hipStream_t stream) {
  (void)in_sizes; (void)n_in; (void)out_size;
  const float* x    = (const float*)d_in[0];
  const float* Wqkv = (const float*)d_in[1];
  const float* Wlr  = (const float*)d_in[2];
  const float* Wo   = (const float*)d_in[3];
  const float* Wsc  = (const float*)d_in[6];
  const float* bs   = (const float*)d_in[7];
  const float* lng  = (const float*)d_in[8];
  const float* lnb  = (const float*)d_in[9];
  const float* w0   = (const float*)d_in[10];
  const float* w1   = (const float*)d_in[11];
  const float* w2   = (const float*)d_in[12];

  float* Q = (float*)d_out;  // last read (k_out2 chunk 3) precedes k_final's write

  float* ws = (float*)d_ws;
  size_t off = 0;
  auto alloc = [&](size_t n) { float* p = ws + off; off += n; return p; };
  float* Km   = alloc((size_t)NH * LSEQ * HD);
  float* V    = alloc((size_t)NH * LSEQ * HD);
  float* Uf   = alloc((size_t)LSEQ * DMODEL / 2);   // U stored as bf16
  float* LR   = alloc((size_t)3 * NH * LSEQ);
  float* SCL  = alloc((size_t)NH * LSEQ);
  float* WW   = alloc((size_t)3 * NH * HD * HD);
  float* WN0  = alloc((size_t)3 * NH * HD);
  float* W1T  = alloc((size_t)NH * HD * HD);
  float* BUF  = alloc((size_t)3 * NH * HD * CH);    // chunk loop scratch
  float* DW   = alloc((size_t)3 * NH * HD * HD);
  float* DWP  = alloc((size_t)3 * NH * 8 * HD * HD);
  if (off * sizeof(float) > ws_size) return;        // clean failure instead of OOB

  unsigned short* U = (unsigned short*)Uf;
  unsigned short* xb  = (unsigned short*)BUF;                                   // pre-qkv
  unsigned short* Wqt = (unsigned short*)(BUF + (size_t)LSEQ * DMODEL / 2);
  float* Plr = BUF;                                                             // lrms partials
  unsigned short* Wot = (unsigned short*)BUF;                                   // post-loop

  k_init_w<<<3 * NH * HD, 64, 0, stream>>>(w0, w1, w2, WW, WN0, W1T);
  k_cast<<<2048, 256, 0, stream>>>(x, xb, LSEQ * DMODEL / 4);
  k_tcast<<<dim3(3 * DMODEL / 64, DMODEL / 64), 256, 0, stream>>>(Wqkv, Wqt, DMODEL, 3 * DMODEL);
  k_qkv_mfma<<<dim3(LSEQ / 128, 48), 256, 0, stream>>>(xb, Wqt, Q, Km, V);
  k_lrms5<<<dim3(LSEQ / 64, 16), 256, 0, stream>>>(x, Wlr, Wsc, Plr);
  k_lrsum<<<LSEQ * 64 / 256, 256, 0, stream>>>(Plr, bs, LR, SCL);

  for (int c = 0; c < 4; ++c) {
    int s = c * CH;
    k_out2<<<dim3(CH / 64, NH), 256, 0, stream>>>(WW, Q, SCL, lng, lnb, U, s);
    if (c < 3) {
      k_fe<<<dim3(CH / 128, NH), 1024, 0, stream>>>(WW, W1T, Km, V, BUF, s);
      k_dwp_mx<<<dim3(8, NH, 3), 256, 0, stream>>>(BUF, Km, V, LR, DWP, s);
      k_ns5_mfma<<<3 * NH, 1024, 0, stream>>>(DWP, DW);
      k_apply<<<3 * NH * HD, 64, 0, stream>>>(WW, DW, WN0, W1T);
    }
  }
  k_tcast<<<dim3(DMODEL / 64, DMODEL / 64), 256, 0, stream>>>(Wo, Wot, DMODEL, DMODEL);
  k_final_mfma<<<dim3(LSEQ / 128, DMODEL / 128), 256, 0, stream>>>(U, Wot, (float*)d_out);
}

// Round 10
// 1342.775 us; speedup vs baseline: 4.4671x; 1.0031x over previous
//
#include <hip/hip_runtime.h>
#include <hip/hip_bf16.h>
#include <cstdint>
#include <cstddef>

#define LSEQ   8192
#define DMODEL 2048
#define NH     16      // heads == groups
#define HD     128     // head dim == hidden dim
#define CH     2048    // chunk length (group-space positions)

typedef __attribute__((ext_vector_type(8))) __bf16 bf16x8;
typedef __attribute__((ext_vector_type(4))) float f32x4;

// ---------------------------------------------------------------- helpers

__device__ __forceinline__ float wave_sum64(float v) {
#pragma unroll
  for (int m = 32; m; m >>= 1) v += __shfl_xor(v, m, 64);
  return v;
}

__device__ __forceinline__ float sigm(float x) { return 1.0f / (1.0f + expf(-x)); }

// RTNE float -> bf16 bits
__device__ __forceinline__ unsigned short f2bf(float f) {
  unsigned int u = __float_as_uint(f);
  u += 0x7FFFu + ((u >> 16) & 1u);
  return (unsigned short)(u >> 16);
}
__device__ __forceinline__ float bf2f(unsigned short h) {
  return __uint_as_float((unsigned int)h << 16);
}

// async global->LDS, 16B per lane.
__device__ __forceinline__ void gload_lds16(const void* g, void* l) {
  __builtin_amdgcn_global_load_lds((__attribute__((address_space(1))) void*)(g),
                                   (__attribute__((address_space(3))) void*)(l), 16, 0, 0);
}

union bfu8 { bf16x8 v; unsigned short u[8]; };

// ---------------------------------------------------------------- casts

__global__ void k_cast(const float* __restrict__ X, unsigned short* __restrict__ Xb, int n4) {
  int i = blockIdx.x * 256 + threadIdx.x;
  int stride = gridDim.x * 256;
  for (; i < n4; i += stride) {
    float4 v = ((const float4*)X)[i];
    ushort4 o;
    o.x = f2bf(v.x); o.y = f2bf(v.y); o.z = f2bf(v.z); o.w = f2bf(v.w);
    ((ushort4*)Xb)[i] = o;
  }
}

// W (K x N, fp32) -> Wt (N x K, bf16). grid (N/64, K/64), block 256.
__global__ void k_tcast(const float* __restrict__ W, unsigned short* __restrict__ Wt,
                        int K, int N) {
  __shared__ float t[64][65];
  const int n0 = blockIdx.x * 64, k0 = blockIdx.y * 64;
  const int tid = threadIdx.x;
  const int cx = tid & 63, ry = tid >> 6;
#pragma unroll
  for (int r = 0; r < 16; ++r) {
    int row = ry + r * 4;
    t[row][cx] = W[(size_t)(k0 + row) * N + n0 + cx];
  }
  __syncthreads();
#pragma unroll
  for (int r = 0; r < 16; ++r) {
    int nn = ry + r * 4;
    Wt[(size_t)(n0 + nn) * K + k0 + cx] = f2bf(t[cx][nn]);
  }
}

// ---------------------------------------------------------------- bf16 MFMA GEMM core (m97 style, kept for k_final)

__device__ __forceinline__ void gemm_core(const unsigned short* __restrict__ A,
                                          const unsigned short* __restrict__ B,
                                          int K, int ldA, int ldB, int row0, int col0,
                                          unsigned short* Al, unsigned short* Bl,
                                          f32x4 acc[4][4]) {
  const int tid = threadIdx.x;
  const int w = tid >> 6, l = tid & 63;
  const int lrow = l & 15, lk = (l >> 4) * 8;
  const int wr = (w >> 1) * 64, wc = (w & 1) * 64;
  const int srow = l >> 2, skk = (l & 3) * 8;

  for (int kk = 0; kk < K; kk += 32) {
#pragma unroll
    for (int q = 0; q < 2; ++q) {
      int c = w * 2 + q;
      gload_lds16(A + (size_t)(row0 + c * 16 + srow) * ldA + kk + skk, &Al[c * 512]);
      gload_lds16(B + (size_t)(col0 + c * 16 + srow) * ldB + kk + skk, &Bl[c * 512]);
    }
    __syncthreads();
    bf16x8 af[4], bfr[4];
#pragma unroll
    for (int m = 0; m < 4; ++m)
      af[m] = *(const bf16x8*)&Al[(wr + m * 16 + lrow) * 32 + lk];
#pragma unroll
    for (int n = 0; n < 4; ++n)
      bfr[n] = *(const bf16x8*)&Bl[(wc + n * 16 + lrow) * 32 + lk];
#pragma unroll
    for (int m = 0; m < 4; ++m)
#pragma unroll
      for (int n = 0; n < 4; ++n)
        acc[m][n] = __builtin_amdgcn_mfma_f32_16x16x32_bf16(af[m], bfr[n], acc[m][n], 0, 0, 0);
    __syncthreads();
  }
}

// ---------------------------------------------------------------- swizzled LDS helpers (bf16, 128-col rows)

__device__ __forceinline__ bf16x8 ld_sw(const unsigned short* base, int row, int kcol) {
  int byte = (row * 256 + kcol * 2) ^ ((row & 7) << 4);
  return *(const bf16x8*)((const char*)base + byte);
}
__device__ __forceinline__ void st_sw(unsigned short* base, int row, int col, unsigned short v) {
  int byte = (row * 256 + col * 2) ^ ((row & 7) << 4);
  *(unsigned short*)((char*)base + byte) = v;
}
__device__ __forceinline__ unsigned short ld_sw1(const unsigned short* base, int row, int col) {
  int byte = (row * 256 + col * 2) ^ ((row & 7) << 4);
  return *(const unsigned short*)((const char*)base + byte);
}

__device__ __forceinline__ void stage_sw(const float* __restrict__ src, int ld,
                                         unsigned short* dst, int tid) {
#pragma unroll
  for (int p = 0; p < 16; ++p) {
    int row = p * 8 + (tid >> 5);
    int col = (tid & 31) * 4;
    float4 v = *(const float4*)(src + (size_t)row * ld + col);
    int byte = (row * 256 + col * 2) ^ ((row & 7) << 4);
    unsigned short* d = (unsigned short*)((char*)dst + byte);
    d[0] = f2bf(v.x); d[1] = f2bf(v.y); d[2] = f2bf(v.z); d[3] = f2bf(v.w);
  }
}

__device__ __forceinline__ void stage_sw64(const float* __restrict__ src, int ld,
                                           unsigned short* dst, int tid) {
#pragma unroll
  for (int p = 0; p < 8; ++p) {
    int row = p * 8 + (tid >> 5);
    int col = (tid & 31) * 4;
    float4 v = *(const float4*)(src + (size_t)row * ld + col);
    int byte = (row * 256 + col * 2) ^ ((row & 7) << 4);
    unsigned short* d = (unsigned short*)((char*)dst + byte);
    d[0] = f2bf(v.x); d[1] = f2bf(v.y); d[2] = f2bf(v.z); d[3] = f2bf(v.w);
  }
}

__device__ __forceinline__ void stage_hl(const float* __restrict__ src, int ld,
                                         unsigned short* H, unsigned short* L, int tid) {
#pragma unroll
  for (int p = 0; p < 16; ++p) {
    int row = p * 8 + (tid >> 5);
    int col = (tid & 31) * 4;
    float4 v = *(const float4*)(src + (size_t)row * ld + col);
    int byte = (row * 256 + col * 2) ^ ((row & 7) << 4);
    unsigned short* h = (unsigned short*)((char*)H + byte);
    unsigned short* l = (unsigned short*)((char*)L + byte);
    const float* pv = (const float*)&v;
#pragma unroll
    for (int i = 0; i < 4; ++i) {
      unsigned short hi = f2bf(pv[i]);
      h[i] = hi;
      l[i] = f2bf(pv[i] - bf2f(hi));
    }
  }
}

__device__ __forceinline__ void stage_hl_1024(const float* __restrict__ src, int ld,
                                              unsigned short* H, unsigned short* L, int tid) {
#pragma unroll
  for (int p = 0; p < 4; ++p) {
    int row = p * 32 + (tid >> 5);
    int col = (tid & 31) * 4;
    float4 v = *(const float4*)(src + (size_t)row * ld + col);
    int byte = (row * 256 + col * 2) ^ ((row & 7) << 4);
    unsigned short* h = (unsigned short*)((char*)H + byte);
    unsigned short* l = (unsigned short*)((char*)L + byte);
    const float* pv = (const float*)&v;
#pragma unroll
    for (int i = 0; i < 4; ++i) {
      unsigned short hi = f2bf(pv[i]);
      h[i] = hi;
      l[i] = f2bf(pv[i] - bf2f(hi));
    }
  }
}

__device__ __forceinline__ void stage_hl_ts(const float* __restrict__ src, int ld,
                                            const float* __restrict__ lr,
                                            unsigned short* H, unsigned short* L, int tid) {
#pragma unroll
  for (int p = 0; p < 16; ++p) {
    int t = p * 8 + (tid >> 5);
    int d = (tid & 31) * 4;
    float4 v = *(const float4*)(src + (size_t)t * ld + d);
    float sc = lr[t];
    const float* pv = (const float*)&v;
#pragma unroll
    for (int i = 0; i < 4; ++i) {
      float x = pv[i] * sc;
      unsigned short hi = f2bf(x);
      st_sw(H, d + i, t, hi);
      st_sw(L, d + i, t, f2bf(x - bf2f(hi)));
    }
  }
}

// ---------------------------------------------------------------- init w + row norms (+ w1^T copy)

__global__ void k_init_w(const float* __restrict__ w0, const float* __restrict__ w1,
                         const float* __restrict__ w2, float* __restrict__ WW,
                         float* __restrict__ WN0, float* __restrict__ W1T) {
  int rid = blockIdx.x;
  int m = rid >> 11;
  int gr = rid & 2047;
  const float* src = (m == 0) ? w0 : (m == 1) ? w1 : w2;
  const float* row = src + (size_t)gr * HD;
  float* drow = WW + ((size_t)m * 2048 + gr) * HD;
  int l = threadIdx.x;
  float v0 = row[l], v1 = row[l + 64];
  drow[l] = v0; drow[l + 64] = v1;
  if (m == 1) {
    int g = gr >> 7, r = gr & 127;
    W1T[((size_t)g * 128 + l) * 128 + r] = v0;
    W1T[((size_t)g * 128 + l + 64) * 128 + r] = v1;
  }
  float s = wave_sum64(v0 * v0 + v1 * v1);
  if (l == 0) WN0[rid] = sqrtf(s);
}

// ---------------------------------------------------------------- qkv projection: 8-phase 256^2 template
// 512 thr = 8 waves (2M x 4N), per-wave 128x64. LDS = 4 rotating slots x (A 16KB + B 16KB).
// Staging: global_load_lds w/ pre-swizzled global src (linear LDS dest); counted vmcnt(4)
// at k-step boundaries (never 0 in main loop); 2 phases/k-step with raw barriers + setprio.
// Epilogue: silu + fused l2norm (Q/K) + scatter to group layout.

// in-slot swizzle: byte = (row*64 + kcol*2) ^ ((((row&3)^((row>>2)&3)))<<4)  [bijective, 2-way banks]
__device__ __forceinline__ bf16x8 ldf8(const char* slotm, int row, int kc) {
  int f = (((row & 3) ^ ((row >> 2) & 3)) << 4);
  int byte = (row * 64 + kc * 2) ^ f;
  return *(const bf16x8*)(slotm + byte);
}

__global__ __launch_bounds__(512, 2) void k_qkv8(const unsigned short* __restrict__ A,
                                                 const unsigned short* __restrict__ B,
                                                 float* __restrict__ Q, float* __restrict__ Km,
                                                 float* __restrict__ V) {
  __shared__ __align__(16) char smem[131072];
  const int tid = threadIdx.x;
  const int w = tid >> 6, l = tid & 63;
  const int wm = w >> 2, wn = w & 3;
  const int lrow = l & 15, lk8 = (l >> 4) * 8;
  const int row0 = blockIdx.x * 256, col0 = blockIdx.y * 256;
  const int NK = DMODEL / 32;

  // per-thread staging geometry: chunks c0=tid, c1=512+tid; r1 = 128 + r0, same ks.
  const int r0 = tid >> 2;
  const int ks0 = ((tid & 3) * 8) ^ ((((r0 & 3) ^ ((r0 >> 2) & 3))) << 3);

  const unsigned short* gA = A + (size_t)(row0 + r0) * DMODEL + ks0;
  const unsigned short* gB = B + (size_t)(col0 + r0) * DMODEL + ks0;

#define SLOT(s)   (smem + (s) * 32768)
#define STAGE_A8(s, j) { const unsigned short* g = gA + (j) * 32;                 \
    gload_lds16(g, SLOT(s) + w * 1024);                                           \
    gload_lds16(g + (size_t)128 * DMODEL, SLOT(s) + 8192 + w * 1024); }
#define STAGE_B8(s, j) { const unsigned short* g = gB + (j) * 32;                 \
    gload_lds16(g, SLOT(s) + 16384 + w * 1024);                                   \
    gload_lds16(g + (size_t)128 * DMODEL, SLOT(s) + 16384 + 8192 + w * 1024); }

  f32x4 acc[8][4];
#pragma unroll
  for (int m = 0; m < 8; ++m)
#pragma unroll
    for (int n = 0; n < 4; ++n) acc[m][n] = {};

  // prologue: slots 0,1 in flight; wait slot 0 (4 newer outstanding)
  STAGE_A8(0, 0); STAGE_B8(0, 0);
  STAGE_A8(1, 1); STAGE_B8(1, 1);
  asm volatile("s_waitcnt vmcnt(4)");
  __builtin_amdgcn_s_barrier();
  __builtin_amdgcn_sched_barrier(0);

#pragma unroll 1
  for (int j = 0; j < NK; ++j) {
    const int s = j & 3;
    const char* As = SLOT(s);
    const char* Bs = SLOT(s) + 16384;
    // ---- phase 0: read A frags + B n0/n1, stage next-A, barrier, 16 MFMA
    bf16x8 af[8];
#pragma unroll
    for (int m = 0; m < 8; ++m) af[m] = ldf8(As, wm * 128 + m * 16 + lrow, lk8);
    bf16x8 b0 = ldf8(Bs, wn * 64 + 0 * 16 + lrow, lk8);
    bf16x8 b1 = ldf8(Bs, wn * 64 + 1 * 16 + lrow, lk8);
    if (j + 2 < NK) STAGE_A8((j + 2) & 3, j + 2);
    __builtin_amdgcn_s_barrier();
    __builtin_amdgcn_s_setprio(1);
#pragma unroll
    for (int m = 0; m < 8; ++m) {
      acc[m][0] = __builtin_amdgcn_mfma_f32_16x16x32_bf16(af[m], b0, acc[m][0], 0, 0, 0);
      acc[m][1] = __builtin_amdgcn_mfma_f32_16x16x32_bf16(af[m], b1, acc[m][1], 0, 0, 0);
    }
    __builtin_amdgcn_s_setprio(0);
    __builtin_amdgcn_s_barrier();
    // ---- phase 1: read B n2/n3, stage next-B, barrier, 16 MFMA
    bf16x8 b2 = ldf8(Bs, wn * 64 + 2 * 16 + lrow, lk8);
    bf16x8 b3 = ldf8(Bs, wn * 64 + 3 * 16 + lrow, lk8);
    if (j + 2 < NK) STAGE_B8((j + 2) & 3, j + 2);
    __builtin_amdgcn_s_barrier();
    __builtin_amdgcn_s_setprio(1);
#pragma unroll
    for (int m = 0; m < 8; ++m) {
      acc[m][2] = __builtin_amdgcn_mfma_f32_16x16x32_bf16(af[m], b2, acc[m][2], 0, 0, 0);
      acc[m][3] = __builtin_amdgcn_mfma_f32_16x16x32_bf16(af[m], b3, acc[m][3], 0, 0, 0);
    }
    __builtin_amdgcn_s_setprio(0);
    // k-step boundary: counted wait (slot j+1 complete; slot j+2's 4 loads stay in flight)
    if (j + 2 < NK) asm volatile("s_waitcnt vmcnt(4)");
    else            asm volatile("s_waitcnt vmcnt(0)");
    __builtin_amdgcn_s_barrier();
    __builtin_amdgcn_sched_barrier(0);
  }
#undef SLOT
#undef STAGE_A8
#undef STAGE_B8

  // ---------------- epilogue: silu + l2norm(Q/K) + scatter
  const int ct = blockIdx.y * 2 + (wn >> 1);
  const int hh = ct / 3, which = ct % 3;
  float* dst = (which == 0) ? Q : (which == 1) ? Km : V;
  float* nrm = (float*)smem;  // [256][2 groups][2 halves]

#pragma unroll
  for (int m = 0; m < 8; ++m)
#pragma unroll
    for (int n = 0; n < 4; ++n)
#pragma unroll
      for (int jj = 0; jj < 4; ++jj) {
        float v = acc[m][n][jj];
        acc[m][n][jj] = v * sigm(v);
      }

  float f[8][4];
#pragma unroll
  for (int m = 0; m < 8; ++m)
#pragma unroll
    for (int jj = 0; jj < 4; ++jj) f[m][jj] = 1.0f;

  if (which != 2) {
#pragma unroll
    for (int m = 0; m < 8; ++m)
#pragma unroll
      for (int jj = 0; jj < 4; ++jj) {
        float p = 0.0f;
#pragma unroll
        for (int n = 0; n < 4; ++n) p = fmaf(acc[m][n][jj], acc[m][n][jj], p);
        p += __shfl_xor(p, 1, 64);
        p += __shfl_xor(p, 2, 64);
        p += __shfl_xor(p, 4, 64);
        p += __shfl_xor(p, 8, 64);
        f[m][jj] = p;
      }
    if ((l & 15) == 0) {
#pragma unroll
      for (int m = 0; m < 8; ++m)
#pragma unroll
        for (int jj = 0; jj < 4; ++jj) {
          int row = wm * 128 + m * 16 + (l >> 4) * 4 + jj;
          nrm[row * 4 + (wn >> 1) * 2 + (wn & 1)] = f[m][jj];
        }
    }
  }
  __syncthreads();
  if (which != 2) {
#pragma unroll
    for (int m = 0; m < 8; ++m)
#pragma unroll
      for (int jj = 0; jj < 4; ++jj) {
        int row = wm * 128 + m * 16 + (l >> 4) * 4 + jj;
        float s2 = nrm[row * 4 + (wn >> 1) * 2 + 0] + nrm[row * 4 + (wn >> 1) * 2 + 1];
        f[m][jj] = 1.0f / (sqrtf(s2) + 1e-5f);
      }
  }

#pragma unroll
  for (int m = 0; m < 8; ++m)
#pragma unroll
    for (int jj = 0; jj < 4; ++jj) {
      int row = wm * 128 + m * 16 + (l >> 4) * 4 + jj;
      int t = row0 + row;
      int fth = t * NH + hh;
      int g = fth >> 13, tp = fth & 8191;
      float* drow = dst + ((size_t)g * LSEQ + tp) * HD + (wn & 1) * 64;
#pragma unroll
      for (int n = 0; n < 4; ++n)
        drow[n * 16 + (l & 15)] = acc[m][n][jj] * f[m][jj];
    }
}

// ---------------------------------------------------------------- lr / scale: K-split GEMM + reduce

__global__ __launch_bounds__(256) void k_lrms5(const float* __restrict__ x,
                                               const float* __restrict__ Wlr,
                                               const float* __restrict__ Wsc,
                                               float* __restrict__ P) {
  __shared__ float Xs[128][67];
  __shared__ float Ws[128][68];
  const int tb = blockIdx.x;
  const int kp = blockIdx.y;
  const int tid = threadIdx.x;
  for (int i = tid; i < 128 * 64; i += 256) {
    int k = i >> 6, c = i & 63;
    float wv = (c < 48) ? Wlr[(size_t)(kp * 128 + k) * 48 + c]
                        : Wsc[(size_t)(kp * 128 + k) * 16 + (c - 48)];
    Ws[k][c] = wv;
  }
  const int t8 = tid >> 5, kk = tid & 31;
#pragma unroll
  for (int r = 0; r < 8; ++r) {
    int t = t8 + r * 8;
    float4 v = *(const float4*)(x + (size_t)(tb * 64 + t) * DMODEL + kp * 128 + kk * 4);
    Xs[kk * 4 + 0][t] = v.x; Xs[kk * 4 + 1][t] = v.y;
    Xs[kk * 4 + 2][t] = v.z; Xs[kk * 4 + 3][t] = v.w;
  }
  __syncthreads();
  const int ty = tid >> 4, tx = tid & 15;
  float acc[4][4];
#pragma unroll
  for (int i = 0; i < 4; ++i)
#pragma unroll
    for (int j = 0; j < 4; ++j) acc[i][j] = 0.0f;
  for (int k = 0; k < 128; ++k) {
    float a[4], b[4];
#pragma unroll
    for (int i = 0; i < 4; ++i) a[i] = Xs[k][ty * 4 + i];
#pragma unroll
    for (int j = 0; j < 4; ++j) b[j] = Ws[k][tx * 4 + j];
#pragma unroll
    for (int i = 0; i < 4; ++i)
#pragma unroll
      for (int j = 0; j < 4; ++j) acc[i][j] = fmaf(a[i], b[j], acc[i][j]);
  }
  float* o = P + ((size_t)tb * 16 + kp) * 4096;
#pragma unroll
  for (int i = 0; i < 4; ++i)
#pragma unroll
    for (int j = 0; j < 4; ++j)
      o[(ty * 4 + i) * 64 + tx * 4 + j] = acc[i][j];
}

__global__ void k_lrsum(const float* __restrict__ P, const float* __restrict__ bs,
                        float* __restrict__ LR, float* __restrict__ SCL) {
  int e = blockIdx.x * 256 + threadIdx.x;
  int t = e >> 6, c = e & 63;
  const float* base = P + ((size_t)(t >> 6) * 16) * 4096 + (t & 63) * 64 + c;
  float sum = 0.0f;
#pragma unroll
  for (int kp = 0; kp < 16; ++kp) sum += base[(size_t)kp * 4096];
  if (c < 48) {
    float base_lr_inv = 0.01f + logf(-expm1f(-0.01f));
    float v = sum + base_lr_inv;
    float sp = fmaxf(v, 0.0f) + log1pf(expf(-fabsf(v)));
    LR[(size_t)c * LSEQ + t] = sp;
  } else {
    float v = sum + bs[c - 48];
    SCL[(size_t)(c - 48) * LSEQ + t] = v * sigm(v);
  }
}

// ---------------------------------------------------------------- per-chunk output (bf16 MFMA + fused LN/scale)

__global__ __launch_bounds__(256) void k_out2(const float* __restrict__ WW,
                                              const float* __restrict__ Q,
                                              const float* __restrict__ SCL,
                                              const float* __restrict__ lng,
                                              const float* __restrict__ lnb,
                                              unsigned short* __restrict__ U, int s) {
  __shared__ __align__(16) char smem[81920];
  unsigned short* Qs  = (unsigned short*)smem;
  unsigned short* W0s = (unsigned short*)(smem + 16384);
  unsigned short* W2s = (unsigned short*)(smem + 49152);
  float* Os = (float*)(smem + 16384);

  const int g = blockIdx.y;
  const int t0 = blockIdx.x * 64;
  const int tid = threadIdx.x;
  const int w = tid >> 6, l = tid & 63;
  const int lrow = l & 15, lk8 = (l >> 4) * 8;
  const int wr = (w >> 1) * 32, wc = (w & 1) * 64;

  const float* Qg  = Q + ((size_t)g * LSEQ + s + t0) * HD;
  const float* w0g = WW + ((size_t)0 * 2048 + g * 128) * 128;
  const float* w1g = WW + ((size_t)1 * 2048 + g * 128) * 128;
  const float* w2g = WW + ((size_t)2 * 2048 + g * 128) * 128;

  stage_sw64(Qg, HD, Qs, tid);
  stage_sw(w0g, 128, W0s, tid);
  stage_sw(w2g, 128, W2s, tid);
  __syncthreads();

  f32x4 ga[2][4], ha[2][4];
#pragma unroll
  for (int m = 0; m < 2; ++m)
#pragma unroll
    for (int n = 0; n < 4; ++n) { ga[m][n] = {}; ha[m][n] = {}; }
#pragma unroll
  for (int kk = 0; kk < 128; kk += 32) {
    bf16x8 af[2], b0[4], b2[4];
#pragma unroll
    for (int m = 0; m < 2; ++m) af[m] = ld_sw(Qs, wr + m * 16 + lrow, kk + lk8);
#pragma unroll
    for (int n = 0; n < 4; ++n) {
      b0[n] = ld_sw(W0s, wc + n * 16 + lrow, kk + lk8);
      b2[n] = ld_sw(W2s, wc + n * 16 + lrow, kk + lk8);
    }
#pragma unroll
    for (int m = 0; m < 2; ++m)
#pragma unroll
      for (int n = 0; n < 4; ++n) {
        ga[m][n] = __builtin_amdgcn_mfma_f32_16x16x32_bf16(af[m], b0[n], ga[m][n], 0, 0, 0);
        ha[m][n] = __builtin_amdgcn_mfma_f32_16x16x32_bf16(af[m], b2[n], ha[m][n], 0, 0, 0);
      }
  }
  __syncthreads();
#pragma unroll
  for (int m = 0; m < 2; ++m)
#pragma unroll
    for (int n = 0; n < 4; ++n)
#pragma unroll
      for (int j = 0; j < 4; ++j) {
        int row = wr + m * 16 + (l >> 4) * 4 + j;
        int col = wc + n * 16 + (l & 15);
        float gv = ga[m][n][j];
        st_sw(Qs, row, col, f2bf(gv * sigm(gv) * ha[m][n][j]));
      }
  stage_sw(w1g, 128, W0s, tid);
  __syncthreads();

  f32x4 oa[2][4];
#pragma unroll
  for (int m = 0; m < 2; ++m)
#pragma unroll
    for (int n = 0; n < 4; ++n) oa[m][n] = {};
#pragma unroll
  for (int kk = 0; kk < 128; kk += 32) {
    bf16x8 af[2], b1[4];
#pragma unroll
    for (int m = 0; m < 2; ++m) af[m] = ld_sw(Qs, wr + m * 16 + lrow, kk + lk8);
#pragma unroll
    for (int n = 0; n < 4; ++n) b1[n] = ld_sw(W0s, wc + n * 16 + lrow, kk + lk8);
#pragma unroll
    for (int m = 0; m < 2; ++m)
#pragma unroll
      for (int n = 0; n < 4; ++n)
        oa[m][n] = __builtin_amdgcn_mfma_f32_16x16x32_bf16(af[m], b1[n], oa[m][n], 0, 0, 0);
  }
  __syncthreads();
#pragma unroll
  for (int m = 0; m < 2; ++m)
#pragma unroll
    for (int n = 0; n < 4; ++n)
#pragma unroll
      for (int j = 0; j < 4; ++j) {
        int row = wr + m * 16 + (l >> 4) * 4 + j;
        int col = wc + n * 16 + (l & 15);
        Os[row * 132 + col] = oa[m][n][j];
      }
  __syncthreads();

  const int tok = tid >> 2, part = tid & 3;
  const float* orow = Os + tok * 132 + part * 32;
  float sum = 0.0f;
#pragma unroll
  for (int q = 0; q < 8; ++q) {
    float4 v = *(const float4*)(orow + q * 4);
    sum += (v.x + v.y) + (v.z + v.w);
  }
  sum += __shfl_xor(sum, 1, 64);
  sum += __shfl_xor(sum, 2, 64);
  float mu = sum * (1.0f / 128.0f);
  float vs = 0.0f;
#pragma unroll
  for (int q = 0; q < 8; ++q) {
    float4 v = *(const float4*)(orow + q * 4);
    float d0 = v.x - mu, d1 = v.y - mu, d2 = v.z - mu, d3 = v.w - mu;
    vs += d0 * d0 + d1 * d1 + d2 * d2 + d3 * d3;
  }
  vs += __shfl_xor(vs, 1, 64);
  vs += __shfl_xor(vs, 2, 64);
  float rstd = rsqrtf(vs * (1.0f / 128.0f) + 1e-6f);
  int tabs = s + t0 + tok;
  float sc = SCL[(size_t)g * LSEQ + tabs];
  unsigned short* urow = U + (size_t)tabs * DMODEL + g * HD + part * 32;
#pragma unroll
  for (int q = 0; q < 8; ++q) {
    float4 v = *(const float4*)(orow + q * 4);
    int d = part * 32 + q * 4;
    ushort4 o;
    o.x = f2bf(((v.x - mu) * rstd * lng[d + 0] + lnb[d + 0]) * sc);
    o.y = f2bf(((v.y - mu) * rstd * lng[d + 1] + lnb[d + 1]) * sc);
    o.z = f2bf(((v.z - mu) * rstd * lng[d + 2] + lnb[d + 2]) * sc);
    o.w = f2bf(((v.w - mu) * rstd * lng[d + 3] + lnb[d + 3]) * sc);
    *(ushort4*)(urow + q * 4) = o;
  }
}

// ---------------------------------------------------------------- fused front GEMMs + elementwise

__global__ __launch_bounds__(1024) void k_fe(const float* __restrict__ WW,
                                             const float* __restrict__ W1T,
                                             const float* __restrict__ Km,
                                             const float* __restrict__ V,
                                             float* __restrict__ BUF, int s) {
  __shared__ __align__(16) char smem[131072];
  unsigned short* KH = (unsigned short*)smem;
  unsigned short* KL = (unsigned short*)(smem + 32768);
  unsigned short* VH = (unsigned short*)(smem + 65536);
  unsigned short* VL = (unsigned short*)(smem + 98304);

  const int tt0 = blockIdx.x * 128;
  const int g = blockIdx.y;
  const int tid = threadIdx.x;
  const int w = tid >> 6, l = tid & 63;
  const int ww = w >> 2, wv = w & 3;
  const int lrow = l & 15, lk8 = (l >> 4) * 8;
  const int frow = (l >> 4) * 4, fcol = l & 15;

  stage_hl_1024(Km + ((size_t)g * LSEQ + s + tt0) * HD, HD, KH, KL, tid);
  stage_hl_1024(V + ((size_t)g * LSEQ + s + tt0) * HD, HD, VH, VL, tid);
  __syncthreads();

  const float* Asrc[3];
  Asrc[0] = WW + ((size_t)0 * 2048 + g * 128) * 128;
  Asrc[1] = WW + ((size_t)2 * 2048 + g * 128) * 128;
  Asrc[2] = W1T + (size_t)g * 16384;

  f32x4 acc[3][2][2];
#pragma unroll
  for (int q = 0; q < 3; ++q)
#pragma unroll
    for (int m = 0; m < 2; ++m)
#pragma unroll
      for (int n = 0; n < 2; ++n) acc[q][m][n] = {};

#pragma unroll 1
  for (int q = 0; q < 3; ++q) {
    const float* src = Asrc[q];
    const unsigned short* BH = (q == 2) ? VH : KH;
    const unsigned short* BL = (q == 2) ? VL : KL;
#pragma unroll
    for (int kk = 0; kk < 128; kk += 32) {
      bf16x8 ah[2], al[2], bh[2], bl[2];
#pragma unroll
      for (int m = 0; m < 2; ++m) {
        int row = ww * 32 + m * 16 + lrow;
        float4 v0 = *(const float4*)(src + (size_t)row * 128 + kk + lk8);
        float4 v1 = *(const float4*)(src + (size_t)row * 128 + kk + lk8 + 4);
        bfu8 h, lo;
        const float* p0 = (const float*)&v0;
        const float* p1 = (const float*)&v1;
#pragma unroll
        for (int i = 0; i < 4; ++i) {
          unsigned short hb0 = f2bf(p0[i]);
          h.u[i] = hb0; lo.u[i] = f2bf(p0[i] - bf2f(hb0));
          unsigned short hb1 = f2bf(p1[i]);
          h.u[i + 4] = hb1; lo.u[i + 4] = f2bf(p1[i] - bf2f(hb1));
        }
        ah[m] = h.v; al[m] = lo.v;
      }
#pragma unroll
      for (int n = 0; n < 2; ++n) {
        int row = wv * 32 + n * 16 + lrow;
        bh[n] = ld_sw(BH, row, kk + lk8);
        bl[n] = ld_sw(BL, row, kk + lk8);
      }
#pragma unroll
      for (int m = 0; m < 2; ++m)
#pragma unroll
        for (int n = 0; n < 2; ++n) {
          acc[q][m][n] = __builtin_amdgcn_mfma_f32_16x16x32_bf16(ah[m], bh[n], acc[q][m][n], 0, 0, 0);
          acc[q][m][n] = __builtin_amdgcn_mfma_f32_16x16x32_bf16(ah[m], bl[n], acc[q][m][n], 0, 0, 0);
          acc[q][m][n] = __builtin_amdgcn_mfma_f32_16x16x32_bf16(al[m], bh[n], acc[q][m][n], 0, 0, 0);
        }
    }
  }

  float* out0 = BUF + (size_t)0 * (NH * 128 * CH) + (size_t)g * 128 * CH;
  float* out1 = BUF + (size_t)1 * (NH * 128 * CH) + (size_t)g * 128 * CH;
  float* out2 = BUF + (size_t)2 * (NH * 128 * CH) + (size_t)g * 128 * CH;
#pragma unroll
  for (int m = 0; m < 2; ++m)
#pragma unroll
    for (int n = 0; n < 2; ++n)
#pragma unroll
      for (int j = 0; j < 4; ++j) {
        int row = ww * 32 + m * 16 + frow + j;
        int col = wv * 32 + n * 16 + fcol;
        float gb = acc[0][m][n][j];
        float hb = acc[1][m][n][j];
        float dh = acc[2][m][n][j];
        float sg = sigm(gb);
        float sgb = gb * sg;
        float hid = sgb * hb;
        float dgate = dh * hb;
        float dgb = dgate * sg * (1.0f + gb * (1.0f - sg));
        float dhb = dh * sgb;
        size_t o = (size_t)row * CH + tt0 + col;
        out0[o] = hid; out1[o] = dgb; out2[o] = dhb;
      }
}

// partial dW GEMMs over 256-token slices (split-bf16). grid (8, NH, 3).
__global__ __launch_bounds__(256) void k_dwp_mx(const float* __restrict__ BUF,
                                                const float* __restrict__ Km,
                                                const float* __restrict__ V,
                                                const float* __restrict__ LR,
                                                float* __restrict__ DWP, int s) {
  __shared__ __align__(16) char smem[131072];
  unsigned short* AH = (unsigned short*)smem;
  unsigned short* AL = (unsigned short*)(smem + 32768);
  unsigned short* BH = (unsigned short*)(smem + 65536);
  unsigned short* BL = (unsigned short*)(smem + 98304);

  const int p = blockIdx.x;
  const int g = blockIdx.y;
  const int z = blockIdx.z;
  const int tid = threadIdx.x;
  const int w = tid >> 6, l = tid & 63;
  const int lrow = l & 15, lk8 = (l >> 4) * 8;
  const int wr = (w >> 1) * 64, wc = (w & 1) * 64;

  const int msel = (z == 0) ? 1 : (z == 1) ? 0 : 2;
  const float* M = BUF + (size_t)msel * (NH * 128 * CH) + (size_t)g * 128 * CH;
  const float* N = (z == 1) ? V : Km;
  const float* lr = LR + (size_t)(z * NH + g) * LSEQ;
  const int ts = p * 256;

  f32x4 acc[4][4];
#pragma unroll
  for (int m = 0; m < 4; ++m)
#pragma unroll
    for (int n = 0; n < 4; ++n) acc[m][n] = {};

  for (int h = 0; h < 2; ++h) {
    if (h) __syncthreads();
    stage_hl(M + ts + h * 128, CH, AH, AL, tid);
    stage_hl_ts(N + ((size_t)g * LSEQ + s + ts + h * 128) * HD, HD,
                lr + s + ts + h * 128, BH, BL, tid);
    __syncthreads();
#pragma unroll
    for (int kk = 0; kk < 128; kk += 32) {
      bf16x8 ah[4], al4[4], bh[4], bl4[4];
#pragma unroll
      for (int m = 0; m < 4; ++m) {
        ah[m] = ld_sw(AH, wr + m * 16 + lrow, kk + lk8);
        al4[m] = ld_sw(AL, wr + m * 16 + lrow, kk + lk8);
      }
#pragma unroll
      for (int n = 0; n < 4; ++n) {
        bh[n] = ld_sw(BH, wc + n * 16 + lrow, kk + lk8);
        bl4[n] = ld_sw(BL, wc + n * 16 + lrow, kk + lk8);
      }
#pragma unroll
      for (int m = 0; m < 4; ++m)
#pragma unroll
        for (int n = 0; n < 4; ++n) {
          acc[m][n] = __builtin_amdgcn_mfma_f32_16x16x32_bf16(ah[m], bh[n], acc[m][n], 0, 0, 0);
          acc[m][n] = __builtin_amdgcn_mfma_f32_16x16x32_bf16(ah[m], bl4[n], acc[m][n], 0, 0, 0);
          acc[m][n] = __builtin_amdgcn_mfma_f32_16x16x32_bf16(al4[m], bh[n], acc[m][n], 0, 0, 0);
        }
    }
  }

  float* outp = DWP + (((size_t)(z * NH + g)) * 8 + p) * 16384;
#pragma unroll
  for (int m = 0; m < 4; ++m)
#pragma unroll
    for (int n = 0; n < 4; ++n)
#pragma unroll
      for (int j = 0; j < 4; ++j) {
        int row = wr + m * 16 + (l >> 4) * 4 + j;
        int col = wc + n * 16 + (l & 15);
        outp[row * 128 + col] = acc[m][n][j];
      }
}

// ---------------------------------------------------------------- Newton-Schulz 5 (split-bf16 MFMA, fused partial-reduce)
__global__ __launch_bounds__(1024) void k_ns5_mfma(const float* __restrict__ DWP,
                                                   float* __restrict__ DW) {
  __shared__ __align__(16) char smem[131072];
  unsigned short* PH = (unsigned short*)smem;
  unsigned short* PL = (unsigned short*)(smem + 32768);
  unsigned short* QH = (unsigned short*)(smem + 65536);
  unsigned short* QL = (unsigned short*)(smem + 98304);
  float* red = (float*)(smem + 65536);

  const float NA[5] = {4.0848f, 3.9505f, 3.7418f, 2.8769f, 2.8366f};
  const float NB[5] = {-6.8946f, -6.3029f, -5.5913f, -3.1427f, -3.0525f};
  const float NC[5] = {2.927f, 2.6377f, 2.3037f, 1.2046f, 1.2012f};
  const int zg = blockIdx.x;
  const int z = zg >> 4;
  const float* base = DWP + (size_t)zg * 8 * 16384;
  float* Gout = DW + (size_t)zg * 16384;
  const int tid = threadIdx.x;
  const int w = tid >> 6, l = tid & 63;
  const int ww = w >> 2, wv = w & 3;
  const int lrow = l & 15, lk8 = (l >> 4) * 8;
  const int frow = (l >> 4) * 4, fcol = l & 15;

  float vals[16];
  float psum = 0.0f;
#pragma unroll
  for (int r = 0; r < 16; ++r) {
    int idx = tid + r * 1024;
    float sv = 0.0f;
#pragma unroll
    for (int p = 0; p < 8; ++p) sv += base[(size_t)p * 16384 + idx];
    vals[r] = sv;
    psum = fmaf(sv, sv, psum);
  }
  psum = wave_sum64(psum);
  if (l == 0) red[w] = psum;
  __syncthreads();
  float tot = 0.0f;
#pragma unroll
  for (int i = 0; i < 16; ++i) tot += red[i];
  float scl = 1.0f / (sqrtf(tot) + 1e-7f);
  __syncthreads();
#pragma unroll
  for (int r = 0; r < 16; ++r) {
    int idx = tid + r * 1024;
    int rr = idx >> 7, cc = idx & 127;
    float v = vals[r] * scl;
    unsigned short hi = f2bf(v);
    st_sw(PH, rr, cc, hi);
    st_sw(PL, rr, cc, f2bf(v - bf2f(hi)));
  }
  __syncthreads();

#pragma unroll 1
  for (int it = 0; it < 5; ++it) {
    const float ac = NA[it], bc = NB[it], cc2 = NC[it];

    f32x4 accA[2][2];
#pragma unroll
    for (int m = 0; m < 2; ++m)
#pragma unroll
      for (int n = 0; n < 2; ++n) accA[m][n] = {};
#pragma unroll
    for (int kk = 0; kk < 128; kk += 32) {
      bf16x8 ah[2], al[2], bh[2], bl[2];
#pragma unroll
      for (int m = 0; m < 2; ++m) {
        ah[m] = ld_sw(PH, ww * 32 + m * 16 + lrow, kk + lk8);
        al[m] = ld_sw(PL, ww * 32 + m * 16 + lrow, kk + lk8);
      }
#pragma unroll
      for (int n = 0; n < 2; ++n) {
        bh[n] = ld_sw(PH, wv * 32 + n * 16 + lrow, kk + lk8);
        bl[n] = ld_sw(PL, wv * 32 + n * 16 + lrow, kk + lk8);
      }
#pragma unroll
      for (int m = 0; m < 2; ++m)
#pragma unroll
        for (int n = 0; n < 2; ++n) {
          accA[m][n] = __builtin_amdgcn_mfma_f32_16x16x32_bf16(ah[m], bh[n], accA[m][n], 0, 0, 0);
          accA[m][n] = __builtin_amdgcn_mfma_f32_16x16x32_bf16(ah[m], bl[n], accA[m][n], 0, 0, 0);
          accA[m][n] = __builtin_amdgcn_mfma_f32_16x16x32_bf16(al[m], bh[n], accA[m][n], 0, 0, 0);
        }
    }
#pragma unroll
    for (int m = 0; m < 2; ++m)
#pragma unroll
      for (int n = 0; n < 2; ++n)
#pragma unroll
        for (int j = 0; j < 4; ++j) {
          int row = ww * 32 + m * 16 + frow + j;
          int col = wv * 32 + n * 16 + fcol;
          float v = accA[m][n][j];
          unsigned short hi = f2bf(v);
          st_sw(QH, row, col, hi);
          st_sw(QL, row, col, f2bf(v - bf2f(hi)));
        }
    __syncthreads();

    f32x4 accB[2][2];
#pragma unroll
    for (int m = 0; m < 2; ++m)
#pragma unroll
      for (int n = 0; n < 2; ++n) accB[m][n] = {};
#pragma unroll
    for (int kk = 0; kk < 128; kk += 32) {
      bf16x8 ah[2], al[2], bh[2], bl[2];
#pragma unroll
      for (int m = 0; m < 2; ++m) {
        ah[m] = ld_sw(QH, ww * 32 + m * 16 + lrow, kk + lk8);
        al[m] = ld_sw(QL, ww * 32 + m * 16 + lrow, kk + lk8);
      }
#pragma unroll
      for (int n = 0; n < 2; ++n) {
        bh[n] = ld_sw(QH, wv * 32 + n * 16 + lrow, kk + lk8);
        bl[n] = ld_sw(QL, wv * 32 + n * 16 + lrow, kk + lk8);
      }
#pragma unroll
      for (int m = 0; m < 2; ++m)
#pragma unroll
        for (int n = 0; n < 2; ++n) {
          accB[m][n] = __builtin_amdgcn_mfma_f32_16x16x32_bf16(ah[m], bh[n], accB[m][n], 0, 0, 0);
          accB[m][n] = __builtin_amdgcn_mfma_f32_16x16x32_bf16(ah[m], bl[n], accB[m][n], 0, 0, 0);
          accB[m][n] = __builtin_amdgcn_mfma_f32_16x16x32_bf16(al[m], bh[n], accB[m][n], 0, 0, 0);
        }
    }
#pragma unroll
    for (int m = 0; m < 2; ++m)
#pragma unroll
      for (int n = 0; n < 2; ++n)
#pragma unroll
        for (int j = 0; j < 4; ++j)
          accB[m][n][j] = fmaf(bc, accA[m][n][j], cc2 * accB[m][n][j]);
    __syncthreads();
#pragma unroll
    for (int m = 0; m < 2; ++m)
#pragma unroll
      for (int n = 0; n < 2; ++n)
#pragma unroll
        for (int j = 0; j < 4; ++j) {
          int row = ww * 32 + m * 16 + frow + j;
          int col = wv * 32 + n * 16 + fcol;
          float v = accB[m][n][j];
          unsigned short hi = f2bf(v);
          st_sw(QH, row, col, hi);
          st_sw(QL, row, col, f2bf(v - bf2f(hi)));
        }
    unsigned short th[16], tl[16];
#pragma unroll
    for (int r = 0; r < 16; ++r) {
      int idx = tid + r * 1024;
      int rr = idx >> 7, ccx = idx & 127;
      th[r] = ld_sw1(PH, rr, ccx);
      tl[r] = ld_sw1(PL, rr, ccx);
    }
    __syncthreads();
#pragma unroll
    for (int r = 0; r < 16; ++r) {
      int idx = tid + r * 1024;
      int rr = idx >> 7, ccx = idx & 127;
      st_sw(PH, ccx, rr, th[r]);
      st_sw(PL, ccx, rr, tl[r]);
    }
    __syncthreads();

    f32x4 accC[2][2];
#pragma unroll
    for (int m = 0; m < 2; ++m)
#pragma unroll
      for (int n = 0; n < 2; ++n) accC[m][n] = {};
#pragma unroll
    for (int kk = 0; kk < 128; kk += 32) {
      bf16x8 ah[2], al[2], bh[2], bl[2];
#pragma unroll
      for (int m = 0; m < 2; ++m) {
        ah[m] = ld_sw(PH, ww * 32 + m * 16 + lrow, kk + lk8);
        al[m] = ld_sw(PL, ww * 32 + m * 16 + lrow, kk + lk8);
      }
#pragma unroll
      for (int n = 0; n < 2; ++n) {
        bh[n] = ld_sw(QH, wv * 32 + n * 16 + lrow, kk + lk8);
        bl[n] = ld_sw(QL, wv * 32 + n * 16 + lrow, kk + lk8);
      }
#pragma unroll
      for (int m = 0; m < 2; ++m)
#pragma unroll
        for (int n = 0; n < 2; ++n) {
          accC[m][n] = __builtin_amdgcn_mfma_f32_16x16x32_bf16(ah[m], bh[n], accC[m][n], 0, 0, 0);
          accC[m][n] = __builtin_amdgcn_mfma_f32_16x16x32_bf16(ah[m], bl[n], accC[m][n], 0, 0, 0);
          accC[m][n] = __builtin_amdgcn_mfma_f32_16x16x32_bf16(al[m], bh[n], accC[m][n], 0, 0, 0);
        }
    }
#pragma unroll
    for (int m = 0; m < 2; ++m)
#pragma unroll
      for (int n = 0; n < 2; ++n)
#pragma unroll
        for (int j = 0; j < 4; ++j) {
          int row = ww * 32 + m * 16 + frow + j;
          int col = wv * 32 + n * 16 + fcol;
          float yv = bf2f(ld_sw1(PH, row, col)) + bf2f(ld_sw1(PL, row, col));
          accC[m][n][j] = fmaf(ac, yv, accC[m][n][j]);
        }
    __syncthreads();
#pragma unroll
    for (int m = 0; m < 2; ++m)
#pragma unroll
      for (int n = 0; n < 2; ++n)
#pragma unroll
        for (int j = 0; j < 4; ++j) {
          int row = ww * 32 + m * 16 + frow + j;
          int col = wv * 32 + n * 16 + fcol;
          float v = accC[m][n][j];
          unsigned short hi = f2bf(v);
          st_sw(PH, row, col, hi);
          st_sw(PL, row, col, f2bf(v - bf2f(hi)));
        }
    __syncthreads();
  }

#pragma unroll
  for (int r = 0; r < 16; ++r) {
    int idx = tid + r * 1024;
    int rr = idx >> 7, ccx = idx & 127;
    if (z == 1)
      Gout[idx] = bf2f(ld_sw1(PH, rr, ccx)) + bf2f(ld_sw1(PL, rr, ccx));
    else
      Gout[idx] = bf2f(ld_sw1(PH, ccx, rr)) + bf2f(ld_sw1(PL, ccx, rr));
  }
}

// w += dw; renormalize; maintain W1T.
__global__ void k_apply(float* __restrict__ WW, const float* __restrict__ DW,
                        const float* __restrict__ WN0, float* __restrict__ W1T) {
  int rid = blockIdx.x;
  int m = rid >> 11;
  int gr = rid & 2047;
  int l = threadIdx.x;
  float* wrow = WW + (size_t)rid * 128;
  const float* drow = DW + (size_t)rid * 128;
  float v0 = wrow[l] + drow[l];
  float v1 = wrow[l + 64] + drow[l + 64];
  float s = wave_sum64(v0 * v0 + v1 * v1);
  float f = WN0[rid] / (sqrtf(s) + 1e-5f);
  v0 *= f; v1 *= f;
  wrow[l] = v0;
  wrow[l + 64] = v1;
  if (m == 1) {
    int g = gr >> 7, r = gr & 127;
    W1T[((size_t)g * 128 + l) * 128 + r] = v0;
    W1T[((size_t)g * 128 + l + 64) * 128 + r] = v1;
  }
}

// ---------------------------------------------------------------- final projection (bf16 MFMA)

__global__ __launch_bounds__(256) void k_final_mfma(const unsigned short* __restrict__ U,
                                                    const unsigned short* __restrict__ Wot,
                                                    float* __restrict__ out) {
  __shared__ unsigned short Al[128 * 32];
  __shared__ unsigned short Bl[128 * 32];
  f32x4 acc[4][4];
#pragma unroll
  for (int m = 0; m < 4; ++m)
#pragma unroll
    for (int n = 0; n < 4; ++n) acc[m][n] = {};

  const int row0 = blockIdx.x * 128, col0 = blockIdx.y * 128;
  gemm_core(U, Wot, DMODEL, DMODEL, DMODEL, row0, col0, Al, Bl, acc);

  const int tid = threadIdx.x, w = tid >> 6, l = tid & 63;
  const int wr = (w >> 1) * 64, wc = (w & 1) * 64;
#pragma unroll
  for (int m = 0; m < 4; ++m)
#pragma unroll
    for (int j = 0; j < 4; ++j) {
      int t = row0 + wr + m * 16 + (l >> 4) * 4 + j;
      float* orow = out + (size_t)t * DMODEL + col0;
#pragma unroll
      for (int n = 0; n < 4; ++n)
        orow[wc + n * 16 + (l & 15)] = acc[m][n][j];
    }
}

// ---------------------------------------------------------------- launch

extern "C" void kernel_launch(void* const* d_in, const int* in_sizes, int n_in,
                              void* d_out, int out_size, void* d_ws, size_t ws_size,
                              hipStream_t stream) {
  (void)in_sizes; (void)n_in; (void)out_size;
  const float* x    = (const float*)d_in[0];
  const float* Wqkv = (const float*)d_in[1];
  const float* Wlr  = (const float*)d_in[2];
  const float* Wo   = (const float*)d_in[3];
  const float* Wsc  = (const float*)d_in[6];
  const float* bs   = (const float*)d_in[7];
  const float* lng  = (const float*)d_in[8];
  const float* lnb  = (const float*)d_in[9];
  const float* w0   = (const float*)d_in[10];
  const float* w1   = (const float*)d_in[11];
  const float* w2   = (const float*)d_in[12];

  float* Q = (float*)d_out;  // last read (k_out2 chunk 3) precedes k_final's write

  float* ws = (float*)d_ws;
  size_t off = 0;
  auto alloc = [&](size_t n) { float* p = ws + off; off += n; return p; };
  float* Km   = alloc((size_t)NH * LSEQ * HD);
  float* V    = alloc((size_t)NH * LSEQ * HD);
  float* Uf   = alloc((size_t)LSEQ * DMODEL / 2);   // U stored as bf16
  float* LR   = alloc((size_t)3 * NH * LSEQ);
  float* SCL  = alloc((size_t)NH * LSEQ);
  float* WW   = alloc((size_t)3 * NH * HD * HD);
  float* WN0  = alloc((size_t)3 * NH * HD);
  float* W1T  = alloc((size_t)NH * HD * HD);
  float* BUF  = alloc((size_t)3 * NH * HD * CH);    // chunk loop scratch
  float* DW   = alloc((size_t)3 * NH * HD * HD);
  float* DWP  = alloc((size_t)3 * NH * 8 * HD * HD);
  if (off * sizeof(float) > ws_size) return;        // clean failure instead of OOB

  unsigned short* U = (unsigned short*)Uf;
  unsigned short* xb  = (unsigned short*)BUF;                                   // pre-qkv
  unsigned short* Wqt = (unsigned short*)(BUF + (size_t)LSEQ * DMODEL / 2);
  float* Plr = BUF;                                                             // lrms partials
  unsigned short* Wot = (unsigned short*)BUF;                                   // post-loop

  k_init_w<<<3 * NH * HD, 64, 0, stream>>>(w0, w1, w2, WW, WN0, W1T);
  k_cast<<<2048, 256, 0, stream>>>(x, xb, LSEQ * DMODEL / 4);
  k_tcast<<<dim3(3 * DMODEL / 64, DMODEL / 64), 256, 0, stream>>>(Wqkv, Wqt, DMODEL, 3 * DMODEL);
  k_qkv8<<<dim3(LSEQ / 256, 3 * DMODEL / 256), 512, 0, stream>>>(xb, Wqt, Q, Km, V);
  k_lrms5<<<dim3(LSEQ / 64, 16), 256, 0, stream>>>(x, Wlr, Wsc, Plr);
  k_lrsum<<<LSEQ * 64 / 256, 256, 0, stream>>>(Plr, bs, LR, SCL);

  for (int c = 0; c < 4; ++c) {
    int s = c * CH;
    k_out2<<<dim3(CH / 64, NH), 256, 0, stream>>>(WW, Q, SCL, lng, lnb, U, s);
    if (c < 3) {
      k_fe<<<dim3(CH / 128, NH), 1024, 0, stream>>>(WW, W1T, Km, V, BUF, s);
      k_dwp_mx<<<dim3(8, NH, 3), 256, 0, stream>>>(BUF, Km, V, LR, DWP, s);
      k_ns5_mfma<<<3 * NH, 1024, 0, stream>>>(DWP, DW);
      k_apply<<<3 * NH * HD, 64, 0, stream>>>(WW, DW, WN0, W1T);
    }
  }
  k_tcast<<<dim3(DMODEL / 64, DMODEL / 64), 256, 0, stream>>>(Wo, Wot, DMODEL, DMODEL);
  k_final_mfma<<<dim3(LSEQ / 128, DMODEL / 128), 256, 0, stream>>>(U, Wot, (float*)d_out);
}

// Round 11
// 1313.078 us; speedup vs baseline: 4.5681x; 1.0226x over previous
//
#include <hip/hip_runtime.h>
#include <hip/hip_bf16.h>
#include <cstdint>
#include <cstddef>

#define LSEQ   8192
#define DMODEL 2048
#define NH     16      // heads == groups
#define HD     128     // head dim == hidden dim
#define CH     2048    // chunk length (group-space positions)

typedef __attribute__((ext_vector_type(8))) __bf16 bf16x8;
typedef __attribute__((ext_vector_type(4))) float f32x4;

// ---------------------------------------------------------------- helpers

__device__ __forceinline__ float wave_sum64(float v) {
#pragma unroll
  for (int m = 32; m; m >>= 1) v += __shfl_xor(v, m, 64);
  return v;
}

__device__ __forceinline__ float sigm(float x) { return 1.0f / (1.0f + expf(-x)); }

// RTNE float -> bf16 bits
__device__ __forceinline__ unsigned short f2bf(float f) {
  unsigned int u = __float_as_uint(f);
  u += 0x7FFFu + ((u >> 16) & 1u);
  return (unsigned short)(u >> 16);
}
__device__ __forceinline__ float bf2f(unsigned short h) {
  return __uint_as_float((unsigned int)h << 16);
}

// async global->LDS, 16B per lane.
__device__ __forceinline__ void gload_lds16(const void* g, void* l) {
  __builtin_amdgcn_global_load_lds((__attribute__((address_space(1))) void*)(g),
                                   (__attribute__((address_space(3))) void*)(l), 16, 0, 0);
}

union bfu8 { bf16x8 v; unsigned short u[8]; };

// ---------------------------------------------------------------- casts

__global__ void k_cast(const float* __restrict__ X, unsigned short* __restrict__ Xb, int n4) {
  int i = blockIdx.x * 256 + threadIdx.x;
  int stride = gridDim.x * 256;
  for (; i < n4; i += stride) {
    float4 v = ((const float4*)X)[i];
    ushort4 o;
    o.x = f2bf(v.x); o.y = f2bf(v.y); o.z = f2bf(v.z); o.w = f2bf(v.w);
    ((ushort4*)Xb)[i] = o;
  }
}

// W (K x N, fp32) -> Wt (N x K, bf16). grid (N/64, K/64), block 256.
__global__ void k_tcast(const float* __restrict__ W, unsigned short* __restrict__ Wt,
                        int K, int N) {
  __shared__ float t[64][65];
  const int n0 = blockIdx.x * 64, k0 = blockIdx.y * 64;
  const int tid = threadIdx.x;
  const int cx = tid & 63, ry = tid >> 6;
#pragma unroll
  for (int r = 0; r < 16; ++r) {
    int row = ry + r * 4;
    t[row][cx] = W[(size_t)(k0 + row) * N + n0 + cx];
  }
  __syncthreads();
#pragma unroll
  for (int r = 0; r < 16; ++r) {
    int nn = ry + r * 4;
    Wt[(size_t)(n0 + nn) * K + k0 + cx] = f2bf(t[cx][nn]);
  }
}

// ---------------------------------------------------------------- bf16 MFMA GEMM core (m97 style)

__device__ __forceinline__ void gemm_core(const unsigned short* __restrict__ A,
                                          const unsigned short* __restrict__ B,
                                          int K, int ldA, int ldB, int row0, int col0,
                                          unsigned short* Al, unsigned short* Bl,
                                          f32x4 acc[4][4]) {
  const int tid = threadIdx.x;
  const int w = tid >> 6, l = tid & 63;
  const int lrow = l & 15, lk = (l >> 4) * 8;
  const int wr = (w >> 1) * 64, wc = (w & 1) * 64;
  const int srow = l >> 2, skk = (l & 3) * 8;

  for (int kk = 0; kk < K; kk += 32) {
#pragma unroll
    for (int q = 0; q < 2; ++q) {
      int c = w * 2 + q;
      gload_lds16(A + (size_t)(row0 + c * 16 + srow) * ldA + kk + skk, &Al[c * 512]);
      gload_lds16(B + (size_t)(col0 + c * 16 + srow) * ldB + kk + skk, &Bl[c * 512]);
    }
    __syncthreads();
    bf16x8 af[4], bfr[4];
#pragma unroll
    for (int m = 0; m < 4; ++m)
      af[m] = *(const bf16x8*)&Al[(wr + m * 16 + lrow) * 32 + lk];
#pragma unroll
    for (int n = 0; n < 4; ++n)
      bfr[n] = *(const bf16x8*)&Bl[(wc + n * 16 + lrow) * 32 + lk];
#pragma unroll
    for (int m = 0; m < 4; ++m)
#pragma unroll
      for (int n = 0; n < 4; ++n)
        acc[m][n] = __builtin_amdgcn_mfma_f32_16x16x32_bf16(af[m], bfr[n], acc[m][n], 0, 0, 0);
    __syncthreads();
  }
}

// ---------------------------------------------------------------- swizzled LDS helpers (bf16, 128-col rows)

__device__ __forceinline__ bf16x8 ld_sw(const unsigned short* base, int row, int kcol) {
  int byte = (row * 256 + kcol * 2) ^ ((row & 7) << 4);
  return *(const bf16x8*)((const char*)base + byte);
}
__device__ __forceinline__ void st_sw(unsigned short* base, int row, int col, unsigned short v) {
  int byte = (row * 256 + col * 2) ^ ((row & 7) << 4);
  *(unsigned short*)((char*)base + byte) = v;
}
__device__ __forceinline__ unsigned short ld_sw1(const unsigned short* base, int row, int col) {
  int byte = (row * 256 + col * 2) ^ ((row & 7) << 4);
  return *(const unsigned short*)((const char*)base + byte);
}

__device__ __forceinline__ void stage_sw(const float* __restrict__ src, int ld,
                                         unsigned short* dst, int tid) {
#pragma unroll
  for (int p = 0; p < 16; ++p) {
    int row = p * 8 + (tid >> 5);
    int col = (tid & 31) * 4;
    float4 v = *(const float4*)(src + (size_t)row * ld + col);
    int byte = (row * 256 + col * 2) ^ ((row & 7) << 4);
    unsigned short* d = (unsigned short*)((char*)dst + byte);
    d[0] = f2bf(v.x); d[1] = f2bf(v.y); d[2] = f2bf(v.z); d[3] = f2bf(v.w);
  }
}

__device__ __forceinline__ void stage_sw64(const float* __restrict__ src, int ld,
                                           unsigned short* dst, int tid) {
#pragma unroll
  for (int p = 0; p < 8; ++p) {
    int row = p * 8 + (tid >> 5);
    int col = (tid & 31) * 4;
    float4 v = *(const float4*)(src + (size_t)row * ld + col);
    int byte = (row * 256 + col * 2) ^ ((row & 7) << 4);
    unsigned short* d = (unsigned short*)((char*)dst + byte);
    d[0] = f2bf(v.x); d[1] = f2bf(v.y); d[2] = f2bf(v.z); d[3] = f2bf(v.w);
  }
}

__device__ __forceinline__ void stage_hl(const float* __restrict__ src, int ld,
                                         unsigned short* H, unsigned short* L, int tid) {
#pragma unroll
  for (int p = 0; p < 16; ++p) {
    int row = p * 8 + (tid >> 5);
    int col = (tid & 31) * 4;
    float4 v = *(const float4*)(src + (size_t)row * ld + col);
    int byte = (row * 256 + col * 2) ^ ((row & 7) << 4);
    unsigned short* h = (unsigned short*)((char*)H + byte);
    unsigned short* l = (unsigned short*)((char*)L + byte);
    const float* pv = (const float*)&v;
#pragma unroll
    for (int i = 0; i < 4; ++i) {
      unsigned short hi = f2bf(pv[i]);
      h[i] = hi;
      l[i] = f2bf(pv[i] - bf2f(hi));
    }
  }
}

__device__ __forceinline__ void stage_hl_1024(const float* __restrict__ src, int ld,
                                              unsigned short* H, unsigned short* L, int tid) {
#pragma unroll
  for (int p = 0; p < 4; ++p) {
    int row = p * 32 + (tid >> 5);
    int col = (tid & 31) * 4;
    float4 v = *(const float4*)(src + (size_t)row * ld + col);
    int byte = (row * 256 + col * 2) ^ ((row & 7) << 4);
    unsigned short* h = (unsigned short*)((char*)H + byte);
    unsigned short* l = (unsigned short*)((char*)L + byte);
    const float* pv = (const float*)&v;
#pragma unroll
    for (int i = 0; i < 4; ++i) {
      unsigned short hi = f2bf(pv[i]);
      h[i] = hi;
      l[i] = f2bf(pv[i] - bf2f(hi));
    }
  }
}

__device__ __forceinline__ void stage_hl_ts(const float* __restrict__ src, int ld,
                                            const float* __restrict__ lr,
                                            unsigned short* H, unsigned short* L, int tid) {
#pragma unroll
  for (int p = 0; p < 16; ++p) {
    int t = p * 8 + (tid >> 5);
    int d = (tid & 31) * 4;
    float4 v = *(const float4*)(src + (size_t)t * ld + d);
    float sc = lr[t];
    const float* pv = (const float*)&v;
#pragma unroll
    for (int i = 0; i < 4; ++i) {
      float x = pv[i] * sc;
      unsigned short hi = f2bf(x);
      st_sw(H, d + i, t, hi);
      st_sw(L, d + i, t, f2bf(x - bf2f(hi)));
    }
  }
}

// ---------------------------------------------------------------- init w + row norms (+ w1^T copy)

__global__ void k_init_w(const float* __restrict__ w0, const float* __restrict__ w1,
                         const float* __restrict__ w2, float* __restrict__ WW,
                         float* __restrict__ WN0, float* __restrict__ W1T) {
  int rid = blockIdx.x;
  int m = rid >> 11;
  int gr = rid & 2047;
  const float* src = (m == 0) ? w0 : (m == 1) ? w1 : w2;
  const float* row = src + (size_t)gr * HD;
  float* drow = WW + ((size_t)m * 2048 + gr) * HD;
  int l = threadIdx.x;
  float v0 = row[l], v1 = row[l + 64];
  drow[l] = v0; drow[l + 64] = v1;
  if (m == 1) {
    int g = gr >> 7, r = gr & 127;
    W1T[((size_t)g * 128 + l) * 128 + r] = v0;
    W1T[((size_t)g * 128 + l + 64) * 128 + r] = v1;
  }
  float s = wave_sum64(v0 * v0 + v1 * v1);
  if (l == 0) WN0[rid] = sqrtf(s);
}

// ---------------------------------------------------------------- qkv projection (bf16 MFMA + fused silu/l2norm)
// m97 structure, natural 2D grid (64, 48). Confirmed 283us / MfmaUtil 33.5% in R9.

__global__ __launch_bounds__(256) void k_qkv_mfma(const unsigned short* __restrict__ xb,
                                                  const unsigned short* __restrict__ Wqt,
                                                  float* __restrict__ Q, float* __restrict__ Km,
                                                  float* __restrict__ V) {
  __shared__ unsigned short Al[128 * 32];
  __shared__ unsigned short Bl[128 * 32];
  __shared__ float nrm[128][2];
  const int bx = blockIdx.x, ct = blockIdx.y;

  f32x4 acc[4][4];
#pragma unroll
  for (int m = 0; m < 4; ++m)
#pragma unroll
    for (int n = 0; n < 4; ++n) acc[m][n] = {};

  gemm_core(xb, Wqt, DMODEL, DMODEL, DMODEL, bx * 128, ct * 128, Al, Bl, acc);

  const int hh = ct / 3, which = ct % 3;
  float* dst = (which == 0) ? Q : (which == 1) ? Km : V;
  const int tid = threadIdx.x, w = tid >> 6, l = tid & 63;
  const int wr = (w >> 1) * 64, wc = (w & 1) * 64;

#pragma unroll
  for (int m = 0; m < 4; ++m)
#pragma unroll
    for (int n = 0; n < 4; ++n)
#pragma unroll
      for (int j = 0; j < 4; ++j) {
        float v = acc[m][n][j];
        acc[m][n][j] = v * sigm(v);
      }

  float f[4][4];
  if (which != 2) {
#pragma unroll
    for (int m = 0; m < 4; ++m)
#pragma unroll
      for (int j = 0; j < 4; ++j) {
        float p = 0.0f;
#pragma unroll
        for (int n = 0; n < 4; ++n) p = fmaf(acc[m][n][j], acc[m][n][j], p);
        p += __shfl_xor(p, 1, 64);
        p += __shfl_xor(p, 2, 64);
        p += __shfl_xor(p, 4, 64);
        p += __shfl_xor(p, 8, 64);
        f[m][j] = p;
      }
    if ((l & 15) == 0) {
#pragma unroll
      for (int m = 0; m < 4; ++m)
#pragma unroll
        for (int j = 0; j < 4; ++j)
          nrm[wr + m * 16 + (l >> 4) * 4 + j][w & 1] = f[m][j];
    }
    __syncthreads();
#pragma unroll
    for (int m = 0; m < 4; ++m)
#pragma unroll
      for (int j = 0; j < 4; ++j) {
        int row = wr + m * 16 + (l >> 4) * 4 + j;
        f[m][j] = 1.0f / (sqrtf(nrm[row][0] + nrm[row][1]) + 1e-5f);
      }
  } else {
#pragma unroll
    for (int m = 0; m < 4; ++m)
#pragma unroll
      for (int j = 0; j < 4; ++j) f[m][j] = 1.0f;
  }

#pragma unroll
  for (int m = 0; m < 4; ++m)
#pragma unroll
    for (int j = 0; j < 4; ++j) {
      int t = bx * 128 + wr + m * 16 + (l >> 4) * 4 + j;
      int fth = t * NH + hh;
      int g = fth >> 13, tp = fth & 8191;
      float* drow = dst + ((size_t)g * LSEQ + tp) * HD;
#pragma unroll
      for (int n = 0; n < 4; ++n)
        drow[wc + n * 16 + (l & 15)] = acc[m][n][j] * f[m][j];
    }
}

// ---------------------------------------------------------------- lr / scale: K-split GEMM + reduce

__global__ __launch_bounds__(256) void k_lrms5(const float* __restrict__ x,
                                               const float* __restrict__ Wlr,
                                               const float* __restrict__ Wsc,
                                               float* __restrict__ P) {
  __shared__ float Xs[128][67];
  __shared__ float Ws[128][68];
  const int tb = blockIdx.x;
  const int kp = blockIdx.y;
  const int tid = threadIdx.x;
  for (int i = tid; i < 128 * 64; i += 256) {
    int k = i >> 6, c = i & 63;
    float wv = (c < 48) ? Wlr[(size_t)(kp * 128 + k) * 48 + c]
                        : Wsc[(size_t)(kp * 128 + k) * 16 + (c - 48)];
    Ws[k][c] = wv;
  }
  const int t8 = tid >> 5, kk = tid & 31;
#pragma unroll
  for (int r = 0; r < 8; ++r) {
    int t = t8 + r * 8;
    float4 v = *(const float4*)(x + (size_t)(tb * 64 + t) * DMODEL + kp * 128 + kk * 4);
    Xs[kk * 4 + 0][t] = v.x; Xs[kk * 4 + 1][t] = v.y;
    Xs[kk * 4 + 2][t] = v.z; Xs[kk * 4 + 3][t] = v.w;
  }
  __syncthreads();
  const int ty = tid >> 4, tx = tid & 15;
  float acc[4][4];
#pragma unroll
  for (int i = 0; i < 4; ++i)
#pragma unroll
    for (int j = 0; j < 4; ++j) acc[i][j] = 0.0f;
  for (int k = 0; k < 128; ++k) {
    float a[4], b[4];
#pragma unroll
    for (int i = 0; i < 4; ++i) a[i] = Xs[k][ty * 4 + i];
#pragma unroll
    for (int j = 0; j < 4; ++j) b[j] = Ws[k][tx * 4 + j];
#pragma unroll
    for (int i = 0; i < 4; ++i)
#pragma unroll
      for (int j = 0; j < 4; ++j) acc[i][j] = fmaf(a[i], b[j], acc[i][j]);
  }
  float* o = P + ((size_t)tb * 16 + kp) * 4096;
#pragma unroll
  for (int i = 0; i < 4; ++i)
#pragma unroll
    for (int j = 0; j < 4; ++j)
      o[(ty * 4 + i) * 64 + tx * 4 + j] = acc[i][j];
}

__global__ void k_lrsum(const float* __restrict__ P, const float* __restrict__ bs,
                        float* __restrict__ LR, float* __restrict__ SCL) {
  int e = blockIdx.x * 256 + threadIdx.x;
  int t = e >> 6, c = e & 63;
  const float* base = P + ((size_t)(t >> 6) * 16) * 4096 + (t & 63) * 64 + c;
  float sum = 0.0f;
#pragma unroll
  for (int kp = 0; kp < 16; ++kp) sum += base[(size_t)kp * 4096];
  if (c < 48) {
    float base_lr_inv = 0.01f + logf(-expm1f(-0.01f));
    float v = sum + base_lr_inv;
    float sp = fmaxf(v, 0.0f) + log1pf(expf(-fabsf(v)));
    LR[(size_t)c * LSEQ + t] = sp;
  } else {
    float v = sum + bs[c - 48];
    SCL[(size_t)(c - 48) * LSEQ + t] = v * sigm(v);
  }
}

// ---------------------------------------------------------------- per-chunk output (bf16 MFMA + fused LN/scale)
// 64-token tiles, 80 KB LDS -> 2 blocks/CU.

__global__ __launch_bounds__(256) void k_out2(const float* __restrict__ WW,
                                              const float* __restrict__ Q,
                                              const float* __restrict__ SCL,
                                              const float* __restrict__ lng,
                                              const float* __restrict__ lnb,
                                              unsigned short* __restrict__ U, int s) {
  __shared__ __align__(16) char smem[81920];
  unsigned short* Qs  = (unsigned short*)smem;
  unsigned short* W0s = (unsigned short*)(smem + 16384);
  unsigned short* W2s = (unsigned short*)(smem + 49152);
  float* Os = (float*)(smem + 16384);

  const int g = blockIdx.y;
  const int t0 = blockIdx.x * 64;
  const int tid = threadIdx.x;
  const int w = tid >> 6, l = tid & 63;
  const int lrow = l & 15, lk8 = (l >> 4) * 8;
  const int wr = (w >> 1) * 32, wc = (w & 1) * 64;

  const float* Qg  = Q + ((size_t)g * LSEQ + s + t0) * HD;
  const float* w0g = WW + ((size_t)0 * 2048 + g * 128) * 128;
  const float* w1g = WW + ((size_t)1 * 2048 + g * 128) * 128;
  const float* w2g = WW + ((size_t)2 * 2048 + g * 128) * 128;

  stage_sw64(Qg, HD, Qs, tid);
  stage_sw(w0g, 128, W0s, tid);
  stage_sw(w2g, 128, W2s, tid);
  __syncthreads();

  f32x4 ga[2][4], ha[2][4];
#pragma unroll
  for (int m = 0; m < 2; ++m)
#pragma unroll
    for (int n = 0; n < 4; ++n) { ga[m][n] = {}; ha[m][n] = {}; }
#pragma unroll
  for (int kk = 0; kk < 128; kk += 32) {
    bf16x8 af[2], b0[4], b2[4];
#pragma unroll
    for (int m = 0; m < 2; ++m) af[m] = ld_sw(Qs, wr + m * 16 + lrow, kk + lk8);
#pragma unroll
    for (int n = 0; n < 4; ++n) {
      b0[n] = ld_sw(W0s, wc + n * 16 + lrow, kk + lk8);
      b2[n] = ld_sw(W2s, wc + n * 16 + lrow, kk + lk8);
    }
#pragma unroll
    for (int m = 0; m < 2; ++m)
#pragma unroll
      for (int n = 0; n < 4; ++n) {
        ga[m][n] = __builtin_amdgcn_mfma_f32_16x16x32_bf16(af[m], b0[n], ga[m][n], 0, 0, 0);
        ha[m][n] = __builtin_amdgcn_mfma_f32_16x16x32_bf16(af[m], b2[n], ha[m][n], 0, 0, 0);
      }
  }
  __syncthreads();
#pragma unroll
  for (int m = 0; m < 2; ++m)
#pragma unroll
    for (int n = 0; n < 4; ++n)
#pragma unroll
      for (int j = 0; j < 4; ++j) {
        int row = wr + m * 16 + (l >> 4) * 4 + j;
        int col = wc + n * 16 + (l & 15);
        float gv = ga[m][n][j];
        st_sw(Qs, row, col, f2bf(gv * sigm(gv) * ha[m][n][j]));
      }
  stage_sw(w1g, 128, W0s, tid);
  __syncthreads();

  f32x4 oa[2][4];
#pragma unroll
  for (int m = 0; m < 2; ++m)
#pragma unroll
    for (int n = 0; n < 4; ++n) oa[m][n] = {};
#pragma unroll
  for (int kk = 0; kk < 128; kk += 32) {
    bf16x8 af[2], b1[4];
#pragma unroll
    for (int m = 0; m < 2; ++m) af[m] = ld_sw(Qs, wr + m * 16 + lrow, kk + lk8);
#pragma unroll
    for (int n = 0; n < 4; ++n) b1[n] = ld_sw(W0s, wc + n * 16 + lrow, kk + lk8);
#pragma unroll
    for (int m = 0; m < 2; ++m)
#pragma unroll
      for (int n = 0; n < 4; ++n)
        oa[m][n] = __builtin_amdgcn_mfma_f32_16x16x32_bf16(af[m], b1[n], oa[m][n], 0, 0, 0);
  }
  __syncthreads();
#pragma unroll
  for (int m = 0; m < 2; ++m)
#pragma unroll
    for (int n = 0; n < 4; ++n)
#pragma unroll
      for (int j = 0; j < 4; ++j) {
        int row = wr + m * 16 + (l >> 4) * 4 + j;
        int col = wc + n * 16 + (l & 15);
        Os[row * 132 + col] = oa[m][n][j];
      }
  __syncthreads();

  const int tok = tid >> 2, part = tid & 3;
  const float* orow = Os + tok * 132 + part * 32;
  float sum = 0.0f;
#pragma unroll
  for (int q = 0; q < 8; ++q) {
    float4 v = *(const float4*)(orow + q * 4);
    sum += (v.x + v.y) + (v.z + v.w);
  }
  sum += __shfl_xor(sum, 1, 64);
  sum += __shfl_xor(sum, 2, 64);
  float mu = sum * (1.0f / 128.0f);
  float vs = 0.0f;
#pragma unroll
  for (int q = 0; q < 8; ++q) {
    float4 v = *(const float4*)(orow + q * 4);
    float d0 = v.x - mu, d1 = v.y - mu, d2 = v.z - mu, d3 = v.w - mu;
    vs += d0 * d0 + d1 * d1 + d2 * d2 + d3 * d3;
  }
  vs += __shfl_xor(vs, 1, 64);
  vs += __shfl_xor(vs, 2, 64);
  float rstd = rsqrtf(vs * (1.0f / 128.0f) + 1e-6f);
  int tabs = s + t0 + tok;
  float sc = SCL[(size_t)g * LSEQ + tabs];
  unsigned short* urow = U + (size_t)tabs * DMODEL + g * HD + part * 32;
#pragma unroll
  for (int q = 0; q < 8; ++q) {
    float4 v = *(const float4*)(orow + q * 4);
    int d = part * 32 + q * 4;
    ushort4 o;
    o.x = f2bf(((v.x - mu) * rstd * lng[d + 0] + lnb[d + 0]) * sc);
    o.y = f2bf(((v.y - mu) * rstd * lng[d + 1] + lnb[d + 1]) * sc);
    o.z = f2bf(((v.z - mu) * rstd * lng[d + 2] + lnb[d + 2]) * sc);
    o.w = f2bf(((v.w - mu) * rstd * lng[d + 3] + lnb[d + 3]) * sc);
    *(ushort4*)(urow + q * 4) = o;
  }
}

// ---------------------------------------------------------------- fused front GEMMs + elementwise

__global__ __launch_bounds__(1024) void k_fe(const float* __restrict__ WW,
                                             const float* __restrict__ W1T,
                                             const float* __restrict__ Km,
                                             const float* __restrict__ V,
                                             float* __restrict__ BUF, int s) {
  __shared__ __align__(16) char smem[131072];
  unsigned short* KH = (unsigned short*)smem;
  unsigned short* KL = (unsigned short*)(smem + 32768);
  unsigned short* VH = (unsigned short*)(smem + 65536);
  unsigned short* VL = (unsigned short*)(smem + 98304);

  const int tt0 = blockIdx.x * 128;
  const int g = blockIdx.y;
  const int tid = threadIdx.x;
  const int w = tid >> 6, l = tid & 63;
  const int ww = w >> 2, wv = w & 3;
  const int lrow = l & 15, lk8 = (l >> 4) * 8;
  const int frow = (l >> 4) * 4, fcol = l & 15;

  stage_hl_1024(Km + ((size_t)g * LSEQ + s + tt0) * HD, HD, KH, KL, tid);
  stage_hl_1024(V + ((size_t)g * LSEQ + s + tt0) * HD, HD, VH, VL, tid);
  __syncthreads();

  const float* Asrc[3];
  Asrc[0] = WW + ((size_t)0 * 2048 + g * 128) * 128;
  Asrc[1] = WW + ((size_t)2 * 2048 + g * 128) * 128;
  Asrc[2] = W1T + (size_t)g * 16384;

  f32x4 acc[3][2][2];
#pragma unroll
  for (int q = 0; q < 3; ++q)
#pragma unroll
    for (int m = 0; m < 2; ++m)
#pragma unroll
      for (int n = 0; n < 2; ++n) acc[q][m][n] = {};

#pragma unroll 1
  for (int q = 0; q < 3; ++q) {
    const float* src = Asrc[q];
    const unsigned short* BH = (q == 2) ? VH : KH;
    const unsigned short* BL = (q == 2) ? VL : KL;
#pragma unroll
    for (int kk = 0; kk < 128; kk += 32) {
      bf16x8 ah[2], al[2], bh[2], bl[2];
#pragma unroll
      for (int m = 0; m < 2; ++m) {
        int row = ww * 32 + m * 16 + lrow;
        float4 v0 = *(const float4*)(src + (size_t)row * 128 + kk + lk8);
        float4 v1 = *(const float4*)(src + (size_t)row * 128 + kk + lk8 + 4);
        bfu8 h, lo;
        const float* p0 = (const float*)&v0;
        const float* p1 = (const float*)&v1;
#pragma unroll
        for (int i = 0; i < 4; ++i) {
          unsigned short hb0 = f2bf(p0[i]);
          h.u[i] = hb0; lo.u[i] = f2bf(p0[i] - bf2f(hb0));
          unsigned short hb1 = f2bf(p1[i]);
          h.u[i + 4] = hb1; lo.u[i + 4] = f2bf(p1[i] - bf2f(hb1));
        }
        ah[m] = h.v; al[m] = lo.v;
      }
#pragma unroll
      for (int n = 0; n < 2; ++n) {
        int row = wv * 32 + n * 16 + lrow;
        bh[n] = ld_sw(BH, row, kk + lk8);
        bl[n] = ld_sw(BL, row, kk + lk8);
      }
#pragma unroll
      for (int m = 0; m < 2; ++m)
#pragma unroll
        for (int n = 0; n < 2; ++n) {
          acc[q][m][n] = __builtin_amdgcn_mfma_f32_16x16x32_bf16(ah[m], bh[n], acc[q][m][n], 0, 0, 0);
          acc[q][m][n] = __builtin_amdgcn_mfma_f32_16x16x32_bf16(ah[m], bl[n], acc[q][m][n], 0, 0, 0);
          acc[q][m][n] = __builtin_amdgcn_mfma_f32_16x16x32_bf16(al[m], bh[n], acc[q][m][n], 0, 0, 0);
        }
    }
  }

  float* out0 = BUF + (size_t)0 * (NH * 128 * CH) + (size_t)g * 128 * CH;
  float* out1 = BUF + (size_t)1 * (NH * 128 * CH) + (size_t)g * 128 * CH;
  float* out2 = BUF + (size_t)2 * (NH * 128 * CH) + (size_t)g * 128 * CH;
#pragma unroll
  for (int m = 0; m < 2; ++m)
#pragma unroll
    for (int n = 0; n < 2; ++n)
#pragma unroll
      for (int j = 0; j < 4; ++j) {
        int row = ww * 32 + m * 16 + frow + j;
        int col = wv * 32 + n * 16 + fcol;
        float gb = acc[0][m][n][j];
        float hb = acc[1][m][n][j];
        float dh = acc[2][m][n][j];
        float sg = sigm(gb);
        float sgb = gb * sg;
        float hid = sgb * hb;
        float dgate = dh * hb;
        float dgb = dgate * sg * (1.0f + gb * (1.0f - sg));
        float dhb = dh * sgb;
        size_t o = (size_t)row * CH + tt0 + col;
        out0[o] = hid; out1[o] = dgb; out2[o] = dhb;
      }
}

// partial dW GEMMs over 256-token slices (split-bf16). grid (8, NH, 3).
__global__ __launch_bounds__(256) void k_dwp_mx(const float* __restrict__ BUF,
                                                const float* __restrict__ Km,
                                                const float* __restrict__ V,
                                                const float* __restrict__ LR,
                                                float* __restrict__ DWP, int s) {
  __shared__ __align__(16) char smem[131072];
  unsigned short* AH = (unsigned short*)smem;
  unsigned short* AL = (unsigned short*)(smem + 32768);
  unsigned short* BH = (unsigned short*)(smem + 65536);
  unsigned short* BL = (unsigned short*)(smem + 98304);

  const int p = blockIdx.x;
  const int g = blockIdx.y;
  const int z = blockIdx.z;
  const int tid = threadIdx.x;
  const int w = tid >> 6, l = tid & 63;
  const int lrow = l & 15, lk8 = (l >> 4) * 8;
  const int wr = (w >> 1) * 64, wc = (w & 1) * 64;

  const int msel = (z == 0) ? 1 : (z == 1) ? 0 : 2;
  const float* M = BUF + (size_t)msel * (NH * 128 * CH) + (size_t)g * 128 * CH;
  const float* N = (z == 1) ? V : Km;
  const float* lr = LR + (size_t)(z * NH + g) * LSEQ;
  const int ts = p * 256;

  f32x4 acc[4][4];
#pragma unroll
  for (int m = 0; m < 4; ++m)
#pragma unroll
    for (int n = 0; n < 4; ++n) acc[m][n] = {};

  for (int h = 0; h < 2; ++h) {
    if (h) __syncthreads();
    stage_hl(M + ts + h * 128, CH, AH, AL, tid);
    stage_hl_ts(N + ((size_t)g * LSEQ + s + ts + h * 128) * HD, HD,
                lr + s + ts + h * 128, BH, BL, tid);
    __syncthreads();
#pragma unroll
    for (int kk = 0; kk < 128; kk += 32) {
      bf16x8 ah[4], al4[4], bh[4], bl4[4];
#pragma unroll
      for (int m = 0; m < 4; ++m) {
        ah[m] = ld_sw(AH, wr + m * 16 + lrow, kk + lk8);
        al4[m] = ld_sw(AL, wr + m * 16 + lrow, kk + lk8);
      }
#pragma unroll
      for (int n = 0; n < 4; ++n) {
        bh[n] = ld_sw(BH, wc + n * 16 + lrow, kk + lk8);
        bl4[n] = ld_sw(BL, wc + n * 16 + lrow, kk + lk8);
      }
#pragma unroll
      for (int m = 0; m < 4; ++m)
#pragma unroll
        for (int n = 0; n < 4; ++n) {
          acc[m][n] = __builtin_amdgcn_mfma_f32_16x16x32_bf16(ah[m], bh[n], acc[m][n], 0, 0, 0);
          acc[m][n] = __builtin_amdgcn_mfma_f32_16x16x32_bf16(ah[m], bl4[n], acc[m][n], 0, 0, 0);
          acc[m][n] = __builtin_amdgcn_mfma_f32_16x16x32_bf16(al4[m], bh[n], acc[m][n], 0, 0, 0);
        }
    }
  }

  float* outp = DWP + (((size_t)(z * NH + g)) * 8 + p) * 16384;
#pragma unroll
  for (int m = 0; m < 4; ++m)
#pragma unroll
    for (int n = 0; n < 4; ++n)
#pragma unroll
      for (int j = 0; j < 4; ++j) {
        int row = wr + m * 16 + (l >> 4) * 4 + j;
        int col = wc + n * 16 + (l & 15);
        outp[row * 128 + col] = acc[m][n][j];
      }
}

// ---------------------------------------------------------------- Newton-Schulz 5 + fused w-update
// Split-bf16 MFMA, fused 8-partial reduce on load; z==1 input is dw1^T and
// NS5(G^T)=NS5(G)^T so P ends as dw1 directly (else dw^T -> read transposed).
// Epilogue applies w += dw, row-renorm to WN0, and maintains W1T (k_apply fused).
__global__ __launch_bounds__(1024) void k_ns5_mfma(const float* __restrict__ DWP,
                                                   float* __restrict__ WW,
                                                   const float* __restrict__ WN0,
                                                   float* __restrict__ W1T) {
  __shared__ __align__(16) char smem[131072];
  unsigned short* PH = (unsigned short*)smem;
  unsigned short* PL = (unsigned short*)(smem + 32768);
  unsigned short* QH = (unsigned short*)(smem + 65536);
  unsigned short* QL = (unsigned short*)(smem + 98304);
  float* red = (float*)(smem + 65536);   // scratch (pre-loop + epilogue; Q region)

  const float NA[5] = {4.0848f, 3.9505f, 3.7418f, 2.8769f, 2.8366f};
  const float NB[5] = {-6.8946f, -6.3029f, -5.5913f, -3.1427f, -3.0525f};
  const float NC[5] = {2.927f, 2.6377f, 2.3037f, 1.2046f, 1.2012f};
  const int zg = blockIdx.x;
  const int z = zg >> 4;
  const float* base = DWP + (size_t)zg * 8 * 16384;
  const int tid = threadIdx.x;
  const int w = tid >> 6, l = tid & 63;
  const int ww = w >> 2, wv = w & 3;
  const int lrow = l & 15, lk8 = (l >> 4) * 8;
  const int frow = (l >> 4) * 4, fcol = l & 15;

  float vals[16];
  float psum = 0.0f;
#pragma unroll
  for (int r = 0; r < 16; ++r) {
    int idx = tid + r * 1024;
    float sv = 0.0f;
#pragma unroll
    for (int p = 0; p < 8; ++p) sv += base[(size_t)p * 16384 + idx];
    vals[r] = sv;
    psum = fmaf(sv, sv, psum);
  }
  psum = wave_sum64(psum);
  if (l == 0) red[w] = psum;
  __syncthreads();
  float tot = 0.0f;
#pragma unroll
  for (int i = 0; i < 16; ++i) tot += red[i];
  float scl = 1.0f / (sqrtf(tot) + 1e-7f);
  __syncthreads();
#pragma unroll
  for (int r = 0; r < 16; ++r) {
    int idx = tid + r * 1024;
    int rr = idx >> 7, cc = idx & 127;
    float v = vals[r] * scl;
    unsigned short hi = f2bf(v);
    st_sw(PH, rr, cc, hi);
    st_sw(PL, rr, cc, f2bf(v - bf2f(hi)));
  }
  __syncthreads();

#pragma unroll 1
  for (int it = 0; it < 5; ++it) {
    const float ac = NA[it], bc = NB[it], cc2 = NC[it];

    f32x4 accA[2][2];
#pragma unroll
    for (int m = 0; m < 2; ++m)
#pragma unroll
      for (int n = 0; n < 2; ++n) accA[m][n] = {};
#pragma unroll
    for (int kk = 0; kk < 128; kk += 32) {
      bf16x8 ah[2], al[2], bh[2], bl[2];
#pragma unroll
      for (int m = 0; m < 2; ++m) {
        ah[m] = ld_sw(PH, ww * 32 + m * 16 + lrow, kk + lk8);
        al[m] = ld_sw(PL, ww * 32 + m * 16 + lrow, kk + lk8);
      }
#pragma unroll
      for (int n = 0; n < 2; ++n) {
        bh[n] = ld_sw(PH, wv * 32 + n * 16 + lrow, kk + lk8);
        bl[n] = ld_sw(PL, wv * 32 + n * 16 + lrow, kk + lk8);
      }
#pragma unroll
      for (int m = 0; m < 2; ++m)
#pragma unroll
        for (int n = 0; n < 2; ++n) {
          accA[m][n] = __builtin_amdgcn_mfma_f32_16x16x32_bf16(ah[m], bh[n], accA[m][n], 0, 0, 0);
          accA[m][n] = __builtin_amdgcn_mfma_f32_16x16x32_bf16(ah[m], bl[n], accA[m][n], 0, 0, 0);
          accA[m][n] = __builtin_amdgcn_mfma_f32_16x16x32_bf16(al[m], bh[n], accA[m][n], 0, 0, 0);
        }
    }
#pragma unroll
    for (int m = 0; m < 2; ++m)
#pragma unroll
      for (int n = 0; n < 2; ++n)
#pragma unroll
        for (int j = 0; j < 4; ++j) {
          int row = ww * 32 + m * 16 + frow + j;
          int col = wv * 32 + n * 16 + fcol;
          float v = accA[m][n][j];
          unsigned short hi = f2bf(v);
          st_sw(QH, row, col, hi);
          st_sw(QL, row, col, f2bf(v - bf2f(hi)));
        }
    __syncthreads();

    f32x4 accB[2][2];
#pragma unroll
    for (int m = 0; m < 2; ++m)
#pragma unroll
      for (int n = 0; n < 2; ++n) accB[m][n] = {};
#pragma unroll
    for (int kk = 0; kk < 128; kk += 32) {
      bf16x8 ah[2], al[2], bh[2], bl[2];
#pragma unroll
      for (int m = 0; m < 2; ++m) {
        ah[m] = ld_sw(QH, ww * 32 + m * 16 + lrow, kk + lk8);
        al[m] = ld_sw(QL, ww * 32 + m * 16 + lrow, kk + lk8);
      }
#pragma unroll
      for (int n = 0; n < 2; ++n) {
        bh[n] = ld_sw(QH, wv * 32 + n * 16 + lrow, kk + lk8);
        bl[n] = ld_sw(QL, wv * 32 + n * 16 + lrow, kk + lk8);
      }
#pragma unroll
      for (int m = 0; m < 2; ++m)
#pragma unroll
        for (int n = 0; n < 2; ++n) {
          accB[m][n] = __builtin_amdgcn_mfma_f32_16x16x32_bf16(ah[m], bh[n], accB[m][n], 0, 0, 0);
          accB[m][n] = __builtin_amdgcn_mfma_f32_16x16x32_bf16(ah[m], bl[n], accB[m][n], 0, 0, 0);
          accB[m][n] = __builtin_amdgcn_mfma_f32_16x16x32_bf16(al[m], bh[n], accB[m][n], 0, 0, 0);
        }
    }
#pragma unroll
    for (int m = 0; m < 2; ++m)
#pragma unroll
      for (int n = 0; n < 2; ++n)
#pragma unroll
        for (int j = 0; j < 4; ++j)
          accB[m][n][j] = fmaf(bc, accA[m][n][j], cc2 * accB[m][n][j]);
    __syncthreads();
#pragma unroll
    for (int m = 0; m < 2; ++m)
#pragma unroll
      for (int n = 0; n < 2; ++n)
#pragma unroll
        for (int j = 0; j < 4; ++j) {
          int row = ww * 32 + m * 16 + frow + j;
          int col = wv * 32 + n * 16 + fcol;
          float v = accB[m][n][j];
          unsigned short hi = f2bf(v);
          st_sw(QH, row, col, hi);
          st_sw(QL, row, col, f2bf(v - bf2f(hi)));
        }
    unsigned short th[16], tl[16];
#pragma unroll
    for (int r = 0; r < 16; ++r) {
      int idx = tid + r * 1024;
      int rr = idx >> 7, ccx = idx & 127;
      th[r] = ld_sw1(PH, rr, ccx);
      tl[r] = ld_sw1(PL, rr, ccx);
    }
    __syncthreads();
#pragma unroll
    for (int r = 0; r < 16; ++r) {
      int idx = tid + r * 1024;
      int rr = idx >> 7, ccx = idx & 127;
      st_sw(PH, ccx, rr, th[r]);
      st_sw(PL, ccx, rr, tl[r]);
    }
    __syncthreads();

    f32x4 accC[2][2];
#pragma unroll
    for (int m = 0; m < 2; ++m)
#pragma unroll
      for (int n = 0; n < 2; ++n) accC[m][n] = {};
#pragma unroll
    for (int kk = 0; kk < 128; kk += 32) {
      bf16x8 ah[2], al[2], bh[2], bl[2];
#pragma unroll
      for (int m = 0; m < 2; ++m) {
        ah[m] = ld_sw(PH, ww * 32 + m * 16 + lrow, kk + lk8);
        al[m] = ld_sw(PL, ww * 32 + m * 16 + lrow, kk + lk8);
      }
#pragma unroll
      for (int n = 0; n < 2; ++n) {
        bh[n] = ld_sw(QH, wv * 32 + n * 16 + lrow, kk + lk8);
        bl[n] = ld_sw(QL, wv * 32 + n * 16 + lrow, kk + lk8);
      }
#pragma unroll
      for (int m = 0; m < 2; ++m)
#pragma unroll
        for (int n = 0; n < 2; ++n) {
          accC[m][n] = __builtin_amdgcn_mfma_f32_16x16x32_bf16(ah[m], bh[n], accC[m][n], 0, 0, 0);
          accC[m][n] = __builtin_amdgcn_mfma_f32_16x16x32_bf16(ah[m], bl[n], accC[m][n], 0, 0, 0);
          accC[m][n] = __builtin_amdgcn_mfma_f32_16x16x32_bf16(al[m], bh[n], accC[m][n], 0, 0, 0);
        }
    }
#pragma unroll
    for (int m = 0; m < 2; ++m)
#pragma unroll
      for (int n = 0; n < 2; ++n)
#pragma unroll
        for (int j = 0; j < 4; ++j) {
          int row = ww * 32 + m * 16 + frow + j;
          int col = wv * 32 + n * 16 + fcol;
          float yv = bf2f(ld_sw1(PH, row, col)) + bf2f(ld_sw1(PL, row, col));
          accC[m][n][j] = fmaf(ac, yv, accC[m][n][j]);
        }
    __syncthreads();
#pragma unroll
    for (int m = 0; m < 2; ++m)
#pragma unroll
      for (int n = 0; n < 2; ++n)
#pragma unroll
        for (int j = 0; j < 4; ++j) {
          int row = ww * 32 + m * 16 + frow + j;
          int col = wv * 32 + n * 16 + fcol;
          float v = accC[m][n][j];
          unsigned short hi = f2bf(v);
          st_sw(PH, row, col, hi);
          st_sw(PL, row, col, f2bf(v - bf2f(hi)));
        }
    __syncthreads();
  }

  // ---- fused apply: dw[rr][cc] = (z==1 ? P[rr][cc] : P[cc][rr]); w += dw; renorm.
  // thread covers (rr = r*8 + tid>>7, cc = tid&127); row rr's 128 cols live in
  // waves w and w^1 (same tid>>7) -> wave_sum64 + partner combine via red[].
  const int hh2 = tid >> 7, cc = tid & 127;
  float wnew[16];
#pragma unroll
  for (int r = 0; r < 16; ++r) {
    int rr = r * 8 + hh2;
    float dv = (z == 1) ? bf2f(ld_sw1(PH, rr, cc)) + bf2f(ld_sw1(PL, rr, cc))
                        : bf2f(ld_sw1(PH, cc, rr)) + bf2f(ld_sw1(PL, cc, rr));
    float wv = WW[(size_t)(zg * 128 + rr) * 128 + cc] + dv;
    wnew[r] = wv;
    float p = wave_sum64(wv * wv);
    if (l == 0) red[w * 16 + r] = p;
  }
  __syncthreads();
#pragma unroll
  for (int r = 0; r < 16; ++r) {
    int rr = r * 8 + hh2;
    float tot2 = red[w * 16 + r] + red[(w ^ 1) * 16 + r];
    float fsc = WN0[zg * 128 + rr] / (sqrtf(tot2) + 1e-5f);
    float wv = wnew[r] * fsc;
    WW[(size_t)(zg * 128 + rr) * 128 + cc] = wv;
    if (z == 1) {
      int g = zg & 15;
      W1T[((size_t)g * 128 + cc) * 128 + rr] = wv;
    }
  }
}

// ---------------------------------------------------------------- final projection (bf16 MFMA)

__global__ __launch_bounds__(256) void k_final_mfma(const unsigned short* __restrict__ U,
                                                    const unsigned short* __restrict__ Wot,
                                                    float* __restrict__ out) {
  __shared__ unsigned short Al[128 * 32];
  __shared__ unsigned short Bl[128 * 32];
  f32x4 acc[4][4];
#pragma unroll
  for (int m = 0; m < 4; ++m)
#pragma unroll
    for (int n = 0; n < 4; ++n) acc[m][n] = {};

  const int row0 = blockIdx.x * 128, col0 = blockIdx.y * 128;
  gemm_core(U, Wot, DMODEL, DMODEL, DMODEL, row0, col0, Al, Bl, acc);

  const int tid = threadIdx.x, w = tid >> 6, l = tid & 63;
  const int wr = (w >> 1) * 64, wc = (w & 1) * 64;
#pragma unroll
  for (int m = 0; m < 4; ++m)
#pragma unroll
    for (int j = 0; j < 4; ++j) {
      int t = row0 + wr + m * 16 + (l >> 4) * 4 + j;
      float* orow = out + (size_t)t * DMODEL + col0;
#pragma unroll
      for (int n = 0; n < 4; ++n)
        orow[wc + n * 16 + (l & 15)] = acc[m][n][j];
    }
}

// ---------------------------------------------------------------- launch

extern "C" void kernel_launch(void* const* d_in, const int* in_sizes, int n_in,
                              void* d_out, int out_size, void* d_ws, size_t ws_size,
                              hipStream_t stream) {
  (void)in_sizes; (void)n_in; (void)out_size;
  const float* x    = (const float*)d_in[0];
  const float* Wqkv = (const float*)d_in[1];
  const float* Wlr  = (const float*)d_in[2];
  const float* Wo   = (const float*)d_in[3];
  const float* Wsc  = (const float*)d_in[6];
  const float* bs   = (const float*)d_in[7];
  const float* lng  = (const float*)d_in[8];
  const float* lnb  = (const float*)d_in[9];
  const float* w0   = (const float*)d_in[10];
  const float* w1   = (const float*)d_in[11];
  const float* w2   = (const float*)d_in[12];

  float* Q = (float*)d_out;  // last read (k_out2 chunk 3) precedes k_final's write

  float* ws = (float*)d_ws;
  size_t off = 0;
  auto alloc = [&](size_t n) { float* p = ws + off; off += n; return p; };
  float* Km   = alloc((size_t)NH * LSEQ * HD);
  float* V    = alloc((size_t)NH * LSEQ * HD);
  float* Uf   = alloc((size_t)LSEQ * DMODEL / 2);   // U stored as bf16
  float* LR   = alloc((size_t)3 * NH * LSEQ);
  float* SCL  = alloc((size_t)NH * LSEQ);
  float* WW   = alloc((size_t)3 * NH * HD * HD);
  float* WN0  = alloc((size_t)3 * NH * HD);
  float* W1T  = alloc((size_t)NH * HD * HD);
  float* BUF  = alloc((size_t)3 * NH * HD * CH);    // chunk loop scratch
  float* DWP  = alloc((size_t)3 * NH * 8 * HD * HD);
  if (off * sizeof(float) > ws_size) return;        // clean failure instead of OOB

  unsigned short* U = (unsigned short*)Uf;
  unsigned short* xb  = (unsigned short*)BUF;                                   // pre-qkv
  unsigned short* Wqt = (unsigned short*)(BUF + (size_t)LSEQ * DMODEL / 2);
  float* Plr = BUF;                                                             // lrms partials
  unsigned short* Wot = (unsigned short*)BUF;                                   // post-loop

  k_init_w<<<3 * NH * HD, 64, 0, stream>>>(w0, w1, w2, WW, WN0, W1T);
  k_cast<<<2048, 256, 0, stream>>>(x, xb, LSEQ * DMODEL / 4);
  k_tcast<<<dim3(3 * DMODEL / 64, DMODEL / 64), 256, 0, stream>>>(Wqkv, Wqt, DMODEL, 3 * DMODEL);
  k_qkv_mfma<<<dim3(LSEQ / 128, 48), 256, 0, stream>>>(xb, Wqt, Q, Km, V);
  k_lrms5<<<dim3(LSEQ / 64, 16), 256, 0, stream>>>(x, Wlr, Wsc, Plr);
  k_lrsum<<<LSEQ * 64 / 256, 256, 0, stream>>>(Plr, bs, LR, SCL);

  for (int c = 0; c < 4; ++c) {
    int s = c * CH;
    k_out2<<<dim3(CH / 64, NH), 256, 0, stream>>>(WW, Q, SCL, lng, lnb, U, s);
    if (c < 3) {
      k_fe<<<dim3(CH / 128, NH), 1024, 0, stream>>>(WW, W1T, Km, V, BUF, s);
      k_dwp_mx<<<dim3(8, NH, 3), 256, 0, stream>>>(BUF, Km, V, LR, DWP, s);
      k_ns5_mfma<<<3 * NH, 1024, 0, stream>>>(DWP, WW, WN0, W1T);
    }
  }
  k_tcast<<<dim3(DMODEL / 64, DMODEL / 64), 256, 0, stream>>>(Wo, Wot, DMODEL, DMODEL);
  k_final_mfma<<<dim3(LSEQ / 128, DMODEL / 128), 256, 0, stream>>>(U, Wot, (float*)d_out);
}